// Round 5
// baseline (2627.774 us; speedup 1.0000x reference)
//
#include <hip/hip_runtime.h>
#include <math.h>

#define NN      8000
#define PP      32
#define EG      128000
#define ES_TOT  131072     // P * 4096
#define ES_P    4096
#define DI      16
#define DD      128
#define KK1     6400
#define KK2     5120
#define KK3     4096
#define CH_P    8
#define RB      64                   // rows per k_wsum block
#define BPG     (NN / RB)            // 125 blocks per graph

static __device__ __forceinline__ unsigned fkey(float f) {
    unsigned u = __float_as_uint(f);
    return (u & 0x80000000u) ? ~u : (u | 0x80000000u);
}

__global__ void k_fill(float* p, float v, int n) {
    int i = blockIdx.x * 256 + threadIdx.x;
    if (i < n) p[i] = v;
}

// agg[(dst[e]-nbase)*Dd + d] += x[srow*Dd + d] * w[e];  Dd=1<<shift
// if degout && d==0: degout[dst[e]-nbase] += w[e]
__global__ void k_agg(const int* __restrict__ src, const int* __restrict__ dst,
                      const float* __restrict__ x, const float* __restrict__ w,
                      float* __restrict__ agg, float* __restrict__ degout,
                      int ne, int shift, int xModN, int nbase) {
    long long idx = (long long)blockIdx.x * 256 + threadIdx.x;
    int e = (int)(idx >> shift);
    if (e >= ne) return;
    int Dd = 1 << shift;
    int d = (int)idx & (Dd - 1);
    float we = w ? w[e] : 1.0f;
    if (we == 0.0f) return;
    int dr = dst[e] - nbase;
    if (degout && d == 0) atomicAdd(&degout[dr], we);
    int s = src[e];
    s = xModN ? (s % NN) : (s - nbase);
    atomicAdd(&agg[(long long)dr * Dd + d], x[(long long)s * Dd + d] * we);
}

// y = tanh( (agg/deg) @ Wl + bl + h @ Wr ), K=16
__global__ __launch_bounds__(256) void k_sage16(
    const float* __restrict__ h, const float* __restrict__ agg, const float* __restrict__ deg,
    const float* __restrict__ Wl, const float* __restrict__ Wr, const float* __restrict__ bl,
    float* __restrict__ y, int nrows)
{
    __shared__ float WlS[16][128], WrS[16][128];
    int tid = threadIdx.x;
    for (int i = tid; i < 16 * 128; i += 256) {
        WlS[i >> 7][i & 127] = Wl[i];
        WrS[i >> 7][i & 127] = Wr[i];
    }
    __syncthreads();
    long long o = (long long)blockIdx.x * 256 + tid;
    int row = (int)(o >> 7);
    if (row >= nrows) return;
    int d = (int)o & 127;
    float invd = 1.0f / fmaxf(deg[row], 1.0f);
    float s = bl[d];
    #pragma unroll
    for (int k = 0; k < 16; ++k)
        s += agg[row * 16 + k] * invd * WlS[k][d] + h[row * 16 + k] * WrS[k][d];
    y[(long long)row * 128 + d] = tanhf(s);
}

// y = tanh( (agg/deg)@Wl + bl + x@Wr ), K=256. BM=128,BN=128,BK=32, 8x8/thread.
// cols per thread: {tx*4..+3, tx*4+64..+67} -> 2-way LDS banks everywhere.
// Optional epilogue dots: tbuf=y@wrel (if wrel), rootd=y@wroot (if wroot).
__global__ __launch_bounds__(256) void k_sage_v3(
    const float* __restrict__ x, const float* __restrict__ agg, const float* __restrict__ deg,
    const float* __restrict__ Wl, const float* __restrict__ Wr, const float* __restrict__ bl,
    float* __restrict__ y, int nrows, int xModN,
    const float* __restrict__ wrel, const float* __restrict__ wroot,
    float* __restrict__ tbuf, float* __restrict__ rootd)
{
    __shared__ float Ws[32 * 128];
    __shared__ float Is[32][132];
    __shared__ float wrelS[128], wrootS[128];
    int tid = threadIdx.x;
    long long row0 = (long long)blockIdx.x * 128;
    if (tid < 128) { if (wrel) wrelS[tid] = wrel[tid]; }
    else           { if (wroot) wrootS[tid - 128] = wroot[tid - 128]; }
    int tx = tid & 15, ty = tid >> 4;
    int srow = tid & 127;
    int koff = (tid >> 7) * 16;
    long long grow = row0 + srow;
    if (grow >= nrows) grow = nrows - 1;   // clamp: harmless duplicate staging
    const float* aggrow = agg + grow * 128;
    long long xrw = xModN ? (grow % NN) : grow;
    const float* xrow = x + xrw * 128;
    float invds = 1.0f / fmaxf(deg[grow], 1.0f);
    float acc[8][8] = {};
    for (int kb = 0; kb < 8; ++kb) {
        __syncthreads();
        const float* Wsrc = (kb < 4) ? (Wl + kb * 32 * 128) : (Wr + (kb - 4) * 32 * 128);
        #pragma unroll
        for (int j = 0; j < 4; ++j) {
            int fl = j * 1024 + tid * 4;
            *reinterpret_cast<float4*>(&Ws[fl]) = *reinterpret_cast<const float4*>(&Wsrc[fl]);
        }
        {
            const float* src = (kb < 4) ? (aggrow + kb * 32 + koff) : (xrow + (kb - 4) * 32 + koff);
            float m = (kb < 4) ? invds : 1.0f;
            #pragma unroll
            for (int q = 0; q < 4; ++q) {
                float4 v = *reinterpret_cast<const float4*>(src + q * 4);
                Is[koff + q*4 + 0][srow] = v.x * m;
                Is[koff + q*4 + 1][srow] = v.y * m;
                Is[koff + q*4 + 2][srow] = v.z * m;
                Is[koff + q*4 + 3][srow] = v.w * m;
            }
        }
        __syncthreads();
        #pragma unroll
        for (int kk = 0; kk < 32; ++kk) {
            float4 w0 = *reinterpret_cast<const float4*>(&Ws[kk * 128 + tx * 4]);
            float4 w1 = *reinterpret_cast<const float4*>(&Ws[kk * 128 + tx * 4 + 64]);
            float4 i0 = *reinterpret_cast<const float4*>(&Is[kk][ty * 8]);
            float4 i1 = *reinterpret_cast<const float4*>(&Is[kk][ty * 8 + 4]);
            float ia[8] = {i0.x, i0.y, i0.z, i0.w, i1.x, i1.y, i1.z, i1.w};
            float wa[8] = {w0.x, w0.y, w0.z, w0.w, w1.x, w1.y, w1.z, w1.w};
            #pragma unroll
            for (int i = 0; i < 8; ++i)
                #pragma unroll
                for (int j = 0; j < 8; ++j)
                    acc[i][j] += ia[i] * wa[j];
        }
    }
    float4 bl0 = *reinterpret_cast<const float4*>(&bl[tx * 4]);
    float4 bl1 = *reinterpret_cast<const float4*>(&bl[tx * 4 + 64]);
    float blr[8] = {bl0.x, bl0.y, bl0.z, bl0.w, bl1.x, bl1.y, bl1.z, bl1.w};
    #pragma unroll
    for (int i = 0; i < 8; ++i) {
        long long row = row0 + ty * 8 + i;
        bool valid = (row < nrows);
        float yv[8];
        #pragma unroll
        for (int j = 0; j < 8; ++j) yv[j] = tanhf(acc[i][j] + blr[j]);
        if (valid) {
            *reinterpret_cast<float4*>(&y[row * 128 + tx * 4]) = make_float4(yv[0], yv[1], yv[2], yv[3]);
            *reinterpret_cast<float4*>(&y[row * 128 + tx * 4 + 64]) = make_float4(yv[4], yv[5], yv[6], yv[7]);
        }
        if (tbuf) {
            float tp = 0.0f, rp = 0.0f;
            #pragma unroll
            for (int j = 0; j < 4; ++j) {
                tp += yv[j] * wrelS[tx*4 + j] + yv[j+4] * wrelS[tx*4 + 64 + j];
                if (rootd) rp += yv[j] * wrootS[tx*4 + j] + yv[j+4] * wrootS[tx*4 + 64 + j];
            }
            #pragma unroll
            for (int m = 8; m >= 1; m >>= 1) {
                tp += __shfl_xor(tp, m, 16);
                if (rootd) rp += __shfl_xor(rp, m, 16);
            }
            if (tx == 0 && valid) {
                tbuf[row] = tp;
                if (rootd) rootd[row] = rp;
            }
        }
    }
}

// stage-1 layer-a gate: g[i] = dot(x[i],gw)  (bias dropped: softmax shift-invariant)
__global__ __launch_bounds__(256) void k_gate(
    const float* __restrict__ X, const float* __restrict__ gw,
    float* __restrict__ g, int nrows)
{
    __shared__ float wS[128];
    if (threadIdx.x < 128) wS[threadIdx.x] = gw[threadIdx.x];
    __syncthreads();
    int i = blockIdx.x * 256 + threadIdx.x;
    if (i >= nrows) return;
    const float4* xrp = reinterpret_cast<const float4*>(X + (long long)i * 128);
    float s = 0.0f;
    #pragma unroll
    for (int k = 0; k < 32; ++k) {
        float4 v = xrp[k];
        s += v.x * wS[4*k] + v.y * wS[4*k+1] + v.z * wS[4*k+2] + v.w * wS[4*k+3];
    }
    g[i] = s;
}

// fused: X[row] *= (alive ? tanh(score) : 0), g[row] = alive ? dot(Xnew,gw) : -inf
__global__ __launch_bounds__(256) void k_maskgate(
    float* __restrict__ X, const float* __restrict__ score, const float* __restrict__ nalive,
    const float* __restrict__ gw, float* __restrict__ g)
{
    __shared__ float gwS[128];
    int tid = threadIdx.x;
    if (tid < 128) gwS[tid] = gw[tid];
    __syncthreads();
    int wv = tid >> 6, lane = tid & 63;
    long long row = (long long)blockIdx.x * 4 + wv;
    bool alive = nalive[row] > 0.5f;
    float f = alive ? tanhf(score[row]) : 0.0f;
    float2 v = *reinterpret_cast<float2*>(&X[row * 128 + lane * 2]);
    v.x *= f; v.y *= f;
    *reinterpret_cast<float2*>(&X[row * 128 + lane * 2]) = v;
    float gp = v.x * gwS[lane * 2] + v.y * gwS[lane * 2 + 1];
    #pragma unroll
    for (int m = 32; m >= 1; m >>= 1) gp += __shfl_xor(gp, m, 64);
    if (lane == 0) g[row] = alive ? gp : -INFINITY;
}

// per-graph softmax: g -> exp(g-max) in place, invp[p] = 1/sum
__global__ __launch_bounds__(1024) void k_smstats(float* __restrict__ g, float* __restrict__ invp) {
    __shared__ float red[1024];
    int p = blockIdx.x, tid = threadIdx.x;
    float* gp = g + (long long)p * NN;
    float lmax = -INFINITY;
    for (int n = tid; n < NN; n += 1024) lmax = fmaxf(lmax, gp[n]);
    red[tid] = lmax; __syncthreads();
    for (int s = 512; s > 0; s >>= 1) { if (tid < s) red[tid] = fmaxf(red[tid], red[tid + s]); __syncthreads(); }
    float mx = red[0]; __syncthreads();
    float ls = 0.0f;
    for (int n = tid; n < NN; n += 1024) { float e = expf(gp[n] - mx); gp[n] = e; ls += e; }
    red[tid] = ls; __syncthreads();
    for (int s = 512; s > 0; s >>= 1) { if (tid < s) red[tid] += red[tid + s]; __syncthreads(); }
    if (tid == 0) invp[p] = 1.0f / red[0];
}

// out[rowbase+p][colOff+d] += invp[p] * sum_{chunk rows} a[p*NN+n]*x[...]
__global__ __launch_bounds__(128) void k_wsum(
    const float* __restrict__ X, const float* __restrict__ a, const float* __restrict__ invp,
    float* __restrict__ ro, int rowbase, int colOff)
{
    int p = blockIdx.x / BPG;
    int chunk = blockIdx.x % BPG;
    int d = threadIdx.x;
    long long base = (long long)p * NN;
    int r0 = chunk * RB, r1 = r0 + RB;
    float s = 0.0f;
    for (int n = r0; n < r1; ++n) {
        float an = a[base + n];
        if (an != 0.0f) s += an * X[(base + n) * 128 + d];
    }
    atomicAdd(&ro[(long long)(rowbase + p) * 384 + colOff + d], s * invp[p]);
}

// one-pass column stats: musum += sum(x), sqsum += sum(x^2)
__global__ void k_colstat(const float* __restrict__ x, float* __restrict__ musum,
                          float* __restrict__ sqsum, int nrows) {
    int d = threadIdx.x;
    int r0 = blockIdx.x * 64;
    int r1 = min(r0 + 64, nrows);
    float s = 0.0f, q = 0.0f;
    for (int r = r0; r < r1; ++r) { float v = x[(long long)r * 128 + d]; s += v; q += v * v; }
    atomicAdd(&musum[d], s);
    atomicAdd(&sqsum[d], q);
}

__global__ void k_gnorm_apply(const float* __restrict__ x, float* __restrict__ y,
                              const float* __restrict__ musum, const float* __restrict__ sqsum,
                              const float* __restrict__ w, const float* __restrict__ b,
                              const float* __restrict__ ms, int nrows) {
    long long i = (long long)blockIdx.x * 256 + threadIdx.x;
    if (i >= (long long)nrows * 128) return;
    int d = (int)(i & 127);
    float inv_n = 1.0f / (float)nrows;
    float mu = musum[d] * inv_n;
    float c = mu * ms[d];
    float var = sqsum[d] * inv_n - 2.0f * c * mu + c * c;
    y[i] = w[d] * (x[i] - c) * rsqrtf(var + 1e-5f) + b[d];
}

__global__ void k_scoreagg(const int* __restrict__ ssrc, const int* __restrict__ sdst,
                           const float* __restrict__ t, const float* __restrict__ eal,
                           float* __restrict__ sagg, int ne, int nbase) {
    int e = blockIdx.x * 256 + threadIdx.x;
    if (e >= ne) return;
    float w = eal[e];
    if (w != 0.0f) atomicAdd(&sagg[sdst[e] - nbase], t[ssrc[e] - nbase] * w);
}

// radix-select top-k per pathway (ties -> lowest index)
__global__ __launch_bounds__(256) void k_topk(
    float* __restrict__ sagg, const float* __restrict__ rootd,
    const float* __restrict__ brelp, int bi,
    float* __restrict__ nalive, int k)
{
    __shared__ unsigned keys[NN];
    __shared__ int hist[256];
    __shared__ int chunkcnt[256];
    __shared__ unsigned sh_pref;
    __shared__ int sh_kneed;
    int p = blockIdx.x, tid = threadIdx.x;
    float* sc = sagg + (long long)p * NN;
    const float* rd = rootd + (long long)p * NN;
    float* na = nalive + (long long)p * NN;
    float brel = brelp[bi];
    for (int n = tid; n < NN; n += 256) {
        float s = sc[n] + brel + rd[n];
        sc[n] = s;
        keys[n] = (na[n] > 0.5f) ? fkey(s) : 0u;
    }
    if (tid == 0) { sh_pref = 0u; sh_kneed = k; }
    __syncthreads();
    for (int lvl = 3; lvl >= 0; --lvl) {
        int sh = lvl * 8;
        hist[tid] = 0;
        unsigned pref = sh_pref; int kneed = sh_kneed;
        unsigned pmask = (lvl == 3) ? 0u : (0xFFFFFFFFu << (8 * (lvl + 1)));
        __syncthreads();
        for (int n = tid; n < NN; n += 256) {
            unsigned kv = keys[n];
            if ((kv & pmask) == pref) atomicAdd(&hist[(kv >> sh) & 255], 1);
        }
        __syncthreads();
        if (tid == 0) {
            int cum = 0, b = 255;
            for (; b >= 0; --b) { cum += hist[b]; if (cum >= kneed) break; }
            sh_pref = pref | ((unsigned)b << sh);
            sh_kneed = kneed - (cum - hist[b]);
        }
        __syncthreads();
    }
    unsigned V = sh_pref;
    int seleq = sh_kneed;
    int c0 = tid * 32, c1 = min(c0 + 32, NN);
    int ceq = 0;
    for (int n = c0; n < c1; ++n) ceq += (keys[n] == V) ? 1 : 0;
    chunkcnt[tid] = ceq; __syncthreads();
    if (tid == 0) {
        int s = 0;
        for (int i = 0; i < 256; ++i) { int c = chunkcnt[i]; chunkcnt[i] = s; s += c; }
    }
    __syncthreads();
    int rank = chunkcnt[tid];
    for (int n = c0; n < c1; ++n) {
        unsigned kk = keys[n];
        bool sel = (kk > V) || (kk == V && rank < seleq);
        if (kk == V) rank++;
        na[n] = sel ? 1.0f : 0.0f;
    }
}

__global__ void k_ealive(const int* __restrict__ ssrc, const int* __restrict__ sdst,
                         const float* __restrict__ nalive, float* __restrict__ eal,
                         int ne, int nbase) {
    int e = blockIdx.x * 256 + threadIdx.x;
    if (e >= ne) return;
    if (nalive[ssrc[e] - nbase] < 0.5f || nalive[sdst[e] - nbase] < 0.5f) eal[e] = 0.0f;
}

__global__ __launch_bounds__(64) void k_head(
    const float* __restrict__ ro, const float* __restrict__ lin_w, const float* __restrict__ lin_b,
    const float* __restrict__ m1w, const float* __restrict__ m1b,
    const float* __restrict__ m2w, const float* __restrict__ m2b,
    const float* __restrict__ m3w, const float* __restrict__ m3b, float* __restrict__ out)
{
    __shared__ float v[33], h1[48], h2[16];
    int t = threadIdx.x;
    if (t < 33) {
        float s = lin_b[0];
        for (int k = 0; k < 384; ++k) s += ro[t * 384 + k] * lin_w[k];
        v[t] = tanhf(s);
    }
    __syncthreads();
    if (t < 48) {
        float s = m1b[t];
        for (int i = 0; i < 33; ++i) s += v[i] * m1w[i * 48 + t];
        h1[t] = tanhf(s);
    }
    __syncthreads();
    if (t < 16) {
        float s = m2b[t];
        for (int i = 0; i < 48; ++i) s += h1[i] * m2w[i * 16 + t];
        h2[t] = tanhf(s);
    }
    __syncthreads();
    if (t == 0) {
        float s = m3b[0];
        for (int i = 0; i < 16; ++i) s += h2[i] * m3w[i];
        float s1 = 1.0f / (1.0f + expf(-s));
        out[0] = 1.0f / (1.0f + expf(-s1));
    }
}

static inline int cdiv(long long a, long long b) { return (int)((a + b - 1) / b); }

extern "C" void kernel_launch(void* const* d_in, const int* in_sizes, int n_in,
                              void* d_out, int out_size, void* d_ws, size_t ws_size,
                              hipStream_t stream)
{
    (void)in_sizes; (void)n_in; (void)out_size;
    const float* h     = (const float*)d_in[0];
    const int*   eidx  = (const int*)d_in[1];
    const int*   seidx = (const int*)d_in[2];
    const float* Wl_a  = (const float*)d_in[3];
    const float* Wr_a  = (const float*)d_in[4];
    const float* bl_a  = (const float*)d_in[5];
    const float* Wl_s  = (const float*)d_in[6];
    const float* Wr_s  = (const float*)d_in[7];
    const float* bl_s  = (const float*)d_in[8];
    const float* gate_w = (const float*)d_in[9];
    const float* gate_b = (const float*)d_in[10];
    const float* p_wrel = (const float*)d_in[11];
    const float* p_brel = (const float*)d_in[12];
    const float* p_wroot= (const float*)d_in[13];
    const float* nw    = (const float*)d_in[14];
    const float* nb    = (const float*)d_in[15];
    const float* nms   = (const float*)d_in[16];
    const float* lin_w = (const float*)d_in[17];
    const float* lin_b = (const float*)d_in[18];
    const float* m1w   = (const float*)d_in[19];
    const float* m1b   = (const float*)d_in[20];
    const float* m2w   = (const float*)d_in[21];
    const float* m2b   = (const float*)d_in[22];
    const float* m3w   = (const float*)d_in[23];
    const float* m3b   = (const float*)d_in[24];
    float* out = (float*)d_out;
    (void)gate_b;

    const int* esrc = eidx;
    const int* edst = eidx + EG;

    // runtime chunk width: single-pass (P=32) if workspace allows, else 4 chunks of 8
    auto need_bytes = [](int chp) -> size_t {
        long long chn = (long long)chp * NN;
        long long che = (long long)chp * ES_P;
        long long f = 2 * chn * 128        // Xc, AGGc
                    + 3LL * NN * 128       // xa, xb, agg1
                    + NN                   // deg1
                    + 6 * chn              // deg2, tbuf, rootd, sagg, nal, gbuf
                    + che                  // eal
                    + 64 + 33 * 384 + 256  // invp, ro, stats
                    + 32 * 64;             // padding slack
        return (size_t)f * 4;
    };
    int chp = (ws_size >= need_bytes(PP)) ? PP : CH_P;
    int nch = PP / chp;
    long long ch_n = (long long)chp * NN;
    int ch_e = chp * ES_P;

    float* W = (float*)d_ws;
    size_t off = 0;
    auto alloc = [&](size_t nf) { float* p = W + off; off += (nf + 63) & ~(size_t)63; return p; };
    float* Xc    = alloc((size_t)ch_n * DD);
    float* AGGc  = alloc((size_t)ch_n * DD);
    float* xa    = alloc((size_t)NN * DD);
    float* xb    = alloc((size_t)NN * DD);
    float* agg1  = alloc((size_t)NN * DD);
    float* deg1  = alloc(NN);
    float* deg2  = alloc(ch_n);
    float* tbuf  = alloc(ch_n);
    float* rootd = alloc(ch_n);
    float* sagg  = alloc(ch_n);
    float* nal   = alloc(ch_n);
    float* eal   = alloc(ch_e);
    float* gbuf  = alloc(ch_n);
    float* invp  = alloc(64);
    float* ro    = alloc(33 * 384);
    float* musum = alloc(128);
    float* sqsum = alloc(128);

    hipMemsetAsync(ro, 0, 33 * 384 * sizeof(float), stream);

    // ================= stage 1 =================
    k_fill<<<cdiv(NN,256),256,0,stream>>>(deg1, 1.0f, NN);   // self-loop degree

    // layer a (DIN=16): deg folded into edge pass
    hipMemcpyAsync(agg1, h, (size_t)NN * DI * sizeof(float), hipMemcpyDeviceToDevice, stream);
    k_agg<<<cdiv((long long)EG*DI,256),256,0,stream>>>(esrc, edst, h, (const float*)nullptr, agg1, deg1, EG, 4, 0, 0);
    k_sage16<<<cdiv((long long)NN*DD,256),256,0,stream>>>(h, agg1, deg1, Wl_a, Wr_a, bl_a, xa, NN);
    k_gate<<<cdiv(NN,256),256,0,stream>>>(xa, gate_w + 0*DD, gbuf, NN);
    k_smstats<<<1,1024,0,stream>>>(gbuf, invp);
    k_wsum<<<BPG,128,0,stream>>>(xa, gbuf, invp, ro, 0, 0);

    // gnorm 1: xa -> xb
    hipMemsetAsync(musum, 0, 128*sizeof(float), stream);
    hipMemsetAsync(sqsum, 0, 128*sizeof(float), stream);
    k_colstat<<<cdiv(NN,64),128,0,stream>>>(xa, musum, sqsum, NN);
    k_gnorm_apply<<<cdiv((long long)NN*DD,256),256,0,stream>>>(xa, xb, musum, sqsum, nw, nb, nms, NN);

    // layer b (gate fused into GEMM epilogue)
    hipMemcpyAsync(agg1, xb, (size_t)NN * DD * sizeof(float), hipMemcpyDeviceToDevice, stream);
    k_agg<<<cdiv((long long)EG*DD,256),256,0,stream>>>(esrc, edst, xb, (const float*)nullptr, agg1, (float*)nullptr, EG, 7, 0, 0);
    k_sage_v3<<<cdiv(NN,128),256,0,stream>>>(xb, agg1, deg1, Wl_s + 0*16384, Wr_s + 0*16384, bl_s + 0*128, xa, NN, 0,
                                             gate_w + 1*DD, nullptr, gbuf, nullptr);
    k_smstats<<<1,1024,0,stream>>>(gbuf, invp);
    k_wsum<<<BPG,128,0,stream>>>(xa, gbuf, invp, ro, 0, 128);

    // gnorm 2: xa -> xb
    hipMemsetAsync(musum, 0, 128*sizeof(float), stream);
    hipMemsetAsync(sqsum, 0, 128*sizeof(float), stream);
    k_colstat<<<cdiv(NN,64),128,0,stream>>>(xa, musum, sqsum, NN);
    k_gnorm_apply<<<cdiv((long long)NN*DD,256),256,0,stream>>>(xa, xb, musum, sqsum, nw, nb, nms, NN);

    // layer c -> xa = x_c
    hipMemcpyAsync(agg1, xb, (size_t)NN * DD * sizeof(float), hipMemcpyDeviceToDevice, stream);
    k_agg<<<cdiv((long long)EG*DD,256),256,0,stream>>>(esrc, edst, xb, (const float*)nullptr, agg1, (float*)nullptr, EG, 7, 0, 0);
    k_sage_v3<<<cdiv(NN,128),256,0,stream>>>(xb, agg1, deg1, Wl_s + 1*16384, Wr_s + 1*16384, bl_s + 1*128, xa, NN, 0,
                                             gate_w + 2*DD, nullptr, gbuf, nullptr);
    k_smstats<<<1,1024,0,stream>>>(gbuf, invp);
    k_wsum<<<BPG,128,0,stream>>>(xa, gbuf, invp, ro, 0, 256);

    // ================= stage 2 =================
    for (int c = 0; c < nch; ++c) {
        const int* ssrc = seidx + (size_t)c * ch_e;
        const int* sdst = seidx + ES_TOT + (size_t)c * ch_e;
        int nbase = (int)(c * ch_n);

        k_fill<<<cdiv(ch_n,256),256,0,stream>>>(nal, 1.0f, (int)ch_n);
        k_fill<<<cdiv(ch_e,256),256,0,stream>>>(eal, 1.0f, ch_e);

        for (int layer = 0; layer < 3; ++layer) {
            const float* Wl = Wl_s + (2 + layer) * 16384;
            const float* Wr = Wr_s + (2 + layer) * 16384;
            const float* bl = bl_s + (2 + layer) * 128;
            int kkeep = (layer == 0) ? KK1 : (layer == 1) ? KK2 : KK3;
            int gi = 3 + layer;

            hipMemsetAsync(AGGc, 0, (size_t)ch_n * DD * sizeof(float), stream);
            hipMemsetAsync(deg2, 0, (size_t)ch_n * sizeof(float), stream);
            if (layer == 0) {
                k_agg<<<cdiv((long long)ch_e*DD,256),256,0,stream>>>(ssrc, sdst, xa, eal, AGGc, deg2, ch_e, 7, 1, nbase);
                k_sage_v3<<<(int)(ch_n/128),256,0,stream>>>(xa, AGGc, deg2, Wl, Wr, bl, Xc, (int)ch_n, 1,
                                                            p_wrel + layer*DD, p_wroot + layer*DD, tbuf, rootd);
            } else {
                k_agg<<<cdiv((long long)ch_e*DD,256),256,0,stream>>>(ssrc, sdst, Xc, eal, AGGc, deg2, ch_e, 7, 0, nbase);
                k_sage_v3<<<(int)(ch_n/128),256,0,stream>>>(Xc, AGGc, deg2, Wl, Wr, bl, Xc, (int)ch_n, 0,
                                                            p_wrel + layer*DD, p_wroot + layer*DD, tbuf, rootd);
            }

            hipMemsetAsync(sagg, 0, (size_t)ch_n * sizeof(float), stream);
            k_scoreagg<<<cdiv(ch_e,256),256,0,stream>>>(ssrc, sdst, tbuf, eal, sagg, ch_e, nbase);
            k_topk<<<chp,256,0,stream>>>(sagg, rootd, p_brel, layer, nal, kkeep);
            k_maskgate<<<(int)(ch_n/4),256,0,stream>>>(Xc, sagg, nal, gate_w + gi*DD, gbuf);
            k_ealive<<<cdiv(ch_e,256),256,0,stream>>>(ssrc, sdst, nal, eal, ch_e, nbase);
            k_smstats<<<chp,1024,0,stream>>>(gbuf, invp);
            k_wsum<<<chp*BPG,128,0,stream>>>(Xc, gbuf, invp, ro, 1 + c*chp, layer*128);
        }
    }

    // ================= head =================
    k_head<<<1,64,0,stream>>>(ro, lin_w, lin_b, m1w, m1b, m2w, m2b, m3w, m3b, out);
}

// Round 6
// 2271.063 us; speedup vs baseline: 1.1571x; 1.1571x over previous
//
#include <hip/hip_runtime.h>
#include <math.h>

#define NN      8000
#define PP      32
#define EG      128000
#define ES_TOT  131072     // P * 4096
#define ES_P    4096
#define PN      256000     // P * NN
#define DI      16
#define DD      128
#define KK1     6400
#define KK2     5120
#define KK3     4096
#define RB      64                   // rows per k_wsum block
#define BPG     (NN / RB)            // 125 blocks per graph

static __device__ __forceinline__ unsigned fkey(float f) {
    unsigned u = __float_as_uint(f);
    return (u & 0x80000000u) ? ~u : (u | 0x80000000u);
}

__global__ void k_fill(float* p, float v, int n) {
    int i = blockIdx.x * 256 + threadIdx.x;
    if (i < n) p[i] = v;
}

// ---------------- CSR build ----------------
__global__ void k_hist(const int* __restrict__ dst, int* __restrict__ cnt, int ne) {
    int e = blockIdx.x * 256 + threadIdx.x;
    if (e < ne) atomicAdd(&cnt[dst[e]], 1);
}

// exclusive scan of cnt[0..n) -> rowptr[0..n], rowptr[n]=total
__global__ __launch_bounds__(1024) void k_scan(const int* __restrict__ cnt,
                                               int* __restrict__ rowptr, int n, int total) {
    __shared__ int part[1024];
    int t = threadIdx.x;
    int c = (n + 1023) >> 10;
    int b = t * c, e = min(b + c, n);
    int s = 0;
    for (int i = b; i < e; ++i) s += cnt[i];
    part[t] = s; __syncthreads();
    for (int off = 1; off < 1024; off <<= 1) {
        int v = (t >= off) ? part[t - off] : 0;
        __syncthreads();
        part[t] += v;
        __syncthreads();
    }
    int run = (t == 0) ? 0 : part[t - 1];
    for (int i = b; i < e; ++i) { rowptr[i] = run; run += cnt[i]; }
    if (t == 1023) rowptr[n] = total;
}

__global__ void k_scatter(const int* __restrict__ src, const int* __restrict__ dst,
                          int* __restrict__ cursor, int* __restrict__ col, int ne) {
    int e = blockIdx.x * 256 + threadIdx.x;
    if (e >= ne) return;
    int pos = atomicAdd(&cursor[dst[e]], 1);
    col[pos] = src[e];
}

// ---------------- stage-1 layer a ----------------
// CSR gather, 16 dims: agg[r][j] = h[r][j] + sum_e h[col][j]; deg[r] = 1 + nedges
__global__ __launch_bounds__(256) void k_agg16(const float* __restrict__ h,
                                               const int* __restrict__ rowptr,
                                               const int* __restrict__ col,
                                               float* __restrict__ agg, float* __restrict__ deg,
                                               int nrows) {
    int i = blockIdx.x * 256 + threadIdx.x;
    int r = i >> 4, j = i & 15;
    if (r >= nrows) return;
    int b = rowptr[r], e = rowptr[r + 1];
    float a = h[r * 16 + j];
    for (int q = b; q < e; ++q) a += h[col[q] * 16 + j];
    agg[r * 16 + j] = a;
    if (j == 0) deg[r] = 1.0f + (float)(e - b);
}

// y = tanh( (agg/deg) @ Wl + bl + h @ Wr ), K=16
__global__ __launch_bounds__(256) void k_sage16(
    const float* __restrict__ h, const float* __restrict__ agg, const float* __restrict__ deg,
    const float* __restrict__ Wl, const float* __restrict__ Wr, const float* __restrict__ bl,
    float* __restrict__ y, int nrows)
{
    __shared__ float WlS[16][128], WrS[16][128];
    int tid = threadIdx.x;
    for (int i = tid; i < 16 * 128; i += 256) {
        WlS[i >> 7][i & 127] = Wl[i];
        WrS[i >> 7][i & 127] = Wr[i];
    }
    __syncthreads();
    long long o = (long long)blockIdx.x * 256 + tid;
    int row = (int)(o >> 7);
    if (row >= nrows) return;
    int d = (int)o & 127;
    float invd = 1.0f / fmaxf(deg[row], 1.0f);
    float s = bl[d];
    #pragma unroll
    for (int k = 0; k < 16; ++k)
        s += agg[row * 16 + k] * invd * WlS[k][d] + h[row * 16 + k] * WrS[k][d];
    y[(long long)row * 128 + d] = tanhf(s);
}

// ---------------- fused SAGE GEMM (CSR agg on the fly) ----------------
// y = tanh( mean_agg@Wl + bl + x_self@Wr ). BM=128,BN=128,BK=32, 8x8/thread.
// agg row computed during staging by walking CSR; weight = nal[src] (or 1).
// feature row of global src s: xModN ? s%NN : s - rowbase.
__global__ __launch_bounds__(256) void k_sage_f(
    const float* __restrict__ x,
    const int* __restrict__ rowptr, const int* __restrict__ col,
    const float* __restrict__ nal, int selfloop, int xModN, int rowbase,
    const float* __restrict__ Wl, const float* __restrict__ Wr, const float* __restrict__ bl,
    float* __restrict__ y, int nrows,
    const float* __restrict__ wrel, const float* __restrict__ wroot,
    float* __restrict__ tbuf, float* __restrict__ rootd)
{
    __shared__ float Ws[32 * 128];
    __shared__ float Is[32][132];
    __shared__ float wrelS[128], wrootS[128];
    int tid = threadIdx.x;
    long long row0 = (long long)blockIdx.x * 128;
    if (tid < 128) { if (wrel) wrelS[tid] = wrel[tid]; }
    else           { if (wroot) wrootS[tid - 128] = wroot[tid - 128]; }
    int tx = tid & 15, ty = tid >> 4;
    int srow = tid & 127;
    int koff = (tid >> 7) * 16;
    long long lrow = row0 + srow;
    if (lrow >= nrows) lrow = nrows - 1;     // clamp: duplicate staging, write-guarded
    int grow = rowbase + (int)lrow;
    int ebeg = rowptr[grow], eend = rowptr[grow + 1];
    int selfr = xModN ? (grow % NN) : (int)lrow;
    const float* xself = x + (long long)selfr * 128;
    float dsum = selfloop ? 1.0f : 0.0f;
    if (nal) { for (int e = ebeg; e < eend; ++e) dsum += nal[col[e] - rowbase]; }
    else dsum += (float)(eend - ebeg);
    float invds = 1.0f / fmaxf(dsum, 1.0f);

    float acc[8][8] = {};
    for (int kb = 0; kb < 8; ++kb) {
        __syncthreads();
        const float* Wsrc = (kb < 4) ? (Wl + kb * 32 * 128) : (Wr + (kb - 4) * 32 * 128);
        #pragma unroll
        for (int j = 0; j < 4; ++j) {
            int fl = j * 1024 + tid * 4;
            *reinterpret_cast<float4*>(&Ws[fl]) = *reinterpret_cast<const float4*>(&Wsrc[fl]);
        }
        if (kb < 4) {
            float a16[16];
            if (selfloop) {
                const float* sp = xself + kb * 32 + koff;
                #pragma unroll
                for (int q = 0; q < 4; ++q) {
                    float4 v = *reinterpret_cast<const float4*>(sp + q * 4);
                    a16[q*4] = v.x; a16[q*4+1] = v.y; a16[q*4+2] = v.z; a16[q*4+3] = v.w;
                }
            } else {
                #pragma unroll
                for (int q = 0; q < 16; ++q) a16[q] = 0.0f;
            }
            for (int e = ebeg; e < eend; ++e) {
                int s = col[e];
                if (nal && nal[s - rowbase] == 0.0f) continue;
                int fr = xModN ? (s % NN) : (s - rowbase);
                const float* xp = x + (long long)fr * 128 + kb * 32 + koff;
                #pragma unroll
                for (int q = 0; q < 4; ++q) {
                    float4 v = *reinterpret_cast<const float4*>(xp + q * 4);
                    a16[q*4] += v.x; a16[q*4+1] += v.y; a16[q*4+2] += v.z; a16[q*4+3] += v.w;
                }
            }
            #pragma unroll
            for (int q = 0; q < 16; ++q) Is[koff + q][srow] = a16[q] * invds;
        } else {
            const float* sp = xself + (kb - 4) * 32 + koff;
            #pragma unroll
            for (int q = 0; q < 4; ++q) {
                float4 v = *reinterpret_cast<const float4*>(sp + q * 4);
                Is[koff + q*4    ][srow] = v.x;
                Is[koff + q*4 + 1][srow] = v.y;
                Is[koff + q*4 + 2][srow] = v.z;
                Is[koff + q*4 + 3][srow] = v.w;
            }
        }
        __syncthreads();
        #pragma unroll
        for (int kk = 0; kk < 32; ++kk) {
            float4 w0 = *reinterpret_cast<const float4*>(&Ws[kk * 128 + tx * 4]);
            float4 w1 = *reinterpret_cast<const float4*>(&Ws[kk * 128 + tx * 4 + 64]);
            float4 i0 = *reinterpret_cast<const float4*>(&Is[kk][ty * 8]);
            float4 i1 = *reinterpret_cast<const float4*>(&Is[kk][ty * 8 + 4]);
            float ia[8] = {i0.x, i0.y, i0.z, i0.w, i1.x, i1.y, i1.z, i1.w};
            float wa[8] = {w0.x, w0.y, w0.z, w0.w, w1.x, w1.y, w1.z, w1.w};
            #pragma unroll
            for (int i = 0; i < 8; ++i)
                #pragma unroll
                for (int j = 0; j < 8; ++j)
                    acc[i][j] += ia[i] * wa[j];
        }
    }
    float4 bl0 = *reinterpret_cast<const float4*>(&bl[tx * 4]);
    float4 bl1 = *reinterpret_cast<const float4*>(&bl[tx * 4 + 64]);
    float blr[8] = {bl0.x, bl0.y, bl0.z, bl0.w, bl1.x, bl1.y, bl1.z, bl1.w};
    #pragma unroll
    for (int i = 0; i < 8; ++i) {
        long long row = row0 + ty * 8 + i;
        bool valid = (row < nrows);
        float yv[8];
        #pragma unroll
        for (int j = 0; j < 8; ++j) yv[j] = tanhf(acc[i][j] + blr[j]);
        if (valid) {
            *reinterpret_cast<float4*>(&y[row * 128 + tx * 4]) = make_float4(yv[0], yv[1], yv[2], yv[3]);
            *reinterpret_cast<float4*>(&y[row * 128 + tx * 4 + 64]) = make_float4(yv[4], yv[5], yv[6], yv[7]);
        }
        if (tbuf) {
            float tp = 0.0f, rp = 0.0f;
            #pragma unroll
            for (int j = 0; j < 4; ++j) {
                tp += yv[j] * wrelS[tx*4 + j] + yv[j+4] * wrelS[tx*4 + 64 + j];
                if (rootd) rp += yv[j] * wrootS[tx*4 + j] + yv[j+4] * wrootS[tx*4 + 64 + j];
            }
            #pragma unroll
            for (int m = 8; m >= 1; m >>= 1) {
                tp += __shfl_xor(tp, m, 16);
                if (rootd) rp += __shfl_xor(rp, m, 16);
            }
            if (tx == 0 && valid) {
                tbuf[row] = tp;
                if (rootd) rootd[row] = rp;
            }
        }
    }
}

// ---------------- readout pieces ----------------
// stage-1 layer-a gate: g[i] = dot(x[i],gw)  (bias dropped: softmax shift-invariant)
__global__ __launch_bounds__(256) void k_gate(
    const float* __restrict__ X, const float* __restrict__ gw,
    float* __restrict__ g, int nrows)
{
    __shared__ float wS[128];
    if (threadIdx.x < 128) wS[threadIdx.x] = gw[threadIdx.x];
    __syncthreads();
    int i = blockIdx.x * 256 + threadIdx.x;
    if (i >= nrows) return;
    const float4* xrp = reinterpret_cast<const float4*>(X + (long long)i * 128);
    float s = 0.0f;
    #pragma unroll
    for (int k = 0; k < 32; ++k) {
        float4 v = xrp[k];
        s += v.x * wS[4*k] + v.y * wS[4*k+1] + v.z * wS[4*k+2] + v.w * wS[4*k+3];
    }
    g[i] = s;
}

// fused: X[row] *= (alive ? tanh(score) : 0), g[row] = alive ? dot(Xnew,gw) : -inf
__global__ __launch_bounds__(256) void k_maskgate(
    float* __restrict__ X, const float* __restrict__ score, const float* __restrict__ nalive,
    const float* __restrict__ gw, float* __restrict__ g)
{
    __shared__ float gwS[128];
    int tid = threadIdx.x;
    if (tid < 128) gwS[tid] = gw[tid];
    __syncthreads();
    int wv = tid >> 6, lane = tid & 63;
    long long row = (long long)blockIdx.x * 4 + wv;
    bool alive = nalive[row] > 0.5f;
    float f = alive ? tanhf(score[row]) : 0.0f;
    float2 v = *reinterpret_cast<float2*>(&X[row * 128 + lane * 2]);
    v.x *= f; v.y *= f;
    *reinterpret_cast<float2*>(&X[row * 128 + lane * 2]) = v;
    float gp = v.x * gwS[lane * 2] + v.y * gwS[lane * 2 + 1];
    #pragma unroll
    for (int m = 32; m >= 1; m >>= 1) gp += __shfl_xor(gp, m, 64);
    if (lane == 0) g[row] = alive ? gp : -INFINITY;
}

// per-graph softmax: g -> exp(g-max) in place, invp[p] = 1/sum
__global__ __launch_bounds__(1024) void k_smstats(float* __restrict__ g, float* __restrict__ invp) {
    __shared__ float red[1024];
    int p = blockIdx.x, tid = threadIdx.x;
    float* gp = g + (long long)p * NN;
    float lmax = -INFINITY;
    for (int n = tid; n < NN; n += 1024) lmax = fmaxf(lmax, gp[n]);
    red[tid] = lmax; __syncthreads();
    for (int s = 512; s > 0; s >>= 1) { if (tid < s) red[tid] = fmaxf(red[tid], red[tid + s]); __syncthreads(); }
    float mx = red[0]; __syncthreads();
    float ls = 0.0f;
    for (int n = tid; n < NN; n += 1024) { float e = expf(gp[n] - mx); gp[n] = e; ls += e; }
    red[tid] = ls; __syncthreads();
    for (int s = 512; s > 0; s >>= 1) { if (tid < s) red[tid] += red[tid + s]; __syncthreads(); }
    if (tid == 0) invp[p] = 1.0f / red[0];
}

// out[rowbase+p][colOff+d] += invp[p] * sum_{chunk rows} a[p*NN+n]*x[...]
__global__ __launch_bounds__(128) void k_wsum(
    const float* __restrict__ X, const float* __restrict__ a, const float* __restrict__ invp,
    float* __restrict__ ro, int rowbase, int colOff)
{
    int p = blockIdx.x / BPG;
    int chunk = blockIdx.x % BPG;
    int d = threadIdx.x;
    long long base = (long long)p * NN;
    int r0 = chunk * RB, r1 = r0 + RB;
    float s = 0.0f;
    for (int n = r0; n < r1; ++n) {
        float an = a[base + n];
        if (an != 0.0f) s += an * X[(base + n) * 128 + d];
    }
    atomicAdd(&ro[(long long)(rowbase + p) * 384 + colOff + d], s * invp[p]);
}

// ---------------- GraphNorm ----------------
__global__ void k_colstat(const float* __restrict__ x, float* __restrict__ musum,
                          float* __restrict__ sqsum, int nrows) {
    int d = threadIdx.x;
    int r0 = blockIdx.x * 64;
    int r1 = min(r0 + 64, nrows);
    float s = 0.0f, q = 0.0f;
    for (int r = r0; r < r1; ++r) { float v = x[(long long)r * 128 + d]; s += v; q += v * v; }
    atomicAdd(&musum[d], s);
    atomicAdd(&sqsum[d], q);
}

__global__ void k_gnorm_apply(const float* __restrict__ x, float* __restrict__ y,
                              const float* __restrict__ musum, const float* __restrict__ sqsum,
                              const float* __restrict__ w, const float* __restrict__ b,
                              const float* __restrict__ ms, int nrows) {
    long long i = (long long)blockIdx.x * 256 + threadIdx.x;
    if (i >= (long long)nrows * 128) return;
    int d = (int)(i & 127);
    float inv_n = 1.0f / (float)nrows;
    float mu = musum[d] * inv_n;
    float c = mu * ms[d];
    float var = sqsum[d] * inv_n - 2.0f * c * mu + c * c;
    y[i] = w[d] * (x[i] - c) * rsqrtf(var + 1e-5f) + b[d];
}

// ---------------- top-k with fused score gather ----------------
// score[n] = sum_{e in CSR row} t[src]*nal[src] + brel + rootd[n]; radix-select top-k.
__global__ __launch_bounds__(256) void k_topk(
    const int* __restrict__ rowptr, const int* __restrict__ col, int rowbase,
    const float* __restrict__ tb, const float* __restrict__ rootd,
    const float* __restrict__ brelp, int bi,
    float* __restrict__ scoreout, float* __restrict__ nalive, int k)
{
    __shared__ unsigned keys[NN];
    __shared__ int hist[256];
    __shared__ int chunkcnt[256];
    __shared__ unsigned sh_pref;
    __shared__ int sh_kneed;
    int p = blockIdx.x, tid = threadIdx.x;
    float brel = brelp[bi];
    for (int n = tid; n < NN; n += 256) {
        long long gl = (long long)p * NN + n;
        int grow = rowbase + (int)gl;
        float s = brel + rootd[gl];
        int b = rowptr[grow], e = rowptr[grow + 1];
        for (int q = b; q < e; ++q) {
            int sl = col[q] - rowbase;
            s += tb[sl] * nalive[sl];
        }
        scoreout[gl] = s;
        keys[n] = (nalive[gl] > 0.5f) ? fkey(s) : 0u;
    }
    if (tid == 0) { sh_pref = 0u; sh_kneed = k; }
    __syncthreads();
    for (int lvl = 3; lvl >= 0; --lvl) {
        int sh = lvl * 8;
        hist[tid] = 0;
        unsigned pref = sh_pref; int kneed = sh_kneed;
        unsigned pmask = (lvl == 3) ? 0u : (0xFFFFFFFFu << (8 * (lvl + 1)));
        __syncthreads();
        for (int n = tid; n < NN; n += 256) {
            unsigned kv = keys[n];
            if ((kv & pmask) == pref) atomicAdd(&hist[(kv >> sh) & 255], 1);
        }
        __syncthreads();
        if (tid == 0) {
            int cum = 0, b = 255;
            for (; b >= 0; --b) { cum += hist[b]; if (cum >= kneed) break; }
            sh_pref = pref | ((unsigned)b << sh);
            sh_kneed = kneed - (cum - hist[b]);
        }
        __syncthreads();
    }
    unsigned V = sh_pref;
    int seleq = sh_kneed;
    int c0 = tid * 32, c1 = min(c0 + 32, NN);
    int ceq = 0;
    for (int n = c0; n < c1; ++n) ceq += (keys[n] == V) ? 1 : 0;
    chunkcnt[tid] = ceq; __syncthreads();
    if (tid == 0) {
        int s = 0;
        for (int i = 0; i < 256; ++i) { int c = chunkcnt[i]; chunkcnt[i] = s; s += c; }
    }
    __syncthreads();
    int rank = chunkcnt[tid];
    float* na = nalive + (long long)p * NN;
    for (int n = c0; n < c1; ++n) {
        unsigned kk = keys[n];
        bool sel = (kk > V) || (kk == V && rank < seleq);
        if (kk == V) rank++;
        na[n] = sel ? 1.0f : 0.0f;
    }
}

// ---------------- head ----------------
__global__ __launch_bounds__(64) void k_head(
    const float* __restrict__ ro, const float* __restrict__ lin_w, const float* __restrict__ lin_b,
    const float* __restrict__ m1w, const float* __restrict__ m1b,
    const float* __restrict__ m2w, const float* __restrict__ m2b,
    const float* __restrict__ m3w, const float* __restrict__ m3b, float* __restrict__ out)
{
    __shared__ float v[33], h1[48], h2[16];
    int t = threadIdx.x;
    if (t < 33) {
        float s = lin_b[0];
        for (int k = 0; k < 384; ++k) s += ro[t * 384 + k] * lin_w[k];
        v[t] = tanhf(s);
    }
    __syncthreads();
    if (t < 48) {
        float s = m1b[t];
        for (int i = 0; i < 33; ++i) s += v[i] * m1w[i * 48 + t];
        h1[t] = tanhf(s);
    }
    __syncthreads();
    if (t < 16) {
        float s = m2b[t];
        for (int i = 0; i < 48; ++i) s += h1[i] * m2w[i * 16 + t];
        h2[t] = tanhf(s);
    }
    __syncthreads();
    if (t == 0) {
        float s = m3b[0];
        for (int i = 0; i < 16; ++i) s += h2[i] * m3w[i];
        float s1 = 1.0f / (1.0f + expf(-s));
        out[0] = 1.0f / (1.0f + expf(-s1));
    }
}

static inline int cdiv(long long a, long long b) { return (int)((a + b - 1) / b); }

extern "C" void kernel_launch(void* const* d_in, const int* in_sizes, int n_in,
                              void* d_out, int out_size, void* d_ws, size_t ws_size,
                              hipStream_t stream)
{
    (void)in_sizes; (void)n_in; (void)out_size;
    const float* h     = (const float*)d_in[0];
    const int*   eidx  = (const int*)d_in[1];
    const int*   seidx = (const int*)d_in[2];
    const float* Wl_a  = (const float*)d_in[3];
    const float* Wr_a  = (const float*)d_in[4];
    const float* bl_a  = (const float*)d_in[5];
    const float* Wl_s  = (const float*)d_in[6];
    const float* Wr_s  = (const float*)d_in[7];
    const float* bl_s  = (const float*)d_in[8];
    const float* gate_w = (const float*)d_in[9];
    const float* p_wrel = (const float*)d_in[11];
    const float* p_brel = (const float*)d_in[12];
    const float* p_wroot= (const float*)d_in[13];
    const float* nw    = (const float*)d_in[14];
    const float* nb    = (const float*)d_in[15];
    const float* nms   = (const float*)d_in[16];
    const float* lin_w = (const float*)d_in[17];
    const float* lin_b = (const float*)d_in[18];
    const float* m1w   = (const float*)d_in[19];
    const float* m1b   = (const float*)d_in[20];
    const float* m2w   = (const float*)d_in[21];
    const float* m2b   = (const float*)d_in[22];
    const float* m3w   = (const float*)d_in[23];
    const float* m3b   = (const float*)d_in[24];
    float* out = (float*)d_out;

    const int* esrc = eidx;
    const int* edst = eidx + EG;
    const int* ssrc = seidx;
    const int* sdst = seidx + ES_TOT;

    // workspace need per chunk width (floats + ints, 4B each)
    auto need_bytes = [](int chp) -> size_t {
        long long chn = (long long)chp * NN;
        long long f = chn * 128                 // Xc
                    + 2LL * NN * 128            // xa, xb
                    + NN * 16 + NN              // agg1, deg1
                    + 5 * chn                   // tbuf, rootd, sagg, nal, gbuf
                    + 64 + 33 * 384 + 256       // invp, ro, stats
                    + (NN + (NN + 1) + NN + EG) // s1 cnt/rowptr/cursor/col
                    + (PN + (PN + 1) + PN + ES_TOT)
                    + 64 * 32;                  // align slack
        return (size_t)f * 4;
    };
    int chp = 8;
    if (ws_size >= need_bytes(32)) chp = 32;
    else if (ws_size >= need_bytes(16)) chp = 16;
    int nch = PP / chp;
    long long ch_n = (long long)chp * NN;

    float* W = (float*)d_ws;
    size_t off = 0;
    auto alloc = [&](size_t nf) { float* p = W + off; off += (nf + 63) & ~(size_t)63; return p; };
    float* Xc    = alloc((size_t)ch_n * DD);
    float* xa    = alloc((size_t)NN * DD);
    float* xb    = alloc((size_t)NN * DD);
    float* agg1  = alloc((size_t)NN * 16);
    float* deg1  = alloc(NN);
    float* tbuf  = alloc(ch_n);
    float* rootd = alloc(ch_n);
    float* sagg  = alloc(ch_n);
    float* nal   = alloc(ch_n);
    float* gbuf  = alloc(ch_n);
    float* invp  = alloc(64);
    float* ro    = alloc(33 * 384);
    float* musum = alloc(128);
    float* sqsum = alloc(128);
    int* s1cnt = (int*)alloc(NN);
    int* s1rp  = (int*)alloc(NN + 1);
    int* s1cur = (int*)alloc(NN);
    int* s1col = (int*)alloc(EG);
    int* s2cnt = (int*)alloc(PN);
    int* s2rp  = (int*)alloc(PN + 1);
    int* s2cur = (int*)alloc(PN);
    int* s2col = (int*)alloc(ES_TOT);

    // ---------- CSR builds ----------
    hipMemsetAsync(s1cnt, 0, NN * sizeof(int), stream);
    k_hist<<<cdiv(EG,256),256,0,stream>>>(edst, s1cnt, EG);
    k_scan<<<1,1024,0,stream>>>(s1cnt, s1rp, NN, EG);
    hipMemcpyAsync(s1cur, s1rp, NN * sizeof(int), hipMemcpyDeviceToDevice, stream);
    k_scatter<<<cdiv(EG,256),256,0,stream>>>(esrc, edst, s1cur, s1col, EG);

    hipMemsetAsync(s2cnt, 0, (size_t)PN * sizeof(int), stream);
    k_hist<<<cdiv(ES_TOT,256),256,0,stream>>>(sdst, s2cnt, ES_TOT);
    k_scan<<<1,1024,0,stream>>>(s2cnt, s2rp, PN, ES_TOT);
    hipMemcpyAsync(s2cur, s2rp, (size_t)PN * sizeof(int), hipMemcpyDeviceToDevice, stream);
    k_scatter<<<cdiv(ES_TOT,256),256,0,stream>>>(ssrc, sdst, s2cur, s2col, ES_TOT);

    hipMemsetAsync(ro, 0, 33 * 384 * sizeof(float), stream);

    // ---------- stage 1 ----------
    // layer a (DIN=16): CSR gather (also writes deg1)
    k_agg16<<<cdiv((long long)NN*16,256),256,0,stream>>>(h, s1rp, s1col, agg1, deg1, NN);
    k_sage16<<<cdiv((long long)NN*DD,256),256,0,stream>>>(h, agg1, deg1, Wl_a, Wr_a, bl_a, xa, NN);
    k_gate<<<cdiv(NN,256),256,0,stream>>>(xa, gate_w + 0*DD, gbuf, NN);
    k_smstats<<<1,1024,0,stream>>>(gbuf, invp);
    k_wsum<<<BPG,128,0,stream>>>(xa, gbuf, invp, ro, 0, 0);

    // gnorm 1: xa -> xb
    hipMemsetAsync(musum, 0, 128*sizeof(float), stream);
    hipMemsetAsync(sqsum, 0, 128*sizeof(float), stream);
    k_colstat<<<cdiv(NN,64),128,0,stream>>>(xa, musum, sqsum, NN);
    k_gnorm_apply<<<cdiv((long long)NN*DD,256),256,0,stream>>>(xa, xb, musum, sqsum, nw, nb, nms, NN);

    // layer b: fused agg+GEMM, gate in epilogue
    k_sage_f<<<cdiv(NN,128),256,0,stream>>>(xb, s1rp, s1col, nullptr, 1, 0, 0,
        Wl_s + 0*16384, Wr_s + 0*16384, bl_s + 0*128, xa, NN,
        gate_w + 1*DD, nullptr, gbuf, nullptr);
    k_smstats<<<1,1024,0,stream>>>(gbuf, invp);
    k_wsum<<<BPG,128,0,stream>>>(xa, gbuf, invp, ro, 0, 128);

    // gnorm 2: xa -> xb
    hipMemsetAsync(musum, 0, 128*sizeof(float), stream);
    hipMemsetAsync(sqsum, 0, 128*sizeof(float), stream);
    k_colstat<<<cdiv(NN,64),128,0,stream>>>(xa, musum, sqsum, NN);
    k_gnorm_apply<<<cdiv((long long)NN*DD,256),256,0,stream>>>(xa, xb, musum, sqsum, nw, nb, nms, NN);

    // layer c -> xa = x_c
    k_sage_f<<<cdiv(NN,128),256,0,stream>>>(xb, s1rp, s1col, nullptr, 1, 0, 0,
        Wl_s + 1*16384, Wr_s + 1*16384, bl_s + 1*128, xa, NN,
        gate_w + 2*DD, nullptr, gbuf, nullptr);
    k_smstats<<<1,1024,0,stream>>>(gbuf, invp);
    k_wsum<<<BPG,128,0,stream>>>(xa, gbuf, invp, ro, 0, 256);

    // ---------- stage 2 ----------
    for (int c = 0; c < nch; ++c) {
        int nbase = (int)(c * ch_n);
        k_fill<<<cdiv(ch_n,256),256,0,stream>>>(nal, 1.0f, (int)ch_n);

        for (int layer = 0; layer < 3; ++layer) {
            const float* Wl = Wl_s + (2 + layer) * 16384;
            const float* Wr = Wr_s + (2 + layer) * 16384;
            const float* bl = bl_s + (2 + layer) * 128;
            int kkeep = (layer == 0) ? KK1 : (layer == 1) ? KK2 : KK3;
            int gi = 3 + layer;

            if (layer == 0) {
                k_sage_f<<<(int)(ch_n/128),256,0,stream>>>(xa, s2rp, s2col, nullptr, 0, 1, nbase,
                    Wl, Wr, bl, Xc, (int)ch_n,
                    p_wrel + layer*DD, p_wroot + layer*DD, tbuf, rootd);
            } else {
                k_sage_f<<<(int)(ch_n/128),256,0,stream>>>(Xc, s2rp, s2col, nal, 0, 0, nbase,
                    Wl, Wr, bl, Xc, (int)ch_n,
                    p_wrel + layer*DD, p_wroot + layer*DD, tbuf, rootd);
            }
            k_topk<<<chp,256,0,stream>>>(s2rp, s2col, nbase, tbuf, rootd, p_brel, layer, sagg, nal, kkeep);
            k_maskgate<<<(int)(ch_n/4),256,0,stream>>>(Xc, sagg, nal, gate_w + gi*DD, gbuf);
            k_smstats<<<chp,1024,0,stream>>>(gbuf, invp);
            k_wsum<<<chp*BPG,128,0,stream>>>(Xc, gbuf, invp, ro, 1 + c*chp, layer*128);
        }
    }

    // ---------- head ----------
    k_head<<<1,64,0,stream>>>(ro, lin_w, lin_b, m1w, m1b, m2w, m2b, m3w, m3b, out);
}

// Round 7
// 2141.515 us; speedup vs baseline: 1.2271x; 1.0605x over previous
//
#include <hip/hip_runtime.h>
#include <math.h>

#define NN      8000
#define PP      32
#define EG      128000
#define ES_TOT  131072     // P * 4096
#define ES_P    4096
#define PN      256000     // P * NN
#define DI      16
#define DD      128
#define KK1     6400
#define KK2     5120
#define KK3     4096
#define RB      64                   // rows per k_wsum block
#define BPG     (NN / RB)            // 125 blocks per graph

static __device__ __forceinline__ unsigned fkey(float f) {
    unsigned u = __float_as_uint(f);
    return (u & 0x80000000u) ? ~u : (u | 0x80000000u);
}

__global__ void k_fill(float* p, float v, int n) {
    int i = blockIdx.x * 256 + threadIdx.x;
    if (i < n) p[i] = v;
}

// ---------------- CSR build ----------------
__global__ void k_hist(const int* __restrict__ dst, int* __restrict__ cnt, int ne) {
    int e = blockIdx.x * 256 + threadIdx.x;
    if (e < ne) atomicAdd(&cnt[dst[e]], 1);
}

// hierarchical scan: A) per-block exclusive scan  B) scan blocksums  C) add + finalize
__global__ __launch_bounds__(1024) void k_scanA(const int* __restrict__ cnt,
                                                int* __restrict__ part,
                                                int* __restrict__ bsum, int n) {
    __shared__ int sh[1024];
    int t = threadIdx.x;
    int i = blockIdx.x * 1024 + t;
    int v = (i < n) ? cnt[i] : 0;
    sh[t] = v; __syncthreads();
    for (int off = 1; off < 1024; off <<= 1) {
        int u = (t >= off) ? sh[t - off] : 0;
        __syncthreads();
        sh[t] += u;
        __syncthreads();
    }
    if (i < n) part[i] = sh[t] - v;
    if (t == 1023) bsum[blockIdx.x] = sh[1023];
}

__global__ __launch_bounds__(1024) void k_scanB(int* __restrict__ bsum, int nb) {
    __shared__ int sh[1024];
    int t = threadIdx.x;
    int v = (t < nb) ? bsum[t] : 0;
    sh[t] = v; __syncthreads();
    for (int off = 1; off < 1024; off <<= 1) {
        int u = (t >= off) ? sh[t - off] : 0;
        __syncthreads();
        sh[t] += u;
        __syncthreads();
    }
    if (t < nb) bsum[t] = sh[t] - v;   // exclusive
}

__global__ void k_scanC(const int* __restrict__ part, const int* __restrict__ bsum,
                        int* __restrict__ rowptr, int* __restrict__ cursor, int n, int total) {
    int i = blockIdx.x * 256 + threadIdx.x;
    if (i < n) {
        int v = part[i] + bsum[i >> 10];
        rowptr[i] = v;
        cursor[i] = v;
    }
    if (i == 0) rowptr[n] = total;
}

__global__ void k_scatter(const int* __restrict__ src, const int* __restrict__ dst,
                          int* __restrict__ cursor, int* __restrict__ col, int ne) {
    int e = blockIdx.x * 256 + threadIdx.x;
    if (e >= ne) return;
    int pos = atomicAdd(&cursor[dst[e]], 1);
    col[pos] = src[e];
}

// ---------------- stage-1 layer a ----------------
__global__ __launch_bounds__(256) void k_agg16(const float* __restrict__ h,
                                               const int* __restrict__ rowptr,
                                               const int* __restrict__ col,
                                               float* __restrict__ agg, float* __restrict__ deg,
                                               int nrows) {
    int i = blockIdx.x * 256 + threadIdx.x;
    int r = i >> 4, j = i & 15;
    if (r >= nrows) return;
    int b = rowptr[r], e = rowptr[r + 1];
    float a = h[r * 16 + j];
    for (int q = b; q < e; ++q) a += h[col[q] * 16 + j];
    agg[r * 16 + j] = a;
    if (j == 0) deg[r] = 1.0f + (float)(e - b);
}

__global__ __launch_bounds__(256) void k_sage16(
    const float* __restrict__ h, const float* __restrict__ agg, const float* __restrict__ deg,
    const float* __restrict__ Wl, const float* __restrict__ Wr, const float* __restrict__ bl,
    float* __restrict__ y, int nrows)
{
    __shared__ float WlS[16][128], WrS[16][128];
    int tid = threadIdx.x;
    for (int i = tid; i < 16 * 128; i += 256) {
        WlS[i >> 7][i & 127] = Wl[i];
        WrS[i >> 7][i & 127] = Wr[i];
    }
    __syncthreads();
    long long o = (long long)blockIdx.x * 256 + tid;
    int row = (int)(o >> 7);
    if (row >= nrows) return;
    int d = (int)o & 127;
    float invd = 1.0f / fmaxf(deg[row], 1.0f);
    float s = bl[d];
    #pragma unroll
    for (int k = 0; k < 16; ++k)
        s += agg[row * 16 + k] * invd * WlS[k][d] + h[row * 16 + k] * WrS[k][d];
    y[(long long)row * 128 + d] = tanhf(s);
}

// ---------------- zself GEMM: y = x@W + b (8000x128, K=128, no tanh) ----------------
__global__ __launch_bounds__(256) void k_gemm_self(
    const float* __restrict__ x, const float* __restrict__ W, const float* __restrict__ b,
    float* __restrict__ y, int nrows)
{
    __shared__ float Ws[32 * 128];
    __shared__ float Is[32][132];
    int tid = threadIdx.x;
    long long row0 = (long long)blockIdx.x * 128;
    int tx = tid & 15, ty = tid >> 4;
    int srow = tid & 127;
    int koff = (tid >> 7) * 16;
    long long lrow = row0 + srow;
    if (lrow >= nrows) lrow = nrows - 1;
    const float* xrow = x + lrow * 128;
    float acc[8][8] = {};
    for (int kb = 0; kb < 4; ++kb) {
        __syncthreads();
        const float* Wsrc = W + kb * 32 * 128;
        #pragma unroll
        for (int j = 0; j < 4; ++j) {
            int fl = j * 1024 + tid * 4;
            *reinterpret_cast<float4*>(&Ws[fl]) = *reinterpret_cast<const float4*>(&Wsrc[fl]);
        }
        {
            const float* sp = xrow + kb * 32 + koff;
            #pragma unroll
            for (int q = 0; q < 4; ++q) {
                float4 v = *reinterpret_cast<const float4*>(sp + q * 4);
                Is[koff + q*4    ][srow] = v.x;
                Is[koff + q*4 + 1][srow] = v.y;
                Is[koff + q*4 + 2][srow] = v.z;
                Is[koff + q*4 + 3][srow] = v.w;
            }
        }
        __syncthreads();
        #pragma unroll
        for (int kk = 0; kk < 32; ++kk) {
            float4 w0 = *reinterpret_cast<const float4*>(&Ws[kk * 128 + tx * 4]);
            float4 w1 = *reinterpret_cast<const float4*>(&Ws[kk * 128 + tx * 4 + 64]);
            float4 i0 = *reinterpret_cast<const float4*>(&Is[kk][ty * 8]);
            float4 i1 = *reinterpret_cast<const float4*>(&Is[kk][ty * 8 + 4]);
            float ia[8] = {i0.x, i0.y, i0.z, i0.w, i1.x, i1.y, i1.z, i1.w};
            float wa[8] = {w0.x, w0.y, w0.z, w0.w, w1.x, w1.y, w1.z, w1.w};
            #pragma unroll
            for (int i = 0; i < 8; ++i)
                #pragma unroll
                for (int j = 0; j < 8; ++j)
                    acc[i][j] += ia[i] * wa[j];
        }
    }
    float4 b0 = *reinterpret_cast<const float4*>(&b[tx * 4]);
    float4 b1 = *reinterpret_cast<const float4*>(&b[tx * 4 + 64]);
    #pragma unroll
    for (int i = 0; i < 8; ++i) {
        long long row = row0 + ty * 8 + i;
        if (row >= nrows) continue;
        *reinterpret_cast<float4*>(&y[row * 128 + tx * 4]) =
            make_float4(acc[i][0] + b0.x, acc[i][1] + b0.y, acc[i][2] + b0.z, acc[i][3] + b0.w);
        *reinterpret_cast<float4*>(&y[row * 128 + tx * 4 + 64]) =
            make_float4(acc[i][4] + b1.x, acc[i][5] + b1.y, acc[i][6] + b1.z, acc[i][7] + b1.w);
    }
}

// ---------------- fused SAGE GEMM ----------------
// mode 0 (stage-1): selfloop in agg+deg, K=256, bias=bl, gather plain.
// mode 1 (s2 L0):   K=128 agg-only (Wl), deg=edge count, epilogue adds zself[row%NN] (has bias).
// mode 2 (s2 L1/2): K=256, features weighted by fvec, deg=sum nal, bias=bl.
// Optional epilogue dots vs wrel/wroot/gw -> tbuf/rootd/gdot.
__global__ __launch_bounds__(256) void k_sage_f(
    const float* __restrict__ x,
    const int* __restrict__ rowptr, const int* __restrict__ col,
    const float* __restrict__ nal, const float* __restrict__ fvec,
    int mode, int xModN, int rowbase,
    const float* __restrict__ Wl, const float* __restrict__ Wr, const float* __restrict__ bl,
    const float* __restrict__ zself,
    float* __restrict__ y, int nrows,
    const float* __restrict__ wrel, const float* __restrict__ wroot, const float* __restrict__ gw,
    float* __restrict__ tbuf, float* __restrict__ rootd, float* __restrict__ gdot)
{
    __shared__ float Ws[32 * 128];
    __shared__ float Is[32][132];
    __shared__ float wrelS[128], wrootS[128], gwS[128];
    int tid = threadIdx.x;
    long long row0 = (long long)blockIdx.x * 128;
    if (tid < 128) {
        if (wrel)  wrelS[tid]  = wrel[tid];
        if (wroot) wrootS[tid] = wroot[tid];
        if (gw)    gwS[tid]    = gw[tid];
    }
    int tx = tid & 15, ty = tid >> 4;
    int srow = tid & 127;
    int koff = (tid >> 7) * 16;
    long long lrow = row0 + srow;
    if (lrow >= nrows) lrow = nrows - 1;     // clamp: duplicate staging, write-guarded
    int grow = rowbase + (int)lrow;
    int ebeg = rowptr[grow], eend = rowptr[grow + 1];
    const float* xself = x + (long long)((mode == 1) ? 0 : lrow) * 128;  // mode1 has no self path
    float fself = 1.0f;
    if (mode == 2) fself = fvec[lrow];
    float dsum;
    if (mode == 0) dsum = 1.0f + (float)(eend - ebeg);
    else if (mode == 1) dsum = (float)(eend - ebeg);
    else {
        dsum = 0.0f;
        for (int e = ebeg; e < eend; ++e) dsum += nal[col[e] - rowbase];
    }
    float invds = 1.0f / fmaxf(dsum, 1.0f);

    int KB = (mode == 1) ? 4 : 8;
    float acc[8][8] = {};
    for (int kb = 0; kb < KB; ++kb) {
        __syncthreads();
        bool isAgg = (kb < 4);
        const float* Wsrc = isAgg ? (Wl + kb * 32 * 128) : (Wr + (kb - 4) * 32 * 128);
        #pragma unroll
        for (int j = 0; j < 4; ++j) {
            int fl = j * 1024 + tid * 4;
            *reinterpret_cast<float4*>(&Ws[fl]) = *reinterpret_cast<const float4*>(&Wsrc[fl]);
        }
        if (isAgg) {
            float a16[16];
            if (mode == 0) {
                const float* sp = xself + kb * 32 + koff;
                #pragma unroll
                for (int q = 0; q < 4; ++q) {
                    float4 v = *reinterpret_cast<const float4*>(sp + q * 4);
                    a16[q*4] = v.x; a16[q*4+1] = v.y; a16[q*4+2] = v.z; a16[q*4+3] = v.w;
                }
            } else {
                #pragma unroll
                for (int q = 0; q < 16; ++q) a16[q] = 0.0f;
            }
            for (int e = ebeg; e < eend; ++e) {
                int s = col[e];
                int fr;
                float fw = 1.0f;
                if (mode == 2) {
                    fr = s - rowbase;
                    fw = fvec[fr];
                    if (fw == 0.0f) continue;
                } else {
                    fr = xModN ? (s % NN) : (s - rowbase);
                }
                const float* xp = x + (long long)fr * 128 + kb * 32 + koff;
                #pragma unroll
                for (int q = 0; q < 4; ++q) {
                    float4 v = *reinterpret_cast<const float4*>(xp + q * 4);
                    a16[q*4] += v.x * fw; a16[q*4+1] += v.y * fw;
                    a16[q*4+2] += v.z * fw; a16[q*4+3] += v.w * fw;
                }
            }
            #pragma unroll
            for (int q = 0; q < 16; ++q) Is[koff + q][srow] = a16[q] * invds;
        } else {
            const float* sp = xself + (kb - 4) * 32 + koff;
            #pragma unroll
            for (int q = 0; q < 4; ++q) {
                float4 v = *reinterpret_cast<const float4*>(sp + q * 4);
                Is[koff + q*4    ][srow] = v.x * fself;
                Is[koff + q*4 + 1][srow] = v.y * fself;
                Is[koff + q*4 + 2][srow] = v.z * fself;
                Is[koff + q*4 + 3][srow] = v.w * fself;
            }
        }
        __syncthreads();
        #pragma unroll
        for (int kk = 0; kk < 32; ++kk) {
            float4 w0 = *reinterpret_cast<const float4*>(&Ws[kk * 128 + tx * 4]);
            float4 w1 = *reinterpret_cast<const float4*>(&Ws[kk * 128 + tx * 4 + 64]);
            float4 i0 = *reinterpret_cast<const float4*>(&Is[kk][ty * 8]);
            float4 i1 = *reinterpret_cast<const float4*>(&Is[kk][ty * 8 + 4]);
            float ia[8] = {i0.x, i0.y, i0.z, i0.w, i1.x, i1.y, i1.z, i1.w};
            float wa[8] = {w0.x, w0.y, w0.z, w0.w, w1.x, w1.y, w1.z, w1.w};
            #pragma unroll
            for (int i = 0; i < 8; ++i)
                #pragma unroll
                for (int j = 0; j < 8; ++j)
                    acc[i][j] += ia[i] * wa[j];
        }
    }
    float br[8];
    if (mode != 1) {
        float4 bl0 = *reinterpret_cast<const float4*>(&bl[tx * 4]);
        float4 bl1 = *reinterpret_cast<const float4*>(&bl[tx * 4 + 64]);
        br[0]=bl0.x; br[1]=bl0.y; br[2]=bl0.z; br[3]=bl0.w;
        br[4]=bl1.x; br[5]=bl1.y; br[6]=bl1.z; br[7]=bl1.w;
    }
    #pragma unroll
    for (int i = 0; i < 8; ++i) {
        long long row = row0 + ty * 8 + i;
        bool valid = (row < nrows);
        float zr[8];
        if (mode == 1) {
            const float* zp = zself + (long long)((int)(row % NN)) * 128;
            float4 z0 = *reinterpret_cast<const float4*>(&zp[tx * 4]);
            float4 z1 = *reinterpret_cast<const float4*>(&zp[tx * 4 + 64]);
            zr[0]=z0.x; zr[1]=z0.y; zr[2]=z0.z; zr[3]=z0.w;
            zr[4]=z1.x; zr[5]=z1.y; zr[6]=z1.z; zr[7]=z1.w;
        } else {
            #pragma unroll
            for (int j = 0; j < 8; ++j) zr[j] = br[j];
        }
        float yv[8];
        #pragma unroll
        for (int j = 0; j < 8; ++j) yv[j] = tanhf(acc[i][j] + zr[j]);
        if (valid) {
            *reinterpret_cast<float4*>(&y[row * 128 + tx * 4]) = make_float4(yv[0], yv[1], yv[2], yv[3]);
            *reinterpret_cast<float4*>(&y[row * 128 + tx * 4 + 64]) = make_float4(yv[4], yv[5], yv[6], yv[7]);
        }
        float tp = 0.0f, rp = 0.0f, gp = 0.0f;
        #pragma unroll
        for (int j = 0; j < 4; ++j) {
            if (tbuf)  tp += yv[j] * wrelS[tx*4 + j]  + yv[j+4] * wrelS[tx*4 + 64 + j];
            if (rootd) rp += yv[j] * wrootS[tx*4 + j] + yv[j+4] * wrootS[tx*4 + 64 + j];
            if (gdot)  gp += yv[j] * gwS[tx*4 + j]    + yv[j+4] * gwS[tx*4 + 64 + j];
        }
        #pragma unroll
        for (int m = 8; m >= 1; m >>= 1) {
            if (tbuf)  tp += __shfl_xor(tp, m, 16);
            if (rootd) rp += __shfl_xor(rp, m, 16);
            if (gdot)  gp += __shfl_xor(gp, m, 16);
        }
        if (tx == 0 && valid) {
            if (tbuf)  tbuf[row]  = tp;
            if (rootd) rootd[row] = rp;
            if (gdot)  gdot[row]  = gp;
        }
    }
}

// ---------------- readout pieces ----------------
__global__ __launch_bounds__(256) void k_gate(
    const float* __restrict__ X, const float* __restrict__ gw,
    float* __restrict__ g, int nrows)
{
    __shared__ float wS[128];
    if (threadIdx.x < 128) wS[threadIdx.x] = gw[threadIdx.x];
    __syncthreads();
    int i = blockIdx.x * 256 + threadIdx.x;
    if (i >= nrows) return;
    const float4* xrp = reinterpret_cast<const float4*>(X + (long long)i * 128);
    float s = 0.0f;
    #pragma unroll
    for (int k = 0; k < 32; ++k) {
        float4 v = xrp[k];
        s += v.x * wS[4*k] + v.y * wS[4*k+1] + v.z * wS[4*k+2] + v.w * wS[4*k+3];
    }
    g[i] = s;
}

// fvec[r] = alive ? tanh(score[r]) : 0 ;  g[r] = alive ? fvec*gdot : -inf
__global__ void k_fvec(const float* __restrict__ score, const float* __restrict__ nal,
                       const float* __restrict__ gd, float* __restrict__ fvec,
                       float* __restrict__ g, int n) {
    int i = blockIdx.x * 256 + threadIdx.x;
    if (i >= n) return;
    bool alive = nal[i] > 0.5f;
    float f = alive ? tanhf(score[i]) : 0.0f;
    fvec[i] = f;
    g[i] = alive ? f * gd[i] : -INFINITY;
}

__global__ __launch_bounds__(1024) void k_smstats(float* __restrict__ g, float* __restrict__ invp) {
    __shared__ float red[1024];
    int p = blockIdx.x, tid = threadIdx.x;
    float* gp = g + (long long)p * NN;
    float lmax = -INFINITY;
    for (int n = tid; n < NN; n += 1024) lmax = fmaxf(lmax, gp[n]);
    red[tid] = lmax; __syncthreads();
    for (int s = 512; s > 0; s >>= 1) { if (tid < s) red[tid] = fmaxf(red[tid], red[tid + s]); __syncthreads(); }
    float mx = red[0]; __syncthreads();
    float ls = 0.0f;
    for (int n = tid; n < NN; n += 1024) { float e = expf(gp[n] - mx); gp[n] = e; ls += e; }
    red[tid] = ls; __syncthreads();
    for (int s = 512; s > 0; s >>= 1) { if (tid < s) red[tid] += red[tid + s]; __syncthreads(); }
    if (tid == 0) invp[p] = 1.0f / red[0];
}

// out[rowbase+p][colOff+d] += invp[p] * sum_{chunk rows} a[n]*(fvec?fvec[n]:1)*x[n][d]
__global__ __launch_bounds__(128) void k_wsum(
    const float* __restrict__ X, const float* __restrict__ a, const float* __restrict__ fvec,
    const float* __restrict__ invp, float* __restrict__ ro, int rowbase, int colOff)
{
    int p = blockIdx.x / BPG;
    int chunk = blockIdx.x % BPG;
    int d = threadIdx.x;
    long long base = (long long)p * NN;
    int r0 = chunk * RB, r1 = r0 + RB;
    float s = 0.0f;
    for (int n = r0; n < r1; ++n) {
        float w = a[base + n];
        if (fvec) w *= fvec[base + n];
        if (w != 0.0f) s += w * X[(base + n) * 128 + d];
    }
    atomicAdd(&ro[(long long)(rowbase + p) * 384 + colOff + d], s * invp[p]);
}

// ---------------- GraphNorm ----------------
__global__ void k_colstat(const float* __restrict__ x, float* __restrict__ musum,
                          float* __restrict__ sqsum, int nrows) {
    int d = threadIdx.x;
    int r0 = blockIdx.x * 64;
    int r1 = min(r0 + 64, nrows);
    float s = 0.0f, q = 0.0f;
    for (int r = r0; r < r1; ++r) { float v = x[(long long)r * 128 + d]; s += v; q += v * v; }
    atomicAdd(&musum[d], s);
    atomicAdd(&sqsum[d], q);
}

__global__ void k_gnorm_apply(const float* __restrict__ x, float* __restrict__ y,
                              const float* __restrict__ musum, const float* __restrict__ sqsum,
                              const float* __restrict__ w, const float* __restrict__ b,
                              const float* __restrict__ ms, int nrows) {
    long long i = (long long)blockIdx.x * 256 + threadIdx.x;
    if (i >= (long long)nrows * 128) return;
    int d = (int)(i & 127);
    float inv_n = 1.0f / (float)nrows;
    float mu = musum[d] * inv_n;
    float c = mu * ms[d];
    float var = sqsum[d] * inv_n - 2.0f * c * mu + c * c;
    y[i] = w[d] * (x[i] - c) * rsqrtf(var + 1e-5f) + b[d];
}

// ---------------- top-k with fused score gather ----------------
__global__ __launch_bounds__(256) void k_topk(
    const int* __restrict__ rowptr, const int* __restrict__ col, int rowbase,
    const float* __restrict__ tb, const float* __restrict__ rootd,
    const float* __restrict__ brelp, int bi,
    float* __restrict__ scoreout, float* __restrict__ nalive, int k)
{
    __shared__ unsigned keys[NN];
    __shared__ int hist[256];
    __shared__ int chunkcnt[256];
    __shared__ unsigned sh_pref;
    __shared__ int sh_kneed;
    int p = blockIdx.x, tid = threadIdx.x;
    float brel = brelp[bi];
    for (int n = tid; n < NN; n += 256) {
        long long gl = (long long)p * NN + n;
        int grow = rowbase + (int)gl;
        float s = brel + rootd[gl];
        int b = rowptr[grow], e = rowptr[grow + 1];
        for (int q = b; q < e; ++q) {
            int sl = col[q] - rowbase;
            s += tb[sl] * nalive[sl];
        }
        scoreout[gl] = s;
        keys[n] = (nalive[gl] > 0.5f) ? fkey(s) : 0u;
    }
    if (tid == 0) { sh_pref = 0u; sh_kneed = k; }
    __syncthreads();
    for (int lvl = 3; lvl >= 0; --lvl) {
        int sh = lvl * 8;
        hist[tid] = 0;
        unsigned pref = sh_pref; int kneed = sh_kneed;
        unsigned pmask = (lvl == 3) ? 0u : (0xFFFFFFFFu << (8 * (lvl + 1)));
        __syncthreads();
        for (int n = tid; n < NN; n += 256) {
            unsigned kv = keys[n];
            if ((kv & pmask) == pref) atomicAdd(&hist[(kv >> sh) & 255], 1);
        }
        __syncthreads();
        if (tid == 0) {
            int cum = 0, b = 255;
            for (; b >= 0; --b) { cum += hist[b]; if (cum >= kneed) break; }
            sh_pref = pref | ((unsigned)b << sh);
            sh_kneed = kneed - (cum - hist[b]);
        }
        __syncthreads();
    }
    unsigned V = sh_pref;
    int seleq = sh_kneed;
    int c0 = tid * 32, c1 = min(c0 + 32, NN);
    int ceq = 0;
    for (int n = c0; n < c1; ++n) ceq += (keys[n] == V) ? 1 : 0;
    chunkcnt[tid] = ceq; __syncthreads();
    if (tid == 0) {
        int s = 0;
        for (int i = 0; i < 256; ++i) { int c = chunkcnt[i]; chunkcnt[i] = s; s += c; }
    }
    __syncthreads();
    int rank = chunkcnt[tid];
    float* na = nalive + (long long)p * NN;
    for (int n = c0; n < c1; ++n) {
        unsigned kk = keys[n];
        bool sel = (kk > V) || (kk == V && rank < seleq);
        if (kk == V) rank++;
        na[n] = sel ? 1.0f : 0.0f;
    }
}

// ---------------- head ----------------
__global__ __launch_bounds__(64) void k_head(
    const float* __restrict__ ro, const float* __restrict__ lin_w, const float* __restrict__ lin_b,
    const float* __restrict__ m1w, const float* __restrict__ m1b,
    const float* __restrict__ m2w, const float* __restrict__ m2b,
    const float* __restrict__ m3w, const float* __restrict__ m3b, float* __restrict__ out)
{
    __shared__ float v[33], h1[48], h2[16];
    int t = threadIdx.x;
    if (t < 33) {
        float s = lin_b[0];
        for (int k = 0; k < 384; ++k) s += ro[t * 384 + k] * lin_w[k];
        v[t] = tanhf(s);
    }
    __syncthreads();
    if (t < 48) {
        float s = m1b[t];
        for (int i = 0; i < 33; ++i) s += v[i] * m1w[i * 48 + t];
        h1[t] = tanhf(s);
    }
    __syncthreads();
    if (t < 16) {
        float s = m2b[t];
        for (int i = 0; i < 48; ++i) s += h1[i] * m2w[i * 16 + t];
        h2[t] = tanhf(s);
    }
    __syncthreads();
    if (t == 0) {
        float s = m3b[0];
        for (int i = 0; i < 16; ++i) s += h2[i] * m3w[i];
        float s1 = 1.0f / (1.0f + expf(-s));
        out[0] = 1.0f / (1.0f + expf(-s1));
    }
}

static inline int cdiv(long long a, long long b) { return (int)((a + b - 1) / b); }

extern "C" void kernel_launch(void* const* d_in, const int* in_sizes, int n_in,
                              void* d_out, int out_size, void* d_ws, size_t ws_size,
                              hipStream_t stream)
{
    (void)in_sizes; (void)n_in; (void)out_size;
    const float* h     = (const float*)d_in[0];
    const int*   eidx  = (const int*)d_in[1];
    const int*   seidx = (const int*)d_in[2];
    const float* Wl_a  = (const float*)d_in[3];
    const float* Wr_a  = (const float*)d_in[4];
    const float* bl_a  = (const float*)d_in[5];
    const float* Wl_s  = (const float*)d_in[6];
    const float* Wr_s  = (const float*)d_in[7];
    const float* bl_s  = (const float*)d_in[8];
    const float* gate_w = (const float*)d_in[9];
    const float* p_wrel = (const float*)d_in[11];
    const float* p_brel = (const float*)d_in[12];
    const float* p_wroot= (const float*)d_in[13];
    const float* nw    = (const float*)d_in[14];
    const float* nb    = (const float*)d_in[15];
    const float* nms   = (const float*)d_in[16];
    const float* lin_w = (const float*)d_in[17];
    const float* lin_b = (const float*)d_in[18];
    const float* m1w   = (const float*)d_in[19];
    const float* m1b   = (const float*)d_in[20];
    const float* m2w   = (const float*)d_in[21];
    const float* m2b   = (const float*)d_in[22];
    const float* m3w   = (const float*)d_in[23];
    const float* m3b   = (const float*)d_in[24];
    float* out = (float*)d_out;

    const int* esrc = eidx;
    const int* edst = eidx + EG;
    const int* ssrc = seidx;
    const int* sdst = seidx + ES_TOT;

    // per-chunk-width workspace need (4B elems)
    auto need_bytes = [](int chp) -> size_t {
        long long chn = (long long)chp * NN;
        long long f = 2 * chn * 128             // XA, XB
                    + 3LL * NN * 128            // xa, xb, zself
                    + NN * 16 + NN              // agg1, deg1
                    + 7 * chn                   // tbuf, rootd, score, nal, fvec, gdot, gbuf
                    + 64 + 33 * 384 + 256       // invp, ro, stats
                    + (NN + (NN+1) + NN + EG + NN + 1024)      // s1 cnt/rp/cur/col/part/bsum
                    + (PN + (PN+1) + PN + ES_TOT + PN + 1024)  // s2 same
                    + 64 * 40;                  // align slack
        return (size_t)f * 4;
    };
    int chp = 8;
    if (ws_size >= need_bytes(32)) chp = 32;
    else if (ws_size >= need_bytes(16)) chp = 16;
    int nch = PP / chp;
    long long ch_n = (long long)chp * NN;

    float* W = (float*)d_ws;
    size_t off = 0;
    auto alloc = [&](size_t nf) { float* p = W + off; off += (nf + 63) & ~(size_t)63; return p; };
    float* XA    = alloc((size_t)ch_n * DD);
    float* XB    = alloc((size_t)ch_n * DD);
    float* xa    = alloc((size_t)NN * DD);
    float* xb    = alloc((size_t)NN * DD);
    float* zself = alloc((size_t)NN * DD);
    float* agg1  = alloc((size_t)NN * 16);
    float* deg1  = alloc(NN);
    float* tbuf  = alloc(ch_n);
    float* rootd = alloc(ch_n);
    float* score = alloc(ch_n);
    float* nal   = alloc(ch_n);
    float* fvec  = alloc(ch_n);
    float* gdot  = alloc(ch_n);
    float* gbuf  = alloc(ch_n);
    float* invp  = alloc(64);
    float* ro    = alloc(33 * 384);
    float* musum = alloc(128);
    float* sqsum = alloc(128);
    int* s1cnt  = (int*)alloc(NN);
    int* s1rp   = (int*)alloc(NN + 1);
    int* s1cur  = (int*)alloc(NN);
    int* s1col  = (int*)alloc(EG);
    int* s1part = (int*)alloc(NN);
    int* s1bsum = (int*)alloc(1024);
    int* s2cnt  = (int*)alloc(PN);
    int* s2rp   = (int*)alloc(PN + 1);
    int* s2cur  = (int*)alloc(PN);
    int* s2col  = (int*)alloc(ES_TOT);
    int* s2part = (int*)alloc(PN);
    int* s2bsum = (int*)alloc(1024);

    // ---------- CSR builds ----------
    int nb1 = cdiv(NN, 1024), nb2 = cdiv(PN, 1024);
    hipMemsetAsync(s1cnt, 0, NN * sizeof(int), stream);
    k_hist<<<cdiv(EG,256),256,0,stream>>>(edst, s1cnt, EG);
    k_scanA<<<nb1,1024,0,stream>>>(s1cnt, s1part, s1bsum, NN);
    k_scanB<<<1,1024,0,stream>>>(s1bsum, nb1);
    k_scanC<<<cdiv(NN,256),256,0,stream>>>(s1part, s1bsum, s1rp, s1cur, NN, EG);
    k_scatter<<<cdiv(EG,256),256,0,stream>>>(esrc, edst, s1cur, s1col, EG);

    hipMemsetAsync(s2cnt, 0, (size_t)PN * sizeof(int), stream);
    k_hist<<<cdiv(ES_TOT,256),256,0,stream>>>(sdst, s2cnt, ES_TOT);
    k_scanA<<<nb2,1024,0,stream>>>(s2cnt, s2part, s2bsum, PN);
    k_scanB<<<1,1024,0,stream>>>(s2bsum, nb2);
    k_scanC<<<cdiv(PN,256),256,0,stream>>>(s2part, s2bsum, s2rp, s2cur, PN, ES_TOT);
    k_scatter<<<cdiv(ES_TOT,256),256,0,stream>>>(ssrc, sdst, s2cur, s2col, ES_TOT);

    hipMemsetAsync(ro, 0, 33 * 384 * sizeof(float), stream);

    // ---------- stage 1 ----------
    k_agg16<<<cdiv((long long)NN*16,256),256,0,stream>>>(h, s1rp, s1col, agg1, deg1, NN);
    k_sage16<<<cdiv((long long)NN*DD,256),256,0,stream>>>(h, agg1, deg1, Wl_a, Wr_a, bl_a, xa, NN);
    k_gate<<<cdiv(NN,256),256,0,stream>>>(xa, gate_w + 0*DD, gbuf, NN);
    k_smstats<<<1,1024,0,stream>>>(gbuf, invp);
    k_wsum<<<BPG,128,0,stream>>>(xa, gbuf, (const float*)nullptr, invp, ro, 0, 0);

    hipMemsetAsync(musum, 0, 128*sizeof(float), stream);
    hipMemsetAsync(sqsum, 0, 128*sizeof(float), stream);
    k_colstat<<<cdiv(NN,64),128,0,stream>>>(xa, musum, sqsum, NN);
    k_gnorm_apply<<<cdiv((long long)NN*DD,256),256,0,stream>>>(xa, xb, musum, sqsum, nw, nb, nms, NN);

    // layer b (mode 0; gate dot in epilogue -> gbuf)
    k_sage_f<<<cdiv(NN,128),256,0,stream>>>(xb, s1rp, s1col, nullptr, nullptr, 0, 0, 0,
        Wl_s + 0*16384, Wr_s + 0*16384, bl_s + 0*128, nullptr, xa, NN,
        nullptr, nullptr, gate_w + 1*DD, nullptr, nullptr, gbuf);
    k_smstats<<<1,1024,0,stream>>>(gbuf, invp);
    k_wsum<<<BPG,128,0,stream>>>(xa, gbuf, (const float*)nullptr, invp, ro, 0, 128);

    hipMemsetAsync(musum, 0, 128*sizeof(float), stream);
    hipMemsetAsync(sqsum, 0, 128*sizeof(float), stream);
    k_colstat<<<cdiv(NN,64),128,0,stream>>>(xa, musum, sqsum, NN);
    k_gnorm_apply<<<cdiv((long long)NN*DD,256),256,0,stream>>>(xa, xb, musum, sqsum, nw, nb, nms, NN);

    // layer c -> xa = x_c
    k_sage_f<<<cdiv(NN,128),256,0,stream>>>(xb, s1rp, s1col, nullptr, nullptr, 0, 0, 0,
        Wl_s + 1*16384, Wr_s + 1*16384, bl_s + 1*128, nullptr, xa, NN,
        nullptr, nullptr, gate_w + 2*DD, nullptr, nullptr, gbuf);
    k_smstats<<<1,1024,0,stream>>>(gbuf, invp);
    k_wsum<<<BPG,128,0,stream>>>(xa, gbuf, (const float*)nullptr, invp, ro, 0, 256);

    // ---------- stage 2 ----------
    // zself for layer 0 (shared by all pathways): xa @ Wr2 + bl2
    k_gemm_self<<<cdiv(NN,128),256,0,stream>>>(xa, Wr_s + 2*16384, bl_s + 2*128, zself, NN);

    for (int c = 0; c < nch; ++c) {
        int nbase = (int)(c * ch_n);
        k_fill<<<cdiv(ch_n,256),256,0,stream>>>(nal, 1.0f, (int)ch_n);

        float* Xbufs[3] = {XA, XB, XA};   // layer i reads Xbufs[i-1] (i>0), writes Xbufs[i]... pattern below
        for (int layer = 0; layer < 3; ++layer) {
            const float* Wl = Wl_s + (2 + layer) * 16384;
            const float* Wr = Wr_s + (2 + layer) * 16384;
            const float* bl = bl_s + (2 + layer) * 128;
            int kkeep = (layer == 0) ? KK1 : (layer == 1) ? KK2 : KK3;
            int gi = 3 + layer;
            float* Ycur = Xbufs[layer];

            if (layer == 0) {
                k_sage_f<<<(int)(ch_n/128),256,0,stream>>>(xa, s2rp, s2col, nullptr, nullptr, 1, 1, nbase,
                    Wl, nullptr, nullptr, zself, Ycur, (int)ch_n,
                    p_wrel + layer*DD, p_wroot + layer*DD, gate_w + gi*DD, tbuf, rootd, gdot);
            } else {
                float* Xprev = Xbufs[layer - 1];
                k_sage_f<<<(int)(ch_n/128),256,0,stream>>>(Xprev, s2rp, s2col, nal, fvec, 2, 0, nbase,
                    Wl, Wr, bl, nullptr, Ycur, (int)ch_n,
                    p_wrel + layer*DD, p_wroot + layer*DD, gate_w + gi*DD, tbuf, rootd, gdot);
            }
            k_topk<<<chp,256,0,stream>>>(s2rp, s2col, nbase, tbuf, rootd, p_brel, layer, score, nal, kkeep);
            k_fvec<<<cdiv(ch_n,256),256,0,stream>>>(score, nal, gdot, fvec, gbuf, (int)ch_n);
            k_smstats<<<chp,1024,0,stream>>>(gbuf, invp);
            k_wsum<<<chp*BPG,128,0,stream>>>(Ycur, gbuf, fvec, invp, ro, 1 + c*chp, layer*128);
        }
    }

    // ---------- head ----------
    k_head<<<1,64,0,stream>>>(ro, lin_w, lin_b, m1w, m1b, m2w, m2b, m3w, m3b, out);
}

// Round 8
// 2125.492 us; speedup vs baseline: 1.2363x; 1.0075x over previous
//
#include <hip/hip_runtime.h>
#include <math.h>

#define NN      8000
#define PP      32
#define EG      128000
#define ES_TOT  131072     // P * 4096
#define ES_P    4096
#define PN      256000     // P * NN
#define DI      16
#define DD      128
#define KK1     6400
#define KK2     5120
#define KK3     4096
#define RB      64                   // rows per wsum block
#define BPG     (NN / RB)            // 125 blocks per graph (stage-1 wsum)

static __device__ __forceinline__ unsigned fkey(float f) {
    unsigned u = __float_as_uint(f);
    return (u & 0x80000000u) ? ~u : (u | 0x80000000u);
}
static __device__ __forceinline__ float fkey_inv(unsigned k) {
    unsigned u = (k & 0x80000000u) ? (k & 0x7FFFFFFFu) : ~k;
    return __uint_as_float(u);
}

__global__ void k_fill(float* p, float v, int n) {
    int i = blockIdx.x * 256 + threadIdx.x;
    if (i < n) p[i] = v;
}

// ---------------- CSR build ----------------
__global__ void k_hist(const int* __restrict__ dst, int* __restrict__ cnt, int ne) {
    int e = blockIdx.x * 256 + threadIdx.x;
    if (e < ne) atomicAdd(&cnt[dst[e]], 1);
}

__global__ __launch_bounds__(1024) void k_scanA(const int* __restrict__ cnt,
                                                int* __restrict__ part,
                                                int* __restrict__ bsum, int n) {
    __shared__ int sh[1024];
    int t = threadIdx.x;
    int i = blockIdx.x * 1024 + t;
    int v = (i < n) ? cnt[i] : 0;
    sh[t] = v; __syncthreads();
    for (int off = 1; off < 1024; off <<= 1) {
        int u = (t >= off) ? sh[t - off] : 0;
        __syncthreads();
        sh[t] += u;
        __syncthreads();
    }
    if (i < n) part[i] = sh[t] - v;
    if (t == 1023) bsum[blockIdx.x] = sh[1023];
}

__global__ __launch_bounds__(1024) void k_scanB(int* __restrict__ bsum, int nb) {
    __shared__ int sh[1024];
    int t = threadIdx.x;
    int v = (t < nb) ? bsum[t] : 0;
    sh[t] = v; __syncthreads();
    for (int off = 1; off < 1024; off <<= 1) {
        int u = (t >= off) ? sh[t - off] : 0;
        __syncthreads();
        sh[t] += u;
        __syncthreads();
    }
    if (t < nb) bsum[t] = sh[t] - v;   // exclusive
}

__global__ void k_scanC(const int* __restrict__ part, const int* __restrict__ bsum,
                        int* __restrict__ rowptr, int* __restrict__ cursor, int n, int total) {
    int i = blockIdx.x * 256 + threadIdx.x;
    if (i < n) {
        int v = part[i] + bsum[i >> 10];
        rowptr[i] = v;
        cursor[i] = v;
    }
    if (i == 0) rowptr[n] = total;
}

__global__ void k_scatter(const int* __restrict__ src, const int* __restrict__ dst,
                          int* __restrict__ cursor, int* __restrict__ col, int ne) {
    int e = blockIdx.x * 256 + threadIdx.x;
    if (e >= ne) return;
    int pos = atomicAdd(&cursor[dst[e]], 1);
    col[pos] = src[e];
}

// ---------------- stage-1 layer a ----------------
__global__ __launch_bounds__(256) void k_agg16(const float* __restrict__ h,
                                               const int* __restrict__ rowptr,
                                               const int* __restrict__ col,
                                               float* __restrict__ agg, float* __restrict__ deg,
                                               int nrows) {
    int i = blockIdx.x * 256 + threadIdx.x;
    int r = i >> 4, j = i & 15;
    if (r >= nrows) return;
    int b = rowptr[r], e = rowptr[r + 1];
    float a = h[r * 16 + j];
    for (int q = b; q < e; ++q) a += h[col[q] * 16 + j];
    agg[r * 16 + j] = a;
    if (j == 0) deg[r] = 1.0f + (float)(e - b);
}

__global__ __launch_bounds__(256) void k_sage16(
    const float* __restrict__ h, const float* __restrict__ agg, const float* __restrict__ deg,
    const float* __restrict__ Wl, const float* __restrict__ Wr, const float* __restrict__ bl,
    float* __restrict__ y, int nrows)
{
    __shared__ float WlS[16][128], WrS[16][128];
    int tid = threadIdx.x;
    for (int i = tid; i < 16 * 128; i += 256) {
        WlS[i >> 7][i & 127] = Wl[i];
        WrS[i >> 7][i & 127] = Wr[i];
    }
    __syncthreads();
    long long o = (long long)blockIdx.x * 256 + tid;
    int row = (int)(o >> 7);
    if (row >= nrows) return;
    int d = (int)o & 127;
    float invd = 1.0f / fmaxf(deg[row], 1.0f);
    float s = bl[d];
    #pragma unroll
    for (int k = 0; k < 16; ++k)
        s += agg[row * 16 + k] * invd * WlS[k][d] + h[row * 16 + k] * WrS[k][d];
    y[(long long)row * 128 + d] = tanhf(s);
}

// ---------------- zself GEMM: y = x@W + b ----------------
__global__ __launch_bounds__(256) void k_gemm_self(
    const float* __restrict__ x, const float* __restrict__ W, const float* __restrict__ b,
    float* __restrict__ y, int nrows)
{
    __shared__ float Ws[32 * 128];
    __shared__ float Is[32][132];
    int tid = threadIdx.x;
    long long row0 = (long long)blockIdx.x * 128;
    int tx = tid & 15, ty = tid >> 4;
    int srow = tid & 127;
    int koff = (tid >> 7) * 16;
    long long lrow = row0 + srow;
    if (lrow >= nrows) lrow = nrows - 1;
    const float* xrow = x + lrow * 128;
    float acc[8][8] = {};
    for (int kb = 0; kb < 4; ++kb) {
        __syncthreads();
        const float* Wsrc = W + kb * 32 * 128;
        #pragma unroll
        for (int j = 0; j < 4; ++j) {
            int fl = j * 1024 + tid * 4;
            *reinterpret_cast<float4*>(&Ws[fl]) = *reinterpret_cast<const float4*>(&Wsrc[fl]);
        }
        {
            const float* sp = xrow + kb * 32 + koff;
            #pragma unroll
            for (int q = 0; q < 4; ++q) {
                float4 v = *reinterpret_cast<const float4*>(sp + q * 4);
                Is[koff + q*4    ][srow] = v.x;
                Is[koff + q*4 + 1][srow] = v.y;
                Is[koff + q*4 + 2][srow] = v.z;
                Is[koff + q*4 + 3][srow] = v.w;
            }
        }
        __syncthreads();
        #pragma unroll
        for (int kk = 0; kk < 32; ++kk) {
            float4 w0 = *reinterpret_cast<const float4*>(&Ws[kk * 128 + tx * 4]);
            float4 w1 = *reinterpret_cast<const float4*>(&Ws[kk * 128 + tx * 4 + 64]);
            float4 i0 = *reinterpret_cast<const float4*>(&Is[kk][ty * 8]);
            float4 i1 = *reinterpret_cast<const float4*>(&Is[kk][ty * 8 + 4]);
            float ia[8] = {i0.x, i0.y, i0.z, i0.w, i1.x, i1.y, i1.z, i1.w};
            float wa[8] = {w0.x, w0.y, w0.z, w0.w, w1.x, w1.y, w1.z, w1.w};
            #pragma unroll
            for (int i = 0; i < 8; ++i)
                #pragma unroll
                for (int j = 0; j < 8; ++j)
                    acc[i][j] += ia[i] * wa[j];
        }
    }
    float4 b0 = *reinterpret_cast<const float4*>(&b[tx * 4]);
    float4 b1 = *reinterpret_cast<const float4*>(&b[tx * 4 + 64]);
    #pragma unroll
    for (int i = 0; i < 8; ++i) {
        long long row = row0 + ty * 8 + i;
        if (row >= nrows) continue;
        *reinterpret_cast<float4*>(&y[row * 128 + tx * 4]) =
            make_float4(acc[i][0] + b0.x, acc[i][1] + b0.y, acc[i][2] + b0.z, acc[i][3] + b0.w);
        *reinterpret_cast<float4*>(&y[row * 128 + tx * 4 + 64]) =
            make_float4(acc[i][4] + b1.x, acc[i][5] + b1.y, acc[i][6] + b1.z, acc[i][7] + b1.w);
    }
}

// ---------------- fused SAGE GEMM ----------------
// mode 0 (stage-1): selfloop in agg+deg, K=256, bias=bl.
// mode 1 (s2 L0):   K=128 agg-only (Wl), deg=edge count, epilogue adds zself[row%NN].
// mode 2 (s2 L1/2): K=256, inputs weighted by fvec, deg=sum nal, bias=bl;
//                   aliveIdx compaction: block rows = aliveIdx[row0..row0+127].
__global__ __launch_bounds__(256) void k_sage_f(
    const float* __restrict__ x,
    const int* __restrict__ rowptr, const int* __restrict__ col,
    const float* __restrict__ nal, const float* __restrict__ fvec,
    const int* __restrict__ aliveIdx,
    int mode, int xModN, int rowbase,
    const float* __restrict__ Wl, const float* __restrict__ Wr, const float* __restrict__ bl,
    const float* __restrict__ zself,
    float* __restrict__ y, int nrows,
    const float* __restrict__ wrel, const float* __restrict__ wroot, const float* __restrict__ gw,
    float* __restrict__ tbuf, float* __restrict__ rootd, float* __restrict__ gdot)
{
    __shared__ float Ws[32 * 128];
    __shared__ float Is[32][132];
    __shared__ float wrelS[128], wrootS[128], gwS[128];
    __shared__ int rowIdxS[128];
    int tid = threadIdx.x;
    long long row0 = (long long)blockIdx.x * 128;
    if (tid < 128) {
        if (wrel)  wrelS[tid]  = wrel[tid];
        if (wroot) wrootS[tid] = wroot[tid];
        if (gw)    gwS[tid]    = gw[tid];
        if (aliveIdx) rowIdxS[tid] = aliveIdx[row0 + tid];
    }
    __syncthreads();
    int tx = tid & 15, ty = tid >> 4;
    int srow = tid & 127;
    int koff = (tid >> 7) * 16;
    long long lrow = row0 + srow;
    if (lrow >= nrows) lrow = nrows - 1;     // clamp (modes 0/1 only; mode2 grids exact)
    int orig = aliveIdx ? rowIdxS[srow] : (int)lrow;
    int grow = rowbase + orig;
    int ebeg = rowptr[grow], eend = rowptr[grow + 1];
    const float* xself = x + (long long)((mode == 1) ? 0 : orig) * 128;
    float fself = 1.0f;
    if (mode == 2) fself = fvec[orig];
    float dsum;
    if (mode == 0) dsum = 1.0f + (float)(eend - ebeg);
    else if (mode == 1) dsum = (float)(eend - ebeg);
    else {
        dsum = 0.0f;
        for (int e = ebeg; e < eend; ++e) dsum += nal[col[e] - rowbase];
    }
    float invds = 1.0f / fmaxf(dsum, 1.0f);

    int KB = (mode == 1) ? 4 : 8;
    float acc[8][8] = {};
    for (int kb = 0; kb < KB; ++kb) {
        __syncthreads();
        bool isAgg = (kb < 4);
        const float* Wsrc = isAgg ? (Wl + kb * 32 * 128) : (Wr + (kb - 4) * 32 * 128);
        #pragma unroll
        for (int j = 0; j < 4; ++j) {
            int fl = j * 1024 + tid * 4;
            *reinterpret_cast<float4*>(&Ws[fl]) = *reinterpret_cast<const float4*>(&Wsrc[fl]);
        }
        if (isAgg) {
            float a16[16];
            if (mode == 0) {
                const float* sp = xself + kb * 32 + koff;
                #pragma unroll
                for (int q = 0; q < 4; ++q) {
                    float4 v = *reinterpret_cast<const float4*>(sp + q * 4);
                    a16[q*4] = v.x; a16[q*4+1] = v.y; a16[q*4+2] = v.z; a16[q*4+3] = v.w;
                }
            } else {
                #pragma unroll
                for (int q = 0; q < 16; ++q) a16[q] = 0.0f;
            }
            for (int e = ebeg; e < eend; ++e) {
                int s = col[e];
                int fr;
                float fw = 1.0f;
                if (mode == 2) {
                    fr = s - rowbase;
                    fw = fvec[fr];
                    if (fw == 0.0f) continue;
                } else {
                    fr = xModN ? (s % NN) : (s - rowbase);
                }
                const float* xp = x + (long long)fr * 128 + kb * 32 + koff;
                #pragma unroll
                for (int q = 0; q < 4; ++q) {
                    float4 v = *reinterpret_cast<const float4*>(xp + q * 4);
                    a16[q*4] += v.x * fw; a16[q*4+1] += v.y * fw;
                    a16[q*4+2] += v.z * fw; a16[q*4+3] += v.w * fw;
                }
            }
            #pragma unroll
            for (int q = 0; q < 16; ++q) Is[koff + q][srow] = a16[q] * invds;
        } else {
            const float* sp = xself + (kb - 4) * 32 + koff;
            #pragma unroll
            for (int q = 0; q < 4; ++q) {
                float4 v = *reinterpret_cast<const float4*>(sp + q * 4);
                Is[koff + q*4    ][srow] = v.x * fself;
                Is[koff + q*4 + 1][srow] = v.y * fself;
                Is[koff + q*4 + 2][srow] = v.z * fself;
                Is[koff + q*4 + 3][srow] = v.w * fself;
            }
        }
        __syncthreads();
        #pragma unroll
        for (int kk = 0; kk < 32; ++kk) {
            float4 w0 = *reinterpret_cast<const float4*>(&Ws[kk * 128 + tx * 4]);
            float4 w1 = *reinterpret_cast<const float4*>(&Ws[kk * 128 + tx * 4 + 64]);
            float4 i0 = *reinterpret_cast<const float4*>(&Is[kk][ty * 8]);
            float4 i1 = *reinterpret_cast<const float4*>(&Is[kk][ty * 8 + 4]);
            float ia[8] = {i0.x, i0.y, i0.z, i0.w, i1.x, i1.y, i1.z, i1.w};
            float wa[8] = {w0.x, w0.y, w0.z, w0.w, w1.x, w1.y, w1.z, w1.w};
            #pragma unroll
            for (int i = 0; i < 8; ++i)
                #pragma unroll
                for (int j = 0; j < 8; ++j)
                    acc[i][j] += ia[i] * wa[j];
        }
    }
    float br[8];
    if (mode != 1) {
        float4 bl0 = *reinterpret_cast<const float4*>(&bl[tx * 4]);
        float4 bl1 = *reinterpret_cast<const float4*>(&bl[tx * 4 + 64]);
        br[0]=bl0.x; br[1]=bl0.y; br[2]=bl0.z; br[3]=bl0.w;
        br[4]=bl1.x; br[5]=bl1.y; br[6]=bl1.z; br[7]=bl1.w;
    }
    #pragma unroll
    for (int i = 0; i < 8; ++i) {
        long long crow = row0 + ty * 8 + i;
        bool valid = (crow < nrows);
        int rout = aliveIdx ? rowIdxS[ty * 8 + i] : (int)crow;
        float zr[8];
        if (mode == 1) {
            const float* zp = zself + (long long)(rout % NN) * 128;
            float4 z0 = *reinterpret_cast<const float4*>(&zp[tx * 4]);
            float4 z1 = *reinterpret_cast<const float4*>(&zp[tx * 4 + 64]);
            zr[0]=z0.x; zr[1]=z0.y; zr[2]=z0.z; zr[3]=z0.w;
            zr[4]=z1.x; zr[5]=z1.y; zr[6]=z1.z; zr[7]=z1.w;
        } else {
            #pragma unroll
            for (int j = 0; j < 8; ++j) zr[j] = br[j];
        }
        float yv[8];
        #pragma unroll
        for (int j = 0; j < 8; ++j) yv[j] = tanhf(acc[i][j] + zr[j]);
        if (valid) {
            *reinterpret_cast<float4*>(&y[(long long)rout * 128 + tx * 4]) = make_float4(yv[0], yv[1], yv[2], yv[3]);
            *reinterpret_cast<float4*>(&y[(long long)rout * 128 + tx * 4 + 64]) = make_float4(yv[4], yv[5], yv[6], yv[7]);
        }
        float tp = 0.0f, rp = 0.0f, gp = 0.0f;
        #pragma unroll
        for (int j = 0; j < 4; ++j) {
            if (tbuf)  tp += yv[j] * wrelS[tx*4 + j]  + yv[j+4] * wrelS[tx*4 + 64 + j];
            if (rootd) rp += yv[j] * wrootS[tx*4 + j] + yv[j+4] * wrootS[tx*4 + 64 + j];
            if (gdot)  gp += yv[j] * gwS[tx*4 + j]    + yv[j+4] * gwS[tx*4 + 64 + j];
        }
        #pragma unroll
        for (int m = 8; m >= 1; m >>= 1) {
            if (tbuf)  tp += __shfl_xor(tp, m, 16);
            if (rootd) rp += __shfl_xor(rp, m, 16);
            if (gdot)  gp += __shfl_xor(gp, m, 16);
        }
        if (tx == 0 && valid) {
            if (tbuf)  tbuf[rout]  = tp;
            if (rootd) rootd[rout] = rp;
            if (gdot)  gdot[rout]  = gp;
        }
    }
}

// ---------------- stage-1 readout pieces ----------------
__global__ __launch_bounds__(256) void k_gate(
    const float* __restrict__ X, const float* __restrict__ gw,
    float* __restrict__ g, int nrows)
{
    __shared__ float wS[128];
    if (threadIdx.x < 128) wS[threadIdx.x] = gw[threadIdx.x];
    __syncthreads();
    int i = blockIdx.x * 256 + threadIdx.x;
    if (i >= nrows) return;
    const float4* xrp = reinterpret_cast<const float4*>(X + (long long)i * 128);
    float s = 0.0f;
    #pragma unroll
    for (int k = 0; k < 32; ++k) {
        float4 v = xrp[k];
        s += v.x * wS[4*k] + v.y * wS[4*k+1] + v.z * wS[4*k+2] + v.w * wS[4*k+3];
    }
    g[i] = s;
}

__global__ __launch_bounds__(1024) void k_smstats(float* __restrict__ g, float* __restrict__ invp) {
    __shared__ float red[1024];
    int p = blockIdx.x, tid = threadIdx.x;
    float* gp = g + (long long)p * NN;
    float lmax = -INFINITY;
    for (int n = tid; n < NN; n += 1024) lmax = fmaxf(lmax, gp[n]);
    red[tid] = lmax; __syncthreads();
    for (int s = 512; s > 0; s >>= 1) { if (tid < s) red[tid] = fmaxf(red[tid], red[tid + s]); __syncthreads(); }
    float mx = red[0]; __syncthreads();
    float ls = 0.0f;
    for (int n = tid; n < NN; n += 1024) { float e = expf(gp[n] - mx); gp[n] = e; ls += e; }
    red[tid] = ls; __syncthreads();
    for (int s = 512; s > 0; s >>= 1) { if (tid < s) red[tid] += red[tid + s]; __syncthreads(); }
    if (tid == 0) invp[p] = 1.0f / red[0];
}

__global__ __launch_bounds__(128) void k_wsum(
    const float* __restrict__ X, const float* __restrict__ a,
    const float* __restrict__ invp, float* __restrict__ ro, int rowbase, int colOff)
{
    int p = blockIdx.x / BPG;
    int chunk = blockIdx.x % BPG;
    int d = threadIdx.x;
    long long base = (long long)p * NN;
    int r0 = chunk * RB, r1 = r0 + RB;
    float s = 0.0f;
    for (int n = r0; n < r1; ++n) {
        float w = a[base + n];
        if (w != 0.0f) s += w * X[(base + n) * 128 + d];
    }
    atomicAdd(&ro[(long long)(rowbase + p) * 384 + colOff + d], s * invp[p]);
}

// stage-2 weighted sum over alive rows only
__global__ __launch_bounds__(128) void k_wsum_c(
    const float* __restrict__ X, const float* __restrict__ gbuf, const float* __restrict__ fvec,
    const float* __restrict__ invp, const int* __restrict__ aliveIdx, int k,
    float* __restrict__ ro, int rowbaseRo, int colOff)
{
    int bpp = k / RB;
    int p = blockIdx.x / bpp;
    int chunk = blockIdx.x % bpp;
    int d = threadIdx.x;
    const int* ai = aliveIdx + (long long)p * k + chunk * RB;
    float s = 0.0f;
    for (int j = 0; j < RB; ++j) {
        int row = ai[j];
        float w = gbuf[row] * fvec[row];
        s += w * X[(long long)row * 128 + d];
    }
    atomicAdd(&ro[(long long)(rowbaseRo + p) * 384 + colOff + d], s * invp[p]);
}

// ---------------- GraphNorm ----------------
__global__ void k_colstat(const float* __restrict__ x, float* __restrict__ musum,
                          float* __restrict__ sqsum, int nrows) {
    int d = threadIdx.x;
    int r0 = blockIdx.x * 64;
    int r1 = min(r0 + 64, nrows);
    float s = 0.0f, q = 0.0f;
    for (int r = r0; r < r1; ++r) { float v = x[(long long)r * 128 + d]; s += v; q += v * v; }
    atomicAdd(&musum[d], s);
    atomicAdd(&sqsum[d], q);
}

__global__ void k_gnorm_apply(const float* __restrict__ x, float* __restrict__ y,
                              const float* __restrict__ musum, const float* __restrict__ sqsum,
                              const float* __restrict__ w, const float* __restrict__ b,
                              const float* __restrict__ ms, int nrows) {
    long long i = (long long)blockIdx.x * 256 + threadIdx.x;
    if (i >= (long long)nrows * 128) return;
    int d = (int)(i & 127);
    float inv_n = 1.0f / (float)nrows;
    float mu = musum[d] * inv_n;
    float c = mu * ms[d];
    float var = sqsum[d] * inv_n - 2.0f * c * mu + c * c;
    y[i] = w[d] * (x[i] - c) * rsqrtf(var + 1e-5f) + b[d];
}

// ---------------- mega top-k ----------------
// score gather + radix select + nal/fvec + gate softmax stats + alive list.
__global__ __launch_bounds__(256) void k_topk2(
    const int* __restrict__ rowptr, const int* __restrict__ col, int rowbase,
    const float* __restrict__ tb, const float* __restrict__ rootd,
    const float* __restrict__ gdot, const float* __restrict__ brelp, int bi,
    float* __restrict__ nalive, float* __restrict__ fvec, float* __restrict__ gbuf,
    float* __restrict__ invp, int* __restrict__ aliveIdx, int k)
{
    __shared__ unsigned keys[NN];
    __shared__ int hist[256];
    __shared__ int chunkcnt[256];
    __shared__ float redf[256];
    __shared__ unsigned sh_pref;
    __shared__ int sh_kneed;
    int p = blockIdx.x, tid = threadIdx.x;
    float brel = brelp[bi];
    long long pbase = (long long)p * NN;
    for (int n = tid; n < NN; n += 256) {
        long long gl = pbase + n;
        int grow = rowbase + (int)gl;
        float s = brel + rootd[gl];
        int b = rowptr[grow], e = rowptr[grow + 1];
        for (int q = b; q < e; ++q) {
            int sl = col[q] - rowbase;
            s += tb[sl] * nalive[sl];
        }
        keys[n] = (nalive[gl] > 0.5f) ? fkey(s) : 0u;
    }
    if (tid == 0) { sh_pref = 0u; sh_kneed = k; }
    __syncthreads();
    for (int lvl = 3; lvl >= 0; --lvl) {
        int sh = lvl * 8;
        hist[tid] = 0;
        unsigned pref = sh_pref; int kneed = sh_kneed;
        unsigned pmask = (lvl == 3) ? 0u : (0xFFFFFFFFu << (8 * (lvl + 1)));
        __syncthreads();
        for (int n = tid; n < NN; n += 256) {
            unsigned kv = keys[n];
            if ((kv & pmask) == pref) atomicAdd(&hist[(kv >> sh) & 255], 1);
        }
        __syncthreads();
        if (tid == 0) {
            int cum = 0, b = 255;
            for (; b >= 0; --b) { cum += hist[b]; if (cum >= kneed) break; }
            sh_pref = pref | ((unsigned)b << sh);
            sh_kneed = kneed - (cum - hist[b]);
        }
        __syncthreads();
    }
    unsigned V = sh_pref;
    int seleq = sh_kneed;
    int c0 = tid * 32, c1 = min(c0 + 32, NN);
    int ceq = 0;
    for (int n = c0; n < c1; ++n) ceq += (keys[n] == V) ? 1 : 0;
    chunkcnt[tid] = ceq; __syncthreads();
    if (tid == 0) {
        int s = 0;
        for (int i = 0; i < 256; ++i) { int c = chunkcnt[i]; chunkcnt[i] = s; s += c; }
    }
    __syncthreads();
    // Walk A: select, write nal + fvec, track gate max, build selmask
    int rank = chunkcnt[tid];
    unsigned selmask = 0u;
    int nsel = 0;
    float lmax = -INFINITY;
    for (int n = c0; n < c1; ++n) {
        unsigned kk = keys[n];
        bool sel = (kk > V) || (kk == V && rank < seleq);
        if (kk == V) rank++;
        long long gl = pbase + n;
        nalive[gl] = sel ? 1.0f : 0.0f;
        float f = 0.0f;
        if (sel) {
            f = tanhf(fkey_inv(kk));
            lmax = fmaxf(lmax, f * gdot[gl]);
            selmask |= (1u << (n - c0));
            ++nsel;
        }
        fvec[gl] = f;
    }
    redf[tid] = lmax; __syncthreads();
    for (int s = 128; s > 0; s >>= 1) { if (tid < s) redf[tid] = fmaxf(redf[tid], redf[tid + s]); __syncthreads(); }
    float mx = redf[0]; __syncthreads();
    chunkcnt[tid] = nsel; __syncthreads();
    if (tid == 0) {
        int s = 0;
        for (int i = 0; i < 256; ++i) { int c = chunkcnt[i]; chunkcnt[i] = s; s += c; }
    }
    __syncthreads();
    // Walk B: exp + sum + alive list
    int pos = chunkcnt[tid];
    float lsum = 0.0f;
    for (int n = c0; n < c1; ++n) {
        if (selmask & (1u << (n - c0))) {
            long long gl = pbase + n;
            float e = expf(fvec[gl] * gdot[gl] - mx);
            gbuf[gl] = e;
            lsum += e;
            aliveIdx[(long long)p * k + pos] = (int)gl;
            ++pos;
        }
    }
    redf[tid] = lsum; __syncthreads();
    for (int s = 128; s > 0; s >>= 1) { if (tid < s) redf[tid] += redf[tid + s]; __syncthreads(); }
    if (tid == 0) invp[p] = 1.0f / redf[0];
}

// ---------------- head ----------------
__global__ __launch_bounds__(64) void k_head(
    const float* __restrict__ ro, const float* __restrict__ lin_w, const float* __restrict__ lin_b,
    const float* __restrict__ m1w, const float* __restrict__ m1b,
    const float* __restrict__ m2w, const float* __restrict__ m2b,
    const float* __restrict__ m3w, const float* __restrict__ m3b, float* __restrict__ out)
{
    __shared__ float v[33], h1[48], h2[16];
    int t = threadIdx.x;
    if (t < 33) {
        float s = lin_b[0];
        for (int k = 0; k < 384; ++k) s += ro[t * 384 + k] * lin_w[k];
        v[t] = tanhf(s);
    }
    __syncthreads();
    if (t < 48) {
        float s = m1b[t];
        for (int i = 0; i < 33; ++i) s += v[i] * m1w[i * 48 + t];
        h1[t] = tanhf(s);
    }
    __syncthreads();
    if (t < 16) {
        float s = m2b[t];
        for (int i = 0; i < 48; ++i) s += h1[i] * m2w[i * 16 + t];
        h2[t] = tanhf(s);
    }
    __syncthreads();
    if (t == 0) {
        float s = m3b[0];
        for (int i = 0; i < 16; ++i) s += h2[i] * m3w[i];
        float s1 = 1.0f / (1.0f + expf(-s));
        out[0] = 1.0f / (1.0f + expf(-s1));
    }
}

static inline int cdiv(long long a, long long b) { return (int)((a + b - 1) / b); }

extern "C" void kernel_launch(void* const* d_in, const int* in_sizes, int n_in,
                              void* d_out, int out_size, void* d_ws, size_t ws_size,
                              hipStream_t stream)
{
    (void)in_sizes; (void)n_in; (void)out_size;
    const float* h     = (const float*)d_in[0];
    const int*   eidx  = (const int*)d_in[1];
    const int*   seidx = (const int*)d_in[2];
    const float* Wl_a  = (const float*)d_in[3];
    const float* Wr_a  = (const float*)d_in[4];
    const float* bl_a  = (const float*)d_in[5];
    const float* Wl_s  = (const float*)d_in[6];
    const float* Wr_s  = (const float*)d_in[7];
    const float* bl_s  = (const float*)d_in[8];
    const float* gate_w = (const float*)d_in[9];
    const float* p_wrel = (const float*)d_in[11];
    const float* p_brel = (const float*)d_in[12];
    const float* p_wroot= (const float*)d_in[13];
    const float* nw    = (const float*)d_in[14];
    const float* nb    = (const float*)d_in[15];
    const float* nms   = (const float*)d_in[16];
    const float* lin_w = (const float*)d_in[17];
    const float* lin_b = (const float*)d_in[18];
    const float* m1w   = (const float*)d_in[19];
    const float* m1b   = (const float*)d_in[20];
    const float* m2w   = (const float*)d_in[21];
    const float* m2b   = (const float*)d_in[22];
    const float* m3w   = (const float*)d_in[23];
    const float* m3b   = (const float*)d_in[24];
    float* out = (float*)d_out;

    const int* esrc = eidx;
    const int* edst = eidx + EG;
    const int* ssrc = seidx;
    const int* sdst = seidx + ES_TOT;

    auto need_bytes = [](int chp) -> size_t {
        long long chn = (long long)chp * NN;
        long long f = 2 * chn * 128
                    + 3LL * NN * 128
                    + NN * 16 + NN
                    + 6 * chn                   // tbuf, rootd, nal, fvec, gdot, gbuf
                    + (long long)chp * KK1      // aliveIdx
                    + 64 + 33 * 384 + 256
                    + (NN + (NN+1) + NN + EG + NN + 1024)
                    + (PN + (PN+1) + PN + ES_TOT + PN + 1024)
                    + 64 * 48;
        return (size_t)f * 4;
    };
    int chp = 8;
    if (ws_size >= need_bytes(32)) chp = 32;
    else if (ws_size >= need_bytes(16)) chp = 16;
    int nch = PP / chp;
    long long ch_n = (long long)chp * NN;

    float* W = (float*)d_ws;
    size_t off = 0;
    auto alloc = [&](size_t nf) { float* p = W + off; off += (nf + 63) & ~(size_t)63; return p; };
    float* XA    = alloc((size_t)ch_n * DD);
    float* XB    = alloc((size_t)ch_n * DD);
    float* xa    = alloc((size_t)NN * DD);
    float* xb    = alloc((size_t)NN * DD);
    float* zself = alloc((size_t)NN * DD);
    float* agg1  = alloc((size_t)NN * 16);
    float* deg1  = alloc(NN);
    float* tbuf  = alloc(ch_n);
    float* rootd = alloc(ch_n);
    float* nal   = alloc(ch_n);
    float* fvec  = alloc(ch_n);
    float* gdot  = alloc(ch_n);
    float* gbuf  = alloc(ch_n);
    float* invp  = alloc(64);
    float* ro    = alloc(33 * 384);
    float* musum = alloc(128);
    float* sqsum = alloc(128);
    int* aliveIdx = (int*)alloc((size_t)chp * KK1);
    int* s1cnt  = (int*)alloc(NN);
    int* s1rp   = (int*)alloc(NN + 1);
    int* s1cur  = (int*)alloc(NN);
    int* s1col  = (int*)alloc(EG);
    int* s1part = (int*)alloc(NN);
    int* s1bsum = (int*)alloc(1024);
    int* s2cnt  = (int*)alloc(PN);
    int* s2rp   = (int*)alloc(PN + 1);
    int* s2cur  = (int*)alloc(PN);
    int* s2col  = (int*)alloc(ES_TOT);
    int* s2part = (int*)alloc(PN);
    int* s2bsum = (int*)alloc(1024);

    // ---------- CSR builds ----------
    int nb1 = cdiv(NN, 1024), nb2 = cdiv(PN, 1024);
    hipMemsetAsync(s1cnt, 0, NN * sizeof(int), stream);
    k_hist<<<cdiv(EG,256),256,0,stream>>>(edst, s1cnt, EG);
    k_scanA<<<nb1,1024,0,stream>>>(s1cnt, s1part, s1bsum, NN);
    k_scanB<<<1,1024,0,stream>>>(s1bsum, nb1);
    k_scanC<<<cdiv(NN,256),256,0,stream>>>(s1part, s1bsum, s1rp, s1cur, NN, EG);
    k_scatter<<<cdiv(EG,256),256,0,stream>>>(esrc, edst, s1cur, s1col, EG);

    hipMemsetAsync(s2cnt, 0, (size_t)PN * sizeof(int), stream);
    k_hist<<<cdiv(ES_TOT,256),256,0,stream>>>(sdst, s2cnt, ES_TOT);
    k_scanA<<<nb2,1024,0,stream>>>(s2cnt, s2part, s2bsum, PN);
    k_scanB<<<1,1024,0,stream>>>(s2bsum, nb2);
    k_scanC<<<cdiv(PN,256),256,0,stream>>>(s2part, s2bsum, s2rp, s2cur, PN, ES_TOT);
    k_scatter<<<cdiv(ES_TOT,256),256,0,stream>>>(ssrc, sdst, s2cur, s2col, ES_TOT);

    hipMemsetAsync(ro, 0, 33 * 384 * sizeof(float), stream);

    // ---------- stage 1 ----------
    k_agg16<<<cdiv((long long)NN*16,256),256,0,stream>>>(h, s1rp, s1col, agg1, deg1, NN);
    k_sage16<<<cdiv((long long)NN*DD,256),256,0,stream>>>(h, agg1, deg1, Wl_a, Wr_a, bl_a, xa, NN);
    k_gate<<<cdiv(NN,256),256,0,stream>>>(xa, gate_w + 0*DD, gbuf, NN);
    k_smstats<<<1,1024,0,stream>>>(gbuf, invp);
    k_wsum<<<BPG,128,0,stream>>>(xa, gbuf, invp, ro, 0, 0);

    hipMemsetAsync(musum, 0, 128*sizeof(float), stream);
    hipMemsetAsync(sqsum, 0, 128*sizeof(float), stream);
    k_colstat<<<cdiv(NN,64),128,0,stream>>>(xa, musum, sqsum, NN);
    k_gnorm_apply<<<cdiv((long long)NN*DD,256),256,0,stream>>>(xa, xb, musum, sqsum, nw, nb, nms, NN);

    k_sage_f<<<cdiv(NN,128),256,0,stream>>>(xb, s1rp, s1col, nullptr, nullptr, nullptr, 0, 0, 0,
        Wl_s + 0*16384, Wr_s + 0*16384, bl_s + 0*128, nullptr, xa, NN,
        nullptr, nullptr, gate_w + 1*DD, nullptr, nullptr, gbuf);
    k_smstats<<<1,1024,0,stream>>>(gbuf, invp);
    k_wsum<<<BPG,128,0,stream>>>(xa, gbuf, invp, ro, 0, 128);

    hipMemsetAsync(musum, 0, 128*sizeof(float), stream);
    hipMemsetAsync(sqsum, 0, 128*sizeof(float), stream);
    k_colstat<<<cdiv(NN,64),128,0,stream>>>(xa, musum, sqsum, NN);
    k_gnorm_apply<<<cdiv((long long)NN*DD,256),256,0,stream>>>(xa, xb, musum, sqsum, nw, nb, nms, NN);

    k_sage_f<<<cdiv(NN,128),256,0,stream>>>(xb, s1rp, s1col, nullptr, nullptr, nullptr, 0, 0, 0,
        Wl_s + 1*16384, Wr_s + 1*16384, bl_s + 1*128, nullptr, xa, NN,
        nullptr, nullptr, gate_w + 2*DD, nullptr, nullptr, gbuf);
    k_smstats<<<1,1024,0,stream>>>(gbuf, invp);
    k_wsum<<<BPG,128,0,stream>>>(xa, gbuf, invp, ro, 0, 256);

    // ---------- stage 2 ----------
    k_gemm_self<<<cdiv(NN,128),256,0,stream>>>(xa, Wr_s + 2*16384, bl_s + 2*128, zself, NN);

    for (int c = 0; c < nch; ++c) {
        int nbase = (int)(c * ch_n);
        k_fill<<<cdiv(ch_n,256),256,0,stream>>>(nal, 1.0f, (int)ch_n);

        // ---- layer 0: all rows ----
        k_sage_f<<<(int)(ch_n/128),256,0,stream>>>(xa, s2rp, s2col, nullptr, nullptr, nullptr, 1, 1, nbase,
            Wl_s + 2*16384, nullptr, nullptr, zself, XA, (int)ch_n,
            p_wrel + 0*DD, p_wroot + 0*DD, gate_w + 3*DD, tbuf, rootd, gdot);
        k_topk2<<<chp,256,0,stream>>>(s2rp, s2col, nbase, tbuf, rootd, gdot, p_brel, 0,
                                      nal, fvec, gbuf, invp, aliveIdx, KK1);
        k_wsum_c<<<chp*(KK1/RB),128,0,stream>>>(XA, gbuf, fvec, invp, aliveIdx, KK1, ro, 1 + c*chp, 0);

        // ---- layer 1: alive K1 rows ----
        k_sage_f<<<chp*(KK1/128),256,0,stream>>>(XA, s2rp, s2col, nal, fvec, aliveIdx, 2, 0, nbase,
            Wl_s + 3*16384, Wr_s + 3*16384, bl_s + 3*128, nullptr, XB, chp*KK1,
            p_wrel + 1*DD, p_wroot + 1*DD, gate_w + 4*DD, tbuf, rootd, gdot);
        k_topk2<<<chp,256,0,stream>>>(s2rp, s2col, nbase, tbuf, rootd, gdot, p_brel, 1,
                                      nal, fvec, gbuf, invp, aliveIdx, KK2);
        k_wsum_c<<<chp*(KK2/RB),128,0,stream>>>(XB, gbuf, fvec, invp, aliveIdx, KK2, ro, 1 + c*chp, 128);

        // ---- layer 2: alive K2 rows ----
        k_sage_f<<<chp*(KK2/128),256,0,stream>>>(XB, s2rp, s2col, nal, fvec, aliveIdx, 2, 0, nbase,
            Wl_s + 4*16384, Wr_s + 4*16384, bl_s + 4*128, nullptr, XA, chp*KK2,
            p_wrel + 2*DD, p_wroot + 2*DD, gate_w + 5*DD, tbuf, rootd, gdot);
        k_topk2<<<chp,256,0,stream>>>(s2rp, s2col, nbase, tbuf, rootd, gdot, p_brel, 2,
                                      nal, fvec, gbuf, invp, aliveIdx, KK3);
        k_wsum_c<<<chp*(KK3/RB),128,0,stream>>>(XA, gbuf, fvec, invp, aliveIdx, KK3, ro, 1 + c*chp, 256);
    }

    // ---------- head ----------
    k_head<<<1,64,0,stream>>>(ro, lin_w, lin_b, m1w, m1b, m2w, m2b, m3w, m3b, out);
}

// Round 9
// 2069.183 us; speedup vs baseline: 1.2700x; 1.0272x over previous
//
#include <hip/hip_runtime.h>
#include <math.h>

#define NN      8000
#define PP      32
#define EG      128000
#define ES_TOT  131072     // P * 4096
#define ES_P    4096
#define PN      256000     // P * NN
#define DI      16
#define DD      128
#define KK1     6400
#define KK2     5120
#define KK3     4096
#define RB      64                   // rows per wsum block
#define BPG     (NN / RB)            // 125 blocks per graph (stage-1 wsum)

static __device__ __forceinline__ unsigned fkey(float f) {
    unsigned u = __float_as_uint(f);
    return (u & 0x80000000u) ? ~u : (u | 0x80000000u);
}
static __device__ __forceinline__ float fkey_inv(unsigned k) {
    unsigned u = (k & 0x80000000u) ? (k & 0x7FFFFFFFu) : ~k;
    return __uint_as_float(u);
}

__global__ void k_fill(float* p, float v, int n) {
    int i = blockIdx.x * 256 + threadIdx.x;
    if (i < n) p[i] = v;
}

// ---------------- CSR build ----------------
__global__ void k_hist(const int* __restrict__ dst, int* __restrict__ cnt, int ne) {
    int e = blockIdx.x * 256 + threadIdx.x;
    if (e < ne) atomicAdd(&cnt[dst[e]], 1);
}

__global__ __launch_bounds__(1024) void k_scanA(const int* __restrict__ cnt,
                                                int* __restrict__ part,
                                                int* __restrict__ bsum, int n) {
    __shared__ int sh[1024];
    int t = threadIdx.x;
    int i = blockIdx.x * 1024 + t;
    int v = (i < n) ? cnt[i] : 0;
    sh[t] = v; __syncthreads();
    for (int off = 1; off < 1024; off <<= 1) {
        int u = (t >= off) ? sh[t - off] : 0;
        __syncthreads();
        sh[t] += u;
        __syncthreads();
    }
    if (i < n) part[i] = sh[t] - v;
    if (t == 1023) bsum[blockIdx.x] = sh[1023];
}

__global__ __launch_bounds__(1024) void k_scanB(int* __restrict__ bsum, int nb) {
    __shared__ int sh[1024];
    int t = threadIdx.x;
    int v = (t < nb) ? bsum[t] : 0;
    sh[t] = v; __syncthreads();
    for (int off = 1; off < 1024; off <<= 1) {
        int u = (t >= off) ? sh[t - off] : 0;
        __syncthreads();
        sh[t] += u;
        __syncthreads();
    }
    if (t < nb) bsum[t] = sh[t] - v;   // exclusive
}

__global__ void k_scanC(const int* __restrict__ part, const int* __restrict__ bsum,
                        int* __restrict__ rowptr, int* __restrict__ cursor, int n, int total) {
    int i = blockIdx.x * 256 + threadIdx.x;
    if (i < n) {
        int v = part[i] + bsum[i >> 10];
        rowptr[i] = v;
        cursor[i] = v;
    }
    if (i == 0) rowptr[n] = total;
}

__global__ void k_scatter(const int* __restrict__ src, const int* __restrict__ dst,
                          int* __restrict__ cursor, int* __restrict__ col, int ne) {
    int e = blockIdx.x * 256 + threadIdx.x;
    if (e >= ne) return;
    int pos = atomicAdd(&cursor[dst[e]], 1);
    col[pos] = src[e];
}

// ---------------- stage-1 layer a ----------------
__global__ __launch_bounds__(256) void k_agg16(const float* __restrict__ h,
                                               const int* __restrict__ rowptr,
                                               const int* __restrict__ col,
                                               float* __restrict__ agg, float* __restrict__ deg,
                                               int nrows) {
    int i = blockIdx.x * 256 + threadIdx.x;
    int r = i >> 4, j = i & 15;
    if (r >= nrows) return;
    int b = rowptr[r], e = rowptr[r + 1];
    float a = h[r * 16 + j];
    for (int q = b; q < e; ++q) a += h[col[q] * 16 + j];
    agg[r * 16 + j] = a;
    if (j == 0) deg[r] = 1.0f + (float)(e - b);
}

__global__ __launch_bounds__(256) void k_sage16(
    const float* __restrict__ h, const float* __restrict__ agg, const float* __restrict__ deg,
    const float* __restrict__ Wl, const float* __restrict__ Wr, const float* __restrict__ bl,
    float* __restrict__ y, int nrows)
{
    __shared__ float WlS[16][128], WrS[16][128];
    int tid = threadIdx.x;
    for (int i = tid; i < 16 * 128; i += 256) {
        WlS[i >> 7][i & 127] = Wl[i];
        WrS[i >> 7][i & 127] = Wr[i];
    }
    __syncthreads();
    long long o = (long long)blockIdx.x * 256 + tid;
    int row = (int)(o >> 7);
    if (row >= nrows) return;
    int d = (int)o & 127;
    float invd = 1.0f / fmaxf(deg[row], 1.0f);
    float s = bl[d];
    #pragma unroll
    for (int k = 0; k < 16; ++k)
        s += agg[row * 16 + k] * invd * WlS[k][d] + h[row * 16 + k] * WrS[k][d];
    y[(long long)row * 128 + d] = tanhf(s);
}

// ---------------- CSR gather-aggregate (row-parallel, no atomics) ----------------
// mode 0 (stage-1): self + neighbors, deg = 1 + edges
// mode 1 (s2 L0):   neighbors only, x row = src % NN, deg = edges
// mode 2 (s2 L1/2): neighbors weighted fvec, deg = sum nal, compact rows via aliveIdx
// AGG[r][*] = mean (invds applied). 8 rows/block x 32 lanes.
__global__ __launch_bounds__(256) void k_aggf(
    const float* __restrict__ x,
    const int* __restrict__ rowptr, const int* __restrict__ col,
    const int* __restrict__ aliveIdx, const float* __restrict__ nal, const float* __restrict__ fvec,
    int mode, int xModN, int rowbase,
    float* __restrict__ AGG, int nrowsC)
{
    int tid = threadIdx.x;
    int r = blockIdx.x * 8 + (tid >> 5);
    if (r >= nrowsC) return;
    int lane = tid & 31;
    int orig = aliveIdx ? aliveIdx[r] : r;
    int grow = rowbase + orig;
    int b = rowptr[grow], e = rowptr[grow + 1];
    float4 a = make_float4(0.0f, 0.0f, 0.0f, 0.0f);
    float dsum = 0.0f;
    if (mode == 0) {
        a = *reinterpret_cast<const float4*>(x + (long long)orig * 128 + lane * 4);
        dsum = 1.0f;
    }
    for (int q = b; q < e; ++q) {
        int s = col[q];
        float fw = 1.0f;
        int fr;
        if (mode == 2) {
            fr = s - rowbase;
            if (nal[fr] == 0.0f) continue;
            dsum += 1.0f;
            fw = fvec[fr];
            if (fw == 0.0f) continue;
        } else {
            fr = xModN ? (s % NN) : (s - rowbase);
            dsum += 1.0f;
        }
        float4 v = *reinterpret_cast<const float4*>(x + (long long)fr * 128 + lane * 4);
        a.x += v.x * fw; a.y += v.y * fw; a.z += v.z * fw; a.w += v.w * fw;
    }
    float invds = 1.0f / fmaxf(dsum, 1.0f);
    a.x *= invds; a.y *= invds; a.z *= invds; a.w *= invds;
    *reinterpret_cast<float4*>(AGG + (long long)r * 128 + lane * 4) = a;
}

// ---------------- dense SAGE GEMM (AGG read linearly) ----------------
// V 0 (stage-1): y=tanh(AGG@Wl + bl + x[crow]@Wr), K=256
// V 1 (s2 L0):   y=tanh(AGG@Wl + zself[crow%NN]), K=128
// V 2 (s2 L1/2): y=tanh(AGG@Wl + bl + fvec[orig]*x[orig]@Wr), orig=aliveIdx[crow], K=256
// Outputs (y and epilogue dots tbuf/rootd/gdot) written at orig row index.
__global__ __launch_bounds__(256) void k_sage_d(
    const float* __restrict__ AGG, const float* __restrict__ xsrc, const float* __restrict__ zself,
    const int* __restrict__ aliveIdx, const float* __restrict__ fvec,
    int V,
    const float* __restrict__ Wl, const float* __restrict__ Wr, const float* __restrict__ bl,
    float* __restrict__ y, int nrowsC,
    const float* __restrict__ wrel, const float* __restrict__ wroot, const float* __restrict__ gw,
    float* __restrict__ tbuf, float* __restrict__ rootd, float* __restrict__ gdot)
{
    __shared__ float Ws[32 * 128];
    __shared__ float Is[32][132];
    __shared__ float wrelS[128], wrootS[128], gwS[128];
    __shared__ int rowIdxS[128];
    int tid = threadIdx.x;
    long long row0 = (long long)blockIdx.x * 128;
    if (tid < 128) {
        if (wrel)  wrelS[tid]  = wrel[tid];
        if (wroot) wrootS[tid] = wroot[tid];
        if (gw)    gwS[tid]    = gw[tid];
        long long lr = row0 + tid;
        if (lr >= nrowsC) lr = nrowsC - 1;
        rowIdxS[tid] = aliveIdx ? aliveIdx[lr] : (int)lr;
    }
    __syncthreads();
    int tx = tid & 15, ty = tid >> 4;
    int srow = tid & 127;
    int koff = (tid >> 7) * 16;
    long long crow = row0 + srow;
    if (crow >= nrowsC) crow = nrowsC - 1;   // clamp: duplicate staging, write-guarded
    int orig = rowIdxS[srow];
    float fself = (V == 2) ? fvec[orig] : 1.0f;
    const float* selfp = (V == 1) ? zself : (xsrc + (long long)orig * 128);
    const float* aggp = AGG + crow * 128;

    int KB = (V == 1) ? 4 : 8;
    float acc[8][8] = {};
    for (int kb = 0; kb < KB; ++kb) {
        __syncthreads();
        bool isAgg = (kb < 4);
        const float* Wsrc = isAgg ? (Wl + kb * 32 * 128) : (Wr + (kb - 4) * 32 * 128);
        #pragma unroll
        for (int j = 0; j < 4; ++j) {
            int fl = j * 1024 + tid * 4;
            *reinterpret_cast<float4*>(&Ws[fl]) = *reinterpret_cast<const float4*>(&Wsrc[fl]);
        }
        if (isAgg) {
            const float* sp = aggp + kb * 32 + koff;
            #pragma unroll
            for (int q = 0; q < 4; ++q) {
                float4 v = *reinterpret_cast<const float4*>(sp + q * 4);
                Is[koff + q*4    ][srow] = v.x;
                Is[koff + q*4 + 1][srow] = v.y;
                Is[koff + q*4 + 2][srow] = v.z;
                Is[koff + q*4 + 3][srow] = v.w;
            }
        } else {
            const float* sp = selfp + (kb - 4) * 32 + koff;
            #pragma unroll
            for (int q = 0; q < 4; ++q) {
                float4 v = *reinterpret_cast<const float4*>(sp + q * 4);
                Is[koff + q*4    ][srow] = v.x * fself;
                Is[koff + q*4 + 1][srow] = v.y * fself;
                Is[koff + q*4 + 2][srow] = v.z * fself;
                Is[koff + q*4 + 3][srow] = v.w * fself;
            }
        }
        __syncthreads();
        #pragma unroll
        for (int kk = 0; kk < 32; ++kk) {
            float4 w0 = *reinterpret_cast<const float4*>(&Ws[kk * 128 + tx * 4]);
            float4 w1 = *reinterpret_cast<const float4*>(&Ws[kk * 128 + tx * 4 + 64]);
            float4 i0 = *reinterpret_cast<const float4*>(&Is[kk][ty * 8]);
            float4 i1 = *reinterpret_cast<const float4*>(&Is[kk][ty * 8 + 4]);
            float ia[8] = {i0.x, i0.y, i0.z, i0.w, i1.x, i1.y, i1.z, i1.w};
            float wa[8] = {w0.x, w0.y, w0.z, w0.w, w1.x, w1.y, w1.z, w1.w};
            #pragma unroll
            for (int i = 0; i < 8; ++i)
                #pragma unroll
                for (int j = 0; j < 8; ++j)
                    acc[i][j] += ia[i] * wa[j];
        }
    }
    float br[8];
    if (V != 1) {
        float4 bl0 = *reinterpret_cast<const float4*>(&bl[tx * 4]);
        float4 bl1 = *reinterpret_cast<const float4*>(&bl[tx * 4 + 64]);
        br[0]=bl0.x; br[1]=bl0.y; br[2]=bl0.z; br[3]=bl0.w;
        br[4]=bl1.x; br[5]=bl1.y; br[6]=bl1.z; br[7]=bl1.w;
    }
    #pragma unroll
    for (int i = 0; i < 8; ++i) {
        long long cr = row0 + ty * 8 + i;
        bool valid = (cr < nrowsC);
        int rout = rowIdxS[ty * 8 + i];
        float zr[8];
        if (V == 1) {
            const float* zp = zself + (long long)(rout % NN) * 128;
            float4 z0 = *reinterpret_cast<const float4*>(&zp[tx * 4]);
            float4 z1 = *reinterpret_cast<const float4*>(&zp[tx * 4 + 64]);
            zr[0]=z0.x; zr[1]=z0.y; zr[2]=z0.z; zr[3]=z0.w;
            zr[4]=z1.x; zr[5]=z1.y; zr[6]=z1.z; zr[7]=z1.w;
        } else {
            #pragma unroll
            for (int j = 0; j < 8; ++j) zr[j] = br[j];
        }
        float yv[8];
        #pragma unroll
        for (int j = 0; j < 8; ++j) yv[j] = tanhf(acc[i][j] + zr[j]);
        if (valid) {
            *reinterpret_cast<float4*>(&y[(long long)rout * 128 + tx * 4]) = make_float4(yv[0], yv[1], yv[2], yv[3]);
            *reinterpret_cast<float4*>(&y[(long long)rout * 128 + tx * 4 + 64]) = make_float4(yv[4], yv[5], yv[6], yv[7]);
        }
        float tp = 0.0f, rp = 0.0f, gp = 0.0f;
        #pragma unroll
        for (int j = 0; j < 4; ++j) {
            if (tbuf)  tp += yv[j] * wrelS[tx*4 + j]  + yv[j+4] * wrelS[tx*4 + 64 + j];
            if (rootd) rp += yv[j] * wrootS[tx*4 + j] + yv[j+4] * wrootS[tx*4 + 64 + j];
            if (gdot)  gp += yv[j] * gwS[tx*4 + j]    + yv[j+4] * gwS[tx*4 + 64 + j];
        }
        #pragma unroll
        for (int m = 8; m >= 1; m >>= 1) {
            if (tbuf)  tp += __shfl_xor(tp, m, 16);
            if (rootd) rp += __shfl_xor(rp, m, 16);
            if (gdot)  gp += __shfl_xor(gp, m, 16);
        }
        if (tx == 0 && valid) {
            if (tbuf)  tbuf[rout]  = tp;
            if (rootd) rootd[rout] = rp;
            if (gdot)  gdot[rout]  = gp;
        }
    }
}

// ---------------- zself GEMM: y = x@W + b (no tanh) ----------------
__global__ __launch_bounds__(256) void k_gemm_self(
    const float* __restrict__ x, const float* __restrict__ W, const float* __restrict__ b,
    float* __restrict__ y, int nrows)
{
    __shared__ float Ws[32 * 128];
    __shared__ float Is[32][132];
    int tid = threadIdx.x;
    long long row0 = (long long)blockIdx.x * 128;
    int tx = tid & 15, ty = tid >> 4;
    int srow = tid & 127;
    int koff = (tid >> 7) * 16;
    long long lrow = row0 + srow;
    if (lrow >= nrows) lrow = nrows - 1;
    const float* xrow = x + lrow * 128;
    float acc[8][8] = {};
    for (int kb = 0; kb < 4; ++kb) {
        __syncthreads();
        const float* Wsrc = W + kb * 32 * 128;
        #pragma unroll
        for (int j = 0; j < 4; ++j) {
            int fl = j * 1024 + tid * 4;
            *reinterpret_cast<float4*>(&Ws[fl]) = *reinterpret_cast<const float4*>(&Wsrc[fl]);
        }
        {
            const float* sp = xrow + kb * 32 + koff;
            #pragma unroll
            for (int q = 0; q < 4; ++q) {
                float4 v = *reinterpret_cast<const float4*>(sp + q * 4);
                Is[koff + q*4    ][srow] = v.x;
                Is[koff + q*4 + 1][srow] = v.y;
                Is[koff + q*4 + 2][srow] = v.z;
                Is[koff + q*4 + 3][srow] = v.w;
            }
        }
        __syncthreads();
        #pragma unroll
        for (int kk = 0; kk < 32; ++kk) {
            float4 w0 = *reinterpret_cast<const float4*>(&Ws[kk * 128 + tx * 4]);
            float4 w1 = *reinterpret_cast<const float4*>(&Ws[kk * 128 + tx * 4 + 64]);
            float4 i0 = *reinterpret_cast<const float4*>(&Is[kk][ty * 8]);
            float4 i1 = *reinterpret_cast<const float4*>(&Is[kk][ty * 8 + 4]);
            float ia[8] = {i0.x, i0.y, i0.z, i0.w, i1.x, i1.y, i1.z, i1.w};
            float wa[8] = {w0.x, w0.y, w0.z, w0.w, w1.x, w1.y, w1.z, w1.w};
            #pragma unroll
            for (int i = 0; i < 8; ++i)
                #pragma unroll
                for (int j = 0; j < 8; ++j)
                    acc[i][j] += ia[i] * wa[j];
        }
    }
    float4 b0 = *reinterpret_cast<const float4*>(&b[tx * 4]);
    float4 b1 = *reinterpret_cast<const float4*>(&b[tx * 4 + 64]);
    #pragma unroll
    for (int i = 0; i < 8; ++i) {
        long long row = row0 + ty * 8 + i;
        if (row >= nrows) continue;
        *reinterpret_cast<float4*>(&y[row * 128 + tx * 4]) =
            make_float4(acc[i][0] + b0.x, acc[i][1] + b0.y, acc[i][2] + b0.z, acc[i][3] + b0.w);
        *reinterpret_cast<float4*>(&y[row * 128 + tx * 4 + 64]) =
            make_float4(acc[i][4] + b1.x, acc[i][5] + b1.y, acc[i][6] + b1.z, acc[i][7] + b1.w);
    }
}

// ---------------- stage-1 readout pieces ----------------
__global__ __launch_bounds__(256) void k_gate(
    const float* __restrict__ X, const float* __restrict__ gw,
    float* __restrict__ g, int nrows)
{
    __shared__ float wS[128];
    if (threadIdx.x < 128) wS[threadIdx.x] = gw[threadIdx.x];
    __syncthreads();
    int i = blockIdx.x * 256 + threadIdx.x;
    if (i >= nrows) return;
    const float4* xrp = reinterpret_cast<const float4*>(X + (long long)i * 128);
    float s = 0.0f;
    #pragma unroll
    for (int k = 0; k < 32; ++k) {
        float4 v = xrp[k];
        s += v.x * wS[4*k] + v.y * wS[4*k+1] + v.z * wS[4*k+2] + v.w * wS[4*k+3];
    }
    g[i] = s;
}

__global__ __launch_bounds__(1024) void k_smstats(float* __restrict__ g, float* __restrict__ invp) {
    __shared__ float red[1024];
    int p = blockIdx.x, tid = threadIdx.x;
    float* gp = g + (long long)p * NN;
    float lmax = -INFINITY;
    for (int n = tid; n < NN; n += 1024) lmax = fmaxf(lmax, gp[n]);
    red[tid] = lmax; __syncthreads();
    for (int s = 512; s > 0; s >>= 1) { if (tid < s) red[tid] = fmaxf(red[tid], red[tid + s]); __syncthreads(); }
    float mx = red[0]; __syncthreads();
    float ls = 0.0f;
    for (int n = tid; n < NN; n += 1024) { float e = expf(gp[n] - mx); gp[n] = e; ls += e; }
    red[tid] = ls; __syncthreads();
    for (int s = 512; s > 0; s >>= 1) { if (tid < s) red[tid] += red[tid + s]; __syncthreads(); }
    if (tid == 0) invp[p] = 1.0f / red[0];
}

__global__ __launch_bounds__(128) void k_wsum(
    const float* __restrict__ X, const float* __restrict__ a,
    const float* __restrict__ invp, float* __restrict__ ro, int rowbase, int colOff)
{
    int p = blockIdx.x / BPG;
    int chunk = blockIdx.x % BPG;
    int d = threadIdx.x;
    long long base = (long long)p * NN;
    int r0 = chunk * RB, r1 = r0 + RB;
    float s = 0.0f;
    for (int n = r0; n < r1; ++n) {
        float w = a[base + n];
        if (w != 0.0f) s += w * X[(base + n) * 128 + d];
    }
    atomicAdd(&ro[(long long)(rowbase + p) * 384 + colOff + d], s * invp[p]);
}

// stage-2 weighted sum over alive rows only
__global__ __launch_bounds__(128) void k_wsum_c(
    const float* __restrict__ X, const float* __restrict__ gbuf, const float* __restrict__ fvec,
    const float* __restrict__ invp, const int* __restrict__ aliveIdx, int k,
    float* __restrict__ ro, int rowbaseRo, int colOff)
{
    int bpp = k / RB;
    int p = blockIdx.x / bpp;
    int chunk = blockIdx.x % bpp;
    int d = threadIdx.x;
    const int* ai = aliveIdx + (long long)p * k + chunk * RB;
    float s = 0.0f;
    for (int j = 0; j < RB; ++j) {
        int row = ai[j];
        float w = gbuf[row] * fvec[row];
        s += w * X[(long long)row * 128 + d];
    }
    atomicAdd(&ro[(long long)(rowbaseRo + p) * 384 + colOff + d], s * invp[p]);
}

// ---------------- GraphNorm ----------------
__global__ void k_colstat(const float* __restrict__ x, float* __restrict__ musum,
                          float* __restrict__ sqsum, int nrows) {
    int d = threadIdx.x;
    int r0 = blockIdx.x * 64;
    int r1 = min(r0 + 64, nrows);
    float s = 0.0f, q = 0.0f;
    for (int r = r0; r < r1; ++r) { float v = x[(long long)r * 128 + d]; s += v; q += v * v; }
    atomicAdd(&musum[d], s);
    atomicAdd(&sqsum[d], q);
}

__global__ void k_gnorm_apply(const float* __restrict__ x, float* __restrict__ y,
                              const float* __restrict__ musum, const float* __restrict__ sqsum,
                              const float* __restrict__ w, const float* __restrict__ b,
                              const float* __restrict__ ms, int nrows) {
    long long i = (long long)blockIdx.x * 256 + threadIdx.x;
    if (i >= (long long)nrows * 128) return;
    int d = (int)(i & 127);
    float inv_n = 1.0f / (float)nrows;
    float mu = musum[d] * inv_n;
    float c = mu * ms[d];
    float var = sqsum[d] * inv_n - 2.0f * c * mu + c * c;
    y[i] = w[d] * (x[i] - c) * rsqrtf(var + 1e-5f) + b[d];
}

// ---------------- mega top-k ----------------
__global__ __launch_bounds__(256) void k_topk2(
    const int* __restrict__ rowptr, const int* __restrict__ col, int rowbase,
    const float* __restrict__ tb, const float* __restrict__ rootd,
    const float* __restrict__ gdot, const float* __restrict__ brelp, int bi,
    float* __restrict__ nalive, float* __restrict__ fvec, float* __restrict__ gbuf,
    float* __restrict__ invp, int* __restrict__ aliveIdx, int k)
{
    __shared__ unsigned keys[NN];
    __shared__ int hist[256];
    __shared__ int chunkcnt[256];
    __shared__ float redf[256];
    __shared__ unsigned sh_pref;
    __shared__ int sh_kneed;
    int p = blockIdx.x, tid = threadIdx.x;
    float brel = brelp[bi];
    long long pbase = (long long)p * NN;
    for (int n = tid; n < NN; n += 256) {
        long long gl = pbase + n;
        int grow = rowbase + (int)gl;
        float s = brel + rootd[gl];
        int b = rowptr[grow], e = rowptr[grow + 1];
        for (int q = b; q < e; ++q) {
            int sl = col[q] - rowbase;
            s += tb[sl] * nalive[sl];
        }
        keys[n] = (nalive[gl] > 0.5f) ? fkey(s) : 0u;
    }
    if (tid == 0) { sh_pref = 0u; sh_kneed = k; }
    __syncthreads();
    for (int lvl = 3; lvl >= 0; --lvl) {
        int sh = lvl * 8;
        hist[tid] = 0;
        unsigned pref = sh_pref; int kneed = sh_kneed;
        unsigned pmask = (lvl == 3) ? 0u : (0xFFFFFFFFu << (8 * (lvl + 1)));
        __syncthreads();
        for (int n = tid; n < NN; n += 256) {
            unsigned kv = keys[n];
            if ((kv & pmask) == pref) atomicAdd(&hist[(kv >> sh) & 255], 1);
        }
        __syncthreads();
        if (tid == 0) {
            int cum = 0, b = 255;
            for (; b >= 0; --b) { cum += hist[b]; if (cum >= kneed) break; }
            sh_pref = pref | ((unsigned)b << sh);
            sh_kneed = kneed - (cum - hist[b]);
        }
        __syncthreads();
    }
    unsigned V = sh_pref;
    int seleq = sh_kneed;
    int c0 = tid * 32, c1 = min(c0 + 32, NN);
    int ceq = 0;
    for (int n = c0; n < c1; ++n) ceq += (keys[n] == V) ? 1 : 0;
    chunkcnt[tid] = ceq; __syncthreads();
    if (tid == 0) {
        int s = 0;
        for (int i = 0; i < 256; ++i) { int c = chunkcnt[i]; chunkcnt[i] = s; s += c; }
    }
    __syncthreads();
    int rank = chunkcnt[tid];
    unsigned selmask = 0u;
    int nsel = 0;
    float lmax = -INFINITY;
    for (int n = c0; n < c1; ++n) {
        unsigned kk = keys[n];
        bool sel = (kk > V) || (kk == V && rank < seleq);
        if (kk == V) rank++;
        long long gl = pbase + n;
        nalive[gl] = sel ? 1.0f : 0.0f;
        float f = 0.0f;
        if (sel) {
            f = tanhf(fkey_inv(kk));
            lmax = fmaxf(lmax, f * gdot[gl]);
            selmask |= (1u << (n - c0));
            ++nsel;
        }
        fvec[gl] = f;
    }
    redf[tid] = lmax; __syncthreads();
    for (int s = 128; s > 0; s >>= 1) { if (tid < s) redf[tid] = fmaxf(redf[tid], redf[tid + s]); __syncthreads(); }
    float mx = redf[0]; __syncthreads();
    chunkcnt[tid] = nsel; __syncthreads();
    if (tid == 0) {
        int s = 0;
        for (int i = 0; i < 256; ++i) { int c = chunkcnt[i]; chunkcnt[i] = s; s += c; }
    }
    __syncthreads();
    int pos = chunkcnt[tid];
    float lsum = 0.0f;
    for (int n = c0; n < c1; ++n) {
        if (selmask & (1u << (n - c0))) {
            long long gl = pbase + n;
            float e = expf(fvec[gl] * gdot[gl] - mx);
            gbuf[gl] = e;
            lsum += e;
            aliveIdx[(long long)p * k + pos] = (int)gl;
            ++pos;
        }
    }
    redf[tid] = lsum; __syncthreads();
    for (int s = 128; s > 0; s >>= 1) { if (tid < s) redf[tid] += redf[tid + s]; __syncthreads(); }
    if (tid == 0) invp[p] = 1.0f / redf[0];
}

// ---------------- head ----------------
__global__ __launch_bounds__(64) void k_head(
    const float* __restrict__ ro, const float* __restrict__ lin_w, const float* __restrict__ lin_b,
    const float* __restrict__ m1w, const float* __restrict__ m1b,
    const float* __restrict__ m2w, const float* __restrict__ m2b,
    const float* __restrict__ m3w, const float* __restrict__ m3b, float* __restrict__ out)
{
    __shared__ float v[33], h1[48], h2[16];
    int t = threadIdx.x;
    if (t < 33) {
        float s = lin_b[0];
        for (int k = 0; k < 384; ++k) s += ro[t * 384 + k] * lin_w[k];
        v[t] = tanhf(s);
    }
    __syncthreads();
    if (t < 48) {
        float s = m1b[t];
        for (int i = 0; i < 33; ++i) s += v[i] * m1w[i * 48 + t];
        h1[t] = tanhf(s);
    }
    __syncthreads();
    if (t < 16) {
        float s = m2b[t];
        for (int i = 0; i < 48; ++i) s += h1[i] * m2w[i * 16 + t];
        h2[t] = tanhf(s);
    }
    __syncthreads();
    if (t == 0) {
        float s = m3b[0];
        for (int i = 0; i < 16; ++i) s += h2[i] * m3w[i];
        float s1 = 1.0f / (1.0f + expf(-s));
        out[0] = 1.0f / (1.0f + expf(-s1));
    }
}

static inline int cdiv(long long a, long long b) { return (int)((a + b - 1) / b); }

extern "C" void kernel_launch(void* const* d_in, const int* in_sizes, int n_in,
                              void* d_out, int out_size, void* d_ws, size_t ws_size,
                              hipStream_t stream)
{
    (void)in_sizes; (void)n_in; (void)out_size;
    const float* h     = (const float*)d_in[0];
    const int*   eidx  = (const int*)d_in[1];
    const int*   seidx = (const int*)d_in[2];
    const float* Wl_a  = (const float*)d_in[3];
    const float* Wr_a  = (const float*)d_in[4];
    const float* bl_a  = (const float*)d_in[5];
    const float* Wl_s  = (const float*)d_in[6];
    const float* Wr_s  = (const float*)d_in[7];
    const float* bl_s  = (const float*)d_in[8];
    const float* gate_w = (const float*)d_in[9];
    const float* p_wrel = (const float*)d_in[11];
    const float* p_brel = (const float*)d_in[12];
    const float* p_wroot= (const float*)d_in[13];
    const float* nw    = (const float*)d_in[14];
    const float* nb    = (const float*)d_in[15];
    const float* nms   = (const float*)d_in[16];
    const float* lin_w = (const float*)d_in[17];
    const float* lin_b = (const float*)d_in[18];
    const float* m1w   = (const float*)d_in[19];
    const float* m1b   = (const float*)d_in[20];
    const float* m2w   = (const float*)d_in[21];
    const float* m2b   = (const float*)d_in[22];
    const float* m3w   = (const float*)d_in[23];
    const float* m3b   = (const float*)d_in[24];
    float* out = (float*)d_out;

    const int* esrc = eidx;
    const int* edst = eidx + EG;
    const int* ssrc = seidx;
    const int* sdst = seidx + ES_TOT;

    auto need_bytes = [](int chp) -> size_t {
        long long chn = (long long)chp * NN;
        long long f = 3 * chn * 128             // XA, XB, AGG
                    + 3LL * NN * 128            // xa, xb, zself
                    + NN * 16 + NN
                    + 6 * chn                   // tbuf, rootd, nal, fvec, gdot, gbuf
                    + (long long)chp * KK1      // aliveIdx
                    + 64 + 33 * 384 + 256
                    + (NN + (NN+1) + NN + EG + NN + 1024)
                    + (PN + (PN+1) + PN + ES_TOT + PN + 1024)
                    + 64 * 48;
        return (size_t)f * 4;
    };
    int chp = 4;
    if (ws_size >= need_bytes(16)) chp = 16;
    else if (ws_size >= need_bytes(8)) chp = 8;
    int nch = PP / chp;
    long long ch_n = (long long)chp * NN;

    float* W = (float*)d_ws;
    size_t off = 0;
    auto alloc = [&](size_t nf) { float* p = W + off; off += (nf + 63) & ~(size_t)63; return p; };
    float* XA    = alloc((size_t)ch_n * DD);
    float* XB    = alloc((size_t)ch_n * DD);
    float* AGG   = alloc((size_t)ch_n * DD);
    float* xa    = alloc((size_t)NN * DD);
    float* xb    = alloc((size_t)NN * DD);
    float* zself = alloc((size_t)NN * DD);
    float* agg1  = alloc((size_t)NN * 16);
    float* deg1  = alloc(NN);
    float* tbuf  = alloc(ch_n);
    float* rootd = alloc(ch_n);
    float* nal   = alloc(ch_n);
    float* fvec  = alloc(ch_n);
    float* gdot  = alloc(ch_n);
    float* gbuf  = alloc(ch_n);
    float* invp  = alloc(64);
    float* ro    = alloc(33 * 384);
    float* musum = alloc(128);
    float* sqsum = alloc(128);
    int* aliveIdx = (int*)alloc((size_t)chp * KK1);
    int* s1cnt  = (int*)alloc(NN);
    int* s1rp   = (int*)alloc(NN + 1);
    int* s1cur  = (int*)alloc(NN);
    int* s1col  = (int*)alloc(EG);
    int* s1part = (int*)alloc(NN);
    int* s1bsum = (int*)alloc(1024);
    int* s2cnt  = (int*)alloc(PN);
    int* s2rp   = (int*)alloc(PN + 1);
    int* s2cur  = (int*)alloc(PN);
    int* s2col  = (int*)alloc(ES_TOT);
    int* s2part = (int*)alloc(PN);
    int* s2bsum = (int*)alloc(1024);

    // ---------- CSR builds ----------
    int nb1 = cdiv(NN, 1024), nb2 = cdiv(PN, 1024);
    hipMemsetAsync(s1cnt, 0, NN * sizeof(int), stream);
    k_hist<<<cdiv(EG,256),256,0,stream>>>(edst, s1cnt, EG);
    k_scanA<<<nb1,1024,0,stream>>>(s1cnt, s1part, s1bsum, NN);
    k_scanB<<<1,1024,0,stream>>>(s1bsum, nb1);
    k_scanC<<<cdiv(NN,256),256,0,stream>>>(s1part, s1bsum, s1rp, s1cur, NN, EG);
    k_scatter<<<cdiv(EG,256),256,0,stream>>>(esrc, edst, s1cur, s1col, EG);

    hipMemsetAsync(s2cnt, 0, (size_t)PN * sizeof(int), stream);
    k_hist<<<cdiv(ES_TOT,256),256,0,stream>>>(sdst, s2cnt, ES_TOT);
    k_scanA<<<nb2,1024,0,stream>>>(s2cnt, s2part, s2bsum, PN);
    k_scanB<<<1,1024,0,stream>>>(s2bsum, nb2);
    k_scanC<<<cdiv(PN,256),256,0,stream>>>(s2part, s2bsum, s2rp, s2cur, PN, ES_TOT);
    k_scatter<<<cdiv(ES_TOT,256),256,0,stream>>>(ssrc, sdst, s2cur, s2col, ES_TOT);

    hipMemsetAsync(ro, 0, 33 * 384 * sizeof(float), stream);

    // ---------- stage 1 ----------
    k_agg16<<<cdiv((long long)NN*16,256),256,0,stream>>>(h, s1rp, s1col, agg1, deg1, NN);
    k_sage16<<<cdiv((long long)NN*DD,256),256,0,stream>>>(h, agg1, deg1, Wl_a, Wr_a, bl_a, xa, NN);
    k_gate<<<cdiv(NN,256),256,0,stream>>>(xa, gate_w + 0*DD, gbuf, NN);
    k_smstats<<<1,1024,0,stream>>>(gbuf, invp);
    k_wsum<<<BPG,128,0,stream>>>(xa, gbuf, invp, ro, 0, 0);

    hipMemsetAsync(musum, 0, 128*sizeof(float), stream);
    hipMemsetAsync(sqsum, 0, 128*sizeof(float), stream);
    k_colstat<<<cdiv(NN,64),128,0,stream>>>(xa, musum, sqsum, NN);
    k_gnorm_apply<<<cdiv((long long)NN*DD,256),256,0,stream>>>(xa, xb, musum, sqsum, nw, nb, nms, NN);

    // layer b: CSR agg -> dense GEMM (gate dot in epilogue)
    k_aggf<<<cdiv(NN,8),256,0,stream>>>(xb, s1rp, s1col, nullptr, nullptr, nullptr, 0, 0, 0, AGG, NN);
    k_sage_d<<<cdiv(NN,128),256,0,stream>>>(AGG, xb, nullptr, nullptr, nullptr, 0,
        Wl_s + 0*16384, Wr_s + 0*16384, bl_s + 0*128, xa, NN,
        nullptr, nullptr, gate_w + 1*DD, nullptr, nullptr, gbuf);
    k_smstats<<<1,1024,0,stream>>>(gbuf, invp);
    k_wsum<<<BPG,128,0,stream>>>(xa, gbuf, invp, ro, 0, 128);

    hipMemsetAsync(musum, 0, 128*sizeof(float), stream);
    hipMemsetAsync(sqsum, 0, 128*sizeof(float), stream);
    k_colstat<<<cdiv(NN,64),128,0,stream>>>(xa, musum, sqsum, NN);
    k_gnorm_apply<<<cdiv((long long)NN*DD,256),256,0,stream>>>(xa, xb, musum, sqsum, nw, nb, nms, NN);

    // layer c -> xa = x_c
    k_aggf<<<cdiv(NN,8),256,0,stream>>>(xb, s1rp, s1col, nullptr, nullptr, nullptr, 0, 0, 0, AGG, NN);
    k_sage_d<<<cdiv(NN,128),256,0,stream>>>(AGG, xb, nullptr, nullptr, nullptr, 0,
        Wl_s + 1*16384, Wr_s + 1*16384, bl_s + 1*128, xa, NN,
        nullptr, nullptr, gate_w + 2*DD, nullptr, nullptr, gbuf);
    k_smstats<<<1,1024,0,stream>>>(gbuf, invp);
    k_wsum<<<BPG,128,0,stream>>>(xa, gbuf, invp, ro, 0, 256);

    // ---------- stage 2 ----------
    k_gemm_self<<<cdiv(NN,128),256,0,stream>>>(xa, Wr_s + 2*16384, bl_s + 2*128, zself, NN);

    for (int c = 0; c < nch; ++c) {
        int nbase = (int)(c * ch_n);
        k_fill<<<cdiv(ch_n,256),256,0,stream>>>(nal, 1.0f, (int)ch_n);

        // ---- layer 0: all rows, K=128 + zself ----
        k_aggf<<<(int)(ch_n/8),256,0,stream>>>(xa, s2rp, s2col, nullptr, nullptr, nullptr, 1, 1, nbase, AGG, (int)ch_n);
        k_sage_d<<<(int)(ch_n/128),256,0,stream>>>(AGG, nullptr, zself, nullptr, nullptr, 1,
            Wl_s + 2*16384, nullptr, nullptr, XA, (int)ch_n,
            p_wrel + 0*DD, p_wroot + 0*DD, gate_w + 3*DD, tbuf, rootd, gdot);
        k_topk2<<<chp,256,0,stream>>>(s2rp, s2col, nbase, tbuf, rootd, gdot, p_brel, 0,
                                      nal, fvec, gbuf, invp, aliveIdx, KK1);
        k_wsum_c<<<chp*(KK1/RB),128,0,stream>>>(XA, gbuf, fvec, invp, aliveIdx, KK1, ro, 1 + c*chp, 0);

        // ---- layer 1: alive K1 rows ----
        k_aggf<<<chp*(KK1/8),256,0,stream>>>(XA, s2rp, s2col, aliveIdx, nal, fvec, 2, 0, nbase, AGG, chp*KK1);
        k_sage_d<<<chp*(KK1/128),256,0,stream>>>(AGG, XA, nullptr, aliveIdx, fvec, 2,
            Wl_s + 3*16384, Wr_s + 3*16384, bl_s + 3*128, XB, chp*KK1,
            p_wrel + 1*DD, p_wroot + 1*DD, gate_w + 4*DD, tbuf, rootd, gdot);
        k_topk2<<<chp,256,0,stream>>>(s2rp, s2col, nbase, tbuf, rootd, gdot, p_brel, 1,
                                      nal, fvec, gbuf, invp, aliveIdx, KK2);
        k_wsum_c<<<chp*(KK2/RB),128,0,stream>>>(XB, gbuf, fvec, invp, aliveIdx, KK2, ro, 1 + c*chp, 128);

        // ---- layer 2: alive K2 rows ----
        k_aggf<<<chp*(KK2/8),256,0,stream>>>(XB, s2rp, s2col, aliveIdx, nal, fvec, 2, 0, nbase, AGG, chp*KK2);
        k_sage_d<<<chp*(KK2/128),256,0,stream>>>(AGG, XB, nullptr, aliveIdx, fvec, 2,
            Wl_s + 4*16384, Wr_s + 4*16384, bl_s + 4*128, XA, chp*KK2,
            p_wrel + 2*DD, p_wroot + 2*DD, gate_w + 5*DD, tbuf, rootd, gdot);
        k_topk2<<<chp,256,0,stream>>>(s2rp, s2col, nbase, tbuf, rootd, gdot, p_brel, 2,
                                      nal, fvec, gbuf, invp, aliveIdx, KK3);
        k_wsum_c<<<chp*(KK3/RB),128,0,stream>>>(XA, gbuf, fvec, invp, aliveIdx, KK3, ro, 1 + c*chp, 256);
    }

    // ---------- head ----------
    k_head<<<1,64,0,stream>>>(ro, lin_w, lin_b, m1w, m1b, m2w, m2b, m3w, m3b, out);
}

// Round 10
// 1781.775 us; speedup vs baseline: 1.4748x; 1.1613x over previous
//
#include <hip/hip_runtime.h>
#include <math.h>

#define NN      8000
#define PP      32
#define EG      128000
#define ES_TOT  131072     // P * 4096
#define ES_P    4096
#define PN      256000     // P * NN
#define DI      16
#define DD      128
#define KK1     6400
#define KK2     5120
#define KK3     4096
#define RB      64                   // rows per wsum block
#define BPG     (NN / RB)            // 125 blocks per graph (stage-1 wsum)

static __device__ __forceinline__ unsigned fkey(float f) {
    unsigned u = __float_as_uint(f);
    return (u & 0x80000000u) ? ~u : (u | 0x80000000u);
}
static __device__ __forceinline__ float fkey_inv(unsigned k) {
    unsigned u = (k & 0x80000000u) ? (k & 0x7FFFFFFFu) : ~k;
    return __uint_as_float(u);
}

__global__ void k_fill(float* p, float v, int n) {
    int i = blockIdx.x * 256 + threadIdx.x;
    if (i < n) p[i] = v;
}

// ---------------- CSR build ----------------
__global__ void k_hist(const int* __restrict__ dst, int* __restrict__ cnt, int ne) {
    int e = blockIdx.x * 256 + threadIdx.x;
    if (e < ne) atomicAdd(&cnt[dst[e]], 1);
}

__global__ __launch_bounds__(1024) void k_scanA(const int* __restrict__ cnt,
                                                int* __restrict__ part,
                                                int* __restrict__ bsum, int n) {
    __shared__ int sh[1024];
    int t = threadIdx.x;
    int i = blockIdx.x * 1024 + t;
    int v = (i < n) ? cnt[i] : 0;
    sh[t] = v; __syncthreads();
    for (int off = 1; off < 1024; off <<= 1) {
        int u = (t >= off) ? sh[t - off] : 0;
        __syncthreads();
        sh[t] += u;
        __syncthreads();
    }
    if (i < n) part[i] = sh[t] - v;
    if (t == 1023) bsum[blockIdx.x] = sh[1023];
}

__global__ __launch_bounds__(1024) void k_scanB(int* __restrict__ bsum, int nb) {
    __shared__ int sh[1024];
    int t = threadIdx.x;
    int v = (t < nb) ? bsum[t] : 0;
    sh[t] = v; __syncthreads();
    for (int off = 1; off < 1024; off <<= 1) {
        int u = (t >= off) ? sh[t - off] : 0;
        __syncthreads();
        sh[t] += u;
        __syncthreads();
    }
    if (t < nb) bsum[t] = sh[t] - v;   // exclusive
}

__global__ void k_scanC(const int* __restrict__ part, const int* __restrict__ bsum,
                        int* __restrict__ rowptr, int* __restrict__ cursor, int n, int total) {
    int i = blockIdx.x * 256 + threadIdx.x;
    if (i < n) {
        int v = part[i] + bsum[i >> 10];
        rowptr[i] = v;
        cursor[i] = v;
    }
    if (i == 0) rowptr[n] = total;
}

__global__ void k_scatter(const int* __restrict__ src, const int* __restrict__ dst,
                          int* __restrict__ cursor, int* __restrict__ col, int ne) {
    int e = blockIdx.x * 256 + threadIdx.x;
    if (e >= ne) return;
    int pos = atomicAdd(&cursor[dst[e]], 1);
    col[pos] = src[e];
}

// ---------------- stage-1 layer a ----------------
__global__ __launch_bounds__(256) void k_agg16(const float* __restrict__ h,
                                               const int* __restrict__ rowptr,
                                               const int* __restrict__ col,
                                               float* __restrict__ agg, float* __restrict__ deg,
                                               int nrows) {
    int i = blockIdx.x * 256 + threadIdx.x;
    int r = i >> 4, j = i & 15;
    if (r >= nrows) return;
    int b = rowptr[r], e = rowptr[r + 1];
    float a = h[r * 16 + j];
    for (int q = b; q < e; ++q) a += h[col[q] * 16 + j];
    agg[r * 16 + j] = a;
    if (j == 0) deg[r] = 1.0f + (float)(e - b);
}

__global__ __launch_bounds__(256) void k_sage16(
    const float* __restrict__ h, const float* __restrict__ agg, const float* __restrict__ deg,
    const float* __restrict__ Wl, const float* __restrict__ Wr, const float* __restrict__ bl,
    float* __restrict__ y, int nrows)
{
    __shared__ float WlS[16][128], WrS[16][128];
    int tid = threadIdx.x;
    for (int i = tid; i < 16 * 128; i += 256) {
        WlS[i >> 7][i & 127] = Wl[i];
        WrS[i >> 7][i & 127] = Wr[i];
    }
    __syncthreads();
    long long o = (long long)blockIdx.x * 256 + tid;
    int row = (int)(o >> 7);
    if (row >= nrows) return;
    int d = (int)o & 127;
    float invd = 1.0f / fmaxf(deg[row], 1.0f);
    float s = bl[d];
    #pragma unroll
    for (int k = 0; k < 16; ++k)
        s += agg[row * 16 + k] * invd * WlS[k][d] + h[row * 16 + k] * WrS[k][d];
    y[(long long)row * 128 + d] = tanhf(s);
}

// ---------------- CSR gather-aggregate (row-parallel, no atomics) ----------------
__global__ __launch_bounds__(256) void k_aggf(
    const float* __restrict__ x,
    const int* __restrict__ rowptr, const int* __restrict__ col,
    const int* __restrict__ aliveIdx, const float* __restrict__ nal, const float* __restrict__ fvec,
    int mode, int xModN, int rowbase,
    float* __restrict__ AGG, int nrowsC)
{
    int tid = threadIdx.x;
    int r = blockIdx.x * 8 + (tid >> 5);
    if (r >= nrowsC) return;
    int lane = tid & 31;
    int orig = aliveIdx ? aliveIdx[r] : r;
    int grow = rowbase + orig;
    int b = rowptr[grow], e = rowptr[grow + 1];
    float4 a = make_float4(0.0f, 0.0f, 0.0f, 0.0f);
    float dsum = 0.0f;
    if (mode == 0) {
        a = *reinterpret_cast<const float4*>(x + (long long)orig * 128 + lane * 4);
        dsum = 1.0f;
    }
    for (int q = b; q < e; ++q) {
        int s = col[q];
        float fw = 1.0f;
        int fr;
        if (mode == 2) {
            fr = s - rowbase;
            if (nal[fr] == 0.0f) continue;
            dsum += 1.0f;
            fw = fvec[fr];
            if (fw == 0.0f) continue;
        } else {
            fr = xModN ? (s % NN) : (s - rowbase);
            dsum += 1.0f;
        }
        float4 v = *reinterpret_cast<const float4*>(x + (long long)fr * 128 + lane * 4);
        a.x += v.x * fw; a.y += v.y * fw; a.z += v.z * fw; a.w += v.w * fw;
    }
    float invds = 1.0f / fmaxf(dsum, 1.0f);
    a.x *= invds; a.y *= invds; a.z *= invds; a.w *= invds;
    *reinterpret_cast<float4*>(AGG + (long long)r * 128 + lane * 4) = a;
}

// ---------------- dense SAGE GEMM (weights straight from global/L1) ----------------
// V 0 (stage-1): y=tanh(AGG@Wl + bl + x[crow]@Wr), K=256
// V 1 (s2 L0):   y=tanh(AGG@Wl + zself[crow%NN]), K=128
// V 2 (s2 L1/2): y=tanh(AGG@Wl + bl + fvec[orig]*x[orig]@Wr), orig=aliveIdx[crow], K=256
__global__ __launch_bounds__(256) void k_sage_d(
    const float* __restrict__ AGG, const float* __restrict__ xsrc, const float* __restrict__ zself,
    const int* __restrict__ aliveIdx, const float* __restrict__ fvec,
    int V,
    const float* __restrict__ Wl, const float* __restrict__ Wr, const float* __restrict__ bl,
    float* __restrict__ y, int nrowsC,
    const float* __restrict__ wrel, const float* __restrict__ wroot, const float* __restrict__ gw,
    float* __restrict__ tbuf, float* __restrict__ rootd, float* __restrict__ gdot)
{
    __shared__ float Is[32][132];
    __shared__ float wrelS[128], wrootS[128], gwS[128];
    __shared__ int rowIdxS[128];
    int tid = threadIdx.x;
    long long row0 = (long long)blockIdx.x * 128;
    if (tid < 128) {
        if (wrel)  wrelS[tid]  = wrel[tid];
        if (wroot) wrootS[tid] = wroot[tid];
        if (gw)    gwS[tid]    = gw[tid];
        long long lr = row0 + tid;
        if (lr >= nrowsC) lr = nrowsC - 1;
        rowIdxS[tid] = aliveIdx ? aliveIdx[lr] : (int)lr;
    }
    __syncthreads();
    int tx = tid & 15, ty = tid >> 4;
    int srow = tid & 127;
    int koff = (tid >> 7) * 16;
    long long crow = row0 + srow;
    if (crow >= nrowsC) crow = nrowsC - 1;   // clamp: duplicate staging, write-guarded
    int orig = rowIdxS[srow];
    float fself = (V == 2) ? fvec[orig] : 1.0f;
    const float* selfp = (V == 1) ? zself : (xsrc + (long long)orig * 128);
    const float* aggp = AGG + crow * 128;

    int KB = (V == 1) ? 4 : 8;
    float acc[8][8] = {};
    for (int kb = 0; kb < KB; ++kb) {
        __syncthreads();
        bool isAgg = (kb < 4);
        if (isAgg) {
            const float* sp = aggp + kb * 32 + koff;
            #pragma unroll
            for (int q = 0; q < 4; ++q) {
                float4 v = *reinterpret_cast<const float4*>(sp + q * 4);
                Is[koff + q*4    ][srow] = v.x;
                Is[koff + q*4 + 1][srow] = v.y;
                Is[koff + q*4 + 2][srow] = v.z;
                Is[koff + q*4 + 3][srow] = v.w;
            }
        } else {
            const float* sp = selfp + (kb - 4) * 32 + koff;
            #pragma unroll
            for (int q = 0; q < 4; ++q) {
                float4 v = *reinterpret_cast<const float4*>(sp + q * 4);
                Is[koff + q*4    ][srow] = v.x * fself;
                Is[koff + q*4 + 1][srow] = v.y * fself;
                Is[koff + q*4 + 2][srow] = v.z * fself;
                Is[koff + q*4 + 3][srow] = v.w * fself;
            }
        }
        __syncthreads();
        const float* Wp = (isAgg ? Wl + kb * 32 * 128 : Wr + (kb - 4) * 32 * 128) + tx * 4;
        #pragma unroll
        for (int kk = 0; kk < 32; ++kk) {
            float4 w0 = *reinterpret_cast<const float4*>(Wp + kk * 128);
            float4 w1 = *reinterpret_cast<const float4*>(Wp + kk * 128 + 64);
            float4 i0 = *reinterpret_cast<const float4*>(&Is[kk][ty * 8]);
            float4 i1 = *reinterpret_cast<const float4*>(&Is[kk][ty * 8 + 4]);
            float ia[8] = {i0.x, i0.y, i0.z, i0.w, i1.x, i1.y, i1.z, i1.w};
            float wa[8] = {w0.x, w0.y, w0.z, w0.w, w1.x, w1.y, w1.z, w1.w};
            #pragma unroll
            for (int i = 0; i < 8; ++i)
                #pragma unroll
                for (int j = 0; j < 8; ++j)
                    acc[i][j] += ia[i] * wa[j];
        }
    }
    float br[8];
    if (V != 1) {
        float4 bl0 = *reinterpret_cast<const float4*>(&bl[tx * 4]);
        float4 bl1 = *reinterpret_cast<const float4*>(&bl[tx * 4 + 64]);
        br[0]=bl0.x; br[1]=bl0.y; br[2]=bl0.z; br[3]=bl0.w;
        br[4]=bl1.x; br[5]=bl1.y; br[6]=bl1.z; br[7]=bl1.w;
    }
    #pragma unroll
    for (int i = 0; i < 8; ++i) {
        long long cr = row0 + ty * 8 + i;
        bool valid = (cr < nrowsC);
        int rout = rowIdxS[ty * 8 + i];
        float zr[8];
        if (V == 1) {
            const float* zp = zself + (long long)(rout % NN) * 128;
            float4 z0 = *reinterpret_cast<const float4*>(&zp[tx * 4]);
            float4 z1 = *reinterpret_cast<const float4*>(&zp[tx * 4 + 64]);
            zr[0]=z0.x; zr[1]=z0.y; zr[2]=z0.z; zr[3]=z0.w;
            zr[4]=z1.x; zr[5]=z1.y; zr[6]=z1.z; zr[7]=z1.w;
        } else {
            #pragma unroll
            for (int j = 0; j < 8; ++j) zr[j] = br[j];
        }
        float yv[8];
        #pragma unroll
        for (int j = 0; j < 8; ++j) yv[j] = tanhf(acc[i][j] + zr[j]);
        if (valid) {
            *reinterpret_cast<float4*>(&y[(long long)rout * 128 + tx * 4]) = make_float4(yv[0], yv[1], yv[2], yv[3]);
            *reinterpret_cast<float4*>(&y[(long long)rout * 128 + tx * 4 + 64]) = make_float4(yv[4], yv[5], yv[6], yv[7]);
        }
        float tp = 0.0f, rp = 0.0f, gp = 0.0f;
        #pragma unroll
        for (int j = 0; j < 4; ++j) {
            if (tbuf)  tp += yv[j] * wrelS[tx*4 + j]  + yv[j+4] * wrelS[tx*4 + 64 + j];
            if (rootd) rp += yv[j] * wrootS[tx*4 + j] + yv[j+4] * wrootS[tx*4 + 64 + j];
            if (gdot)  gp += yv[j] * gwS[tx*4 + j]    + yv[j+4] * gwS[tx*4 + 64 + j];
        }
        #pragma unroll
        for (int m = 8; m >= 1; m >>= 1) {
            if (tbuf)  tp += __shfl_xor(tp, m, 16);
            if (rootd) rp += __shfl_xor(rp, m, 16);
            if (gdot)  gp += __shfl_xor(gp, m, 16);
        }
        if (tx == 0 && valid) {
            if (tbuf)  tbuf[rout]  = tp;
            if (rootd) rootd[rout] = rp;
            if (gdot)  gdot[rout]  = gp;
        }
    }
}

// ---------------- zself GEMM: y = x@W + b (no tanh, W from global) ----------------
__global__ __launch_bounds__(256) void k_gemm_self(
    const float* __restrict__ x, const float* __restrict__ W, const float* __restrict__ b,
    float* __restrict__ y, int nrows)
{
    __shared__ float Is[32][132];
    int tid = threadIdx.x;
    long long row0 = (long long)blockIdx.x * 128;
    int tx = tid & 15, ty = tid >> 4;
    int srow = tid & 127;
    int koff = (tid >> 7) * 16;
    long long lrow = row0 + srow;
    if (lrow >= nrows) lrow = nrows - 1;
    const float* xrow = x + lrow * 128;
    float acc[8][8] = {};
    for (int kb = 0; kb < 4; ++kb) {
        __syncthreads();
        {
            const float* sp = xrow + kb * 32 + koff;
            #pragma unroll
            for (int q = 0; q < 4; ++q) {
                float4 v = *reinterpret_cast<const float4*>(sp + q * 4);
                Is[koff + q*4    ][srow] = v.x;
                Is[koff + q*4 + 1][srow] = v.y;
                Is[koff + q*4 + 2][srow] = v.z;
                Is[koff + q*4 + 3][srow] = v.w;
            }
        }
        __syncthreads();
        const float* Wp = W + kb * 32 * 128 + tx * 4;
        #pragma unroll
        for (int kk = 0; kk < 32; ++kk) {
            float4 w0 = *reinterpret_cast<const float4*>(Wp + kk * 128);
            float4 w1 = *reinterpret_cast<const float4*>(Wp + kk * 128 + 64);
            float4 i0 = *reinterpret_cast<const float4*>(&Is[kk][ty * 8]);
            float4 i1 = *reinterpret_cast<const float4*>(&Is[kk][ty * 8 + 4]);
            float ia[8] = {i0.x, i0.y, i0.z, i0.w, i1.x, i1.y, i1.z, i1.w};
            float wa[8] = {w0.x, w0.y, w0.z, w0.w, w1.x, w1.y, w1.z, w1.w};
            #pragma unroll
            for (int i = 0; i < 8; ++i)
                #pragma unroll
                for (int j = 0; j < 8; ++j)
                    acc[i][j] += ia[i] * wa[j];
        }
    }
    float4 b0 = *reinterpret_cast<const float4*>(&b[tx * 4]);
    float4 b1 = *reinterpret_cast<const float4*>(&b[tx * 4 + 64]);
    #pragma unroll
    for (int i = 0; i < 8; ++i) {
        long long row = row0 + ty * 8 + i;
        if (row >= nrows) continue;
        *reinterpret_cast<float4*>(&y[row * 128 + tx * 4]) =
            make_float4(acc[i][0] + b0.x, acc[i][1] + b0.y, acc[i][2] + b0.z, acc[i][3] + b0.w);
        *reinterpret_cast<float4*>(&y[row * 128 + tx * 4 + 64]) =
            make_float4(acc[i][4] + b1.x, acc[i][5] + b1.y, acc[i][6] + b1.z, acc[i][7] + b1.w);
    }
}

// ---------------- stage-1 readout pieces ----------------
__global__ __launch_bounds__(256) void k_gate(
    const float* __restrict__ X, const float* __restrict__ gw,
    float* __restrict__ g, int nrows)
{
    __shared__ float wS[128];
    if (threadIdx.x < 128) wS[threadIdx.x] = gw[threadIdx.x];
    __syncthreads();
    int i = blockIdx.x * 256 + threadIdx.x;
    if (i >= nrows) return;
    const float4* xrp = reinterpret_cast<const float4*>(X + (long long)i * 128);
    float s = 0.0f;
    #pragma unroll
    for (int k = 0; k < 32; ++k) {
        float4 v = xrp[k];
        s += v.x * wS[4*k] + v.y * wS[4*k+1] + v.z * wS[4*k+2] + v.w * wS[4*k+3];
    }
    g[i] = s;
}

__global__ __launch_bounds__(1024) void k_smstats(float* __restrict__ g, float* __restrict__ invp) {
    __shared__ float red[1024];
    int p = blockIdx.x, tid = threadIdx.x;
    float* gp = g + (long long)p * NN;
    float lmax = -INFINITY;
    for (int n = tid; n < NN; n += 1024) lmax = fmaxf(lmax, gp[n]);
    red[tid] = lmax; __syncthreads();
    for (int s = 512; s > 0; s >>= 1) { if (tid < s) red[tid] = fmaxf(red[tid], red[tid + s]); __syncthreads(); }
    float mx = red[0]; __syncthreads();
    float ls = 0.0f;
    for (int n = tid; n < NN; n += 1024) { float e = expf(gp[n] - mx); gp[n] = e; ls += e; }
    red[tid] = ls; __syncthreads();
    for (int s = 512; s > 0; s >>= 1) { if (tid < s) red[tid] += red[tid + s]; __syncthreads(); }
    if (tid == 0) invp[p] = 1.0f / red[0];
}

__global__ __launch_bounds__(128) void k_wsum(
    const float* __restrict__ X, const float* __restrict__ a,
    const float* __restrict__ invp, float* __restrict__ ro, int rowbase, int colOff)
{
    int p = blockIdx.x / BPG;
    int chunk = blockIdx.x % BPG;
    int d = threadIdx.x;
    long long base = (long long)p * NN;
    int r0 = chunk * RB, r1 = r0 + RB;
    float s = 0.0f;
    for (int n = r0; n < r1; ++n) {
        float w = a[base + n];
        if (w != 0.0f) s += w * X[(base + n) * 128 + d];
    }
    atomicAdd(&ro[(long long)(rowbase + p) * 384 + colOff + d], s * invp[p]);
}

// stage-2 weighted sum over alive rows only
__global__ __launch_bounds__(128) void k_wsum_c(
    const float* __restrict__ X, const float* __restrict__ gbuf, const float* __restrict__ fvec,
    const float* __restrict__ invp, const int* __restrict__ aliveIdx, int k,
    float* __restrict__ ro, int rowbaseRo, int colOff)
{
    int bpp = k / RB;
    int p = blockIdx.x / bpp;
    int chunk = blockIdx.x % bpp;
    int d = threadIdx.x;
    const int* ai = aliveIdx + (long long)p * k + chunk * RB;
    float s = 0.0f;
    for (int j = 0; j < RB; ++j) {
        int row = ai[j];
        float w = gbuf[row] * fvec[row];
        s += w * X[(long long)row * 128 + d];
    }
    atomicAdd(&ro[(long long)(rowbaseRo + p) * 384 + colOff + d], s * invp[p]);
}

// ---------------- GraphNorm ----------------
__global__ void k_colstat(const float* __restrict__ x, float* __restrict__ musum,
                          float* __restrict__ sqsum, int nrows) {
    int d = threadIdx.x;
    int r0 = blockIdx.x * 64;
    int r1 = min(r0 + 64, nrows);
    float s = 0.0f, q = 0.0f;
    for (int r = r0; r < r1; ++r) { float v = x[(long long)r * 128 + d]; s += v; q += v * v; }
    atomicAdd(&musum[d], s);
    atomicAdd(&sqsum[d], q);
}

__global__ void k_gnorm_apply(const float* __restrict__ x, float* __restrict__ y,
                              const float* __restrict__ musum, const float* __restrict__ sqsum,
                              const float* __restrict__ w, const float* __restrict__ b,
                              const float* __restrict__ ms, int nrows) {
    long long i = (long long)blockIdx.x * 256 + threadIdx.x;
    if (i >= (long long)nrows * 128) return;
    int d = (int)(i & 127);
    float inv_n = 1.0f / (float)nrows;
    float mu = musum[d] * inv_n;
    float c = mu * ms[d];
    float var = sqsum[d] * inv_n - 2.0f * c * mu + c * c;
    y[i] = w[d] * (x[i] - c) * rsqrtf(var + 1e-5f) + b[d];
}

// ---------------- mega top-k (1024 threads) ----------------
#define TCH 8   // NN/1024 rounded up
__global__ __launch_bounds__(1024) void k_topk2(
    const int* __restrict__ rowptr, const int* __restrict__ col, int rowbase,
    const float* __restrict__ tb, const float* __restrict__ rootd,
    const float* __restrict__ gdot, const float* __restrict__ brelp, int bi,
    float* __restrict__ nalive, float* __restrict__ fvec, float* __restrict__ gbuf,
    float* __restrict__ invp, int* __restrict__ aliveIdx, int k)
{
    __shared__ unsigned keys[NN];
    __shared__ int hist[256];
    __shared__ int scan[1024];
    __shared__ float redf[1024];
    __shared__ unsigned sh_pref;
    __shared__ int sh_kneed;
    int p = blockIdx.x, tid = threadIdx.x;
    float brel = brelp[bi];
    long long pbase = (long long)p * NN;
    for (int n = tid; n < NN; n += 1024) {
        long long gl = pbase + n;
        int grow = rowbase + (int)gl;
        float s = brel + rootd[gl];
        int b = rowptr[grow], e = rowptr[grow + 1];
        for (int q = b; q < e; ++q) {
            int sl = col[q] - rowbase;
            s += tb[sl] * nalive[sl];
        }
        keys[n] = (nalive[gl] > 0.5f) ? fkey(s) : 0u;
    }
    if (tid == 0) { sh_pref = 0u; sh_kneed = k; }
    __syncthreads();
    for (int lvl = 3; lvl >= 0; --lvl) {
        int sh = lvl * 8;
        if (tid < 256) hist[tid] = 0;
        unsigned pref = sh_pref; int kneed = sh_kneed;
        unsigned pmask = (lvl == 3) ? 0u : (0xFFFFFFFFu << (8 * (lvl + 1)));
        __syncthreads();
        for (int n = tid; n < NN; n += 1024) {
            unsigned kv = keys[n];
            if ((kv & pmask) == pref) atomicAdd(&hist[(kv >> sh) & 255], 1);
        }
        __syncthreads();
        if (tid == 0) {
            int cum = 0, b = 255;
            for (; b >= 0; --b) { cum += hist[b]; if (cum >= kneed) break; }
            sh_pref = pref | ((unsigned)b << sh);
            sh_kneed = kneed - (cum - hist[b]);
        }
        __syncthreads();
    }
    unsigned V = sh_pref;
    int seleq = sh_kneed;
    int c0 = tid * TCH, c1 = min(c0 + TCH, NN);
    int ceq = 0;
    for (int n = c0; n < c1; ++n) ceq += (keys[n] == V) ? 1 : 0;
    // exclusive scan of ceq over 1024 threads
    scan[tid] = ceq; __syncthreads();
    for (int off = 1; off < 1024; off <<= 1) {
        int u = (tid >= off) ? scan[tid - off] : 0;
        __syncthreads();
        scan[tid] += u;
        __syncthreads();
    }
    int rank = scan[tid] - ceq;
    unsigned selmask = 0u;
    int nsel = 0;
    float lmax = -INFINITY;
    for (int n = c0; n < c1; ++n) {
        unsigned kk = keys[n];
        bool sel = (kk > V) || (kk == V && rank < seleq);
        if (kk == V) rank++;
        long long gl = pbase + n;
        nalive[gl] = sel ? 1.0f : 0.0f;
        float f = 0.0f;
        if (sel) {
            f = tanhf(fkey_inv(kk));
            lmax = fmaxf(lmax, f * gdot[gl]);
            selmask |= (1u << (n - c0));
            ++nsel;
        }
        fvec[gl] = f;
    }
    redf[tid] = lmax; __syncthreads();
    for (int s = 512; s > 0; s >>= 1) { if (tid < s) redf[tid] = fmaxf(redf[tid], redf[tid + s]); __syncthreads(); }
    float mx = redf[0]; __syncthreads();
    // exclusive scan of nsel
    scan[tid] = nsel; __syncthreads();
    for (int off = 1; off < 1024; off <<= 1) {
        int u = (tid >= off) ? scan[tid - off] : 0;
        __syncthreads();
        scan[tid] += u;
        __syncthreads();
    }
    int pos = scan[tid] - nsel;
    float lsum = 0.0f;
    for (int n = c0; n < c1; ++n) {
        if (selmask & (1u << (n - c0))) {
            long long gl = pbase + n;
            float e = expf(fvec[gl] * gdot[gl] - mx);
            gbuf[gl] = e;
            lsum += e;
            aliveIdx[(long long)p * k + pos] = (int)gl;
            ++pos;
        }
    }
    redf[tid] = lsum; __syncthreads();
    for (int s = 512; s > 0; s >>= 1) { if (tid < s) redf[tid] += redf[tid + s]; __syncthreads(); }
    if (tid == 0) invp[p] = 1.0f / redf[0];
}

// ---------------- head ----------------
__global__ __launch_bounds__(64) void k_head(
    const float* __restrict__ ro, const float* __restrict__ lin_w, const float* __restrict__ lin_b,
    const float* __restrict__ m1w, const float* __restrict__ m1b,
    const float* __restrict__ m2w, const float* __restrict__ m2b,
    const float* __restrict__ m3w, const float* __restrict__ m3b, float* __restrict__ out)
{
    __shared__ float v[33], h1[48], h2[16];
    int t = threadIdx.x;
    if (t < 33) {
        float s = lin_b[0];
        for (int k = 0; k < 384; ++k) s += ro[t * 384 + k] * lin_w[k];
        v[t] = tanhf(s);
    }
    __syncthreads();
    if (t < 48) {
        float s = m1b[t];
        for (int i = 0; i < 33; ++i) s += v[i] * m1w[i * 48 + t];
        h1[t] = tanhf(s);
    }
    __syncthreads();
    if (t < 16) {
        float s = m2b[t];
        for (int i = 0; i < 48; ++i) s += h1[i] * m2w[i * 16 + t];
        h2[t] = tanhf(s);
    }
    __syncthreads();
    if (t == 0) {
        float s = m3b[0];
        for (int i = 0; i < 16; ++i) s += h2[i] * m3w[i];
        float s1 = 1.0f / (1.0f + expf(-s));
        out[0] = 1.0f / (1.0f + expf(-s1));
    }
}

static inline int cdiv(long long a, long long b) { return (int)((a + b - 1) / b); }

extern "C" void kernel_launch(void* const* d_in, const int* in_sizes, int n_in,
                              void* d_out, int out_size, void* d_ws, size_t ws_size,
                              hipStream_t stream)
{
    (void)in_sizes; (void)n_in; (void)out_size;
    const float* h     = (const float*)d_in[0];
    const int*   eidx  = (const int*)d_in[1];
    const int*   seidx = (const int*)d_in[2];
    const float* Wl_a  = (const float*)d_in[3];
    const float* Wr_a  = (const float*)d_in[4];
    const float* bl_a  = (const float*)d_in[5];
    const float* Wl_s  = (const float*)d_in[6];
    const float* Wr_s  = (const float*)d_in[7];
    const float* bl_s  = (const float*)d_in[8];
    const float* gate_w = (const float*)d_in[9];
    const float* p_wrel = (const float*)d_in[11];
    const float* p_brel = (const float*)d_in[12];
    const float* p_wroot= (const float*)d_in[13];
    const float* nw    = (const float*)d_in[14];
    const float* nb    = (const float*)d_in[15];
    const float* nms   = (const float*)d_in[16];
    const float* lin_w = (const float*)d_in[17];
    const float* lin_b = (const float*)d_in[18];
    const float* m1w   = (const float*)d_in[19];
    const float* m1b   = (const float*)d_in[20];
    const float* m2w   = (const float*)d_in[21];
    const float* m2b   = (const float*)d_in[22];
    const float* m3w   = (const float*)d_in[23];
    const float* m3b   = (const float*)d_in[24];
    float* out = (float*)d_out;

    const int* esrc = eidx;
    const int* edst = eidx + EG;
    const int* ssrc = seidx;
    const int* sdst = seidx + ES_TOT;

    auto need_bytes = [](int chp) -> size_t {
        long long chn = (long long)chp * NN;
        long long f = 3 * chn * 128
                    + 3LL * NN * 128
                    + NN * 16 + NN
                    + 6 * chn
                    + (long long)chp * KK1
                    + 64 + 33 * 384 + 256
                    + (NN + (NN+1) + NN + EG + NN + 1024)
                    + (PN + (PN+1) + PN + ES_TOT + PN + 1024)
                    + 64 * 48;
        return (size_t)f * 4;
    };
    int chp = 4;
    if (ws_size >= need_bytes(16)) chp = 16;
    else if (ws_size >= need_bytes(8)) chp = 8;
    int nch = PP / chp;
    long long ch_n = (long long)chp * NN;

    float* W = (float*)d_ws;
    size_t off = 0;
    auto alloc = [&](size_t nf) { float* p = W + off; off += (nf + 63) & ~(size_t)63; return p; };
    float* XA    = alloc((size_t)ch_n * DD);
    float* XB    = alloc((size_t)ch_n * DD);
    float* AGG   = alloc((size_t)ch_n * DD);
    float* xa    = alloc((size_t)NN * DD);
    float* xb    = alloc((size_t)NN * DD);
    float* zself = alloc((size_t)NN * DD);
    float* agg1  = alloc((size_t)NN * 16);
    float* deg1  = alloc(NN);
    float* tbuf  = alloc(ch_n);
    float* rootd = alloc(ch_n);
    float* nal   = alloc(ch_n);
    float* fvec  = alloc(ch_n);
    float* gdot  = alloc(ch_n);
    float* gbuf  = alloc(ch_n);
    float* invp  = alloc(64);
    float* ro    = alloc(33 * 384);
    float* musum = alloc(128);
    float* sqsum = alloc(128);
    int* aliveIdx = (int*)alloc((size_t)chp * KK1);
    int* s1cnt  = (int*)alloc(NN);
    int* s1rp   = (int*)alloc(NN + 1);
    int* s1cur  = (int*)alloc(NN);
    int* s1col  = (int*)alloc(EG);
    int* s1part = (int*)alloc(NN);
    int* s1bsum = (int*)alloc(1024);
    int* s2cnt  = (int*)alloc(PN);
    int* s2rp   = (int*)alloc(PN + 1);
    int* s2cur  = (int*)alloc(PN);
    int* s2col  = (int*)alloc(ES_TOT);
    int* s2part = (int*)alloc(PN);
    int* s2bsum = (int*)alloc(1024);

    // ---------- CSR builds ----------
    int nb1 = cdiv(NN, 1024), nb2 = cdiv(PN, 1024);
    hipMemsetAsync(s1cnt, 0, NN * sizeof(int), stream);
    k_hist<<<cdiv(EG,256),256,0,stream>>>(edst, s1cnt, EG);
    k_scanA<<<nb1,1024,0,stream>>>(s1cnt, s1part, s1bsum, NN);
    k_scanB<<<1,1024,0,stream>>>(s1bsum, nb1);
    k_scanC<<<cdiv(NN,256),256,0,stream>>>(s1part, s1bsum, s1rp, s1cur, NN, EG);
    k_scatter<<<cdiv(EG,256),256,0,stream>>>(esrc, edst, s1cur, s1col, EG);

    hipMemsetAsync(s2cnt, 0, (size_t)PN * sizeof(int), stream);
    k_hist<<<cdiv(ES_TOT,256),256,0,stream>>>(sdst, s2cnt, ES_TOT);
    k_scanA<<<nb2,1024,0,stream>>>(s2cnt, s2part, s2bsum, PN);
    k_scanB<<<1,1024,0,stream>>>(s2bsum, nb2);
    k_scanC<<<cdiv(PN,256),256,0,stream>>>(s2part, s2bsum, s2rp, s2cur, PN, ES_TOT);
    k_scatter<<<cdiv(ES_TOT,256),256,0,stream>>>(ssrc, sdst, s2cur, s2col, ES_TOT);

    hipMemsetAsync(ro, 0, 33 * 384 * sizeof(float), stream);

    // ---------- stage 1 ----------
    k_agg16<<<cdiv((long long)NN*16,256),256,0,stream>>>(h, s1rp, s1col, agg1, deg1, NN);
    k_sage16<<<cdiv((long long)NN*DD,256),256,0,stream>>>(h, agg1, deg1, Wl_a, Wr_a, bl_a, xa, NN);
    k_gate<<<cdiv(NN,256),256,0,stream>>>(xa, gate_w + 0*DD, gbuf, NN);
    k_smstats<<<1,1024,0,stream>>>(gbuf, invp);
    k_wsum<<<BPG,128,0,stream>>>(xa, gbuf, invp, ro, 0, 0);

    hipMemsetAsync(musum, 0, 128*sizeof(float), stream);
    hipMemsetAsync(sqsum, 0, 128*sizeof(float), stream);
    k_colstat<<<cdiv(NN,64),128,0,stream>>>(xa, musum, sqsum, NN);
    k_gnorm_apply<<<cdiv((long long)NN*DD,256),256,0,stream>>>(xa, xb, musum, sqsum, nw, nb, nms, NN);

    k_aggf<<<cdiv(NN,8),256,0,stream>>>(xb, s1rp, s1col, nullptr, nullptr, nullptr, 0, 0, 0, AGG, NN);
    k_sage_d<<<cdiv(NN,128),256,0,stream>>>(AGG, xb, nullptr, nullptr, nullptr, 0,
        Wl_s + 0*16384, Wr_s + 0*16384, bl_s + 0*128, xa, NN,
        nullptr, nullptr, gate_w + 1*DD, nullptr, nullptr, gbuf);
    k_smstats<<<1,1024,0,stream>>>(gbuf, invp);
    k_wsum<<<BPG,128,0,stream>>>(xa, gbuf, invp, ro, 0, 128);

    hipMemsetAsync(musum, 0, 128*sizeof(float), stream);
    hipMemsetAsync(sqsum, 0, 128*sizeof(float), stream);
    k_colstat<<<cdiv(NN,64),128,0,stream>>>(xa, musum, sqsum, NN);
    k_gnorm_apply<<<cdiv((long long)NN*DD,256),256,0,stream>>>(xa, xb, musum, sqsum, nw, nb, nms, NN);

    k_aggf<<<cdiv(NN,8),256,0,stream>>>(xb, s1rp, s1col, nullptr, nullptr, nullptr, 0, 0, 0, AGG, NN);
    k_sage_d<<<cdiv(NN,128),256,0,stream>>>(AGG, xb, nullptr, nullptr, nullptr, 0,
        Wl_s + 1*16384, Wr_s + 1*16384, bl_s + 1*128, xa, NN,
        nullptr, nullptr, gate_w + 2*DD, nullptr, nullptr, gbuf);
    k_smstats<<<1,1024,0,stream>>>(gbuf, invp);
    k_wsum<<<BPG,128,0,stream>>>(xa, gbuf, invp, ro, 0, 256);

    // ---------- stage 2 ----------
    k_gemm_self<<<cdiv(NN,128),256,0,stream>>>(xa, Wr_s + 2*16384, bl_s + 2*128, zself, NN);

    for (int c = 0; c < nch; ++c) {
        int nbase = (int)(c * ch_n);
        k_fill<<<cdiv(ch_n,256),256,0,stream>>>(nal, 1.0f, (int)ch_n);

        // ---- layer 0: all rows, K=128 + zself ----
        k_aggf<<<(int)(ch_n/8),256,0,stream>>>(xa, s2rp, s2col, nullptr, nullptr, nullptr, 1, 1, nbase, AGG, (int)ch_n);
        k_sage_d<<<(int)(ch_n/128),256,0,stream>>>(AGG, nullptr, zself, nullptr, nullptr, 1,
            Wl_s + 2*16384, nullptr, nullptr, XA, (int)ch_n,
            p_wrel + 0*DD, p_wroot + 0*DD, gate_w + 3*DD, tbuf, rootd, gdot);
        k_topk2<<<chp,1024,0,stream>>>(s2rp, s2col, nbase, tbuf, rootd, gdot, p_brel, 0,
                                       nal, fvec, gbuf, invp, aliveIdx, KK1);
        k_wsum_c<<<chp*(KK1/RB),128,0,stream>>>(XA, gbuf, fvec, invp, aliveIdx, KK1, ro, 1 + c*chp, 0);

        // ---- layer 1: alive K1 rows ----
        k_aggf<<<chp*(KK1/8),256,0,stream>>>(XA, s2rp, s2col, aliveIdx, nal, fvec, 2, 0, nbase, AGG, chp*KK1);
        k_sage_d<<<chp*(KK1/128),256,0,stream>>>(AGG, XA, nullptr, aliveIdx, fvec, 2,
            Wl_s + 3*16384, Wr_s + 3*16384, bl_s + 3*128, XB, chp*KK1,
            p_wrel + 1*DD, p_wroot + 1*DD, gate_w + 4*DD, tbuf, rootd, gdot);
        k_topk2<<<chp,1024,0,stream>>>(s2rp, s2col, nbase, tbuf, rootd, gdot, p_brel, 1,
                                       nal, fvec, gbuf, invp, aliveIdx, KK2);
        k_wsum_c<<<chp*(KK2/RB),128,0,stream>>>(XB, gbuf, fvec, invp, aliveIdx, KK2, ro, 1 + c*chp, 128);

        // ---- layer 2: alive K2 rows ----
        k_aggf<<<chp*(KK2/8),256,0,stream>>>(XB, s2rp, s2col, aliveIdx, nal, fvec, 2, 0, nbase, AGG, chp*KK2);
        k_sage_d<<<chp*(KK2/128),256,0,stream>>>(AGG, XB, nullptr, aliveIdx, fvec, 2,
            Wl_s + 4*16384, Wr_s + 4*16384, bl_s + 4*128, XA, chp*KK2,
            p_wrel + 2*DD, p_wroot + 2*DD, gate_w + 5*DD, tbuf, rootd, gdot);
        k_topk2<<<chp,1024,0,stream>>>(s2rp, s2col, nbase, tbuf, rootd, gdot, p_brel, 2,
                                       nal, fvec, gbuf, invp, aliveIdx, KK3);
        k_wsum_c<<<chp*(KK3/RB),128,0,stream>>>(XA, gbuf, fvec, invp, aliveIdx, KK3, ro, 1 + c*chp, 256);
    }

    // ---------- head ----------
    k_head<<<1,64,0,stream>>>(ro, lin_w, lin_b, m1w, m1b, m2w, m2b, m3w, m3b, out);
}

// Round 11
// 1525.335 us; speedup vs baseline: 1.7228x; 1.1681x over previous
//
#include <hip/hip_runtime.h>
#include <math.h>

#define NN      8000
#define PP      32
#define EG      128000
#define ES_TOT  131072     // P * 4096
#define ES_P    4096
#define PN      256000     // P * NN
#define DI      16
#define DD      128
#define KK1     6400
#define KK2     5120
#define KK3     4096
#define RB      64                   // rows per wsum block
#define BPG     (NN / RB)            // 125 blocks per graph (stage-1 wsum)

static __device__ __forceinline__ unsigned fkey(float f) {
    unsigned u = __float_as_uint(f);
    return (u & 0x80000000u) ? ~u : (u | 0x80000000u);
}
static __device__ __forceinline__ float fkey_inv(unsigned k) {
    unsigned u = (k & 0x80000000u) ? (k & 0x7FFFFFFFu) : ~k;
    return __uint_as_float(u);
}

__global__ void k_fill(float* p, float v, int n) {
    int i = blockIdx.x * 256 + threadIdx.x;
    if (i < n) p[i] = v;
}

// ---------------- CSR build ----------------
__global__ void k_hist(const int* __restrict__ dst, int* __restrict__ cnt, int ne) {
    int e = blockIdx.x * 256 + threadIdx.x;
    if (e < ne) atomicAdd(&cnt[dst[e]], 1);
}

__global__ __launch_bounds__(1024) void k_scanA(const int* __restrict__ cnt,
                                                int* __restrict__ part,
                                                int* __restrict__ bsum, int n) {
    __shared__ int sh[1024];
    int t = threadIdx.x;
    int i = blockIdx.x * 1024 + t;
    int v = (i < n) ? cnt[i] : 0;
    sh[t] = v; __syncthreads();
    for (int off = 1; off < 1024; off <<= 1) {
        int u = (t >= off) ? sh[t - off] : 0;
        __syncthreads();
        sh[t] += u;
        __syncthreads();
    }
    if (i < n) part[i] = sh[t] - v;
    if (t == 1023) bsum[blockIdx.x] = sh[1023];
}

__global__ __launch_bounds__(1024) void k_scanB(int* __restrict__ bsum, int nb) {
    __shared__ int sh[1024];
    int t = threadIdx.x;
    int v = (t < nb) ? bsum[t] : 0;
    sh[t] = v; __syncthreads();
    for (int off = 1; off < 1024; off <<= 1) {
        int u = (t >= off) ? sh[t - off] : 0;
        __syncthreads();
        sh[t] += u;
        __syncthreads();
    }
    if (t < nb) bsum[t] = sh[t] - v;   // exclusive
}

__global__ void k_scanC(const int* __restrict__ part, const int* __restrict__ bsum,
                        int* __restrict__ rowptr, int* __restrict__ cursor, int n, int total) {
    int i = blockIdx.x * 256 + threadIdx.x;
    if (i < n) {
        int v = part[i] + bsum[i >> 10];
        rowptr[i] = v;
        cursor[i] = v;
    }
    if (i == 0) rowptr[n] = total;
}

__global__ void k_scatter(const int* __restrict__ src, const int* __restrict__ dst,
                          int* __restrict__ cursor, int* __restrict__ col, int ne) {
    int e = blockIdx.x * 256 + threadIdx.x;
    if (e >= ne) return;
    int pos = atomicAdd(&cursor[dst[e]], 1);
    col[pos] = src[e];
}

// ---------------- stage-1 layer a ----------------
__global__ __launch_bounds__(256) void k_agg16(const float* __restrict__ h,
                                               const int* __restrict__ rowptr,
                                               const int* __restrict__ col,
                                               float* __restrict__ agg, float* __restrict__ deg,
                                               int nrows) {
    int i = blockIdx.x * 256 + threadIdx.x;
    int r = i >> 4, j = i & 15;
    if (r >= nrows) return;
    int b = rowptr[r], e = rowptr[r + 1];
    float a = h[r * 16 + j];
    for (int q = b; q < e; ++q) a += h[col[q] * 16 + j];
    agg[r * 16 + j] = a;
    if (j == 0) deg[r] = 1.0f + (float)(e - b);
}

__global__ __launch_bounds__(256) void k_sage16(
    const float* __restrict__ h, const float* __restrict__ agg, const float* __restrict__ deg,
    const float* __restrict__ Wl, const float* __restrict__ Wr, const float* __restrict__ bl,
    float* __restrict__ y, int nrows)
{
    __shared__ float WlS[16][128], WrS[16][128];
    int tid = threadIdx.x;
    for (int i = tid; i < 16 * 128; i += 256) {
        WlS[i >> 7][i & 127] = Wl[i];
        WrS[i >> 7][i & 127] = Wr[i];
    }
    __syncthreads();
    long long o = (long long)blockIdx.x * 256 + tid;
    int row = (int)(o >> 7);
    if (row >= nrows) return;
    int d = (int)o & 127;
    float invd = 1.0f / fmaxf(deg[row], 1.0f);
    float s = bl[d];
    #pragma unroll
    for (int k = 0; k < 16; ++k)
        s += agg[row * 16 + k] * invd * WlS[k][d] + h[row * 16 + k] * WrS[k][d];
    y[(long long)row * 128 + d] = tanhf(s);
}

// ---------------- CSR gather-aggregate (row-parallel, no atomics) ----------------
__global__ __launch_bounds__(256) void k_aggf(
    const float* __restrict__ x,
    const int* __restrict__ rowptr, const int* __restrict__ col,
    const int* __restrict__ aliveIdx, const float* __restrict__ nal, const float* __restrict__ fvec,
    int mode, int xModN, int rowbase,
    float* __restrict__ AGG, int nrowsC)
{
    int tid = threadIdx.x;
    int r = blockIdx.x * 8 + (tid >> 5);
    if (r >= nrowsC) return;
    int lane = tid & 31;
    int orig = aliveIdx ? aliveIdx[r] : r;
    int grow = rowbase + orig;
    int b = rowptr[grow], e = rowptr[grow + 1];
    float4 a = make_float4(0.0f, 0.0f, 0.0f, 0.0f);
    float dsum = 0.0f;
    if (mode == 0) {
        a = *reinterpret_cast<const float4*>(x + (long long)orig * 128 + lane * 4);
        dsum = 1.0f;
    }
    for (int q = b; q < e; ++q) {
        int s = col[q];
        float fw = 1.0f;
        int fr;
        if (mode == 2) {
            fr = s - rowbase;
            if (nal[fr] == 0.0f) continue;
            dsum += 1.0f;
            fw = fvec[fr];
            if (fw == 0.0f) continue;
        } else {
            fr = xModN ? (s % NN) : (s - rowbase);
            dsum += 1.0f;
        }
        float4 v = *reinterpret_cast<const float4*>(x + (long long)fr * 128 + lane * 4);
        a.x += v.x * fw; a.y += v.y * fw; a.z += v.z * fw; a.w += v.w * fw;
    }
    float invds = 1.0f / fmaxf(dsum, 1.0f);
    a.x *= invds; a.y *= invds; a.z *= invds; a.w *= invds;
    *reinterpret_cast<float4*>(AGG + (long long)r * 128 + lane * 4) = a;
}

// ---------------- dense SAGE GEMM, v2 tile: BM=64, 8x4 acc, low VGPR ----------------
// V 0 (stage-1): y=tanh(AGG@Wl + bl + x[crow]@Wr), K=256
// V 1 (s2 L0):   y=tanh(AGG@Wl + zself[crow%NN]), K=128
// V 2 (s2 L1/2): y=tanh(AGG@Wl + bl + fvec[orig]*x[orig]@Wr), orig=aliveIdx[crow], K=256
__global__ __launch_bounds__(256) void k_sage_d(
    const float* __restrict__ AGG, const float* __restrict__ xsrc, const float* __restrict__ zself,
    const int* __restrict__ aliveIdx, const float* __restrict__ fvec,
    int V,
    const float* __restrict__ Wl, const float* __restrict__ Wr, const float* __restrict__ bl,
    float* __restrict__ y, int nrowsC,
    const float* __restrict__ wrel, const float* __restrict__ wroot, const float* __restrict__ gw,
    float* __restrict__ tbuf, float* __restrict__ rootd, float* __restrict__ gdot)
{
    __shared__ float Ws[32 * 128];
    __shared__ float Is[32][68];
    __shared__ float wrelS[128], wrootS[128], gwS[128];
    __shared__ int rowIdxS[64];
    int tid = threadIdx.x;
    long long row0 = (long long)blockIdx.x * 64;
    if (tid < 128) {
        if (wrel)  wrelS[tid]  = wrel[tid];
        if (wroot) wrootS[tid] = wroot[tid];
        if (gw)    gwS[tid]    = gw[tid];
    }
    if (tid < 64) {
        long long lr = row0 + tid;
        if (lr >= nrowsC) lr = nrowsC - 1;
        rowIdxS[tid] = aliveIdx ? aliveIdx[lr] : (int)lr;
    }
    __syncthreads();
    int tx = tid & 31, ty = tid >> 5;       // cols tx*4..+3, rows ty*8..+7
    int srow = tid & 63;
    int koff = (tid >> 6) * 8;              // quarter-wave stages 8 k-dims
    long long crow = row0 + srow;
    if (crow >= nrowsC) crow = nrowsC - 1;  // clamp: duplicate staging, write-guarded
    int orig = rowIdxS[srow];
    float fself = (V == 2) ? fvec[orig] : 1.0f;
    const float* selfp = (V == 1) ? nullptr : (xsrc + (long long)orig * 128);
    const float* aggp = AGG + crow * 128;

    int KB = (V == 1) ? 4 : 8;
    float acc[8][4] = {};
    for (int kb = 0; kb < KB; ++kb) {
        __syncthreads();
        bool isAgg = (kb < 4);
        const float* Wsrc = isAgg ? (Wl + kb * 32 * 128) : (Wr + (kb - 4) * 32 * 128);
        #pragma unroll
        for (int j = 0; j < 4; ++j) {
            int fl = j * 1024 + tid * 4;
            *reinterpret_cast<float4*>(&Ws[fl]) = *reinterpret_cast<const float4*>(&Wsrc[fl]);
        }
        {
            const float* sp = (isAgg ? (aggp + kb * 32) : (selfp + (kb - 4) * 32)) + koff;
            float m = isAgg ? 1.0f : fself;
            float4 v0 = *reinterpret_cast<const float4*>(sp);
            float4 v1 = *reinterpret_cast<const float4*>(sp + 4);
            Is[koff + 0][srow] = v0.x * m; Is[koff + 1][srow] = v0.y * m;
            Is[koff + 2][srow] = v0.z * m; Is[koff + 3][srow] = v0.w * m;
            Is[koff + 4][srow] = v1.x * m; Is[koff + 5][srow] = v1.y * m;
            Is[koff + 6][srow] = v1.z * m; Is[koff + 7][srow] = v1.w * m;
        }
        __syncthreads();
        #pragma unroll
        for (int kk = 0; kk < 32; ++kk) {
            float4 wv = *reinterpret_cast<const float4*>(&Ws[kk * 128 + tx * 4]);
            float4 i0 = *reinterpret_cast<const float4*>(&Is[kk][ty * 8]);
            float4 i1 = *reinterpret_cast<const float4*>(&Is[kk][ty * 8 + 4]);
            float ia[8] = {i0.x, i0.y, i0.z, i0.w, i1.x, i1.y, i1.z, i1.w};
            float wa[4] = {wv.x, wv.y, wv.z, wv.w};
            #pragma unroll
            for (int i = 0; i < 8; ++i)
                #pragma unroll
                for (int j = 0; j < 4; ++j)
                    acc[i][j] += ia[i] * wa[j];
        }
    }
    float br[4];
    if (V != 1) {
        float4 bl0 = *reinterpret_cast<const float4*>(&bl[tx * 4]);
        br[0] = bl0.x; br[1] = bl0.y; br[2] = bl0.z; br[3] = bl0.w;
    }
    #pragma unroll
    for (int i = 0; i < 8; ++i) {
        long long cr = row0 + ty * 8 + i;
        bool valid = (cr < nrowsC);
        int rout = rowIdxS[ty * 8 + i];
        float zr[4];
        if (V == 1) {
            const float* zp = zself + (long long)(rout % NN) * 128;
            float4 z0 = *reinterpret_cast<const float4*>(&zp[tx * 4]);
            zr[0] = z0.x; zr[1] = z0.y; zr[2] = z0.z; zr[3] = z0.w;
        } else {
            #pragma unroll
            for (int j = 0; j < 4; ++j) zr[j] = br[j];
        }
        float yv[4];
        #pragma unroll
        for (int j = 0; j < 4; ++j) yv[j] = tanhf(acc[i][j] + zr[j]);
        if (valid)
            *reinterpret_cast<float4*>(&y[(long long)rout * 128 + tx * 4]) = make_float4(yv[0], yv[1], yv[2], yv[3]);
        float tp = 0.0f, rp = 0.0f, gp = 0.0f;
        #pragma unroll
        for (int j = 0; j < 4; ++j) {
            if (tbuf)  tp += yv[j] * wrelS[tx*4 + j];
            if (rootd) rp += yv[j] * wrootS[tx*4 + j];
            if (gdot)  gp += yv[j] * gwS[tx*4 + j];
        }
        #pragma unroll
        for (int m = 16; m >= 1; m >>= 1) {
            if (tbuf)  tp += __shfl_xor(tp, m, 32);
            if (rootd) rp += __shfl_xor(rp, m, 32);
            if (gdot)  gp += __shfl_xor(gp, m, 32);
        }
        if (tx == 0 && valid) {
            if (tbuf)  tbuf[rout]  = tp;
            if (rootd) rootd[rout] = rp;
            if (gdot)  gdot[rout]  = gp;
        }
    }
}

// ---------------- zself GEMM: y = x@W + b (no tanh), v2 tile ----------------
__global__ __launch_bounds__(256) void k_gemm_self(
    const float* __restrict__ x, const float* __restrict__ W, const float* __restrict__ b,
    float* __restrict__ y, int nrows)
{
    __shared__ float Ws[32 * 128];
    __shared__ float Is[32][68];
    int tid = threadIdx.x;
    long long row0 = (long long)blockIdx.x * 64;
    int tx = tid & 31, ty = tid >> 5;
    int srow = tid & 63;
    int koff = (tid >> 6) * 8;
    long long lrow = row0 + srow;
    if (lrow >= nrows) lrow = nrows - 1;
    const float* xrow = x + lrow * 128;
    float acc[8][4] = {};
    for (int kb = 0; kb < 4; ++kb) {
        __syncthreads();
        const float* Wsrc = W + kb * 32 * 128;
        #pragma unroll
        for (int j = 0; j < 4; ++j) {
            int fl = j * 1024 + tid * 4;
            *reinterpret_cast<float4*>(&Ws[fl]) = *reinterpret_cast<const float4*>(&Wsrc[fl]);
        }
        {
            const float* sp = xrow + kb * 32 + koff;
            float4 v0 = *reinterpret_cast<const float4*>(sp);
            float4 v1 = *reinterpret_cast<const float4*>(sp + 4);
            Is[koff + 0][srow] = v0.x; Is[koff + 1][srow] = v0.y;
            Is[koff + 2][srow] = v0.z; Is[koff + 3][srow] = v0.w;
            Is[koff + 4][srow] = v1.x; Is[koff + 5][srow] = v1.y;
            Is[koff + 6][srow] = v1.z; Is[koff + 7][srow] = v1.w;
        }
        __syncthreads();
        #pragma unroll
        for (int kk = 0; kk < 32; ++kk) {
            float4 wv = *reinterpret_cast<const float4*>(&Ws[kk * 128 + tx * 4]);
            float4 i0 = *reinterpret_cast<const float4*>(&Is[kk][ty * 8]);
            float4 i1 = *reinterpret_cast<const float4*>(&Is[kk][ty * 8 + 4]);
            float ia[8] = {i0.x, i0.y, i0.z, i0.w, i1.x, i1.y, i1.z, i1.w};
            float wa[4] = {wv.x, wv.y, wv.z, wv.w};
            #pragma unroll
            for (int i = 0; i < 8; ++i)
                #pragma unroll
                for (int j = 0; j < 4; ++j)
                    acc[i][j] += ia[i] * wa[j];
        }
    }
    float4 b0 = *reinterpret_cast<const float4*>(&b[tx * 4]);
    #pragma unroll
    for (int i = 0; i < 8; ++i) {
        long long row = row0 + ty * 8 + i;
        if (row >= nrows) continue;
        *reinterpret_cast<float4*>(&y[row * 128 + tx * 4]) =
            make_float4(acc[i][0] + b0.x, acc[i][1] + b0.y, acc[i][2] + b0.z, acc[i][3] + b0.w);
    }
}

// ---------------- stage-1 readout pieces ----------------
__global__ __launch_bounds__(256) void k_gate(
    const float* __restrict__ X, const float* __restrict__ gw,
    float* __restrict__ g, int nrows)
{
    __shared__ float wS[128];
    if (threadIdx.x < 128) wS[threadIdx.x] = gw[threadIdx.x];
    __syncthreads();
    int i = blockIdx.x * 256 + threadIdx.x;
    if (i >= nrows) return;
    const float4* xrp = reinterpret_cast<const float4*>(X + (long long)i * 128);
    float s = 0.0f;
    #pragma unroll
    for (int k = 0; k < 32; ++k) {
        float4 v = xrp[k];
        s += v.x * wS[4*k] + v.y * wS[4*k+1] + v.z * wS[4*k+2] + v.w * wS[4*k+3];
    }
    g[i] = s;
}

__global__ __launch_bounds__(1024) void k_smstats(float* __restrict__ g, float* __restrict__ invp) {
    __shared__ float red[1024];
    int p = blockIdx.x, tid = threadIdx.x;
    float* gp = g + (long long)p * NN;
    float lmax = -INFINITY;
    for (int n = tid; n < NN; n += 1024) lmax = fmaxf(lmax, gp[n]);
    red[tid] = lmax; __syncthreads();
    for (int s = 512; s > 0; s >>= 1) { if (tid < s) red[tid] = fmaxf(red[tid], red[tid + s]); __syncthreads(); }
    float mx = red[0]; __syncthreads();
    float ls = 0.0f;
    for (int n = tid; n < NN; n += 1024) { float e = expf(gp[n] - mx); gp[n] = e; ls += e; }
    red[tid] = ls; __syncthreads();
    for (int s = 512; s > 0; s >>= 1) { if (tid < s) red[tid] += red[tid + s]; __syncthreads(); }
    if (tid == 0) invp[p] = 1.0f / red[0];
}

__global__ __launch_bounds__(128) void k_wsum(
    const float* __restrict__ X, const float* __restrict__ a,
    const float* __restrict__ invp, float* __restrict__ ro, int rowbase, int colOff)
{
    int p = blockIdx.x / BPG;
    int chunk = blockIdx.x % BPG;
    int d = threadIdx.x;
    long long base = (long long)p * NN;
    int r0 = chunk * RB, r1 = r0 + RB;
    float s = 0.0f;
    for (int n = r0; n < r1; ++n) {
        float w = a[base + n];
        if (w != 0.0f) s += w * X[(base + n) * 128 + d];
    }
    atomicAdd(&ro[(long long)(rowbase + p) * 384 + colOff + d], s * invp[p]);
}

// stage-2 weighted sum over alive rows only
__global__ __launch_bounds__(128) void k_wsum_c(
    const float* __restrict__ X, const float* __restrict__ gbuf, const float* __restrict__ fvec,
    const float* __restrict__ invp, const int* __restrict__ aliveIdx, int k,
    float* __restrict__ ro, int rowbaseRo, int colOff)
{
    int bpp = k / RB;
    int p = blockIdx.x / bpp;
    int chunk = blockIdx.x % bpp;
    int d = threadIdx.x;
    const int* ai = aliveIdx + (long long)p * k + chunk * RB;
    float s = 0.0f;
    for (int j = 0; j < RB; ++j) {
        int row = ai[j];
        float w = gbuf[row] * fvec[row];
        s += w * X[(long long)row * 128 + d];
    }
    atomicAdd(&ro[(long long)(rowbaseRo + p) * 384 + colOff + d], s * invp[p]);
}

// ---------------- GraphNorm ----------------
__global__ void k_colstat(const float* __restrict__ x, float* __restrict__ musum,
                          float* __restrict__ sqsum, int nrows) {
    int d = threadIdx.x;
    int r0 = blockIdx.x * 64;
    int r1 = min(r0 + 64, nrows);
    float s = 0.0f, q = 0.0f;
    for (int r = r0; r < r1; ++r) { float v = x[(long long)r * 128 + d]; s += v; q += v * v; }
    atomicAdd(&musum[d], s);
    atomicAdd(&sqsum[d], q);
}

__global__ void k_gnorm_apply(const float* __restrict__ x, float* __restrict__ y,
                              const float* __restrict__ musum, const float* __restrict__ sqsum,
                              const float* __restrict__ w, const float* __restrict__ b,
                              const float* __restrict__ ms, int nrows) {
    long long i = (long long)blockIdx.x * 256 + threadIdx.x;
    if (i >= (long long)nrows * 128) return;
    int d = (int)(i & 127);
    float inv_n = 1.0f / (float)nrows;
    float mu = musum[d] * inv_n;
    float c = mu * ms[d];
    float var = sqsum[d] * inv_n - 2.0f * c * mu + c * c;
    y[i] = w[d] * (x[i] - c) * rsqrtf(var + 1e-5f) + b[d];
}

// ---------------- mega top-k (1024 threads) ----------------
#define TCH 8   // NN/1024 rounded up
__global__ __launch_bounds__(1024) void k_topk2(
    const int* __restrict__ rowptr, const int* __restrict__ col, int rowbase,
    const float* __restrict__ tb, const float* __restrict__ rootd,
    const float* __restrict__ gdot, const float* __restrict__ brelp, int bi,
    float* __restrict__ nalive, float* __restrict__ fvec, float* __restrict__ gbuf,
    float* __restrict__ invp, int* __restrict__ aliveIdx, int k)
{
    __shared__ unsigned keys[NN];
    __shared__ int hist[256];
    __shared__ int scan[1024];
    __shared__ float redf[1024];
    __shared__ unsigned sh_pref;
    __shared__ int sh_kneed;
    int p = blockIdx.x, tid = threadIdx.x;
    float brel = brelp[bi];
    long long pbase = (long long)p * NN;
    for (int n = tid; n < NN; n += 1024) {
        long long gl = pbase + n;
        int grow = rowbase + (int)gl;
        float s = brel + rootd[gl];
        int b = rowptr[grow], e = rowptr[grow + 1];
        for (int q = b; q < e; ++q) {
            int sl = col[q] - rowbase;
            s += tb[sl] * nalive[sl];
        }
        keys[n] = (nalive[gl] > 0.5f) ? fkey(s) : 0u;
    }
    if (tid == 0) { sh_pref = 0u; sh_kneed = k; }
    __syncthreads();
    for (int lvl = 3; lvl >= 0; --lvl) {
        int sh = lvl * 8;
        if (tid < 256) hist[tid] = 0;
        unsigned pref = sh_pref; int kneed = sh_kneed;
        unsigned pmask = (lvl == 3) ? 0u : (0xFFFFFFFFu << (8 * (lvl + 1)));
        __syncthreads();
        for (int n = tid; n < NN; n += 1024) {
            unsigned kv = keys[n];
            if ((kv & pmask) == pref) atomicAdd(&hist[(kv >> sh) & 255], 1);
        }
        __syncthreads();
        if (tid == 0) {
            int cum = 0, b = 255;
            for (; b >= 0; --b) { cum += hist[b]; if (cum >= kneed) break; }
            sh_pref = pref | ((unsigned)b << sh);
            sh_kneed = kneed - (cum - hist[b]);
        }
        __syncthreads();
    }
    unsigned V = sh_pref;
    int seleq = sh_kneed;
    int c0 = tid * TCH, c1 = min(c0 + TCH, NN);
    int ceq = 0;
    for (int n = c0; n < c1; ++n) ceq += (keys[n] == V) ? 1 : 0;
    scan[tid] = ceq; __syncthreads();
    for (int off = 1; off < 1024; off <<= 1) {
        int u = (tid >= off) ? scan[tid - off] : 0;
        __syncthreads();
        scan[tid] += u;
        __syncthreads();
    }
    int rank = scan[tid] - ceq;
    unsigned selmask = 0u;
    int nsel = 0;
    float lmax = -INFINITY;
    for (int n = c0; n < c1; ++n) {
        unsigned kk = keys[n];
        bool sel = (kk > V) || (kk == V && rank < seleq);
        if (kk == V) rank++;
        long long gl = pbase + n;
        nalive[gl] = sel ? 1.0f : 0.0f;
        float f = 0.0f;
        if (sel) {
            f = tanhf(fkey_inv(kk));
            lmax = fmaxf(lmax, f * gdot[gl]);
            selmask |= (1u << (n - c0));
            ++nsel;
        }
        fvec[gl] = f;
    }
    redf[tid] = lmax; __syncthreads();
    for (int s = 512; s > 0; s >>= 1) { if (tid < s) redf[tid] = fmaxf(redf[tid], redf[tid + s]); __syncthreads(); }
    float mx = redf[0]; __syncthreads();
    scan[tid] = nsel; __syncthreads();
    for (int off = 1; off < 1024; off <<= 1) {
        int u = (tid >= off) ? scan[tid - off] : 0;
        __syncthreads();
        scan[tid] += u;
        __syncthreads();
    }
    int pos = scan[tid] - nsel;
    float lsum = 0.0f;
    for (int n = c0; n < c1; ++n) {
        if (selmask & (1u << (n - c0))) {
            long long gl = pbase + n;
            float e = expf(fvec[gl] * gdot[gl] - mx);
            gbuf[gl] = e;
            lsum += e;
            aliveIdx[(long long)p * k + pos] = (int)gl;
            ++pos;
        }
    }
    redf[tid] = lsum; __syncthreads();
    for (int s = 512; s > 0; s >>= 1) { if (tid < s) redf[tid] += redf[tid + s]; __syncthreads(); }
    if (tid == 0) invp[p] = 1.0f / redf[0];
}

// ---------------- head ----------------
__global__ __launch_bounds__(64) void k_head(
    const float* __restrict__ ro, const float* __restrict__ lin_w, const float* __restrict__ lin_b,
    const float* __restrict__ m1w, const float* __restrict__ m1b,
    const float* __restrict__ m2w, const float* __restrict__ m2b,
    const float* __restrict__ m3w, const float* __restrict__ m3b, float* __restrict__ out)
{
    __shared__ float v[33], h1[48], h2[16];
    int t = threadIdx.x;
    if (t < 33) {
        float s = lin_b[0];
        for (int k = 0; k < 384; ++k) s += ro[t * 384 + k] * lin_w[k];
        v[t] = tanhf(s);
    }
    __syncthreads();
    if (t < 48) {
        float s = m1b[t];
        for (int i = 0; i < 33; ++i) s += v[i] * m1w[i * 48 + t];
        h1[t] = tanhf(s);
    }
    __syncthreads();
    if (t < 16) {
        float s = m2b[t];
        for (int i = 0; i < 48; ++i) s += h1[i] * m2w[i * 16 + t];
        h2[t] = tanhf(s);
    }
    __syncthreads();
    if (t == 0) {
        float s = m3b[0];
        for (int i = 0; i < 16; ++i) s += h2[i] * m3w[i];
        float s1 = 1.0f / (1.0f + expf(-s));
        out[0] = 1.0f / (1.0f + expf(-s1));
    }
}

static inline int cdiv(long long a, long long b) { return (int)((a + b - 1) / b); }

extern "C" void kernel_launch(void* const* d_in, const int* in_sizes, int n_in,
                              void* d_out, int out_size, void* d_ws, size_t ws_size,
                              hipStream_t stream)
{
    (void)in_sizes; (void)n_in; (void)out_size;
    const float* h     = (const float*)d_in[0];
    const int*   eidx  = (const int*)d_in[1];
    const int*   seidx = (const int*)d_in[2];
    const float* Wl_a  = (const float*)d_in[3];
    const float* Wr_a  = (const float*)d_in[4];
    const float* bl_a  = (const float*)d_in[5];
    const float* Wl_s  = (const float*)d_in[6];
    const float* Wr_s  = (const float*)d_in[7];
    const float* bl_s  = (const float*)d_in[8];
    const float* gate_w = (const float*)d_in[9];
    const float* p_wrel = (const float*)d_in[11];
    const float* p_brel = (const float*)d_in[12];
    const float* p_wroot= (const float*)d_in[13];
    const float* nw    = (const float*)d_in[14];
    const float* nb    = (const float*)d_in[15];
    const float* nms   = (const float*)d_in[16];
    const float* lin_w = (const float*)d_in[17];
    const float* lin_b = (const float*)d_in[18];
    const float* m1w   = (const float*)d_in[19];
    const float* m1b   = (const float*)d_in[20];
    const float* m2w   = (const float*)d_in[21];
    const float* m2b   = (const float*)d_in[22];
    const float* m3w   = (const float*)d_in[23];
    const float* m3b   = (const float*)d_in[24];
    float* out = (float*)d_out;

    const int* esrc = eidx;
    const int* edst = eidx + EG;
    const int* ssrc = seidx;
    const int* sdst = seidx + ES_TOT;

    auto need_bytes = [](int chp) -> size_t {
        long long chn = (long long)chp * NN;
        long long f = 3 * chn * 128
                    + 3LL * NN * 128
                    + NN * 16 + NN
                    + 6 * chn
                    + (long long)chp * KK1
                    + 64 + 33 * 384 + 256
                    + (NN + (NN+1) + NN + EG + NN + 1024)
                    + (PN + (PN+1) + PN + ES_TOT + PN + 1024)
                    + 64 * 48;
        return (size_t)f * 4;
    };
    int chp = 4;
    if (ws_size >= need_bytes(16)) chp = 16;
    else if (ws_size >= need_bytes(8)) chp = 8;
    int nch = PP / chp;
    long long ch_n = (long long)chp * NN;

    float* W = (float*)d_ws;
    size_t off = 0;
    auto alloc = [&](size_t nf) { float* p = W + off; off += (nf + 63) & ~(size_t)63; return p; };
    float* XA    = alloc((size_t)ch_n * DD);
    float* XB    = alloc((size_t)ch_n * DD);
    float* AGG   = alloc((size_t)ch_n * DD);
    float* xa    = alloc((size_t)NN * DD);
    float* xb    = alloc((size_t)NN * DD);
    float* zself = alloc((size_t)NN * DD);
    float* agg1  = alloc((size_t)NN * 16);
    float* deg1  = alloc(NN);
    float* tbuf  = alloc(ch_n);
    float* rootd = alloc(ch_n);
    float* nal   = alloc(ch_n);
    float* fvec  = alloc(ch_n);
    float* gdot  = alloc(ch_n);
    float* gbuf  = alloc(ch_n);
    float* invp  = alloc(64);
    float* ro    = alloc(33 * 384);
    float* musum = alloc(128);
    float* sqsum = alloc(128);
    int* aliveIdx = (int*)alloc((size_t)chp * KK1);
    int* s1cnt  = (int*)alloc(NN);
    int* s1rp   = (int*)alloc(NN + 1);
    int* s1cur  = (int*)alloc(NN);
    int* s1col  = (int*)alloc(EG);
    int* s1part = (int*)alloc(NN);
    int* s1bsum = (int*)alloc(1024);
    int* s2cnt  = (int*)alloc(PN);
    int* s2rp   = (int*)alloc(PN + 1);
    int* s2cur  = (int*)alloc(PN);
    int* s2col  = (int*)alloc(ES_TOT);
    int* s2part = (int*)alloc(PN);
    int* s2bsum = (int*)alloc(1024);

    // ---------- CSR builds ----------
    int nb1 = cdiv(NN, 1024), nb2 = cdiv(PN, 1024);
    hipMemsetAsync(s1cnt, 0, NN * sizeof(int), stream);
    k_hist<<<cdiv(EG,256),256,0,stream>>>(edst, s1cnt, EG);
    k_scanA<<<nb1,1024,0,stream>>>(s1cnt, s1part, s1bsum, NN);
    k_scanB<<<1,1024,0,stream>>>(s1bsum, nb1);
    k_scanC<<<cdiv(NN,256),256,0,stream>>>(s1part, s1bsum, s1rp, s1cur, NN, EG);
    k_scatter<<<cdiv(EG,256),256,0,stream>>>(esrc, edst, s1cur, s1col, EG);

    hipMemsetAsync(s2cnt, 0, (size_t)PN * sizeof(int), stream);
    k_hist<<<cdiv(ES_TOT,256),256,0,stream>>>(sdst, s2cnt, ES_TOT);
    k_scanA<<<nb2,1024,0,stream>>>(s2cnt, s2part, s2bsum, PN);
    k_scanB<<<1,1024,0,stream>>>(s2bsum, nb2);
    k_scanC<<<cdiv(PN,256),256,0,stream>>>(s2part, s2bsum, s2rp, s2cur, PN, ES_TOT);
    k_scatter<<<cdiv(ES_TOT,256),256,0,stream>>>(ssrc, sdst, s2cur, s2col, ES_TOT);

    hipMemsetAsync(ro, 0, 33 * 384 * sizeof(float), stream);

    // ---------- stage 1 ----------
    k_agg16<<<cdiv((long long)NN*16,256),256,0,stream>>>(h, s1rp, s1col, agg1, deg1, NN);
    k_sage16<<<cdiv((long long)NN*DD,256),256,0,stream>>>(h, agg1, deg1, Wl_a, Wr_a, bl_a, xa, NN);
    k_gate<<<cdiv(NN,256),256,0,stream>>>(xa, gate_w + 0*DD, gbuf, NN);
    k_smstats<<<1,1024,0,stream>>>(gbuf, invp);
    k_wsum<<<BPG,128,0,stream>>>(xa, gbuf, invp, ro, 0, 0);

    hipMemsetAsync(musum, 0, 128*sizeof(float), stream);
    hipMemsetAsync(sqsum, 0, 128*sizeof(float), stream);
    k_colstat<<<cdiv(NN,64),128,0,stream>>>(xa, musum, sqsum, NN);
    k_gnorm_apply<<<cdiv((long long)NN*DD,256),256,0,stream>>>(xa, xb, musum, sqsum, nw, nb, nms, NN);

    k_aggf<<<cdiv(NN,8),256,0,stream>>>(xb, s1rp, s1col, nullptr, nullptr, nullptr, 0, 0, 0, AGG, NN);
    k_sage_d<<<cdiv(NN,64),256,0,stream>>>(AGG, xb, nullptr, nullptr, nullptr, 0,
        Wl_s + 0*16384, Wr_s + 0*16384, bl_s + 0*128, xa, NN,
        nullptr, nullptr, gate_w + 1*DD, nullptr, nullptr, gbuf);
    k_smstats<<<1,1024,0,stream>>>(gbuf, invp);
    k_wsum<<<BPG,128,0,stream>>>(xa, gbuf, invp, ro, 0, 128);

    hipMemsetAsync(musum, 0, 128*sizeof(float), stream);
    hipMemsetAsync(sqsum, 0, 128*sizeof(float), stream);
    k_colstat<<<cdiv(NN,64),128,0,stream>>>(xa, musum, sqsum, NN);
    k_gnorm_apply<<<cdiv((long long)NN*DD,256),256,0,stream>>>(xa, xb, musum, sqsum, nw, nb, nms, NN);

    k_aggf<<<cdiv(NN,8),256,0,stream>>>(xb, s1rp, s1col, nullptr, nullptr, nullptr, 0, 0, 0, AGG, NN);
    k_sage_d<<<cdiv(NN,64),256,0,stream>>>(AGG, xb, nullptr, nullptr, nullptr, 0,
        Wl_s + 1*16384, Wr_s + 1*16384, bl_s + 1*128, xa, NN,
        nullptr, nullptr, gate_w + 2*DD, nullptr, nullptr, gbuf);
    k_smstats<<<1,1024,0,stream>>>(gbuf, invp);
    k_wsum<<<BPG,128,0,stream>>>(xa, gbuf, invp, ro, 0, 256);

    // ---------- stage 2 ----------
    k_gemm_self<<<cdiv(NN,64),256,0,stream>>>(xa, Wr_s + 2*16384, bl_s + 2*128, zself, NN);

    for (int c = 0; c < nch; ++c) {
        int nbase = (int)(c * ch_n);
        k_fill<<<cdiv(ch_n,256),256,0,stream>>>(nal, 1.0f, (int)ch_n);

        // ---- layer 0: all rows, K=128 + zself ----
        k_aggf<<<(int)(ch_n/8),256,0,stream>>>(xa, s2rp, s2col, nullptr, nullptr, nullptr, 1, 1, nbase, AGG, (int)ch_n);
        k_sage_d<<<(int)(ch_n/64),256,0,stream>>>(AGG, nullptr, zself, nullptr, nullptr, 1,
            Wl_s + 2*16384, nullptr, nullptr, XA, (int)ch_n,
            p_wrel + 0*DD, p_wroot + 0*DD, gate_w + 3*DD, tbuf, rootd, gdot);
        k_topk2<<<chp,1024,0,stream>>>(s2rp, s2col, nbase, tbuf, rootd, gdot, p_brel, 0,
                                       nal, fvec, gbuf, invp, aliveIdx, KK1);
        k_wsum_c<<<chp*(KK1/RB),128,0,stream>>>(XA, gbuf, fvec, invp, aliveIdx, KK1, ro, 1 + c*chp, 0);

        // ---- layer 1: alive K1 rows ----
        k_aggf<<<chp*(KK1/8),256,0,stream>>>(XA, s2rp, s2col, aliveIdx, nal, fvec, 2, 0, nbase, AGG, chp*KK1);
        k_sage_d<<<chp*(KK1/64),256,0,stream>>>(AGG, XA, nullptr, aliveIdx, fvec, 2,
            Wl_s + 3*16384, Wr_s + 3*16384, bl_s + 3*128, XB, chp*KK1,
            p_wrel + 1*DD, p_wroot + 1*DD, gate_w + 4*DD, tbuf, rootd, gdot);
        k_topk2<<<chp,1024,0,stream>>>(s2rp, s2col, nbase, tbuf, rootd, gdot, p_brel, 1,
                                       nal, fvec, gbuf, invp, aliveIdx, KK2);
        k_wsum_c<<<chp*(KK2/RB),128,0,stream>>>(XB, gbuf, fvec, invp, aliveIdx, KK2, ro, 1 + c*chp, 128);

        // ---- layer 2: alive K2 rows ----
        k_aggf<<<chp*(KK2/8),256,0,stream>>>(XB, s2rp, s2col, aliveIdx, nal, fvec, 2, 0, nbase, AGG, chp*KK2);
        k_sage_d<<<chp*(KK2/64),256,0,stream>>>(AGG, XB, nullptr, aliveIdx, fvec, 2,
            Wl_s + 4*16384, Wr_s + 4*16384, bl_s + 4*128, XA, chp*KK2,
            p_wrel + 2*DD, p_wroot + 2*DD, gate_w + 5*DD, tbuf, rootd, gdot);
        k_topk2<<<chp,1024,0,stream>>>(s2rp, s2col, nbase, tbuf, rootd, gdot, p_brel, 2,
                                       nal, fvec, gbuf, invp, aliveIdx, KK3);
        k_wsum_c<<<chp*(KK3/RB),128,0,stream>>>(XA, gbuf, fvec, invp, aliveIdx, KK3, ro, 1 + c*chp, 256);
    }

    // ---------- head ----------
    k_head<<<1,64,0,stream>>>(ro, lin_w, lin_b, m1w, m1b, m2w, m2b, m3w, m3b, out);
}

// Round 12
// 1380.241 us; speedup vs baseline: 1.9039x; 1.1051x over previous
//
#include <hip/hip_runtime.h>
#include <math.h>

#define NN      8000
#define PP      32
#define EG      128000
#define ES_TOT  131072     // P * 4096
#define ES_P    4096
#define PN      256000     // P * NN
#define DI      16
#define DD      128
#define KK1     6400
#define KK2     5120
#define KK3     4096
#define RB      64                   // rows per wsum block
#define BPG     (NN / RB)            // 125 blocks per graph (stage-1 wsum)

static __device__ __forceinline__ unsigned fkey(float f) {
    unsigned u = __float_as_uint(f);
    return (u & 0x80000000u) ? ~u : (u | 0x80000000u);
}
static __device__ __forceinline__ float fkey_inv(unsigned k) {
    unsigned u = (k & 0x80000000u) ? (k & 0x7FFFFFFFu) : ~k;
    return __uint_as_float(u);
}

__global__ void k_fill(float* p, float v, int n) {
    int i = blockIdx.x * 256 + threadIdx.x;
    if (i < n) p[i] = v;
}

// ---------------- CSR build ----------------
__global__ void k_hist(const int* __restrict__ dst, int* __restrict__ cnt, int ne) {
    int e = blockIdx.x * 256 + threadIdx.x;
    if (e < ne) atomicAdd(&cnt[dst[e]], 1);
}

__global__ __launch_bounds__(1024) void k_scanA(const int* __restrict__ cnt,
                                                int* __restrict__ part,
                                                int* __restrict__ bsum, int n) {
    __shared__ int sh[1024];
    int t = threadIdx.x;
    int i = blockIdx.x * 1024 + t;
    int v = (i < n) ? cnt[i] : 0;
    sh[t] = v; __syncthreads();
    for (int off = 1; off < 1024; off <<= 1) {
        int u = (t >= off) ? sh[t - off] : 0;
        __syncthreads();
        sh[t] += u;
        __syncthreads();
    }
    if (i < n) part[i] = sh[t] - v;
    if (t == 1023) bsum[blockIdx.x] = sh[1023];
}

__global__ __launch_bounds__(1024) void k_scanB(int* __restrict__ bsum, int nb) {
    __shared__ int sh[1024];
    int t = threadIdx.x;
    int v = (t < nb) ? bsum[t] : 0;
    sh[t] = v; __syncthreads();
    for (int off = 1; off < 1024; off <<= 1) {
        int u = (t >= off) ? sh[t - off] : 0;
        __syncthreads();
        sh[t] += u;
        __syncthreads();
    }
    if (t < nb) bsum[t] = sh[t] - v;   // exclusive
}

__global__ void k_scanC(const int* __restrict__ part, const int* __restrict__ bsum,
                        int* __restrict__ rowptr, int* __restrict__ cursor, int n, int total) {
    int i = blockIdx.x * 256 + threadIdx.x;
    if (i < n) {
        int v = part[i] + bsum[i >> 10];
        rowptr[i] = v;
        cursor[i] = v;
    }
    if (i == 0) rowptr[n] = total;
}

__global__ void k_scatter(const int* __restrict__ src, const int* __restrict__ dst,
                          int* __restrict__ cursor, int* __restrict__ col, int ne) {
    int e = blockIdx.x * 256 + threadIdx.x;
    if (e >= ne) return;
    int pos = atomicAdd(&cursor[dst[e]], 1);
    col[pos] = src[e];
}

// ---------------- stage-1 layer a ----------------
__global__ __launch_bounds__(256) void k_agg16(const float* __restrict__ h,
                                               const int* __restrict__ rowptr,
                                               const int* __restrict__ col,
                                               float* __restrict__ agg, float* __restrict__ deg,
                                               int nrows) {
    int i = blockIdx.x * 256 + threadIdx.x;
    int r = i >> 4, j = i & 15;
    if (r >= nrows) return;
    int b = rowptr[r], e = rowptr[r + 1];
    float a = h[r * 16 + j];
    for (int q = b; q < e; ++q) a += h[col[q] * 16 + j];
    agg[r * 16 + j] = a;
    if (j == 0) deg[r] = 1.0f + (float)(e - b);
}

__global__ __launch_bounds__(256) void k_sage16(
    const float* __restrict__ h, const float* __restrict__ agg, const float* __restrict__ deg,
    const float* __restrict__ Wl, const float* __restrict__ Wr, const float* __restrict__ bl,
    float* __restrict__ y, int nrows)
{
    __shared__ float WlS[16][128], WrS[16][128];
    int tid = threadIdx.x;
    for (int i = tid; i < 16 * 128; i += 256) {
        WlS[i >> 7][i & 127] = Wl[i];
        WrS[i >> 7][i & 127] = Wr[i];
    }
    __syncthreads();
    long long o = (long long)blockIdx.x * 256 + tid;
    int row = (int)(o >> 7);
    if (row >= nrows) return;
    int d = (int)o & 127;
    float invd = 1.0f / fmaxf(deg[row], 1.0f);
    float s = bl[d];
    #pragma unroll
    for (int k = 0; k < 16; ++k)
        s += agg[row * 16 + k] * invd * WlS[k][d] + h[row * 16 + k] * WrS[k][d];
    y[(long long)row * 128 + d] = tanhf(s);
}

// ---------------- CSR gather-aggregate (row-parallel, no atomics) ----------------
__global__ __launch_bounds__(256) void k_aggf(
    const float* __restrict__ x,
    const int* __restrict__ rowptr, const int* __restrict__ col,
    const int* __restrict__ aliveIdx, const float* __restrict__ nal, const float* __restrict__ fvec,
    int mode, int xModN, int rowbase,
    float* __restrict__ AGG, int nrowsC)
{
    int tid = threadIdx.x;
    int r = blockIdx.x * 8 + (tid >> 5);
    if (r >= nrowsC) return;
    int lane = tid & 31;
    int orig = aliveIdx ? aliveIdx[r] : r;
    int grow = rowbase + orig;
    int b = rowptr[grow], e = rowptr[grow + 1];
    float4 a = make_float4(0.0f, 0.0f, 0.0f, 0.0f);
    float dsum = 0.0f;
    if (mode == 0) {
        a = *reinterpret_cast<const float4*>(x + (long long)orig * 128 + lane * 4);
        dsum = 1.0f;
    }
    for (int q = b; q < e; ++q) {
        int s = col[q];
        float fw = 1.0f;
        int fr;
        if (mode == 2) {
            fr = s - rowbase;
            if (nal[fr] == 0.0f) continue;
            dsum += 1.0f;
            fw = fvec[fr];
            if (fw == 0.0f) continue;
        } else {
            fr = xModN ? (s % NN) : (s - rowbase);
            dsum += 1.0f;
        }
        float4 v = *reinterpret_cast<const float4*>(x + (long long)fr * 128 + lane * 4);
        a.x += v.x * fw; a.y += v.y * fw; a.z += v.z * fw; a.w += v.w * fw;
    }
    float invds = 1.0f / fmaxf(dsum, 1.0f);
    a.x *= invds; a.y *= invds; a.z *= invds; a.w *= invds;
    *reinterpret_cast<float4*>(AGG + (long long)r * 128 + lane * 4) = a;
}

// ---------------- dense SAGE GEMM, v2 tile: BM=64, 8x4 acc, low VGPR ----------------
// V 0 (stage-1): y=tanh(AGG@Wl + bl + x[crow]@Wr), K=256
// V 2 (s2 L1/2): y=tanh(AGG@Wl + bl + fvec[orig]*x[orig]@Wr), orig=aliveIdx[crow], K=256
__global__ __launch_bounds__(256) void k_sage_d(
    const float* __restrict__ AGG, const float* __restrict__ xsrc,
    const int* __restrict__ aliveIdx, const float* __restrict__ fvec,
    int V,
    const float* __restrict__ Wl, const float* __restrict__ Wr, const float* __restrict__ bl,
    float* __restrict__ y, int nrowsC,
    const float* __restrict__ wrel, const float* __restrict__ wroot, const float* __restrict__ gw,
    float* __restrict__ tbuf, float* __restrict__ rootd, float* __restrict__ gdot)
{
    __shared__ float Ws[32 * 128];
    __shared__ float Is[32][68];
    __shared__ float wrelS[128], wrootS[128], gwS[128];
    __shared__ int rowIdxS[64];
    int tid = threadIdx.x;
    long long row0 = (long long)blockIdx.x * 64;
    if (tid < 128) {
        if (wrel)  wrelS[tid]  = wrel[tid];
        if (wroot) wrootS[tid] = wroot[tid];
        if (gw)    gwS[tid]    = gw[tid];
    }
    if (tid < 64) {
        long long lr = row0 + tid;
        if (lr >= nrowsC) lr = nrowsC - 1;
        rowIdxS[tid] = aliveIdx ? aliveIdx[lr] : (int)lr;
    }
    __syncthreads();
    int tx = tid & 31, ty = tid >> 5;
    int srow = tid & 63;
    int koff = (tid >> 6) * 8;
    long long crow = row0 + srow;
    if (crow >= nrowsC) crow = nrowsC - 1;
    int orig = rowIdxS[srow];
    float fself = (V == 2) ? fvec[orig] : 1.0f;
    const float* selfp = xsrc + (long long)orig * 128;
    const float* aggp = AGG + crow * 128;

    float acc[8][4] = {};
    for (int kb = 0; kb < 8; ++kb) {
        __syncthreads();
        bool isAgg = (kb < 4);
        const float* Wsrc = isAgg ? (Wl + kb * 32 * 128) : (Wr + (kb - 4) * 32 * 128);
        #pragma unroll
        for (int j = 0; j < 4; ++j) {
            int fl = j * 1024 + tid * 4;
            *reinterpret_cast<float4*>(&Ws[fl]) = *reinterpret_cast<const float4*>(&Wsrc[fl]);
        }
        {
            const float* sp = (isAgg ? (aggp + kb * 32) : (selfp + (kb - 4) * 32)) + koff;
            float m = isAgg ? 1.0f : fself;
            float4 v0 = *reinterpret_cast<const float4*>(sp);
            float4 v1 = *reinterpret_cast<const float4*>(sp + 4);
            Is[koff + 0][srow] = v0.x * m; Is[koff + 1][srow] = v0.y * m;
            Is[koff + 2][srow] = v0.z * m; Is[koff + 3][srow] = v0.w * m;
            Is[koff + 4][srow] = v1.x * m; Is[koff + 5][srow] = v1.y * m;
            Is[koff + 6][srow] = v1.z * m; Is[koff + 7][srow] = v1.w * m;
        }
        __syncthreads();
        #pragma unroll
        for (int kk = 0; kk < 32; ++kk) {
            float4 wv = *reinterpret_cast<const float4*>(&Ws[kk * 128 + tx * 4]);
            float4 i0 = *reinterpret_cast<const float4*>(&Is[kk][ty * 8]);
            float4 i1 = *reinterpret_cast<const float4*>(&Is[kk][ty * 8 + 4]);
            float ia[8] = {i0.x, i0.y, i0.z, i0.w, i1.x, i1.y, i1.z, i1.w};
            float wa[4] = {wv.x, wv.y, wv.z, wv.w};
            #pragma unroll
            for (int i = 0; i < 8; ++i)
                #pragma unroll
                for (int j = 0; j < 4; ++j)
                    acc[i][j] += ia[i] * wa[j];
        }
    }
    float4 bl0 = *reinterpret_cast<const float4*>(&bl[tx * 4]);
    float br[4] = {bl0.x, bl0.y, bl0.z, bl0.w};
    #pragma unroll
    for (int i = 0; i < 8; ++i) {
        long long cr = row0 + ty * 8 + i;
        bool valid = (cr < nrowsC);
        int rout = rowIdxS[ty * 8 + i];
        float yv[4];
        #pragma unroll
        for (int j = 0; j < 4; ++j) yv[j] = tanhf(acc[i][j] + br[j]);
        if (valid)
            *reinterpret_cast<float4*>(&y[(long long)rout * 128 + tx * 4]) = make_float4(yv[0], yv[1], yv[2], yv[3]);
        float tp = 0.0f, rp = 0.0f, gp = 0.0f;
        #pragma unroll
        for (int j = 0; j < 4; ++j) {
            if (tbuf)  tp += yv[j] * wrelS[tx*4 + j];
            if (rootd) rp += yv[j] * wrootS[tx*4 + j];
            if (gdot)  gp += yv[j] * gwS[tx*4 + j];
        }
        #pragma unroll
        for (int m = 16; m >= 1; m >>= 1) {
            if (tbuf)  tp += __shfl_xor(tp, m, 32);
            if (rootd) rp += __shfl_xor(rp, m, 32);
            if (gdot)  gp += __shfl_xor(gp, m, 32);
        }
        if (tx == 0 && valid) {
            if (tbuf)  tbuf[rout]  = tp;
            if (rootd) rootd[rout] = rp;
            if (gdot)  gdot[rout]  = gp;
        }
    }
}

// ---------------- plain GEMM: y = x@W (+ b), v2 tile ----------------
__global__ __launch_bounds__(256) void k_gemm_self(
    const float* __restrict__ x, const float* __restrict__ W, const float* __restrict__ b,
    float* __restrict__ y, int nrows)
{
    __shared__ float Ws[32 * 128];
    __shared__ float Is[32][68];
    int tid = threadIdx.x;
    long long row0 = (long long)blockIdx.x * 64;
    int tx = tid & 31, ty = tid >> 5;
    int srow = tid & 63;
    int koff = (tid >> 6) * 8;
    long long lrow = row0 + srow;
    if (lrow >= nrows) lrow = nrows - 1;
    const float* xrow = x + lrow * 128;
    float acc[8][4] = {};
    for (int kb = 0; kb < 4; ++kb) {
        __syncthreads();
        const float* Wsrc = W + kb * 32 * 128;
        #pragma unroll
        for (int j = 0; j < 4; ++j) {
            int fl = j * 1024 + tid * 4;
            *reinterpret_cast<float4*>(&Ws[fl]) = *reinterpret_cast<const float4*>(&Wsrc[fl]);
        }
        {
            const float* sp = xrow + kb * 32 + koff;
            float4 v0 = *reinterpret_cast<const float4*>(sp);
            float4 v1 = *reinterpret_cast<const float4*>(sp + 4);
            Is[koff + 0][srow] = v0.x; Is[koff + 1][srow] = v0.y;
            Is[koff + 2][srow] = v0.z; Is[koff + 3][srow] = v0.w;
            Is[koff + 4][srow] = v1.x; Is[koff + 5][srow] = v1.y;
            Is[koff + 6][srow] = v1.z; Is[koff + 7][srow] = v1.w;
        }
        __syncthreads();
        #pragma unroll
        for (int kk = 0; kk < 32; ++kk) {
            float4 wv = *reinterpret_cast<const float4*>(&Ws[kk * 128 + tx * 4]);
            float4 i0 = *reinterpret_cast<const float4*>(&Is[kk][ty * 8]);
            float4 i1 = *reinterpret_cast<const float4*>(&Is[kk][ty * 8 + 4]);
            float ia[8] = {i0.x, i0.y, i0.z, i0.w, i1.x, i1.y, i1.z, i1.w};
            float wa[4] = {wv.x, wv.y, wv.z, wv.w};
            #pragma unroll
            for (int i = 0; i < 8; ++i)
                #pragma unroll
                for (int j = 0; j < 4; ++j)
                    acc[i][j] += ia[i] * wa[j];
        }
    }
    float4 b0 = b ? *reinterpret_cast<const float4*>(&b[tx * 4]) : make_float4(0.f, 0.f, 0.f, 0.f);
    #pragma unroll
    for (int i = 0; i < 8; ++i) {
        long long row = row0 + ty * 8 + i;
        if (row >= nrows) continue;
        *reinterpret_cast<float4*>(&y[row * 128 + tx * 4]) =
            make_float4(acc[i][0] + b0.x, acc[i][1] + b0.y, acc[i][2] + b0.z, acc[i][3] + b0.w);
    }
}

// ---------------- stage-2 L0 combine (linear-map trick, no GEMM) ----------------
// y[r] = tanh( mean_{j in CSR row} ZL0[col[j]%NN] + zself[r%NN] ), plus epilogue dots.
// 8 rows/block x 32 lanes x 4 dims.
__global__ __launch_bounds__(256) void k_l0comb(
    const float* __restrict__ ZL0, const float* __restrict__ zself,
    const int* __restrict__ rowptr, const int* __restrict__ col, int rowbase,
    const float* __restrict__ wrel, const float* __restrict__ wroot, const float* __restrict__ gw,
    float* __restrict__ y, float* __restrict__ tbuf, float* __restrict__ rootd, float* __restrict__ gdot,
    int nrowsC)
{
    __shared__ float wrelS[128], wrootS[128], gwS[128];
    int tid = threadIdx.x;
    if (tid < 128) {
        wrelS[tid]  = wrel[tid];
        wrootS[tid] = wroot[tid];
        gwS[tid]    = gw[tid];
    }
    __syncthreads();
    int r = blockIdx.x * 8 + (tid >> 5);
    if (r >= nrowsC) return;
    int lane = tid & 31;
    int grow = rowbase + r;
    int b = rowptr[grow], e = rowptr[grow + 1];
    float4 a = make_float4(0.0f, 0.0f, 0.0f, 0.0f);
    for (int q = b; q < e; ++q) {
        int fr = col[q] % NN;
        float4 v = *reinterpret_cast<const float4*>(ZL0 + (long long)fr * 128 + lane * 4);
        a.x += v.x; a.y += v.y; a.z += v.z; a.w += v.w;
    }
    float invds = 1.0f / fmaxf((float)(e - b), 1.0f);
    const float4 z = *reinterpret_cast<const float4*>(zself + (long long)(r % NN) * 128 + lane * 4);
    float yv[4];
    yv[0] = tanhf(a.x * invds + z.x);
    yv[1] = tanhf(a.y * invds + z.y);
    yv[2] = tanhf(a.z * invds + z.z);
    yv[3] = tanhf(a.w * invds + z.w);
    *reinterpret_cast<float4*>(y + (long long)r * 128 + lane * 4) = make_float4(yv[0], yv[1], yv[2], yv[3]);
    float tp = 0.0f, rp = 0.0f, gp = 0.0f;
    #pragma unroll
    for (int j = 0; j < 4; ++j) {
        tp += yv[j] * wrelS[lane*4 + j];
        rp += yv[j] * wrootS[lane*4 + j];
        gp += yv[j] * gwS[lane*4 + j];
    }
    #pragma unroll
    for (int m = 16; m >= 1; m >>= 1) {
        tp += __shfl_xor(tp, m, 32);
        rp += __shfl_xor(rp, m, 32);
        gp += __shfl_xor(gp, m, 32);
    }
    if (lane == 0) {
        tbuf[r]  = tp;
        rootd[r] = rp;
        gdot[r]  = gp;
    }
}

// ---------------- stage-1 readout pieces ----------------
__global__ __launch_bounds__(256) void k_gate(
    const float* __restrict__ X, const float* __restrict__ gw,
    float* __restrict__ g, int nrows)
{
    __shared__ float wS[128];
    if (threadIdx.x < 128) wS[threadIdx.x] = gw[threadIdx.x];
    __syncthreads();
    int i = blockIdx.x * 256 + threadIdx.x;
    if (i >= nrows) return;
    const float4* xrp = reinterpret_cast<const float4*>(X + (long long)i * 128);
    float s = 0.0f;
    #pragma unroll
    for (int k = 0; k < 32; ++k) {
        float4 v = xrp[k];
        s += v.x * wS[4*k] + v.y * wS[4*k+1] + v.z * wS[4*k+2] + v.w * wS[4*k+3];
    }
    g[i] = s;
}

__global__ __launch_bounds__(1024) void k_smstats(float* __restrict__ g, float* __restrict__ invp) {
    __shared__ float red[1024];
    int p = blockIdx.x, tid = threadIdx.x;
    float* gp = g + (long long)p * NN;
    float lmax = -INFINITY;
    for (int n = tid; n < NN; n += 1024) lmax = fmaxf(lmax, gp[n]);
    red[tid] = lmax; __syncthreads();
    for (int s = 512; s > 0; s >>= 1) { if (tid < s) red[tid] = fmaxf(red[tid], red[tid + s]); __syncthreads(); }
    float mx = red[0]; __syncthreads();
    float ls = 0.0f;
    for (int n = tid; n < NN; n += 1024) { float e = expf(gp[n] - mx); gp[n] = e; ls += e; }
    red[tid] = ls; __syncthreads();
    for (int s = 512; s > 0; s >>= 1) { if (tid < s) red[tid] += red[tid + s]; __syncthreads(); }
    if (tid == 0) invp[p] = 1.0f / red[0];
}

__global__ __launch_bounds__(128) void k_wsum(
    const float* __restrict__ X, const float* __restrict__ a,
    const float* __restrict__ invp, float* __restrict__ ro, int rowbase, int colOff)
{
    int p = blockIdx.x / BPG;
    int chunk = blockIdx.x % BPG;
    int d = threadIdx.x;
    long long base = (long long)p * NN;
    int r0 = chunk * RB, r1 = r0 + RB;
    float s = 0.0f;
    for (int n = r0; n < r1; ++n) {
        float w = a[base + n];
        if (w != 0.0f) s += w * X[(base + n) * 128 + d];
    }
    atomicAdd(&ro[(long long)(rowbase + p) * 384 + colOff + d], s * invp[p]);
}

// stage-2 weighted sum over alive rows only
__global__ __launch_bounds__(128) void k_wsum_c(
    const float* __restrict__ X, const float* __restrict__ gbuf, const float* __restrict__ fvec,
    const float* __restrict__ invp, const int* __restrict__ aliveIdx, int k,
    float* __restrict__ ro, int rowbaseRo, int colOff)
{
    int bpp = k / RB;
    int p = blockIdx.x / bpp;
    int chunk = blockIdx.x % bpp;
    int d = threadIdx.x;
    const int* ai = aliveIdx + (long long)p * k + chunk * RB;
    float s = 0.0f;
    for (int j = 0; j < RB; ++j) {
        int row = ai[j];
        float w = gbuf[row] * fvec[row];
        s += w * X[(long long)row * 128 + d];
    }
    atomicAdd(&ro[(long long)(rowbaseRo + p) * 384 + colOff + d], s * invp[p]);
}

// ---------------- GraphNorm ----------------
__global__ void k_colstat(const float* __restrict__ x, float* __restrict__ musum,
                          float* __restrict__ sqsum, int nrows) {
    int d = threadIdx.x;
    int r0 = blockIdx.x * 64;
    int r1 = min(r0 + 64, nrows);
    float s = 0.0f, q = 0.0f;
    for (int r = r0; r < r1; ++r) { float v = x[(long long)r * 128 + d]; s += v; q += v * v; }
    atomicAdd(&musum[d], s);
    atomicAdd(&sqsum[d], q);
}

__global__ void k_gnorm_apply(const float* __restrict__ x, float* __restrict__ y,
                              const float* __restrict__ musum, const float* __restrict__ sqsum,
                              const float* __restrict__ w, const float* __restrict__ b,
                              const float* __restrict__ ms, int nrows) {
    long long i = (long long)blockIdx.x * 256 + threadIdx.x;
    if (i >= (long long)nrows * 128) return;
    int d = (int)(i & 127);
    float inv_n = 1.0f / (float)nrows;
    float mu = musum[d] * inv_n;
    float c = mu * ms[d];
    float var = sqsum[d] * inv_n - 2.0f * c * mu + c * c;
    y[i] = w[d] * (x[i] - c) * rsqrtf(var + 1e-5f) + b[d];
}

// ---------------- mega top-k (1024 threads) ----------------
#define TCH 8   // NN/1024 rounded up
__global__ __launch_bounds__(1024) void k_topk2(
    const int* __restrict__ rowptr, const int* __restrict__ col, int rowbase,
    const float* __restrict__ tb, const float* __restrict__ rootd,
    const float* __restrict__ gdot, const float* __restrict__ brelp, int bi,
    float* __restrict__ nalive, float* __restrict__ fvec, float* __restrict__ gbuf,
    float* __restrict__ invp, int* __restrict__ aliveIdx, int k)
{
    __shared__ unsigned keys[NN];
    __shared__ int hist[256];
    __shared__ int scan[1024];
    __shared__ float redf[1024];
    __shared__ unsigned sh_pref;
    __shared__ int sh_kneed;
    int p = blockIdx.x, tid = threadIdx.x;
    float brel = brelp[bi];
    long long pbase = (long long)p * NN;
    for (int n = tid; n < NN; n += 1024) {
        long long gl = pbase + n;
        int grow = rowbase + (int)gl;
        float s = brel + rootd[gl];
        int b = rowptr[grow], e = rowptr[grow + 1];
        for (int q = b; q < e; ++q) {
            int sl = col[q] - rowbase;
            s += tb[sl] * nalive[sl];
        }
        keys[n] = (nalive[gl] > 0.5f) ? fkey(s) : 0u;
    }
    if (tid == 0) { sh_pref = 0u; sh_kneed = k; }
    __syncthreads();
    for (int lvl = 3; lvl >= 0; --lvl) {
        int sh = lvl * 8;
        if (tid < 256) hist[tid] = 0;
        unsigned pref = sh_pref; int kneed = sh_kneed;
        unsigned pmask = (lvl == 3) ? 0u : (0xFFFFFFFFu << (8 * (lvl + 1)));
        __syncthreads();
        for (int n = tid; n < NN; n += 1024) {
            unsigned kv = keys[n];
            if ((kv & pmask) == pref) atomicAdd(&hist[(kv >> sh) & 255], 1);
        }
        __syncthreads();
        if (tid == 0) {
            int cum = 0, b = 255;
            for (; b >= 0; --b) { cum += hist[b]; if (cum >= kneed) break; }
            sh_pref = pref | ((unsigned)b << sh);
            sh_kneed = kneed - (cum - hist[b]);
        }
        __syncthreads();
    }
    unsigned V = sh_pref;
    int seleq = sh_kneed;
    int c0 = tid * TCH, c1 = min(c0 + TCH, NN);
    int ceq = 0;
    for (int n = c0; n < c1; ++n) ceq += (keys[n] == V) ? 1 : 0;
    scan[tid] = ceq; __syncthreads();
    for (int off = 1; off < 1024; off <<= 1) {
        int u = (tid >= off) ? scan[tid - off] : 0;
        __syncthreads();
        scan[tid] += u;
        __syncthreads();
    }
    int rank = scan[tid] - ceq;
    unsigned selmask = 0u;
    int nsel = 0;
    float lmax = -INFINITY;
    for (int n = c0; n < c1; ++n) {
        unsigned kk = keys[n];
        bool sel = (kk > V) || (kk == V && rank < seleq);
        if (kk == V) rank++;
        long long gl = pbase + n;
        nalive[gl] = sel ? 1.0f : 0.0f;
        float f = 0.0f;
        if (sel) {
            f = tanhf(fkey_inv(kk));
            lmax = fmaxf(lmax, f * gdot[gl]);
            selmask |= (1u << (n - c0));
            ++nsel;
        }
        fvec[gl] = f;
    }
    redf[tid] = lmax; __syncthreads();
    for (int s = 512; s > 0; s >>= 1) { if (tid < s) redf[tid] = fmaxf(redf[tid], redf[tid + s]); __syncthreads(); }
    float mx = redf[0]; __syncthreads();
    scan[tid] = nsel; __syncthreads();
    for (int off = 1; off < 1024; off <<= 1) {
        int u = (tid >= off) ? scan[tid - off] : 0;
        __syncthreads();
        scan[tid] += u;
        __syncthreads();
    }
    int pos = scan[tid] - nsel;
    float lsum = 0.0f;
    for (int n = c0; n < c1; ++n) {
        if (selmask & (1u << (n - c0))) {
            long long gl = pbase + n;
            float e = expf(fvec[gl] * gdot[gl] - mx);
            gbuf[gl] = e;
            lsum += e;
            aliveIdx[(long long)p * k + pos] = (int)gl;
            ++pos;
        }
    }
    redf[tid] = lsum; __syncthreads();
    for (int s = 512; s > 0; s >>= 1) { if (tid < s) redf[tid] += redf[tid + s]; __syncthreads(); }
    if (tid == 0) invp[p] = 1.0f / redf[0];
}

// ---------------- head ----------------
__global__ __launch_bounds__(64) void k_head(
    const float* __restrict__ ro, const float* __restrict__ lin_w, const float* __restrict__ lin_b,
    const float* __restrict__ m1w, const float* __restrict__ m1b,
    const float* __restrict__ m2w, const float* __restrict__ m2b,
    const float* __restrict__ m3w, const float* __restrict__ m3b, float* __restrict__ out)
{
    __shared__ float v[33], h1[48], h2[16];
    int t = threadIdx.x;
    if (t < 33) {
        float s = lin_b[0];
        for (int k = 0; k < 384; ++k) s += ro[t * 384 + k] * lin_w[k];
        v[t] = tanhf(s);
    }
    __syncthreads();
    if (t < 48) {
        float s = m1b[t];
        for (int i = 0; i < 33; ++i) s += v[i] * m1w[i * 48 + t];
        h1[t] = tanhf(s);
    }
    __syncthreads();
    if (t < 16) {
        float s = m2b[t];
        for (int i = 0; i < 48; ++i) s += h1[i] * m2w[i * 16 + t];
        h2[t] = tanhf(s);
    }
    __syncthreads();
    if (t == 0) {
        float s = m3b[0];
        for (int i = 0; i < 16; ++i) s += h2[i] * m3w[i];
        float s1 = 1.0f / (1.0f + expf(-s));
        out[0] = 1.0f / (1.0f + expf(-s1));
    }
}

static inline int cdiv(long long a, long long b) { return (int)((a + b - 1) / b); }

extern "C" void kernel_launch(void* const* d_in, const int* in_sizes, int n_in,
                              void* d_out, int out_size, void* d_ws, size_t ws_size,
                              hipStream_t stream)
{
    (void)in_sizes; (void)n_in; (void)out_size;
    const float* h     = (const float*)d_in[0];
    const int*   eidx  = (const int*)d_in[1];
    const int*   seidx = (const int*)d_in[2];
    const float* Wl_a  = (const float*)d_in[3];
    const float* Wr_a  = (const float*)d_in[4];
    const float* bl_a  = (const float*)d_in[5];
    const float* Wl_s  = (const float*)d_in[6];
    const float* Wr_s  = (const float*)d_in[7];
    const float* bl_s  = (const float*)d_in[8];
    const float* gate_w = (const float*)d_in[9];
    const float* p_wrel = (const float*)d_in[11];
    const float* p_brel = (const float*)d_in[12];
    const float* p_wroot= (const float*)d_in[13];
    const float* nw    = (const float*)d_in[14];
    const float* nb    = (const float*)d_in[15];
    const float* nms   = (const float*)d_in[16];
    const float* lin_w = (const float*)d_in[17];
    const float* lin_b = (const float*)d_in[18];
    const float* m1w   = (const float*)d_in[19];
    const float* m1b   = (const float*)d_in[20];
    const float* m2w   = (const float*)d_in[21];
    const float* m2b   = (const float*)d_in[22];
    const float* m3w   = (const float*)d_in[23];
    const float* m3b   = (const float*)d_in[24];
    float* out = (float*)d_out;

    const int* esrc = eidx;
    const int* edst = eidx + EG;
    const int* ssrc = seidx;
    const int* sdst = seidx + ES_TOT;

    auto need_bytes = [](int chp) -> size_t {
        long long chn = (long long)chp * NN;
        long long f = 3 * chn * 128
                    + 4LL * NN * 128            // xa, xb, zself, ZL0
                    + NN * 16 + NN
                    + 6 * chn
                    + (long long)chp * KK1
                    + 64 + 33 * 384 + 256
                    + (NN + (NN+1) + NN + EG + NN + 1024)
                    + (PN + (PN+1) + PN + ES_TOT + PN + 1024)
                    + 64 * 48;
        return (size_t)f * 4;
    };
    int chp = 4;
    if (ws_size >= need_bytes(16)) chp = 16;
    else if (ws_size >= need_bytes(8)) chp = 8;
    int nch = PP / chp;
    long long ch_n = (long long)chp * NN;

    float* W = (float*)d_ws;
    size_t off = 0;
    auto alloc = [&](size_t nf) { float* p = W + off; off += (nf + 63) & ~(size_t)63; return p; };
    float* XA    = alloc((size_t)ch_n * DD);
    float* XB    = alloc((size_t)ch_n * DD);
    float* AGG   = alloc((size_t)ch_n * DD);
    float* xa    = alloc((size_t)NN * DD);
    float* xb    = alloc((size_t)NN * DD);
    float* zself = alloc((size_t)NN * DD);
    float* ZL0   = alloc((size_t)NN * DD);
    float* agg1  = alloc((size_t)NN * 16);
    float* deg1  = alloc(NN);
    float* tbuf  = alloc(ch_n);
    float* rootd = alloc(ch_n);
    float* nal   = alloc(ch_n);
    float* fvec  = alloc(ch_n);
    float* gdot  = alloc(ch_n);
    float* gbuf  = alloc(ch_n);
    float* invp  = alloc(64);
    float* ro    = alloc(33 * 384);
    float* musum = alloc(128);
    float* sqsum = alloc(128);
    int* aliveIdx = (int*)alloc((size_t)chp * KK1);
    int* s1cnt  = (int*)alloc(NN);
    int* s1rp   = (int*)alloc(NN + 1);
    int* s1cur  = (int*)alloc(NN);
    int* s1col  = (int*)alloc(EG);
    int* s1part = (int*)alloc(NN);
    int* s1bsum = (int*)alloc(1024);
    int* s2cnt  = (int*)alloc(PN);
    int* s2rp   = (int*)alloc(PN + 1);
    int* s2cur  = (int*)alloc(PN);
    int* s2col  = (int*)alloc(ES_TOT);
    int* s2part = (int*)alloc(PN);
    int* s2bsum = (int*)alloc(1024);

    // ---------- CSR builds ----------
    int nb1 = cdiv(NN, 1024), nb2 = cdiv(PN, 1024);
    hipMemsetAsync(s1cnt, 0, NN * sizeof(int), stream);
    k_hist<<<cdiv(EG,256),256,0,stream>>>(edst, s1cnt, EG);
    k_scanA<<<nb1,1024,0,stream>>>(s1cnt, s1part, s1bsum, NN);
    k_scanB<<<1,1024,0,stream>>>(s1bsum, nb1);
    k_scanC<<<cdiv(NN,256),256,0,stream>>>(s1part, s1bsum, s1rp, s1cur, NN, EG);
    k_scatter<<<cdiv(EG,256),256,0,stream>>>(esrc, edst, s1cur, s1col, EG);

    hipMemsetAsync(s2cnt, 0, (size_t)PN * sizeof(int), stream);
    k_hist<<<cdiv(ES_TOT,256),256,0,stream>>>(sdst, s2cnt, ES_TOT);
    k_scanA<<<nb2,1024,0,stream>>>(s2cnt, s2part, s2bsum, PN);
    k_scanB<<<1,1024,0,stream>>>(s2bsum, nb2);
    k_scanC<<<cdiv(PN,256),256,0,stream>>>(s2part, s2bsum, s2rp, s2cur, PN, ES_TOT);
    k_scatter<<<cdiv(ES_TOT,256),256,0,stream>>>(ssrc, sdst, s2cur, s2col, ES_TOT);

    hipMemsetAsync(ro, 0, 33 * 384 * sizeof(float), stream);

    // ---------- stage 1 ----------
    k_agg16<<<cdiv((long long)NN*16,256),256,0,stream>>>(h, s1rp, s1col, agg1, deg1, NN);
    k_sage16<<<cdiv((long long)NN*DD,256),256,0,stream>>>(h, agg1, deg1, Wl_a, Wr_a, bl_a, xa, NN);
    k_gate<<<cdiv(NN,256),256,0,stream>>>(xa, gate_w + 0*DD, gbuf, NN);
    k_smstats<<<1,1024,0,stream>>>(gbuf, invp);
    k_wsum<<<BPG,128,0,stream>>>(xa, gbuf, invp, ro, 0, 0);

    hipMemsetAsync(musum, 0, 128*sizeof(float), stream);
    hipMemsetAsync(sqsum, 0, 128*sizeof(float), stream);
    k_colstat<<<cdiv(NN,64),128,0,stream>>>(xa, musum, sqsum, NN);
    k_gnorm_apply<<<cdiv((long long)NN*DD,256),256,0,stream>>>(xa, xb, musum, sqsum, nw, nb, nms, NN);

    k_aggf<<<cdiv(NN,8),256,0,stream>>>(xb, s1rp, s1col, nullptr, nullptr, nullptr, 0, 0, 0, AGG, NN);
    k_sage_d<<<cdiv(NN,64),256,0,stream>>>(AGG, xb, nullptr, nullptr, 0,
        Wl_s + 0*16384, Wr_s + 0*16384, bl_s + 0*128, xa, NN,
        nullptr, nullptr, gate_w + 1*DD, nullptr, nullptr, gbuf);
    k_smstats<<<1,1024,0,stream>>>(gbuf, invp);
    k_wsum<<<BPG,128,0,stream>>>(xa, gbuf, invp, ro, 0, 128);

    hipMemsetAsync(musum, 0, 128*sizeof(float), stream);
    hipMemsetAsync(sqsum, 0, 128*sizeof(float), stream);
    k_colstat<<<cdiv(NN,64),128,0,stream>>>(xa, musum, sqsum, NN);
    k_gnorm_apply<<<cdiv((long long)NN*DD,256),256,0,stream>>>(xa, xb, musum, sqsum, nw, nb, nms, NN);

    k_aggf<<<cdiv(NN,8),256,0,stream>>>(xb, s1rp, s1col, nullptr, nullptr, nullptr, 0, 0, 0, AGG, NN);
    k_sage_d<<<cdiv(NN,64),256,0,stream>>>(AGG, xb, nullptr, nullptr, 0,
        Wl_s + 1*16384, Wr_s + 1*16384, bl_s + 1*128, xa, NN,
        nullptr, nullptr, gate_w + 2*DD, nullptr, nullptr, gbuf);
    k_smstats<<<1,1024,0,stream>>>(gbuf, invp);
    k_wsum<<<BPG,128,0,stream>>>(xa, gbuf, invp, ro, 0, 256);

    // ---------- stage 2 ----------
    // L0 linear-map trick: ZL0 = x_c @ Wl2 (no bias), zself = x_c @ Wr2 + bl2
    k_gemm_self<<<cdiv(NN,64),256,0,stream>>>(xa, Wl_s + 2*16384, nullptr, ZL0, NN);
    k_gemm_self<<<cdiv(NN,64),256,0,stream>>>(xa, Wr_s + 2*16384, bl_s + 2*128, zself, NN);

    for (int c = 0; c < nch; ++c) {
        int nbase = (int)(c * ch_n);
        k_fill<<<cdiv(ch_n,256),256,0,stream>>>(nal, 1.0f, (int)ch_n);

        // ---- layer 0: gather-mean of ZL0 + zself (no GEMM) ----
        k_l0comb<<<(int)(ch_n/8),256,0,stream>>>(ZL0, zself, s2rp, s2col, nbase,
            p_wrel + 0*DD, p_wroot + 0*DD, gate_w + 3*DD,
            XA, tbuf, rootd, gdot, (int)ch_n);
        k_topk2<<<chp,1024,0,stream>>>(s2rp, s2col, nbase, tbuf, rootd, gdot, p_brel, 0,
                                       nal, fvec, gbuf, invp, aliveIdx, KK1);
        k_wsum_c<<<chp*(KK1/RB),128,0,stream>>>(XA, gbuf, fvec, invp, aliveIdx, KK1, ro, 1 + c*chp, 0);

        // ---- layer 1: alive K1 rows ----
        k_aggf<<<chp*(KK1/8),256,0,stream>>>(XA, s2rp, s2col, aliveIdx, nal, fvec, 2, 0, nbase, AGG, chp*KK1);
        k_sage_d<<<chp*(KK1/64),256,0,stream>>>(AGG, XA, aliveIdx, fvec, 2,
            Wl_s + 3*16384, Wr_s + 3*16384, bl_s + 3*128, XB, chp*KK1,
            p_wrel + 1*DD, p_wroot + 1*DD, gate_w + 4*DD, tbuf, rootd, gdot);
        k_topk2<<<chp,1024,0,stream>>>(s2rp, s2col, nbase, tbuf, rootd, gdot, p_brel, 1,
                                       nal, fvec, gbuf, invp, aliveIdx, KK2);
        k_wsum_c<<<chp*(KK2/RB),128,0,stream>>>(XB, gbuf, fvec, invp, aliveIdx, KK2, ro, 1 + c*chp, 128);

        // ---- layer 2: alive K2 rows ----
        k_aggf<<<chp*(KK2/8),256,0,stream>>>(XB, s2rp, s2col, aliveIdx, nal, fvec, 2, 0, nbase, AGG, chp*KK2);
        k_sage_d<<<chp*(KK2/64),256,0,stream>>>(AGG, XB, aliveIdx, fvec, 2,
            Wl_s + 4*16384, Wr_s + 4*16384, bl_s + 4*128, XA, chp*KK2,
            p_wrel + 2*DD, p_wroot + 2*DD, gate_w + 5*DD, tbuf, rootd, gdot);
        k_topk2<<<chp,1024,0,stream>>>(s2rp, s2col, nbase, tbuf, rootd, gdot, p_brel, 2,
                                       nal, fvec, gbuf, invp, aliveIdx, KK3);
        k_wsum_c<<<chp*(KK3/RB),128,0,stream>>>(XA, gbuf, fvec, invp, aliveIdx, KK3, ro, 1 + c*chp, 256);
    }

    // ---------- head ----------
    k_head<<<1,64,0,stream>>>(ro, lin_w, lin_b, m1w, m1b, m2w, m2b, m3w, m3b, out);
}

// Round 13
// 1363.551 us; speedup vs baseline: 1.9272x; 1.0122x over previous
//
#include <hip/hip_runtime.h>
#include <math.h>

#define NN      8000
#define PP      32
#define EG      128000
#define ES_TOT  131072     // P * 4096
#define ES_P    4096
#define PN      256000     // P * NN
#define DI      16
#define DD      128
#define KK1     6400
#define KK2     5120
#define KK3     4096
#define RB      64                   // rows per wsum block
#define BPG     (NN / RB)            // 125 blocks per graph (stage-1 wsum)

static __device__ __forceinline__ unsigned fkey(float f) {
    unsigned u = __float_as_uint(f);
    return (u & 0x80000000u) ? ~u : (u | 0x80000000u);
}
static __device__ __forceinline__ float fkey_inv(unsigned k) {
    unsigned u = (k & 0x80000000u) ? (k & 0x7FFFFFFFu) : ~k;
    return __uint_as_float(u);
}

// ---------------- CSR build ----------------
__global__ void k_hist(const int* __restrict__ dst, int* __restrict__ cnt, int ne) {
    int e = blockIdx.x * 256 + threadIdx.x;
    if (e < ne) atomicAdd(&cnt[dst[e]], 1);
}

__global__ __launch_bounds__(1024) void k_scanA(const int* __restrict__ cnt,
                                                int* __restrict__ part,
                                                int* __restrict__ bsum, int n) {
    __shared__ int sh[1024];
    int t = threadIdx.x;
    int i = blockIdx.x * 1024 + t;
    int v = (i < n) ? cnt[i] : 0;
    sh[t] = v; __syncthreads();
    for (int off = 1; off < 1024; off <<= 1) {
        int u = (t >= off) ? sh[t - off] : 0;
        __syncthreads();
        sh[t] += u;
        __syncthreads();
    }
    if (i < n) part[i] = sh[t] - v;
    if (t == 1023) bsum[blockIdx.x] = sh[1023];
}

__global__ __launch_bounds__(1024) void k_scanB(int* __restrict__ bsum, int nb) {
    __shared__ int sh[1024];
    int t = threadIdx.x;
    int v = (t < nb) ? bsum[t] : 0;
    sh[t] = v; __syncthreads();
    for (int off = 1; off < 1024; off <<= 1) {
        int u = (t >= off) ? sh[t - off] : 0;
        __syncthreads();
        sh[t] += u;
        __syncthreads();
    }
    if (t < nb) bsum[t] = sh[t] - v;   // exclusive
}

__global__ void k_scanC(const int* __restrict__ part, const int* __restrict__ bsum,
                        int* __restrict__ rowptr, int* __restrict__ cursor, int n, int total) {
    int i = blockIdx.x * 256 + threadIdx.x;
    if (i < n) {
        int v = part[i] + bsum[i >> 10];
        rowptr[i] = v;
        cursor[i] = v;
    }
    if (i == 0) rowptr[n] = total;
}

__global__ void k_scatter(const int* __restrict__ src, const int* __restrict__ dst,
                          int* __restrict__ cursor, int* __restrict__ col, int ne) {
    int e = blockIdx.x * 256 + threadIdx.x;
    if (e >= ne) return;
    int pos = atomicAdd(&cursor[dst[e]], 1);
    col[pos] = src[e];
}

// ---------------- stage-1 layer a ----------------
__global__ __launch_bounds__(256) void k_agg16(const float* __restrict__ h,
                                               const int* __restrict__ rowptr,
                                               const int* __restrict__ col,
                                               float* __restrict__ agg, float* __restrict__ deg,
                                               int nrows) {
    int i = blockIdx.x * 256 + threadIdx.x;
    int r = i >> 4, j = i & 15;
    if (r >= nrows) return;
    int b = rowptr[r], e = rowptr[r + 1];
    float a = h[r * 16 + j];
    for (int q = b; q < e; ++q) a += h[col[q] * 16 + j];
    agg[r * 16 + j] = a;
    if (j == 0) deg[r] = 1.0f + (float)(e - b);
}

__global__ __launch_bounds__(256) void k_sage16(
    const float* __restrict__ h, const float* __restrict__ agg, const float* __restrict__ deg,
    const float* __restrict__ Wl, const float* __restrict__ Wr, const float* __restrict__ bl,
    float* __restrict__ y, int nrows)
{
    __shared__ float WlS[16][128], WrS[16][128];
    int tid = threadIdx.x;
    for (int i = tid; i < 16 * 128; i += 256) {
        WlS[i >> 7][i & 127] = Wl[i];
        WrS[i >> 7][i & 127] = Wr[i];
    }
    __syncthreads();
    long long o = (long long)blockIdx.x * 256 + tid;
    int row = (int)(o >> 7);
    if (row >= nrows) return;
    int d = (int)o & 127;
    float invd = 1.0f / fmaxf(deg[row], 1.0f);
    float s = bl[d];
    #pragma unroll
    for (int k = 0; k < 16; ++k)
        s += agg[row * 16 + k] * invd * WlS[k][d] + h[row * 16 + k] * WrS[k][d];
    y[(long long)row * 128 + d] = tanhf(s);
}

// ---------------- CSR gather-aggregate (row-parallel, no atomics) ----------------
__global__ __launch_bounds__(256) void k_aggf(
    const float* __restrict__ x,
    const int* __restrict__ rowptr, const int* __restrict__ col,
    const int* __restrict__ aliveIdx, const float* __restrict__ nal, const float* __restrict__ fvec,
    int mode, int xModN, int rowbase,
    float* __restrict__ AGG, int nrowsC)
{
    int tid = threadIdx.x;
    int r = blockIdx.x * 8 + (tid >> 5);
    if (r >= nrowsC) return;
    int lane = tid & 31;
    int orig = aliveIdx ? aliveIdx[r] : r;
    int grow = rowbase + orig;
    int b = rowptr[grow], e = rowptr[grow + 1];
    float4 a = make_float4(0.0f, 0.0f, 0.0f, 0.0f);
    float dsum = 0.0f;
    if (mode == 0) {
        a = *reinterpret_cast<const float4*>(x + (long long)orig * 128 + lane * 4);
        dsum = 1.0f;
    }
    for (int q = b; q < e; ++q) {
        int s = col[q];
        float fw = 1.0f;
        int fr;
        if (mode == 2) {
            fr = s - rowbase;
            if (nal[fr] == 0.0f) continue;
            dsum += 1.0f;
            fw = fvec[fr];
            if (fw == 0.0f) continue;
        } else {
            fr = xModN ? (s % NN) : (s - rowbase);
            dsum += 1.0f;
        }
        float4 v = *reinterpret_cast<const float4*>(x + (long long)fr * 128 + lane * 4);
        a.x += v.x * fw; a.y += v.y * fw; a.z += v.z * fw; a.w += v.w * fw;
    }
    float invds = 1.0f / fmaxf(dsum, 1.0f);
    a.x *= invds; a.y *= invds; a.z *= invds; a.w *= invds;
    *reinterpret_cast<float4*>(AGG + (long long)r * 128 + lane * 4) = a;
}

// ---------------- dense SAGE GEMM, v2 tile: BM=64, 8x4 acc, low VGPR ----------------
// V 0 (stage-1): y=tanh(AGG@Wl + bl + x[crow]@Wr), K=256
// V 2 (s2 L1/2): y=tanh(AGG@Wl + bl + fvec[orig]*x[orig]@Wr), orig=aliveIdx[crow], K=256
// NOTE: y may alias xsrc (each row read only by its own block, reads precede writes).
__global__ __launch_bounds__(256) void k_sage_d(
    const float* __restrict__ AGG, const float* __restrict__ xsrc,
    const int* __restrict__ aliveIdx, const float* __restrict__ fvec,
    int V,
    const float* __restrict__ Wl, const float* __restrict__ Wr, const float* __restrict__ bl,
    float* __restrict__ y, int nrowsC,
    const float* __restrict__ wrel, const float* __restrict__ wroot, const float* __restrict__ gw,
    float* __restrict__ tbuf, float* __restrict__ rootd, float* __restrict__ gdot)
{
    __shared__ float Ws[32 * 128];
    __shared__ float Is[32][68];
    __shared__ float wrelS[128], wrootS[128], gwS[128];
    __shared__ int rowIdxS[64];
    int tid = threadIdx.x;
    long long row0 = (long long)blockIdx.x * 64;
    if (tid < 128) {
        if (wrel)  wrelS[tid]  = wrel[tid];
        if (wroot) wrootS[tid] = wroot[tid];
        if (gw)    gwS[tid]    = gw[tid];
    }
    if (tid < 64) {
        long long lr = row0 + tid;
        if (lr >= nrowsC) lr = nrowsC - 1;
        rowIdxS[tid] = aliveIdx ? aliveIdx[lr] : (int)lr;
    }
    __syncthreads();
    int tx = tid & 31, ty = tid >> 5;
    // hoist epilogue dot weights into registers (avoids per-row conflicted LDS reads)
    float wr4[4] = {0,0,0,0}, wo4[4] = {0,0,0,0}, gg4[4] = {0,0,0,0};
    if (wrel)  { wr4[0]=wrelS[tx*4]; wr4[1]=wrelS[tx*4+1]; wr4[2]=wrelS[tx*4+2]; wr4[3]=wrelS[tx*4+3]; }
    if (wroot) { wo4[0]=wrootS[tx*4]; wo4[1]=wrootS[tx*4+1]; wo4[2]=wrootS[tx*4+2]; wo4[3]=wrootS[tx*4+3]; }
    if (gw)    { gg4[0]=gwS[tx*4]; gg4[1]=gwS[tx*4+1]; gg4[2]=gwS[tx*4+2]; gg4[3]=gwS[tx*4+3]; }
    int srow = tid & 63;
    int koff = (tid >> 6) * 8;
    long long crow = row0 + srow;
    if (crow >= nrowsC) crow = nrowsC - 1;
    int orig = rowIdxS[srow];
    float fself = (V == 2) ? fvec[orig] : 1.0f;
    const float* selfp = xsrc + (long long)orig * 128;
    const float* aggp = AGG + crow * 128;

    float acc[8][4] = {};
    for (int kb = 0; kb < 8; ++kb) {
        __syncthreads();
        bool isAgg = (kb < 4);
        const float* Wsrc = isAgg ? (Wl + kb * 32 * 128) : (Wr + (kb - 4) * 32 * 128);
        #pragma unroll
        for (int j = 0; j < 4; ++j) {
            int fl = j * 1024 + tid * 4;
            *reinterpret_cast<float4*>(&Ws[fl]) = *reinterpret_cast<const float4*>(&Wsrc[fl]);
        }
        {
            const float* sp = (isAgg ? (aggp + kb * 32) : (selfp + (kb - 4) * 32)) + koff;
            float m = isAgg ? 1.0f : fself;
            float4 v0 = *reinterpret_cast<const float4*>(sp);
            float4 v1 = *reinterpret_cast<const float4*>(sp + 4);
            Is[koff + 0][srow] = v0.x * m; Is[koff + 1][srow] = v0.y * m;
            Is[koff + 2][srow] = v0.z * m; Is[koff + 3][srow] = v0.w * m;
            Is[koff + 4][srow] = v1.x * m; Is[koff + 5][srow] = v1.y * m;
            Is[koff + 6][srow] = v1.z * m; Is[koff + 7][srow] = v1.w * m;
        }
        __syncthreads();
        #pragma unroll
        for (int kk = 0; kk < 32; ++kk) {
            float4 wv = *reinterpret_cast<const float4*>(&Ws[kk * 128 + tx * 4]);
            float4 i0 = *reinterpret_cast<const float4*>(&Is[kk][ty * 8]);
            float4 i1 = *reinterpret_cast<const float4*>(&Is[kk][ty * 8 + 4]);
            float ia[8] = {i0.x, i0.y, i0.z, i0.w, i1.x, i1.y, i1.z, i1.w};
            float wa[4] = {wv.x, wv.y, wv.z, wv.w};
            #pragma unroll
            for (int i = 0; i < 8; ++i)
                #pragma unroll
                for (int j = 0; j < 4; ++j)
                    acc[i][j] += ia[i] * wa[j];
        }
    }
    float4 bl0 = *reinterpret_cast<const float4*>(&bl[tx * 4]);
    float br[4] = {bl0.x, bl0.y, bl0.z, bl0.w};
    #pragma unroll
    for (int i = 0; i < 8; ++i) {
        long long cr = row0 + ty * 8 + i;
        bool valid = (cr < nrowsC);
        int rout = rowIdxS[ty * 8 + i];
        float yv[4];
        #pragma unroll
        for (int j = 0; j < 4; ++j) yv[j] = tanhf(acc[i][j] + br[j]);
        if (valid)
            *reinterpret_cast<float4*>(&y[(long long)rout * 128 + tx * 4]) = make_float4(yv[0], yv[1], yv[2], yv[3]);
        float tp = 0.0f, rp = 0.0f, gp = 0.0f;
        #pragma unroll
        for (int j = 0; j < 4; ++j) {
            if (tbuf)  tp += yv[j] * wr4[j];
            if (rootd) rp += yv[j] * wo4[j];
            if (gdot)  gp += yv[j] * gg4[j];
        }
        #pragma unroll
        for (int m = 16; m >= 1; m >>= 1) {
            if (tbuf)  tp += __shfl_xor(tp, m, 32);
            if (rootd) rp += __shfl_xor(rp, m, 32);
            if (gdot)  gp += __shfl_xor(gp, m, 32);
        }
        if (tx == 0 && valid) {
            if (tbuf)  tbuf[rout]  = tp;
            if (rootd) rootd[rout] = rp;
            if (gdot)  gdot[rout]  = gp;
        }
    }
}

// ---------------- plain GEMM: y = x@W (+ b), v2 tile ----------------
__global__ __launch_bounds__(256) void k_gemm_self(
    const float* __restrict__ x, const float* __restrict__ W, const float* __restrict__ b,
    float* __restrict__ y, int nrows)
{
    __shared__ float Ws[32 * 128];
    __shared__ float Is[32][68];
    int tid = threadIdx.x;
    long long row0 = (long long)blockIdx.x * 64;
    int tx = tid & 31, ty = tid >> 5;
    int srow = tid & 63;
    int koff = (tid >> 6) * 8;
    long long lrow = row0 + srow;
    if (lrow >= nrows) lrow = nrows - 1;
    const float* xrow = x + lrow * 128;
    float acc[8][4] = {};
    for (int kb = 0; kb < 4; ++kb) {
        __syncthreads();
        const float* Wsrc = W + kb * 32 * 128;
        #pragma unroll
        for (int j = 0; j < 4; ++j) {
            int fl = j * 1024 + tid * 4;
            *reinterpret_cast<float4*>(&Ws[fl]) = *reinterpret_cast<const float4*>(&Wsrc[fl]);
        }
        {
            const float* sp = xrow + kb * 32 + koff;
            float4 v0 = *reinterpret_cast<const float4*>(sp);
            float4 v1 = *reinterpret_cast<const float4*>(sp + 4);
            Is[koff + 0][srow] = v0.x; Is[koff + 1][srow] = v0.y;
            Is[koff + 2][srow] = v0.z; Is[koff + 3][srow] = v0.w;
            Is[koff + 4][srow] = v1.x; Is[koff + 5][srow] = v1.y;
            Is[koff + 6][srow] = v1.z; Is[koff + 7][srow] = v1.w;
        }
        __syncthreads();
        #pragma unroll
        for (int kk = 0; kk < 32; ++kk) {
            float4 wv = *reinterpret_cast<const float4*>(&Ws[kk * 128 + tx * 4]);
            float4 i0 = *reinterpret_cast<const float4*>(&Is[kk][ty * 8]);
            float4 i1 = *reinterpret_cast<const float4*>(&Is[kk][ty * 8 + 4]);
            float ia[8] = {i0.x, i0.y, i0.z, i0.w, i1.x, i1.y, i1.z, i1.w};
            float wa[4] = {wv.x, wv.y, wv.z, wv.w};
            #pragma unroll
            for (int i = 0; i < 8; ++i)
                #pragma unroll
                for (int j = 0; j < 4; ++j)
                    acc[i][j] += ia[i] * wa[j];
        }
    }
    float4 b0 = b ? *reinterpret_cast<const float4*>(&b[tx * 4]) : make_float4(0.f, 0.f, 0.f, 0.f);
    #pragma unroll
    for (int i = 0; i < 8; ++i) {
        long long row = row0 + ty * 8 + i;
        if (row >= nrows) continue;
        *reinterpret_cast<float4*>(&y[row * 128 + tx * 4]) =
            make_float4(acc[i][0] + b0.x, acc[i][1] + b0.y, acc[i][2] + b0.z, acc[i][3] + b0.w);
    }
}

// ---------------- stage-2 L0 combine (linear-map trick, no GEMM) ----------------
__global__ __launch_bounds__(256) void k_l0comb(
    const float* __restrict__ ZL0, const float* __restrict__ zself,
    const int* __restrict__ rowptr, const int* __restrict__ col, int rowbase,
    const float* __restrict__ wrel, const float* __restrict__ wroot, const float* __restrict__ gw,
    float* __restrict__ y, float* __restrict__ tbuf, float* __restrict__ rootd, float* __restrict__ gdot,
    int nrowsC)
{
    __shared__ float wrelS[128], wrootS[128], gwS[128];
    int tid = threadIdx.x;
    if (tid < 128) {
        wrelS[tid]  = wrel[tid];
        wrootS[tid] = wroot[tid];
        gwS[tid]    = gw[tid];
    }
    __syncthreads();
    int r = blockIdx.x * 8 + (tid >> 5);
    if (r >= nrowsC) return;
    int lane = tid & 31;
    int grow = rowbase + r;
    int b = rowptr[grow], e = rowptr[grow + 1];
    float4 a = make_float4(0.0f, 0.0f, 0.0f, 0.0f);
    for (int q = b; q < e; ++q) {
        int fr = col[q] % NN;
        float4 v = *reinterpret_cast<const float4*>(ZL0 + (long long)fr * 128 + lane * 4);
        a.x += v.x; a.y += v.y; a.z += v.z; a.w += v.w;
    }
    float invds = 1.0f / fmaxf((float)(e - b), 1.0f);
    const float4 z = *reinterpret_cast<const float4*>(zself + (long long)(r % NN) * 128 + lane * 4);
    float yv[4];
    yv[0] = tanhf(a.x * invds + z.x);
    yv[1] = tanhf(a.y * invds + z.y);
    yv[2] = tanhf(a.z * invds + z.z);
    yv[3] = tanhf(a.w * invds + z.w);
    *reinterpret_cast<float4*>(y + (long long)r * 128 + lane * 4) = make_float4(yv[0], yv[1], yv[2], yv[3]);
    float tp = 0.0f, rp = 0.0f, gp = 0.0f;
    #pragma unroll
    for (int j = 0; j < 4; ++j) {
        tp += yv[j] * wrelS[lane*4 + j];
        rp += yv[j] * wrootS[lane*4 + j];
        gp += yv[j] * gwS[lane*4 + j];
    }
    #pragma unroll
    for (int m = 16; m >= 1; m >>= 1) {
        tp += __shfl_xor(tp, m, 32);
        rp += __shfl_xor(rp, m, 32);
        gp += __shfl_xor(gp, m, 32);
    }
    if (lane == 0) {
        tbuf[r]  = tp;
        rootd[r] = rp;
        gdot[r]  = gp;
    }
}

// ---------------- stage-1 readout pieces ----------------
__global__ __launch_bounds__(256) void k_gate(
    const float* __restrict__ X, const float* __restrict__ gw,
    float* __restrict__ g, int nrows)
{
    __shared__ float wS[128];
    if (threadIdx.x < 128) wS[threadIdx.x] = gw[threadIdx.x];
    __syncthreads();
    int i = blockIdx.x * 256 + threadIdx.x;
    if (i >= nrows) return;
    const float4* xrp = reinterpret_cast<const float4*>(X + (long long)i * 128);
    float s = 0.0f;
    #pragma unroll
    for (int k = 0; k < 32; ++k) {
        float4 v = xrp[k];
        s += v.x * wS[4*k] + v.y * wS[4*k+1] + v.z * wS[4*k+2] + v.w * wS[4*k+3];
    }
    g[i] = s;
}

__global__ __launch_bounds__(1024) void k_smstats(float* __restrict__ g, float* __restrict__ invp) {
    __shared__ float red[1024];
    int p = blockIdx.x, tid = threadIdx.x;
    float* gp = g + (long long)p * NN;
    float lmax = -INFINITY;
    for (int n = tid; n < NN; n += 1024) lmax = fmaxf(lmax, gp[n]);
    red[tid] = lmax; __syncthreads();
    for (int s = 512; s > 0; s >>= 1) { if (tid < s) red[tid] = fmaxf(red[tid], red[tid + s]); __syncthreads(); }
    float mx = red[0]; __syncthreads();
    float ls = 0.0f;
    for (int n = tid; n < NN; n += 1024) { float e = expf(gp[n] - mx); gp[n] = e; ls += e; }
    red[tid] = ls; __syncthreads();
    for (int s = 512; s > 0; s >>= 1) { if (tid < s) red[tid] += red[tid + s]; __syncthreads(); }
    if (tid == 0) invp[p] = 1.0f / red[0];
}

__global__ __launch_bounds__(128) void k_wsum(
    const float* __restrict__ X, const float* __restrict__ a,
    const float* __restrict__ invp, float* __restrict__ ro, int rowbase, int colOff)
{
    int p = blockIdx.x / BPG;
    int chunk = blockIdx.x % BPG;
    int d = threadIdx.x;
    long long base = (long long)p * NN;
    int r0 = chunk * RB, r1 = r0 + RB;
    float s = 0.0f;
    for (int n = r0; n < r1; ++n) {
        float w = a[base + n];
        if (w != 0.0f) s += w * X[(base + n) * 128 + d];
    }
    atomicAdd(&ro[(long long)(rowbase + p) * 384 + colOff + d], s * invp[p]);
}

// stage-2 weighted sum over alive rows only
__global__ __launch_bounds__(128) void k_wsum_c(
    const float* __restrict__ X, const float* __restrict__ gbuf, const float* __restrict__ fvec,
    const float* __restrict__ invp, const int* __restrict__ aliveIdx, int k,
    float* __restrict__ ro, int rowbaseRo, int colOff)
{
    int bpp = k / RB;
    int p = blockIdx.x / bpp;
    int chunk = blockIdx.x % bpp;
    int d = threadIdx.x;
    const int* ai = aliveIdx + (long long)p * k + chunk * RB;
    float s = 0.0f;
    for (int j = 0; j < RB; ++j) {
        int row = ai[j];
        float w = gbuf[row] * fvec[row];
        s += w * X[(long long)row * 128 + d];
    }
    atomicAdd(&ro[(long long)(rowbaseRo + p) * 384 + colOff + d], s * invp[p]);
}

// ---------------- GraphNorm ----------------
__global__ void k_colstat(const float* __restrict__ x, float* __restrict__ musum,
                          float* __restrict__ sqsum, int nrows) {
    int d = threadIdx.x;
    int r0 = blockIdx.x * 64;
    int r1 = min(r0 + 64, nrows);
    float s = 0.0f, q = 0.0f;
    for (int r = r0; r < r1; ++r) { float v = x[(long long)r * 128 + d]; s += v; q += v * v; }
    atomicAdd(&musum[d], s);
    atomicAdd(&sqsum[d], q);
}

__global__ void k_gnorm_apply(const float* __restrict__ x, float* __restrict__ y,
                              const float* __restrict__ musum, const float* __restrict__ sqsum,
                              const float* __restrict__ w, const float* __restrict__ b,
                              const float* __restrict__ ms, int nrows) {
    long long i = (long long)blockIdx.x * 256 + threadIdx.x;
    if (i >= (long long)nrows * 128) return;
    int d = (int)(i & 127);
    float inv_n = 1.0f / (float)nrows;
    float mu = musum[d] * inv_n;
    float c = mu * ms[d];
    float var = sqsum[d] * inv_n - 2.0f * c * mu + c * c;
    y[i] = w[d] * (x[i] - c) * rsqrtf(var + 1e-5f) + b[d];
}

// ---------------- mega top-k (1024 threads) ----------------
#define TCH 8   // NN/1024
__global__ __launch_bounds__(1024) void k_topk2(
    const int* __restrict__ rowptr, const int* __restrict__ col, int rowbase,
    const float* __restrict__ tb, const float* __restrict__ rootd,
    const float* __restrict__ gdot, const float* __restrict__ brelp, int bi, int allAlive,
    float* __restrict__ nalive, float* __restrict__ fvec, float* __restrict__ gbuf,
    float* __restrict__ invp, int* __restrict__ aliveIdx, int k)
{
    __shared__ unsigned keys[NN];
    __shared__ int hist[256];
    __shared__ int scan[1024];
    __shared__ float redf[1024];
    __shared__ unsigned sh_pref;
    __shared__ int sh_kneed;
    int p = blockIdx.x, tid = threadIdx.x;
    float brel = brelp[bi];
    long long pbase = (long long)p * NN;
    for (int n = tid; n < NN; n += 1024) {
        long long gl = pbase + n;
        int grow = rowbase + (int)gl;
        float s = brel + rootd[gl];
        int b = rowptr[grow], e = rowptr[grow + 1];
        for (int q = b; q < e; ++q) {
            int sl = col[q] - rowbase;
            s += allAlive ? tb[sl] : (tb[sl] * nalive[sl]);
        }
        bool alive = allAlive || (nalive[gl] > 0.5f);
        keys[n] = alive ? fkey(s) : 0u;
    }
    if (tid == 0) { sh_pref = 0u; sh_kneed = k; }
    __syncthreads();
    for (int lvl = 3; lvl >= 0; --lvl) {
        int sh = lvl * 8;
        if (tid < 256) hist[tid] = 0;
        unsigned pref = sh_pref; int kneed = sh_kneed;
        unsigned pmask = (lvl == 3) ? 0u : (0xFFFFFFFFu << (8 * (lvl + 1)));
        __syncthreads();
        for (int n = tid; n < NN; n += 1024) {
            unsigned kv = keys[n];
            if ((kv & pmask) == pref) atomicAdd(&hist[(kv >> sh) & 255], 1);
        }
        __syncthreads();
        if (tid == 0) {
            int cum = 0, b = 255;
            for (; b >= 0; --b) { cum += hist[b]; if (cum >= kneed) break; }
            sh_pref = pref | ((unsigned)b << sh);
            sh_kneed = kneed - (cum - hist[b]);
        }
        __syncthreads();
    }
    unsigned V = sh_pref;
    int seleq = sh_kneed;
    int c0 = tid * TCH, c1 = min(c0 + TCH, NN);
    int ceq = 0;
    for (int n = c0; n < c1; ++n) ceq += (keys[n] == V) ? 1 : 0;
    scan[tid] = ceq; __syncthreads();
    for (int off = 1; off < 1024; off <<= 1) {
        int u = (tid >= off) ? scan[tid - off] : 0;
        __syncthreads();
        scan[tid] += u;
        __syncthreads();
    }
    int rank = scan[tid] - ceq;
    unsigned selmask = 0u;
    int nsel = 0;
    float lmax = -INFINITY;
    for (int n = c0; n < c1; ++n) {
        unsigned kk = keys[n];
        bool sel = (kk > V) || (kk == V && rank < seleq);
        if (kk == V) rank++;
        long long gl = pbase + n;
        nalive[gl] = sel ? 1.0f : 0.0f;
        float f = 0.0f;
        if (sel) {
            f = tanhf(fkey_inv(kk));
            lmax = fmaxf(lmax, f * gdot[gl]);
            selmask |= (1u << (n - c0));
            ++nsel;
        }
        fvec[gl] = f;
    }
    redf[tid] = lmax; __syncthreads();
    for (int s = 512; s > 0; s >>= 1) { if (tid < s) redf[tid] = fmaxf(redf[tid], redf[tid + s]); __syncthreads(); }
    float mx = redf[0]; __syncthreads();
    scan[tid] = nsel; __syncthreads();
    for (int off = 1; off < 1024; off <<= 1) {
        int u = (tid >= off) ? scan[tid - off] : 0;
        __syncthreads();
        scan[tid] += u;
        __syncthreads();
    }
    int pos = scan[tid] - nsel;
    float lsum = 0.0f;
    for (int n = c0; n < c1; ++n) {
        if (selmask & (1u << (n - c0))) {
            long long gl = pbase + n;
            float e = expf(fvec[gl] * gdot[gl] - mx);
            gbuf[gl] = e;
            lsum += e;
            aliveIdx[(long long)p * k + pos] = (int)gl;
            ++pos;
        }
    }
    redf[tid] = lsum; __syncthreads();
    for (int s = 512; s > 0; s >>= 1) { if (tid < s) redf[tid] += redf[tid + s]; __syncthreads(); }
    if (tid == 0) invp[p] = 1.0f / redf[0];
}

// ---------------- head ----------------
__global__ __launch_bounds__(64) void k_head(
    const float* __restrict__ ro, const float* __restrict__ lin_w, const float* __restrict__ lin_b,
    const float* __restrict__ m1w, const float* __restrict__ m1b,
    const float* __restrict__ m2w, const float* __restrict__ m2b,
    const float* __restrict__ m3w, const float* __restrict__ m3b, float* __restrict__ out)
{
    __shared__ float v[33], h1[48], h2[16];
    int t = threadIdx.x;
    if (t < 33) {
        float s = lin_b[0];
        for (int k = 0; k < 384; ++k) s += ro[t * 384 + k] * lin_w[k];
        v[t] = tanhf(s);
    }
    __syncthreads();
    if (t < 48) {
        float s = m1b[t];
        for (int i = 0; i < 33; ++i) s += v[i] * m1w[i * 48 + t];
        h1[t] = tanhf(s);
    }
    __syncthreads();
    if (t < 16) {
        float s = m2b[t];
        for (int i = 0; i < 48; ++i) s += h1[i] * m2w[i * 16 + t];
        h2[t] = tanhf(s);
    }
    __syncthreads();
    if (t == 0) {
        float s = m3b[0];
        for (int i = 0; i < 16; ++i) s += h2[i] * m3w[i];
        float s1 = 1.0f / (1.0f + expf(-s));
        out[0] = 1.0f / (1.0f + expf(-s1));
    }
}

static inline int cdiv(long long a, long long b) { return (int)((a + b - 1) / b); }

extern "C" void kernel_launch(void* const* d_in, const int* in_sizes, int n_in,
                              void* d_out, int out_size, void* d_ws, size_t ws_size,
                              hipStream_t stream)
{
    (void)in_sizes; (void)n_in; (void)out_size;
    const float* h     = (const float*)d_in[0];
    const int*   eidx  = (const int*)d_in[1];
    const int*   seidx = (const int*)d_in[2];
    const float* Wl_a  = (const float*)d_in[3];
    const float* Wr_a  = (const float*)d_in[4];
    const float* bl_a  = (const float*)d_in[5];
    const float* Wl_s  = (const float*)d_in[6];
    const float* Wr_s  = (const float*)d_in[7];
    const float* bl_s  = (const float*)d_in[8];
    const float* gate_w = (const float*)d_in[9];
    const float* p_wrel = (const float*)d_in[11];
    const float* p_brel = (const float*)d_in[12];
    const float* p_wroot= (const float*)d_in[13];
    const float* nw    = (const float*)d_in[14];
    const float* nb    = (const float*)d_in[15];
    const float* nms   = (const float*)d_in[16];
    const float* lin_w = (const float*)d_in[17];
    const float* lin_b = (const float*)d_in[18];
    const float* m1w   = (const float*)d_in[19];
    const float* m1b   = (const float*)d_in[20];
    const float* m2w   = (const float*)d_in[21];
    const float* m2b   = (const float*)d_in[22];
    const float* m3w   = (const float*)d_in[23];
    const float* m3b   = (const float*)d_in[24];
    float* out = (float*)d_out;

    const int* esrc = eidx;
    const int* edst = eidx + EG;
    const int* ssrc = seidx;
    const int* sdst = seidx + ES_TOT;

    // workspace need (no XB: GEMM writes in place)
    auto need_bytes = [](int chp) -> size_t {
        long long chn = (long long)chp * NN;
        long long f = 2 * chn * 128             // XA, AGG
                    + 4LL * NN * 128            // xa, xb, zself, ZL0
                    + NN * 16 + NN
                    + 6 * chn
                    + (long long)chp * KK1
                    + 64 + 33 * 384 + 256
                    + (NN + (NN+1) + NN + EG + NN + 1024)
                    + (PN + (PN+1) + PN + ES_TOT + PN + 1024)
                    + 64 * 48;
        return (size_t)f * 4;
    };
    int chp = 8;
    if (ws_size >= need_bytes(32)) chp = 32;
    else if (ws_size >= need_bytes(16)) chp = 16;
    int nch = PP / chp;
    long long ch_n = (long long)chp * NN;

    float* W = (float*)d_ws;
    size_t off = 0;
    auto alloc = [&](size_t nf) { float* p = W + off; off += (nf + 63) & ~(size_t)63; return p; };
    float* XA    = alloc((size_t)ch_n * DD);
    float* AGG   = alloc((size_t)ch_n * DD);
    float* xa    = alloc((size_t)NN * DD);
    float* xb    = alloc((size_t)NN * DD);
    float* zself = alloc((size_t)NN * DD);
    float* ZL0   = alloc((size_t)NN * DD);
    float* agg1  = alloc((size_t)NN * 16);
    float* deg1  = alloc(NN);
    float* tbuf  = alloc(ch_n);
    float* rootd = alloc(ch_n);
    float* nal   = alloc(ch_n);
    float* fvec  = alloc(ch_n);
    float* gdot  = alloc(ch_n);
    float* gbuf  = alloc(ch_n);
    float* invp  = alloc(64);
    float* ro    = alloc(33 * 384);
    float* musum = alloc(128);
    float* sqsum = alloc(128);
    int* aliveIdx = (int*)alloc((size_t)chp * KK1);
    int* s1cnt  = (int*)alloc(NN);
    int* s1rp   = (int*)alloc(NN + 1);
    int* s1cur  = (int*)alloc(NN);
    int* s1col  = (int*)alloc(EG);
    int* s1part = (int*)alloc(NN);
    int* s1bsum = (int*)alloc(1024);
    int* s2cnt  = (int*)alloc(PN);
    int* s2rp   = (int*)alloc(PN + 1);
    int* s2cur  = (int*)alloc(PN);
    int* s2col  = (int*)alloc(ES_TOT);
    int* s2part = (int*)alloc(PN);
    int* s2bsum = (int*)alloc(1024);

    // ---------- CSR builds ----------
    int nb1 = cdiv(NN, 1024), nb2 = cdiv(PN, 1024);
    hipMemsetAsync(s1cnt, 0, NN * sizeof(int), stream);
    k_hist<<<cdiv(EG,256),256,0,stream>>>(edst, s1cnt, EG);
    k_scanA<<<nb1,1024,0,stream>>>(s1cnt, s1part, s1bsum, NN);
    k_scanB<<<1,1024,0,stream>>>(s1bsum, nb1);
    k_scanC<<<cdiv(NN,256),256,0,stream>>>(s1part, s1bsum, s1rp, s1cur, NN, EG);
    k_scatter<<<cdiv(EG,256),256,0,stream>>>(esrc, edst, s1cur, s1col, EG);

    hipMemsetAsync(s2cnt, 0, (size_t)PN * sizeof(int), stream);
    k_hist<<<cdiv(ES_TOT,256),256,0,stream>>>(sdst, s2cnt, ES_TOT);
    k_scanA<<<nb2,1024,0,stream>>>(s2cnt, s2part, s2bsum, PN);
    k_scanB<<<1,1024,0,stream>>>(s2bsum, nb2);
    k_scanC<<<cdiv(PN,256),256,0,stream>>>(s2part, s2bsum, s2rp, s2cur, PN, ES_TOT);
    k_scatter<<<cdiv(ES_TOT,256),256,0,stream>>>(ssrc, sdst, s2cur, s2col, ES_TOT);

    hipMemsetAsync(ro, 0, 33 * 384 * sizeof(float), stream);

    // ---------- stage 1 ----------
    k_agg16<<<cdiv((long long)NN*16,256),256,0,stream>>>(h, s1rp, s1col, agg1, deg1, NN);
    k_sage16<<<cdiv((long long)NN*DD,256),256,0,stream>>>(h, agg1, deg1, Wl_a, Wr_a, bl_a, xa, NN);
    k_gate<<<cdiv(NN,256),256,0,stream>>>(xa, gate_w + 0*DD, gbuf, NN);
    k_smstats<<<1,1024,0,stream>>>(gbuf, invp);
    k_wsum<<<BPG,128,0,stream>>>(xa, gbuf, invp, ro, 0, 0);

    hipMemsetAsync(musum, 0, 128*sizeof(float), stream);
    hipMemsetAsync(sqsum, 0, 128*sizeof(float), stream);
    k_colstat<<<cdiv(NN,64),128,0,stream>>>(xa, musum, sqsum, NN);
    k_gnorm_apply<<<cdiv((long long)NN*DD,256),256,0,stream>>>(xa, xb, musum, sqsum, nw, nb, nms, NN);

    k_aggf<<<cdiv(NN,8),256,0,stream>>>(xb, s1rp, s1col, nullptr, nullptr, nullptr, 0, 0, 0, AGG, NN);
    k_sage_d<<<cdiv(NN,64),256,0,stream>>>(AGG, xb, nullptr, nullptr, 0,
        Wl_s + 0*16384, Wr_s + 0*16384, bl_s + 0*128, xa, NN,
        nullptr, nullptr, gate_w + 1*DD, nullptr, nullptr, gbuf);
    k_smstats<<<1,1024,0,stream>>>(gbuf, invp);
    k_wsum<<<BPG,128,0,stream>>>(xa, gbuf, invp, ro, 0, 128);

    hipMemsetAsync(musum, 0, 128*sizeof(float), stream);
    hipMemsetAsync(sqsum, 0, 128*sizeof(float), stream);
    k_colstat<<<cdiv(NN,64),128,0,stream>>>(xa, musum, sqsum, NN);
    k_gnorm_apply<<<cdiv((long long)NN*DD,256),256,0,stream>>>(xa, xb, musum, sqsum, nw, nb, nms, NN);

    k_aggf<<<cdiv(NN,8),256,0,stream>>>(xb, s1rp, s1col, nullptr, nullptr, nullptr, 0, 0, 0, AGG, NN);
    k_sage_d<<<cdiv(NN,64),256,0,stream>>>(AGG, xb, nullptr, nullptr, 0,
        Wl_s + 1*16384, Wr_s + 1*16384, bl_s + 1*128, xa, NN,
        nullptr, nullptr, gate_w + 2*DD, nullptr, nullptr, gbuf);
    k_smstats<<<1,1024,0,stream>>>(gbuf, invp);
    k_wsum<<<BPG,128,0,stream>>>(xa, gbuf, invp, ro, 0, 256);

    // ---------- stage 2 ----------
    k_gemm_self<<<cdiv(NN,64),256,0,stream>>>(xa, Wl_s + 2*16384, nullptr, ZL0, NN);
    k_gemm_self<<<cdiv(NN,64),256,0,stream>>>(xa, Wr_s + 2*16384, bl_s + 2*128, zself, NN);

    for (int c = 0; c < nch; ++c) {
        int nbase = (int)(c * ch_n);

        // ---- layer 0: gather-mean of ZL0 + zself (no GEMM; all rows alive) ----
        k_l0comb<<<(int)(ch_n/8),256,0,stream>>>(ZL0, zself, s2rp, s2col, nbase,
            p_wrel + 0*DD, p_wroot + 0*DD, gate_w + 3*DD,
            XA, tbuf, rootd, gdot, (int)ch_n);
        k_topk2<<<chp,1024,0,stream>>>(s2rp, s2col, nbase, tbuf, rootd, gdot, p_brel, 0, 1,
                                       nal, fvec, gbuf, invp, aliveIdx, KK1);
        k_wsum_c<<<chp*(KK1/RB),128,0,stream>>>(XA, gbuf, fvec, invp, aliveIdx, KK1, ro, 1 + c*chp, 0);

        // ---- layer 1: alive K1 rows (in-place on XA) ----
        k_aggf<<<chp*(KK1/8),256,0,stream>>>(XA, s2rp, s2col, aliveIdx, nal, fvec, 2, 0, nbase, AGG, chp*KK1);
        k_sage_d<<<chp*(KK1/64),256,0,stream>>>(AGG, XA, aliveIdx, fvec, 2,
            Wl_s + 3*16384, Wr_s + 3*16384, bl_s + 3*128, XA, chp*KK1,
            p_wrel + 1*DD, p_wroot + 1*DD, gate_w + 4*DD, tbuf, rootd, gdot);
        k_topk2<<<chp,1024,0,stream>>>(s2rp, s2col, nbase, tbuf, rootd, gdot, p_brel, 1, 0,
                                       nal, fvec, gbuf, invp, aliveIdx, KK2);
        k_wsum_c<<<chp*(KK2/RB),128,0,stream>>>(XA, gbuf, fvec, invp, aliveIdx, KK2, ro, 1 + c*chp, 128);

        // ---- layer 2: alive K2 rows (in-place on XA) ----
        k_aggf<<<chp*(KK2/8),256,0,stream>>>(XA, s2rp, s2col, aliveIdx, nal, fvec, 2, 0, nbase, AGG, chp*KK2);
        k_sage_d<<<chp*(KK2/64),256,0,stream>>>(AGG, XA, aliveIdx, fvec, 2,
            Wl_s + 4*16384, Wr_s + 4*16384, bl_s + 4*128, XA, chp*KK2,
            p_wrel + 2*DD, p_wroot + 2*DD, gate_w + 5*DD, tbuf, rootd, gdot);
        k_topk2<<<chp,1024,0,stream>>>(s2rp, s2col, nbase, tbuf, rootd, gdot, p_brel, 2, 0,
                                       nal, fvec, gbuf, invp, aliveIdx, KK3);
        k_wsum_c<<<chp*(KK3/RB),128,0,stream>>>(XA, gbuf, fvec, invp, aliveIdx, KK3, ro, 1 + c*chp, 256);
    }

    // ---------- head ----------
    k_head<<<1,64,0,stream>>>(ro, lin_w, lin_b, m1w, m1b, m2w, m2b, m3w, m3b, out);
}

// Round 14
// 978.905 us; speedup vs baseline: 2.6844x; 1.3929x over previous
//
#include <hip/hip_runtime.h>
#include <math.h>

#define NN      8000
#define PP      32
#define EG      128000
#define ES_TOT  131072     // P * 4096
#define ES_P    4096
#define PN      256000     // P * NN
#define DI      16
#define DD      128
#define KK1     6400
#define KK2     5120
#define KK3     4096
#define RB      64                   // rows per wsum block
#define BPG     (NN / RB)            // 125 blocks per graph (stage-1 wsum)

static __device__ __forceinline__ unsigned fkey(float f) {
    unsigned u = __float_as_uint(f);
    return (u & 0x80000000u) ? ~u : (u | 0x80000000u);
}
static __device__ __forceinline__ float fkey_inv(unsigned k) {
    unsigned u = (k & 0x80000000u) ? (k & 0x7FFFFFFFu) : ~k;
    return __uint_as_float(u);
}

// ---------------- CSR build ----------------
__global__ void k_hist(const int* __restrict__ dst, int* __restrict__ cnt, int ne) {
    int e = blockIdx.x * 256 + threadIdx.x;
    if (e < ne) atomicAdd(&cnt[dst[e]], 1);
}

__global__ __launch_bounds__(1024) void k_scanA(const int* __restrict__ cnt,
                                                int* __restrict__ part,
                                                int* __restrict__ bsum, int n) {
    __shared__ int sh[1024];
    int t = threadIdx.x;
    int i = blockIdx.x * 1024 + t;
    int v = (i < n) ? cnt[i] : 0;
    sh[t] = v; __syncthreads();
    for (int off = 1; off < 1024; off <<= 1) {
        int u = (t >= off) ? sh[t - off] : 0;
        __syncthreads();
        sh[t] += u;
        __syncthreads();
    }
    if (i < n) part[i] = sh[t] - v;
    if (t == 1023) bsum[blockIdx.x] = sh[1023];
}

__global__ __launch_bounds__(1024) void k_scanB(int* __restrict__ bsum, int nb) {
    __shared__ int sh[1024];
    int t = threadIdx.x;
    int v = (t < nb) ? bsum[t] : 0;
    sh[t] = v; __syncthreads();
    for (int off = 1; off < 1024; off <<= 1) {
        int u = (t >= off) ? sh[t - off] : 0;
        __syncthreads();
        sh[t] += u;
        __syncthreads();
    }
    if (t < nb) bsum[t] = sh[t] - v;   // exclusive
}

__global__ void k_scanC(const int* __restrict__ part, const int* __restrict__ bsum,
                        int* __restrict__ rowptr, int* __restrict__ cursor, int n, int total) {
    int i = blockIdx.x * 256 + threadIdx.x;
    if (i < n) {
        int v = part[i] + bsum[i >> 10];
        rowptr[i] = v;
        cursor[i] = v;
    }
    if (i == 0) rowptr[n] = total;
}

__global__ void k_scatter(const int* __restrict__ src, const int* __restrict__ dst,
                          int* __restrict__ cursor, int* __restrict__ col, int ne) {
    int e = blockIdx.x * 256 + threadIdx.x;
    if (e >= ne) return;
    int pos = atomicAdd(&cursor[dst[e]], 1);
    col[pos] = src[e];
}

// ---------------- stage-1 layer a ----------------
__global__ __launch_bounds__(256) void k_agg16(const float* __restrict__ h,
                                               const int* __restrict__ rowptr,
                                               const int* __restrict__ col,
                                               float* __restrict__ agg, float* __restrict__ deg,
                                               int nrows) {
    int i = blockIdx.x * 256 + threadIdx.x;
    int r = i >> 4, j = i & 15;
    if (r >= nrows) return;
    int b = rowptr[r], e = rowptr[r + 1];
    float a = h[r * 16 + j];
    for (int q = b; q < e; ++q) a += h[col[q] * 16 + j];
    agg[r * 16 + j] = a;
    if (j == 0) deg[r] = 1.0f + (float)(e - b);
}

__global__ __launch_bounds__(256) void k_sage16(
    const float* __restrict__ h, const float* __restrict__ agg, const float* __restrict__ deg,
    const float* __restrict__ Wl, const float* __restrict__ Wr, const float* __restrict__ bl,
    float* __restrict__ y, int nrows)
{
    __shared__ float WlS[16][128], WrS[16][128];
    int tid = threadIdx.x;
    for (int i = tid; i < 16 * 128; i += 256) {
        WlS[i >> 7][i & 127] = Wl[i];
        WrS[i >> 7][i & 127] = Wr[i];
    }
    __syncthreads();
    long long o = (long long)blockIdx.x * 256 + tid;
    int row = (int)(o >> 7);
    if (row >= nrows) return;
    int d = (int)o & 127;
    float invd = 1.0f / fmaxf(deg[row], 1.0f);
    float s = bl[d];
    #pragma unroll
    for (int k = 0; k < 16; ++k)
        s += agg[row * 16 + k] * invd * WlS[k][d] + h[row * 16 + k] * WrS[k][d];
    y[(long long)row * 128 + d] = tanhf(s);
}

// ---------------- CSR gather-aggregate (row-parallel, no atomics) ----------------
__global__ __launch_bounds__(256) void k_aggf(
    const float* __restrict__ x,
    const int* __restrict__ rowptr, const int* __restrict__ col,
    const int* __restrict__ aliveIdx, const float* __restrict__ nal, const float* __restrict__ fvec,
    int mode, int xModN, int rowbase,
    float* __restrict__ AGG, int nrowsC)
{
    int tid = threadIdx.x;
    int r = blockIdx.x * 8 + (tid >> 5);
    if (r >= nrowsC) return;
    int lane = tid & 31;
    int orig = aliveIdx ? aliveIdx[r] : r;
    int grow = rowbase + orig;
    int b = rowptr[grow], e = rowptr[grow + 1];
    float4 a = make_float4(0.0f, 0.0f, 0.0f, 0.0f);
    float dsum = 0.0f;
    if (mode == 0) {
        a = *reinterpret_cast<const float4*>(x + (long long)orig * 128 + lane * 4);
        dsum = 1.0f;
    }
    for (int q = b; q < e; ++q) {
        int s = col[q];
        float fw = 1.0f;
        int fr;
        if (mode == 2) {
            fr = s - rowbase;
            if (nal[fr] == 0.0f) continue;
            dsum += 1.0f;
            fw = fvec[fr];
            if (fw == 0.0f) continue;
        } else {
            fr = xModN ? (s % NN) : (s - rowbase);
            dsum += 1.0f;
        }
        float4 v = *reinterpret_cast<const float4*>(x + (long long)fr * 128 + lane * 4);
        a.x += v.x * fw; a.y += v.y * fw; a.z += v.z * fw; a.w += v.w * fw;
    }
    float invds = 1.0f / fmaxf(dsum, 1.0f);
    a.x *= invds; a.y *= invds; a.z *= invds; a.w *= invds;
    *reinterpret_cast<float4*>(AGG + (long long)r * 128 + lane * 4) = a;
}

// ---------------- dense SAGE GEMM, v2 tile: BM=64, 8x4 acc, low VGPR ----------------
// V 0 (stage-1): y=tanh(AGG@Wl + bl + x[crow]@Wr), K=256
// V 2 (s2 L1/2): y=tanh(AGG@Wl + bl + fvec[orig]*x[orig]@Wr), orig=aliveIdx[crow], K=256
// NOTE: y may alias xsrc (each row read only by its own block, reads precede writes).
__global__ __launch_bounds__(256) void k_sage_d(
    const float* __restrict__ AGG, const float* __restrict__ xsrc,
    const int* __restrict__ aliveIdx, const float* __restrict__ fvec,
    int V,
    const float* __restrict__ Wl, const float* __restrict__ Wr, const float* __restrict__ bl,
    float* __restrict__ y, int nrowsC,
    const float* __restrict__ wrel, const float* __restrict__ wroot, const float* __restrict__ gw,
    float* __restrict__ tbuf, float* __restrict__ rootd, float* __restrict__ gdot)
{
    __shared__ float Ws[32 * 128];
    __shared__ float Is[32][68];
    __shared__ float wrelS[128], wrootS[128], gwS[128];
    __shared__ int rowIdxS[64];
    int tid = threadIdx.x;
    long long row0 = (long long)blockIdx.x * 64;
    if (tid < 128) {
        if (wrel)  wrelS[tid]  = wrel[tid];
        if (wroot) wrootS[tid] = wroot[tid];
        if (gw)    gwS[tid]    = gw[tid];
    }
    if (tid < 64) {
        long long lr = row0 + tid;
        if (lr >= nrowsC) lr = nrowsC - 1;
        rowIdxS[tid] = aliveIdx ? aliveIdx[lr] : (int)lr;
    }
    __syncthreads();
    int tx = tid & 31, ty = tid >> 5;
    float wr4[4] = {0,0,0,0}, wo4[4] = {0,0,0,0}, gg4[4] = {0,0,0,0};
    if (wrel)  { wr4[0]=wrelS[tx*4]; wr4[1]=wrelS[tx*4+1]; wr4[2]=wrelS[tx*4+2]; wr4[3]=wrelS[tx*4+3]; }
    if (wroot) { wo4[0]=wrootS[tx*4]; wo4[1]=wrootS[tx*4+1]; wo4[2]=wrootS[tx*4+2]; wo4[3]=wrootS[tx*4+3]; }
    if (gw)    { gg4[0]=gwS[tx*4]; gg4[1]=gwS[tx*4+1]; gg4[2]=gwS[tx*4+2]; gg4[3]=gwS[tx*4+3]; }
    int srow = tid & 63;
    int koff = (tid >> 6) * 8;
    long long crow = row0 + srow;
    if (crow >= nrowsC) crow = nrowsC - 1;
    int orig = rowIdxS[srow];
    float fself = (V == 2) ? fvec[orig] : 1.0f;
    const float* selfp = xsrc + (long long)orig * 128;
    const float* aggp = AGG + crow * 128;

    float acc[8][4] = {};
    for (int kb = 0; kb < 8; ++kb) {
        __syncthreads();
        bool isAgg = (kb < 4);
        const float* Wsrc = isAgg ? (Wl + kb * 32 * 128) : (Wr + (kb - 4) * 32 * 128);
        #pragma unroll
        for (int j = 0; j < 4; ++j) {
            int fl = j * 1024 + tid * 4;
            *reinterpret_cast<float4*>(&Ws[fl]) = *reinterpret_cast<const float4*>(&Wsrc[fl]);
        }
        {
            const float* sp = (isAgg ? (aggp + kb * 32) : (selfp + (kb - 4) * 32)) + koff;
            float m = isAgg ? 1.0f : fself;
            float4 v0 = *reinterpret_cast<const float4*>(sp);
            float4 v1 = *reinterpret_cast<const float4*>(sp + 4);
            Is[koff + 0][srow] = v0.x * m; Is[koff + 1][srow] = v0.y * m;
            Is[koff + 2][srow] = v0.z * m; Is[koff + 3][srow] = v0.w * m;
            Is[koff + 4][srow] = v1.x * m; Is[koff + 5][srow] = v1.y * m;
            Is[koff + 6][srow] = v1.z * m; Is[koff + 7][srow] = v1.w * m;
        }
        __syncthreads();
        #pragma unroll
        for (int kk = 0; kk < 32; ++kk) {
            float4 wv = *reinterpret_cast<const float4*>(&Ws[kk * 128 + tx * 4]);
            float4 i0 = *reinterpret_cast<const float4*>(&Is[kk][ty * 8]);
            float4 i1 = *reinterpret_cast<const float4*>(&Is[kk][ty * 8 + 4]);
            float ia[8] = {i0.x, i0.y, i0.z, i0.w, i1.x, i1.y, i1.z, i1.w};
            float wa[4] = {wv.x, wv.y, wv.z, wv.w};
            #pragma unroll
            for (int i = 0; i < 8; ++i)
                #pragma unroll
                for (int j = 0; j < 4; ++j)
                    acc[i][j] += ia[i] * wa[j];
        }
    }
    float4 bl0 = *reinterpret_cast<const float4*>(&bl[tx * 4]);
    float br[4] = {bl0.x, bl0.y, bl0.z, bl0.w};
    #pragma unroll
    for (int i = 0; i < 8; ++i) {
        long long cr = row0 + ty * 8 + i;
        bool valid = (cr < nrowsC);
        int rout = rowIdxS[ty * 8 + i];
        float yv[4];
        #pragma unroll
        for (int j = 0; j < 4; ++j) yv[j] = tanhf(acc[i][j] + br[j]);
        if (valid)
            *reinterpret_cast<float4*>(&y[(long long)rout * 128 + tx * 4]) = make_float4(yv[0], yv[1], yv[2], yv[3]);
        float tp = 0.0f, rp = 0.0f, gp = 0.0f;
        #pragma unroll
        for (int j = 0; j < 4; ++j) {
            if (tbuf)  tp += yv[j] * wr4[j];
            if (rootd) rp += yv[j] * wo4[j];
            if (gdot)  gp += yv[j] * gg4[j];
        }
        #pragma unroll
        for (int m = 16; m >= 1; m >>= 1) {
            if (tbuf)  tp += __shfl_xor(tp, m, 32);
            if (rootd) rp += __shfl_xor(rp, m, 32);
            if (gdot)  gp += __shfl_xor(gp, m, 32);
        }
        if (tx == 0 && valid) {
            if (tbuf)  tbuf[rout]  = tp;
            if (rootd) rootd[rout] = rp;
            if (gdot)  gdot[rout]  = gp;
        }
    }
}

// ---------------- plain GEMM: y = x@W (+ b), v2 tile ----------------
__global__ __launch_bounds__(256) void k_gemm_self(
    const float* __restrict__ x, const float* __restrict__ W, const float* __restrict__ b,
    float* __restrict__ y, int nrows)
{
    __shared__ float Ws[32 * 128];
    __shared__ float Is[32][68];
    int tid = threadIdx.x;
    long long row0 = (long long)blockIdx.x * 64;
    int tx = tid & 31, ty = tid >> 5;
    int srow = tid & 63;
    int koff = (tid >> 6) * 8;
    long long lrow = row0 + srow;
    if (lrow >= nrows) lrow = nrows - 1;
    const float* xrow = x + lrow * 128;
    float acc[8][4] = {};
    for (int kb = 0; kb < 4; ++kb) {
        __syncthreads();
        const float* Wsrc = W + kb * 32 * 128;
        #pragma unroll
        for (int j = 0; j < 4; ++j) {
            int fl = j * 1024 + tid * 4;
            *reinterpret_cast<float4*>(&Ws[fl]) = *reinterpret_cast<const float4*>(&Wsrc[fl]);
        }
        {
            const float* sp = xrow + kb * 32 + koff;
            float4 v0 = *reinterpret_cast<const float4*>(sp);
            float4 v1 = *reinterpret_cast<const float4*>(sp + 4);
            Is[koff + 0][srow] = v0.x; Is[koff + 1][srow] = v0.y;
            Is[koff + 2][srow] = v0.z; Is[koff + 3][srow] = v0.w;
            Is[koff + 4][srow] = v1.x; Is[koff + 5][srow] = v1.y;
            Is[koff + 6][srow] = v1.z; Is[koff + 7][srow] = v1.w;
        }
        __syncthreads();
        #pragma unroll
        for (int kk = 0; kk < 32; ++kk) {
            float4 wv = *reinterpret_cast<const float4*>(&Ws[kk * 128 + tx * 4]);
            float4 i0 = *reinterpret_cast<const float4*>(&Is[kk][ty * 8]);
            float4 i1 = *reinterpret_cast<const float4*>(&Is[kk][ty * 8 + 4]);
            float ia[8] = {i0.x, i0.y, i0.z, i0.w, i1.x, i1.y, i1.z, i1.w};
            float wa[4] = {wv.x, wv.y, wv.z, wv.w};
            #pragma unroll
            for (int i = 0; i < 8; ++i)
                #pragma unroll
                for (int j = 0; j < 4; ++j)
                    acc[i][j] += ia[i] * wa[j];
        }
    }
    float4 b0 = b ? *reinterpret_cast<const float4*>(&b[tx * 4]) : make_float4(0.f, 0.f, 0.f, 0.f);
    #pragma unroll
    for (int i = 0; i < 8; ++i) {
        long long row = row0 + ty * 8 + i;
        if (row >= nrows) continue;
        *reinterpret_cast<float4*>(&y[row * 128 + tx * 4]) =
            make_float4(acc[i][0] + b0.x, acc[i][1] + b0.y, acc[i][2] + b0.z, acc[i][3] + b0.w);
    }
}

// ---------------- stage-2 L0 combine (linear-map trick, no GEMM) ----------------
__global__ __launch_bounds__(256) void k_l0comb(
    const float* __restrict__ ZL0, const float* __restrict__ zself,
    const int* __restrict__ rowptr, const int* __restrict__ col, int rowbase,
    const float* __restrict__ wrel, const float* __restrict__ wroot, const float* __restrict__ gw,
    float* __restrict__ y, float* __restrict__ tbuf, float* __restrict__ rootd, float* __restrict__ gdot,
    int nrowsC)
{
    __shared__ float wrelS[128], wrootS[128], gwS[128];
    int tid = threadIdx.x;
    if (tid < 128) {
        wrelS[tid]  = wrel[tid];
        wrootS[tid] = wroot[tid];
        gwS[tid]    = gw[tid];
    }
    __syncthreads();
    int r = blockIdx.x * 8 + (tid >> 5);
    if (r >= nrowsC) return;
    int lane = tid & 31;
    int grow = rowbase + r;
    int b = rowptr[grow], e = rowptr[grow + 1];
    float4 a = make_float4(0.0f, 0.0f, 0.0f, 0.0f);
    for (int q = b; q < e; ++q) {
        int fr = col[q] % NN;
        float4 v = *reinterpret_cast<const float4*>(ZL0 + (long long)fr * 128 + lane * 4);
        a.x += v.x; a.y += v.y; a.z += v.z; a.w += v.w;
    }
    float invds = 1.0f / fmaxf((float)(e - b), 1.0f);
    const float4 z = *reinterpret_cast<const float4*>(zself + (long long)(r % NN) * 128 + lane * 4);
    float yv[4];
    yv[0] = tanhf(a.x * invds + z.x);
    yv[1] = tanhf(a.y * invds + z.y);
    yv[2] = tanhf(a.z * invds + z.z);
    yv[3] = tanhf(a.w * invds + z.w);
    *reinterpret_cast<float4*>(y + (long long)r * 128 + lane * 4) = make_float4(yv[0], yv[1], yv[2], yv[3]);
    float tp = 0.0f, rp = 0.0f, gp = 0.0f;
    #pragma unroll
    for (int j = 0; j < 4; ++j) {
        tp += yv[j] * wrelS[lane*4 + j];
        rp += yv[j] * wrootS[lane*4 + j];
        gp += yv[j] * gwS[lane*4 + j];
    }
    #pragma unroll
    for (int m = 16; m >= 1; m >>= 1) {
        tp += __shfl_xor(tp, m, 32);
        rp += __shfl_xor(rp, m, 32);
        gp += __shfl_xor(gp, m, 32);
    }
    if (lane == 0) {
        tbuf[r]  = tp;
        rootd[r] = rp;
        gdot[r]  = gp;
    }
}

// ---------------- stage-1 readout pieces ----------------
__global__ __launch_bounds__(256) void k_gate(
    const float* __restrict__ X, const float* __restrict__ gw,
    float* __restrict__ g, int nrows)
{
    __shared__ float wS[128];
    if (threadIdx.x < 128) wS[threadIdx.x] = gw[threadIdx.x];
    __syncthreads();
    int i = blockIdx.x * 256 + threadIdx.x;
    if (i >= nrows) return;
    const float4* xrp = reinterpret_cast<const float4*>(X + (long long)i * 128);
    float s = 0.0f;
    #pragma unroll
    for (int k = 0; k < 32; ++k) {
        float4 v = xrp[k];
        s += v.x * wS[4*k] + v.y * wS[4*k+1] + v.z * wS[4*k+2] + v.w * wS[4*k+3];
    }
    g[i] = s;
}

__global__ __launch_bounds__(1024) void k_smstats(float* __restrict__ g, float* __restrict__ invp) {
    __shared__ float red[1024];
    int p = blockIdx.x, tid = threadIdx.x;
    float* gp = g + (long long)p * NN;
    float lmax = -INFINITY;
    for (int n = tid; n < NN; n += 1024) lmax = fmaxf(lmax, gp[n]);
    red[tid] = lmax; __syncthreads();
    for (int s = 512; s > 0; s >>= 1) { if (tid < s) red[tid] = fmaxf(red[tid], red[tid + s]); __syncthreads(); }
    float mx = red[0]; __syncthreads();
    float ls = 0.0f;
    for (int n = tid; n < NN; n += 1024) { float e = expf(gp[n] - mx); gp[n] = e; ls += e; }
    red[tid] = ls; __syncthreads();
    for (int s = 512; s > 0; s >>= 1) { if (tid < s) red[tid] += red[tid + s]; __syncthreads(); }
    if (tid == 0) invp[p] = 1.0f / red[0];
}

__global__ __launch_bounds__(128) void k_wsum(
    const float* __restrict__ X, const float* __restrict__ a,
    const float* __restrict__ invp, float* __restrict__ ro, int rowbase, int colOff)
{
    int p = blockIdx.x / BPG;
    int chunk = blockIdx.x % BPG;
    int d = threadIdx.x;
    long long base = (long long)p * NN;
    int r0 = chunk * RB, r1 = r0 + RB;
    float s = 0.0f;
    for (int n = r0; n < r1; ++n) {
        float w = a[base + n];
        if (w != 0.0f) s += w * X[(base + n) * 128 + d];
    }
    atomicAdd(&ro[(long long)(rowbase + p) * 384 + colOff + d], s * invp[p]);
}

// stage-2 weighted sum over alive rows only
__global__ __launch_bounds__(128) void k_wsum_c(
    const float* __restrict__ X, const float* __restrict__ gbuf, const float* __restrict__ fvec,
    const float* __restrict__ invp, const int* __restrict__ aliveIdx, int k,
    float* __restrict__ ro, int rowbaseRo, int colOff)
{
    int bpp = k / RB;
    int p = blockIdx.x / bpp;
    int chunk = blockIdx.x % bpp;
    int d = threadIdx.x;
    const int* ai = aliveIdx + (long long)p * k + chunk * RB;
    float s = 0.0f;
    for (int j = 0; j < RB; ++j) {
        int row = ai[j];
        float w = gbuf[row] * fvec[row];
        s += w * X[(long long)row * 128 + d];
    }
    atomicAdd(&ro[(long long)(rowbaseRo + p) * 384 + colOff + d], s * invp[p]);
}

// ---------------- GraphNorm ----------------
__global__ void k_colstat(const float* __restrict__ x, float* __restrict__ musum,
                          float* __restrict__ sqsum, int nrows) {
    int d = threadIdx.x;
    int r0 = blockIdx.x * 64;
    int r1 = min(r0 + 64, nrows);
    float s = 0.0f, q = 0.0f;
    for (int r = r0; r < r1; ++r) { float v = x[(long long)r * 128 + d]; s += v; q += v * v; }
    atomicAdd(&musum[d], s);
    atomicAdd(&sqsum[d], q);
}

__global__ void k_gnorm_apply(const float* __restrict__ x, float* __restrict__ y,
                              const float* __restrict__ musum, const float* __restrict__ sqsum,
                              const float* __restrict__ w, const float* __restrict__ b,
                              const float* __restrict__ ms, int nrows) {
    long long i = (long long)blockIdx.x * 256 + threadIdx.x;
    if (i >= (long long)nrows * 128) return;
    int d = (int)(i & 127);
    float inv_n = 1.0f / (float)nrows;
    float mu = musum[d] * inv_n;
    float c = mu * ms[d];
    float var = sqsum[d] * inv_n - 2.0f * c * mu + c * c;
    y[i] = w[d] * (x[i] - c) * rsqrtf(var + 1e-5f) + b[d];
}

// ---------------- mega top-k (1024 threads, parallel bucket select) ----------------
#define TCH 8   // NN/1024
__global__ __launch_bounds__(1024) void k_topk2(
    const int* __restrict__ rowptr, const int* __restrict__ col, int rowbase,
    const float* __restrict__ tb, const float* __restrict__ rootd,
    const float* __restrict__ gdot, const float* __restrict__ brelp, int bi, int allAlive,
    float* __restrict__ nalive, float* __restrict__ fvec, float* __restrict__ gbuf,
    float* __restrict__ invp, int* __restrict__ aliveIdx, int k)
{
    __shared__ unsigned keys[NN];
    __shared__ int hist[256];
    __shared__ int scan[1024];
    __shared__ float redf[1024];
    __shared__ unsigned sh_pref;
    __shared__ int sh_kneed;
    int p = blockIdx.x, tid = threadIdx.x;
    float brel = brelp[bi];
    long long pbase = (long long)p * NN;
    for (int n = tid; n < NN; n += 1024) {
        long long gl = pbase + n;
        int grow = rowbase + (int)gl;
        float s = brel + rootd[gl];
        int b = rowptr[grow], e = rowptr[grow + 1];
        for (int q = b; q < e; ++q) {
            int sl = col[q] - rowbase;
            s += allAlive ? tb[sl] : (tb[sl] * nalive[sl]);
        }
        bool alive = allAlive || (nalive[gl] > 0.5f);
        keys[n] = alive ? fkey(s) : 0u;
    }
    if (tid == 0) { sh_pref = 0u; sh_kneed = k; }
    __syncthreads();
    for (int lvl = 3; lvl >= 0; --lvl) {
        int sh = lvl * 8;
        if (tid < 256) hist[tid] = 0;
        unsigned pref = sh_pref; int kneed = sh_kneed;
        unsigned pmask = (lvl == 3) ? 0u : (0xFFFFFFFFu << (8 * (lvl + 1)));
        __syncthreads();
        for (int n = tid; n < NN; n += 1024) {
            unsigned kv = keys[n];
            if ((kv & pmask) == pref) atomicAdd(&hist[(kv >> sh) & 255], 1);
        }
        __syncthreads();
        // parallel suffix-sum of hist over 256 bins
        if (tid < 256) scan[tid] = hist[tid];
        __syncthreads();
        for (int off = 1; off < 256; off <<= 1) {
            int v = 0;
            if (tid < 256 && tid + off < 256) v = scan[tid + off];
            __syncthreads();
            if (tid < 256) scan[tid] += v;
            __syncthreads();
        }
        if (tid < 256) {
            int c = scan[tid];
            int cex = c - hist[tid];   // suffix sum of bins > tid
            if (c >= kneed && cex < kneed) {
                sh_pref = pref | ((unsigned)tid << sh);
                sh_kneed = kneed - cex;
            }
        }
        __syncthreads();
    }
    unsigned V = sh_pref;
    int seleq = sh_kneed;
    int c0 = tid * TCH, c1 = min(c0 + TCH, NN);
    int ceq = 0;
    for (int n = c0; n < c1; ++n) ceq += (keys[n] == V) ? 1 : 0;
    scan[tid] = ceq; __syncthreads();
    for (int off = 1; off < 1024; off <<= 1) {
        int u = (tid >= off) ? scan[tid - off] : 0;
        __syncthreads();
        scan[tid] += u;
        __syncthreads();
    }
    int rank = scan[tid] - ceq;
    unsigned selmask = 0u;
    int nsel = 0;
    float lmax = -INFINITY;
    for (int n = c0; n < c1; ++n) {
        unsigned kk = keys[n];
        bool sel = (kk > V) || (kk == V && rank < seleq);
        if (kk == V) rank++;
        long long gl = pbase + n;
        nalive[gl] = sel ? 1.0f : 0.0f;
        float f = 0.0f;
        if (sel) {
            f = tanhf(fkey_inv(kk));
            lmax = fmaxf(lmax, f * gdot[gl]);
            selmask |= (1u << (n - c0));
            ++nsel;
        }
        fvec[gl] = f;
    }
    redf[tid] = lmax; __syncthreads();
    for (int s = 512; s > 0; s >>= 1) { if (tid < s) redf[tid] = fmaxf(redf[tid], redf[tid + s]); __syncthreads(); }
    float mx = redf[0]; __syncthreads();
    scan[tid] = nsel; __syncthreads();
    for (int off = 1; off < 1024; off <<= 1) {
        int u = (tid >= off) ? scan[tid - off] : 0;
        __syncthreads();
        scan[tid] += u;
        __syncthreads();
    }
    int pos = scan[tid] - nsel;
    float lsum = 0.0f;
    for (int n = c0; n < c1; ++n) {
        if (selmask & (1u << (n - c0))) {
            long long gl = pbase + n;
            float e = expf(fvec[gl] * gdot[gl] - mx);
            gbuf[gl] = e;
            lsum += e;
            aliveIdx[(long long)p * k + pos] = (int)gl;
            ++pos;
        }
    }
    redf[tid] = lsum; __syncthreads();
    for (int s = 512; s > 0; s >>= 1) { if (tid < s) redf[tid] += redf[tid + s]; __syncthreads(); }
    if (tid == 0) invp[p] = 1.0f / redf[0];
}

// ---------------- head ----------------
__global__ __launch_bounds__(64) void k_head(
    const float* __restrict__ ro, const float* __restrict__ lin_w, const float* __restrict__ lin_b,
    const float* __restrict__ m1w, const float* __restrict__ m1b,
    const float* __restrict__ m2w, const float* __restrict__ m2b,
    const float* __restrict__ m3w, const float* __restrict__ m3b, float* __restrict__ out)
{
    __shared__ float v[33], h1[48], h2[16];
    int t = threadIdx.x;
    if (t < 33) {
        float s = lin_b[0];
        for (int k = 0; k < 384; ++k) s += ro[t * 384 + k] * lin_w[k];
        v[t] = tanhf(s);
    }
    __syncthreads();
    if (t < 48) {
        float s = m1b[t];
        for (int i = 0; i < 33; ++i) s += v[i] * m1w[i * 48 + t];
        h1[t] = tanhf(s);
    }
    __syncthreads();
    if (t < 16) {
        float s = m2b[t];
        for (int i = 0; i < 48; ++i) s += h1[i] * m2w[i * 16 + t];
        h2[t] = tanhf(s);
    }
    __syncthreads();
    if (t == 0) {
        float s = m3b[0];
        for (int i = 0; i < 16; ++i) s += h2[i] * m3w[i];
        float s1 = 1.0f / (1.0f + expf(-s));
        out[0] = 1.0f / (1.0f + expf(-s1));
    }
}

static inline int cdiv(long long a, long long b) { return (int)((a + b - 1) / b); }

extern "C" void kernel_launch(void* const* d_in, const int* in_sizes, int n_in,
                              void* d_out, int out_size, void* d_ws, size_t ws_size,
                              hipStream_t stream)
{
    (void)in_sizes; (void)n_in; (void)out_size;
    const float* h     = (const float*)d_in[0];
    const int*   eidx  = (const int*)d_in[1];
    const int*   seidx = (const int*)d_in[2];
    const float* Wl_a  = (const float*)d_in[3];
    const float* Wr_a  = (const float*)d_in[4];
    const float* bl_a  = (const float*)d_in[5];
    const float* Wl_s  = (const float*)d_in[6];
    const float* Wr_s  = (const float*)d_in[7];
    const float* bl_s  = (const float*)d_in[8];
    const float* gate_w = (const float*)d_in[9];
    const float* p_wrel = (const float*)d_in[11];
    const float* p_brel = (const float*)d_in[12];
    const float* p_wroot= (const float*)d_in[13];
    const float* nw    = (const float*)d_in[14];
    const float* nb    = (const float*)d_in[15];
    const float* nms   = (const float*)d_in[16];
    const float* lin_w = (const float*)d_in[17];
    const float* lin_b = (const float*)d_in[18];
    const float* m1w   = (const float*)d_in[19];
    const float* m1b   = (const float*)d_in[20];
    const float* m2w   = (const float*)d_in[21];
    const float* m2b   = (const float*)d_in[22];
    const float* m3w   = (const float*)d_in[23];
    const float* m3b   = (const float*)d_in[24];
    float* out = (float*)d_out;

    const int* esrc = eidx;
    const int* edst = eidx + EG;
    const int* ssrc = seidx;
    const int* sdst = seidx + ES_TOT;

    // persistent workspace need (stage-1 + CSR temps overlaid inside XA)
    auto need_bytes = [](int chp) -> size_t {
        long long chn = (long long)chp * NN;
        long long f = chn * 128                      // XA
                    + (long long)chp * KK1 * 128     // AGG (alive-K1 rows max)
                    + 2LL * NN * 128                 // ZL0, zself
                    + 5 * chn                        // tbuf(=gbuf), rootd, nal, fvec, gdot
                    + 64 + 33 * 384                  // invp, ro
                    + (long long)chp * KK1           // aliveIdx
                    + (PN + 1) + ES_TOT              // s2rp, s2col
                    + 64 * 24;                       // align slack
        return (size_t)f * 4;
    };
    int chp = 8;
    if (ws_size >= need_bytes(32)) chp = 32;
    else if (ws_size >= need_bytes(16)) chp = 16;
    int nch = PP / chp;
    long long ch_n = (long long)chp * NN;

    float* W = (float*)d_ws;
    size_t off = 0;
    auto alloc = [&](size_t nf) { float* p = W + off; off += (nf + 63) & ~(size_t)63; return p; };
    float* XA    = alloc((size_t)ch_n * DD);
    float* AGG   = alloc((size_t)chp * KK1 * DD);
    float* ZL0   = alloc((size_t)NN * DD);
    float* zself = alloc((size_t)NN * DD);
    float* tbuf  = alloc(ch_n);                 // aliased as gbuf
    float* rootd = alloc(ch_n);
    float* nal   = alloc(ch_n);
    float* fvec  = alloc(ch_n);
    float* gdot  = alloc(ch_n);
    float* invp  = alloc(64);
    float* ro    = alloc(33 * 384);
    int* aliveIdx = (int*)alloc((size_t)chp * KK1);
    int* s2rp    = (int*)alloc(PN + 1);
    int* s2col   = (int*)alloc(ES_TOT);
    float* gbuf = tbuf;

    // overlay: stage-1-only + CSR build temps live inside XA (dead before XA's first write)
    size_t ooff = 0;
    auto oalloc = [&](size_t nf) { float* p = XA + ooff; ooff += (nf + 63) & ~(size_t)63; return p; };
    float* xa    = oalloc((size_t)NN * DD);
    float* xb    = oalloc((size_t)NN * DD);
    float* agg1  = oalloc((size_t)NN * 16);
    float* deg1  = oalloc(NN);
    float* musum = oalloc(128);
    float* sqsum = oalloc(128);
    int* s1cnt  = (int*)oalloc(NN);
    int* s1rp   = (int*)oalloc(NN + 1);
    int* s1cur  = (int*)oalloc(NN);
    int* s1col  = (int*)oalloc(EG);
    int* s1part = (int*)oalloc(NN);
    int* s1bsum = (int*)oalloc(1024);
    int* s2cnt  = (int*)oalloc(PN);
    int* s2cur  = (int*)oalloc(PN);
    int* s2part = (int*)oalloc(PN);
    int* s2bsum = (int*)oalloc(1024);

    // ---------- CSR builds ----------
    int nb1 = cdiv(NN, 1024), nb2 = cdiv(PN, 1024);
    hipMemsetAsync(s1cnt, 0, NN * sizeof(int), stream);
    k_hist<<<cdiv(EG,256),256,0,stream>>>(edst, s1cnt, EG);
    k_scanA<<<nb1,1024,0,stream>>>(s1cnt, s1part, s1bsum, NN);
    k_scanB<<<1,1024,0,stream>>>(s1bsum, nb1);
    k_scanC<<<cdiv(NN,256),256,0,stream>>>(s1part, s1bsum, s1rp, s1cur, NN, EG);
    k_scatter<<<cdiv(EG,256),256,0,stream>>>(esrc, edst, s1cur, s1col, EG);

    hipMemsetAsync(s2cnt, 0, (size_t)PN * sizeof(int), stream);
    k_hist<<<cdiv(ES_TOT,256),256,0,stream>>>(sdst, s2cnt, ES_TOT);
    k_scanA<<<nb2,1024,0,stream>>>(s2cnt, s2part, s2bsum, PN);
    k_scanB<<<1,1024,0,stream>>>(s2bsum, nb2);
    k_scanC<<<cdiv(PN,256),256,0,stream>>>(s2part, s2bsum, s2rp, s2cur, PN, ES_TOT);
    k_scatter<<<cdiv(ES_TOT,256),256,0,stream>>>(ssrc, sdst, s2cur, s2col, ES_TOT);

    hipMemsetAsync(ro, 0, 33 * 384 * sizeof(float), stream);

    // ---------- stage 1 ----------
    k_agg16<<<cdiv((long long)NN*16,256),256,0,stream>>>(h, s1rp, s1col, agg1, deg1, NN);
    k_sage16<<<cdiv((long long)NN*DD,256),256,0,stream>>>(h, agg1, deg1, Wl_a, Wr_a, bl_a, xa, NN);
    k_gate<<<cdiv(NN,256),256,0,stream>>>(xa, gate_w + 0*DD, gbuf, NN);
    k_smstats<<<1,1024,0,stream>>>(gbuf, invp);
    k_wsum<<<BPG,128,0,stream>>>(xa, gbuf, invp, ro, 0, 0);

    hipMemsetAsync(musum, 0, 128*sizeof(float), stream);
    hipMemsetAsync(sqsum, 0, 128*sizeof(float), stream);
    k_colstat<<<cdiv(NN,64),128,0,stream>>>(xa, musum, sqsum, NN);
    k_gnorm_apply<<<cdiv((long long)NN*DD,256),256,0,stream>>>(xa, xb, musum, sqsum, nw, nb, nms, NN);

    k_aggf<<<cdiv(NN,8),256,0,stream>>>(xb, s1rp, s1col, nullptr, nullptr, nullptr, 0, 0, 0, AGG, NN);
    k_sage_d<<<cdiv(NN,64),256,0,stream>>>(AGG, xb, nullptr, nullptr, 0,
        Wl_s + 0*16384, Wr_s + 0*16384, bl_s + 0*128, xa, NN,
        nullptr, nullptr, gate_w + 1*DD, nullptr, nullptr, gbuf);
    k_smstats<<<1,1024,0,stream>>>(gbuf, invp);
    k_wsum<<<BPG,128,0,stream>>>(xa, gbuf, invp, ro, 0, 128);

    hipMemsetAsync(musum, 0, 128*sizeof(float), stream);
    hipMemsetAsync(sqsum, 0, 128*sizeof(float), stream);
    k_colstat<<<cdiv(NN,64),128,0,stream>>>(xa, musum, sqsum, NN);
    k_gnorm_apply<<<cdiv((long long)NN*DD,256),256,0,stream>>>(xa, xb, musum, sqsum, nw, nb, nms, NN);

    k_aggf<<<cdiv(NN,8),256,0,stream>>>(xb, s1rp, s1col, nullptr, nullptr, nullptr, 0, 0, 0, AGG, NN);
    k_sage_d<<<cdiv(NN,64),256,0,stream>>>(AGG, xb, nullptr, nullptr, 0,
        Wl_s + 1*16384, Wr_s + 1*16384, bl_s + 1*128, xa, NN,
        nullptr, nullptr, gate_w + 2*DD, nullptr, nullptr, gbuf);
    k_smstats<<<1,1024,0,stream>>>(gbuf, invp);
    k_wsum<<<BPG,128,0,stream>>>(xa, gbuf, invp, ro, 0, 256);

    // ---------- stage 2 ----------
    // L0 linear-map trick (reads xa, writes ZL0/zself — before XA overlay is clobbered)
    k_gemm_self<<<cdiv(NN,64),256,0,stream>>>(xa, Wl_s + 2*16384, nullptr, ZL0, NN);
    k_gemm_self<<<cdiv(NN,64),256,0,stream>>>(xa, Wr_s + 2*16384, bl_s + 2*128, zself, NN);

    for (int c = 0; c < nch; ++c) {
        int nbase = (int)(c * ch_n);

        // ---- layer 0: gather-mean of ZL0 + zself (no GEMM; all rows alive) ----
        k_l0comb<<<(int)(ch_n/8),256,0,stream>>>(ZL0, zself, s2rp, s2col, nbase,
            p_wrel + 0*DD, p_wroot + 0*DD, gate_w + 3*DD,
            XA, tbuf, rootd, gdot, (int)ch_n);
        k_topk2<<<chp,1024,0,stream>>>(s2rp, s2col, nbase, tbuf, rootd, gdot, p_brel, 0, 1,
                                       nal, fvec, gbuf, invp, aliveIdx, KK1);
        k_wsum_c<<<chp*(KK1/RB),128,0,stream>>>(XA, gbuf, fvec, invp, aliveIdx, KK1, ro, 1 + c*chp, 0);

        // ---- layer 1: alive K1 rows (in-place on XA) ----
        k_aggf<<<chp*(KK1/8),256,0,stream>>>(XA, s2rp, s2col, aliveIdx, nal, fvec, 2, 0, nbase, AGG, chp*KK1);
        k_sage_d<<<chp*(KK1/64),256,0,stream>>>(AGG, XA, aliveIdx, fvec, 2,
            Wl_s + 3*16384, Wr_s + 3*16384, bl_s + 3*128, XA, chp*KK1,
            p_wrel + 1*DD, p_wroot + 1*DD, gate_w + 4*DD, tbuf, rootd, gdot);
        k_topk2<<<chp,1024,0,stream>>>(s2rp, s2col, nbase, tbuf, rootd, gdot, p_brel, 1, 0,
                                       nal, fvec, gbuf, invp, aliveIdx, KK2);
        k_wsum_c<<<chp*(KK2/RB),128,0,stream>>>(XA, gbuf, fvec, invp, aliveIdx, KK2, ro, 1 + c*chp, 128);

        // ---- layer 2: alive K2 rows (in-place on XA) ----
        k_aggf<<<chp*(KK2/8),256,0,stream>>>(XA, s2rp, s2col, aliveIdx, nal, fvec, 2, 0, nbase, AGG, chp*KK2);
        k_sage_d<<<chp*(KK2/64),256,0,stream>>>(AGG, XA, aliveIdx, fvec, 2,
            Wl_s + 4*16384, Wr_s + 4*16384, bl_s + 4*128, XA, chp*KK2,
            p_wrel + 2*DD, p_wroot + 2*DD, gate_w + 5*DD, tbuf, rootd, gdot);
        k_topk2<<<chp,1024,0,stream>>>(s2rp, s2col, nbase, tbuf, rootd, gdot, p_brel, 2, 0,
                                       nal, fvec, gbuf, invp, aliveIdx, KK3);
        k_wsum_c<<<chp*(KK3/RB),128,0,stream>>>(XA, gbuf, fvec, invp, aliveIdx, KK3, ro, 1 + c*chp, 256);
    }

    // ---------- head ----------
    k_head<<<1,64,0,stream>>>(ro, lin_w, lin_b, m1w, m1b, m2w, m2b, m3w, m3b, out);
}

// Round 15
// 796.635 us; speedup vs baseline: 3.2986x; 1.2288x over previous
//
#include <hip/hip_runtime.h>
#include <math.h>

#define NN      8000
#define PP      32
#define EG      128000
#define ES_TOT  131072     // P * 4096
#define ES_P    4096
#define PN      256000     // P * NN
#define DI      16
#define DD      128
#define KK1     6400
#define KK2     5120
#define KK3     4096
#define RB      64                   // rows per wsum block
#define BPG     (NN / RB)            // 125 blocks per graph (stage-1 wsum)

typedef __attribute__((ext_vector_type(8))) short short8;
typedef __attribute__((ext_vector_type(4))) float f32x4;

static __device__ __forceinline__ unsigned fkey(float f) {
    unsigned u = __float_as_uint(f);
    return (u & 0x80000000u) ? ~u : (u | 0x80000000u);
}
static __device__ __forceinline__ float fkey_inv(unsigned k) {
    unsigned u = (k & 0x80000000u) ? (k & 0x7FFFFFFFu) : ~k;
    return __uint_as_float(u);
}
static __device__ __forceinline__ unsigned short f2bf(float f) {
    unsigned u = __float_as_uint(f);
    u += 0x7FFFu + ((u >> 16) & 1u);   // RNE to bf16
    return (unsigned short)(u >> 16);
}

// ---------------- CSR build ----------------
__global__ void k_hist(const int* __restrict__ dst, int* __restrict__ cnt, int ne) {
    int e = blockIdx.x * 256 + threadIdx.x;
    if (e < ne) atomicAdd(&cnt[dst[e]], 1);
}

__global__ __launch_bounds__(1024) void k_scanA(const int* __restrict__ cnt,
                                                int* __restrict__ part,
                                                int* __restrict__ bsum, int n) {
    __shared__ int sh[1024];
    int t = threadIdx.x;
    int i = blockIdx.x * 1024 + t;
    int v = (i < n) ? cnt[i] : 0;
    sh[t] = v; __syncthreads();
    for (int off = 1; off < 1024; off <<= 1) {
        int u = (t >= off) ? sh[t - off] : 0;
        __syncthreads();
        sh[t] += u;
        __syncthreads();
    }
    if (i < n) part[i] = sh[t] - v;
    if (t == 1023) bsum[blockIdx.x] = sh[1023];
}

__global__ __launch_bounds__(1024) void k_scanB(int* __restrict__ bsum, int nb) {
    __shared__ int sh[1024];
    int t = threadIdx.x;
    int v = (t < nb) ? bsum[t] : 0;
    sh[t] = v; __syncthreads();
    for (int off = 1; off < 1024; off <<= 1) {
        int u = (t >= off) ? sh[t - off] : 0;
        __syncthreads();
        sh[t] += u;
        __syncthreads();
    }
    if (t < nb) bsum[t] = sh[t] - v;   // exclusive
}

__global__ void k_scanC(const int* __restrict__ part, const int* __restrict__ bsum,
                        int* __restrict__ rowptr, int* __restrict__ cursor, int n, int total) {
    int i = blockIdx.x * 256 + threadIdx.x;
    if (i < n) {
        int v = part[i] + bsum[i >> 10];
        rowptr[i] = v;
        cursor[i] = v;
    }
    if (i == 0) rowptr[n] = total;
}

__global__ void k_scatter(const int* __restrict__ src, const int* __restrict__ dst,
                          int* __restrict__ cursor, int* __restrict__ col, int ne) {
    int e = blockIdx.x * 256 + threadIdx.x;
    if (e >= ne) return;
    int pos = atomicAdd(&cursor[dst[e]], 1);
    col[pos] = src[e];
}

// ---------------- stage-1 layer a ----------------
__global__ __launch_bounds__(256) void k_agg16(const float* __restrict__ h,
                                               const int* __restrict__ rowptr,
                                               const int* __restrict__ col,
                                               float* __restrict__ agg, float* __restrict__ deg,
                                               int nrows) {
    int i = blockIdx.x * 256 + threadIdx.x;
    int r = i >> 4, j = i & 15;
    if (r >= nrows) return;
    int b = rowptr[r], e = rowptr[r + 1];
    float a = h[r * 16 + j];
    for (int q = b; q < e; ++q) a += h[col[q] * 16 + j];
    agg[r * 16 + j] = a;
    if (j == 0) deg[r] = 1.0f + (float)(e - b);
}

__global__ __launch_bounds__(256) void k_sage16(
    const float* __restrict__ h, const float* __restrict__ agg, const float* __restrict__ deg,
    const float* __restrict__ Wl, const float* __restrict__ Wr, const float* __restrict__ bl,
    float* __restrict__ y, int nrows)
{
    __shared__ float WlS[16][128], WrS[16][128];
    int tid = threadIdx.x;
    for (int i = tid; i < 16 * 128; i += 256) {
        WlS[i >> 7][i & 127] = Wl[i];
        WrS[i >> 7][i & 127] = Wr[i];
    }
    __syncthreads();
    long long o = (long long)blockIdx.x * 256 + tid;
    int row = (int)(o >> 7);
    if (row >= nrows) return;
    int d = (int)o & 127;
    float invd = 1.0f / fmaxf(deg[row], 1.0f);
    float s = bl[d];
    #pragma unroll
    for (int k = 0; k < 16; ++k)
        s += agg[row * 16 + k] * invd * WlS[k][d] + h[row * 16 + k] * WrS[k][d];
    y[(long long)row * 128 + d] = tanhf(s);
}

// ---------------- CSR gather-aggregate (row-parallel, no atomics) ----------------
__global__ __launch_bounds__(256) void k_aggf(
    const float* __restrict__ x,
    const int* __restrict__ rowptr, const int* __restrict__ col,
    const int* __restrict__ aliveIdx, const float* __restrict__ nal, const float* __restrict__ fvec,
    int mode, int xModN, int rowbase,
    float* __restrict__ AGG, int nrowsC)
{
    int tid = threadIdx.x;
    int r = blockIdx.x * 8 + (tid >> 5);
    if (r >= nrowsC) return;
    int lane = tid & 31;
    int orig = aliveIdx ? aliveIdx[r] : r;
    int grow = rowbase + orig;
    int b = rowptr[grow], e = rowptr[grow + 1];
    float4 a = make_float4(0.0f, 0.0f, 0.0f, 0.0f);
    float dsum = 0.0f;
    if (mode == 0) {
        a = *reinterpret_cast<const float4*>(x + (long long)orig * 128 + lane * 4);
        dsum = 1.0f;
    }
    for (int q = b; q < e; ++q) {
        int s = col[q];
        float fw = 1.0f;
        int fr;
        if (mode == 2) {
            fr = s - rowbase;
            if (nal[fr] == 0.0f) continue;
            dsum += 1.0f;
            fw = fvec[fr];
            if (fw == 0.0f) continue;
        } else {
            fr = xModN ? (s % NN) : (s - rowbase);
            dsum += 1.0f;
        }
        float4 v = *reinterpret_cast<const float4*>(x + (long long)fr * 128 + lane * 4);
        a.x += v.x * fw; a.y += v.y * fw; a.z += v.z * fw; a.w += v.w * fw;
    }
    float invds = 1.0f / fmaxf(dsum, 1.0f);
    a.x *= invds; a.y *= invds; a.z *= invds; a.w *= invds;
    *reinterpret_cast<float4*>(AGG + (long long)r * 128 + lane * 4) = a;
}

// ---------------- dense SAGE GEMM (fp32 v2 tile) — stage-1 only ----------------
__global__ __launch_bounds__(256) void k_sage_d(
    const float* __restrict__ AGG, const float* __restrict__ xsrc,
    const int* __restrict__ aliveIdx, const float* __restrict__ fvec,
    int V,
    const float* __restrict__ Wl, const float* __restrict__ Wr, const float* __restrict__ bl,
    float* __restrict__ y, int nrowsC,
    const float* __restrict__ wrel, const float* __restrict__ wroot, const float* __restrict__ gw,
    float* __restrict__ tbuf, float* __restrict__ rootd, float* __restrict__ gdot)
{
    __shared__ float Ws[32 * 128];
    __shared__ float Is[32][68];
    __shared__ float wrelS[128], wrootS[128], gwS[128];
    __shared__ int rowIdxS[64];
    int tid = threadIdx.x;
    long long row0 = (long long)blockIdx.x * 64;
    if (tid < 128) {
        if (wrel)  wrelS[tid]  = wrel[tid];
        if (wroot) wrootS[tid] = wroot[tid];
        if (gw)    gwS[tid]    = gw[tid];
    }
    if (tid < 64) {
        long long lr = row0 + tid;
        if (lr >= nrowsC) lr = nrowsC - 1;
        rowIdxS[tid] = aliveIdx ? aliveIdx[lr] : (int)lr;
    }
    __syncthreads();
    int tx = tid & 31, ty = tid >> 5;
    float wr4[4] = {0,0,0,0}, wo4[4] = {0,0,0,0}, gg4[4] = {0,0,0,0};
    if (wrel)  { wr4[0]=wrelS[tx*4]; wr4[1]=wrelS[tx*4+1]; wr4[2]=wrelS[tx*4+2]; wr4[3]=wrelS[tx*4+3]; }
    if (wroot) { wo4[0]=wrootS[tx*4]; wo4[1]=wrootS[tx*4+1]; wo4[2]=wrootS[tx*4+2]; wo4[3]=wrootS[tx*4+3]; }
    if (gw)    { gg4[0]=gwS[tx*4]; gg4[1]=gwS[tx*4+1]; gg4[2]=gwS[tx*4+2]; gg4[3]=gwS[tx*4+3]; }
    int srow = tid & 63;
    int koff = (tid >> 6) * 8;
    long long crow = row0 + srow;
    if (crow >= nrowsC) crow = nrowsC - 1;
    int orig = rowIdxS[srow];
    float fself = (V == 2) ? fvec[orig] : 1.0f;
    const float* selfp = xsrc + (long long)orig * 128;
    const float* aggp = AGG + crow * 128;

    float acc[8][4] = {};
    for (int kb = 0; kb < 8; ++kb) {
        __syncthreads();
        bool isAgg = (kb < 4);
        const float* Wsrc = isAgg ? (Wl + kb * 32 * 128) : (Wr + (kb - 4) * 32 * 128);
        #pragma unroll
        for (int j = 0; j < 4; ++j) {
            int fl = j * 1024 + tid * 4;
            *reinterpret_cast<float4*>(&Ws[fl]) = *reinterpret_cast<const float4*>(&Wsrc[fl]);
        }
        {
            const float* sp = (isAgg ? (aggp + kb * 32) : (selfp + (kb - 4) * 32)) + koff;
            float m = isAgg ? 1.0f : fself;
            float4 v0 = *reinterpret_cast<const float4*>(sp);
            float4 v1 = *reinterpret_cast<const float4*>(sp + 4);
            Is[koff + 0][srow] = v0.x * m; Is[koff + 1][srow] = v0.y * m;
            Is[koff + 2][srow] = v0.z * m; Is[koff + 3][srow] = v0.w * m;
            Is[koff + 4][srow] = v1.x * m; Is[koff + 5][srow] = v1.y * m;
            Is[koff + 6][srow] = v1.z * m; Is[koff + 7][srow] = v1.w * m;
        }
        __syncthreads();
        #pragma unroll
        for (int kk = 0; kk < 32; ++kk) {
            float4 wv = *reinterpret_cast<const float4*>(&Ws[kk * 128 + tx * 4]);
            float4 i0 = *reinterpret_cast<const float4*>(&Is[kk][ty * 8]);
            float4 i1 = *reinterpret_cast<const float4*>(&Is[kk][ty * 8 + 4]);
            float ia[8] = {i0.x, i0.y, i0.z, i0.w, i1.x, i1.y, i1.z, i1.w};
            float wa[4] = {wv.x, wv.y, wv.z, wv.w};
            #pragma unroll
            for (int i = 0; i < 8; ++i)
                #pragma unroll
                for (int j = 0; j < 4; ++j)
                    acc[i][j] += ia[i] * wa[j];
        }
    }
    float4 bl0 = *reinterpret_cast<const float4*>(&bl[tx * 4]);
    float br[4] = {bl0.x, bl0.y, bl0.z, bl0.w};
    #pragma unroll
    for (int i = 0; i < 8; ++i) {
        long long cr = row0 + ty * 8 + i;
        bool valid = (cr < nrowsC);
        int rout = rowIdxS[ty * 8 + i];
        float yv[4];
        #pragma unroll
        for (int j = 0; j < 4; ++j) yv[j] = tanhf(acc[i][j] + br[j]);
        if (valid)
            *reinterpret_cast<float4*>(&y[(long long)rout * 128 + tx * 4]) = make_float4(yv[0], yv[1], yv[2], yv[3]);
        float tp = 0.0f, rp = 0.0f, gp = 0.0f;
        #pragma unroll
        for (int j = 0; j < 4; ++j) {
            if (tbuf)  tp += yv[j] * wr4[j];
            if (rootd) rp += yv[j] * wo4[j];
            if (gdot)  gp += yv[j] * gg4[j];
        }
        #pragma unroll
        for (int m = 16; m >= 1; m >>= 1) {
            if (tbuf)  tp += __shfl_xor(tp, m, 32);
            if (rootd) rp += __shfl_xor(rp, m, 32);
            if (gdot)  gp += __shfl_xor(gp, m, 32);
        }
        if (tx == 0 && valid) {
            if (tbuf)  tbuf[rout]  = tp;
            if (rootd) rootd[rout] = rp;
            if (gdot)  gdot[rout]  = gp;
        }
    }
}

// ---------------- bf16 weight pack: Wb[kt][ct][lane][e], k=kt*32+(lane>>4)*8+e, c=ct*16+(lane&15)
__global__ void k_packW(const float* __restrict__ Wl, const float* __restrict__ Wr,
                        short* __restrict__ Wb) {
    int i = blockIdx.x * 256 + threadIdx.x;
    if (i >= 32768) return;
    int kt = i >> 12, rem = i & 4095;
    int ct = rem >> 9; rem &= 511;
    int lane = rem >> 3, e = rem & 7;
    int k = kt * 32 + (lane >> 4) * 8 + e;
    int c = ct * 16 + (lane & 15);
    float v = (k < 128) ? Wl[k * 128 + c] : Wr[(k - 128) * 128 + c];
    Wb[i] = (short)f2bf(v);
}

// ---------------- MFMA SAGE GEMM (stage-2 L1/L2): bf16 inputs, fp32 accum ----------------
// y[orig] = tanh(AGG[crow]@Wl + fvec[orig]*X[orig]@Wr + bl). rows multiple of 128.
__global__ __launch_bounds__(256) void k_sage_m(
    const float* __restrict__ AGG, const float* __restrict__ X,
    const int* __restrict__ aliveIdx, const float* __restrict__ fvec,
    const short* __restrict__ Wb, const float* __restrict__ bl,
    float* __restrict__ y, int nrowsC,
    const float* __restrict__ wrel, const float* __restrict__ wroot, const float* __restrict__ gw,
    float* __restrict__ tbuf, float* __restrict__ rootd, float* __restrict__ gdot)
{
    __shared__ short8 lB[2048];   // half of Wb: 4kt x 8ct x 64lane frags = 32KB
    int tid = threadIdx.x;
    int lane = tid & 63;
    int wv = tid >> 6;
    long long rows0 = (long long)blockIdx.x * 128 + wv * 32;
    int arow = lane & 15;
    int ksl = (lane >> 4) * 8;

    int growA[2], origA[2];
    float fsA[2];
    #pragma unroll
    for (int rt = 0; rt < 2; ++rt) {
        growA[rt] = (int)(rows0 + rt * 16 + arow);
        origA[rt] = aliveIdx[growA[rt]];
        fsA[rt] = fvec[origA[rt]];
    }

    f32x4 acc[2][8] = {};
    const short8* Wbv = (const short8*)Wb;

    for (int half = 0; half < 2; ++half) {
        __syncthreads();
        #pragma unroll
        for (int i = 0; i < 8; ++i) {
            int idx = i * 256 + tid;
            lB[idx] = Wbv[half * 2048 + idx];
        }
        __syncthreads();
        #pragma unroll
        for (int ktl = 0; ktl < 4; ++ktl) {
            int kt = half * 4 + ktl;
            short8 bfr[8];
            #pragma unroll
            for (int ct = 0; ct < 8; ++ct)
                bfr[ct] = lB[(ktl * 8 + ct) * 64 + lane];
            #pragma unroll
            for (int rt = 0; rt < 2; ++rt) {
                const float* ap;
                float m;
                if (kt < 4) { ap = AGG + (long long)growA[rt] * 128 + kt * 32 + ksl; m = 1.0f; }
                else        { ap = X + (long long)origA[rt] * 128 + (kt - 4) * 32 + ksl; m = fsA[rt]; }
                float4 a0 = *reinterpret_cast<const float4*>(ap);
                float4 a1 = *reinterpret_cast<const float4*>(ap + 4);
                short8 afr;
                afr[0] = (short)f2bf(a0.x * m); afr[1] = (short)f2bf(a0.y * m);
                afr[2] = (short)f2bf(a0.z * m); afr[3] = (short)f2bf(a0.w * m);
                afr[4] = (short)f2bf(a1.x * m); afr[5] = (short)f2bf(a1.y * m);
                afr[6] = (short)f2bf(a1.z * m); afr[7] = (short)f2bf(a1.w * m);
                #pragma unroll
                for (int ct = 0; ct < 8; ++ct)
                    acc[rt][ct] = __builtin_amdgcn_mfma_f32_16x16x32_bf16(afr, bfr[ct], acc[rt][ct], 0, 0, 0);
            }
        }
    }

    // epilogue: C/D layout col=lane&15, row=(lane>>4)*4+j  [verified m89]
    int ocol = lane & 15;
    float blv[8], wrv[8], wov[8], ggv[8];
    #pragma unroll
    for (int ct = 0; ct < 8; ++ct) {
        int c = ct * 16 + ocol;
        blv[ct] = bl[c];
        wrv[ct] = wrel[c];
        wov[ct] = wroot[c];
        ggv[ct] = gw[c];
    }
    #pragma unroll
    for (int rt = 0; rt < 2; ++rt) {
        #pragma unroll
        for (int j = 0; j < 4; ++j) {
            int rloc = (lane >> 4) * 4 + j;
            long long grow = rows0 + rt * 16 + rloc;
            int orig = aliveIdx[grow];
            float tp = 0.0f, rp = 0.0f, gp = 0.0f;
            #pragma unroll
            for (int ct = 0; ct < 8; ++ct) {
                float v = tanhf(acc[rt][ct][j] + blv[ct]);
                y[(long long)orig * 128 + ct * 16 + ocol] = v;
                tp += v * wrv[ct]; rp += v * wov[ct]; gp += v * ggv[ct];
            }
            #pragma unroll
            for (int mm = 8; mm >= 1; mm >>= 1) {
                tp += __shfl_xor(tp, mm, 16);
                rp += __shfl_xor(rp, mm, 16);
                gp += __shfl_xor(gp, mm, 16);
            }
            if (ocol == 0) { tbuf[orig] = tp; rootd[orig] = rp; gdot[orig] = gp; }
        }
    }
}

// ---------------- plain GEMM: y = x@W (+ b), v2 tile ----------------
__global__ __launch_bounds__(256) void k_gemm_self(
    const float* __restrict__ x, const float* __restrict__ W, const float* __restrict__ b,
    float* __restrict__ y, int nrows)
{
    __shared__ float Ws[32 * 128];
    __shared__ float Is[32][68];
    int tid = threadIdx.x;
    long long row0 = (long long)blockIdx.x * 64;
    int tx = tid & 31, ty = tid >> 5;
    int srow = tid & 63;
    int koff = (tid >> 6) * 8;
    long long lrow = row0 + srow;
    if (lrow >= nrows) lrow = nrows - 1;
    const float* xrow = x + lrow * 128;
    float acc[8][4] = {};
    for (int kb = 0; kb < 4; ++kb) {
        __syncthreads();
        const float* Wsrc = W + kb * 32 * 128;
        #pragma unroll
        for (int j = 0; j < 4; ++j) {
            int fl = j * 1024 + tid * 4;
            *reinterpret_cast<float4*>(&Ws[fl]) = *reinterpret_cast<const float4*>(&Wsrc[fl]);
        }
        {
            const float* sp = xrow + kb * 32 + koff;
            float4 v0 = *reinterpret_cast<const float4*>(sp);
            float4 v1 = *reinterpret_cast<const float4*>(sp + 4);
            Is[koff + 0][srow] = v0.x; Is[koff + 1][srow] = v0.y;
            Is[koff + 2][srow] = v0.z; Is[koff + 3][srow] = v0.w;
            Is[koff + 4][srow] = v1.x; Is[koff + 5][srow] = v1.y;
            Is[koff + 6][srow] = v1.z; Is[koff + 7][srow] = v1.w;
        }
        __syncthreads();
        #pragma unroll
        for (int kk = 0; kk < 32; ++kk) {
            float4 wv = *reinterpret_cast<const float4*>(&Ws[kk * 128 + tx * 4]);
            float4 i0 = *reinterpret_cast<const float4*>(&Is[kk][ty * 8]);
            float4 i1 = *reinterpret_cast<const float4*>(&Is[kk][ty * 8 + 4]);
            float ia[8] = {i0.x, i0.y, i0.z, i0.w, i1.x, i1.y, i1.z, i1.w};
            float wa[4] = {wv.x, wv.y, wv.z, wv.w};
            #pragma unroll
            for (int i = 0; i < 8; ++i)
                #pragma unroll
                for (int j = 0; j < 4; ++j)
                    acc[i][j] += ia[i] * wa[j];
        }
    }
    float4 b0 = b ? *reinterpret_cast<const float4*>(&b[tx * 4]) : make_float4(0.f, 0.f, 0.f, 0.f);
    #pragma unroll
    for (int i = 0; i < 8; ++i) {
        long long row = row0 + ty * 8 + i;
        if (row >= nrows) continue;
        *reinterpret_cast<float4*>(&y[row * 128 + tx * 4]) =
            make_float4(acc[i][0] + b0.x, acc[i][1] + b0.y, acc[i][2] + b0.z, acc[i][3] + b0.w);
    }
}

// ---------------- stage-2 L0 combine (linear-map trick, no GEMM) ----------------
__global__ __launch_bounds__(256) void k_l0comb(
    const float* __restrict__ ZL0, const float* __restrict__ zself,
    const int* __restrict__ rowptr, const int* __restrict__ col, int rowbase,
    const float* __restrict__ wrel, const float* __restrict__ wroot, const float* __restrict__ gw,
    float* __restrict__ y, float* __restrict__ tbuf, float* __restrict__ rootd, float* __restrict__ gdot,
    int nrowsC)
{
    __shared__ float wrelS[128], wrootS[128], gwS[128];
    int tid = threadIdx.x;
    if (tid < 128) {
        wrelS[tid]  = wrel[tid];
        wrootS[tid] = wroot[tid];
        gwS[tid]    = gw[tid];
    }
    __syncthreads();
    int r = blockIdx.x * 8 + (tid >> 5);
    if (r >= nrowsC) return;
    int lane = tid & 31;
    int grow = rowbase + r;
    int b = rowptr[grow], e = rowptr[grow + 1];
    float4 a = make_float4(0.0f, 0.0f, 0.0f, 0.0f);
    for (int q = b; q < e; ++q) {
        int fr = col[q] % NN;
        float4 v = *reinterpret_cast<const float4*>(ZL0 + (long long)fr * 128 + lane * 4);
        a.x += v.x; a.y += v.y; a.z += v.z; a.w += v.w;
    }
    float invds = 1.0f / fmaxf((float)(e - b), 1.0f);
    const float4 z = *reinterpret_cast<const float4*>(zself + (long long)(r % NN) * 128 + lane * 4);
    float yv[4];
    yv[0] = tanhf(a.x * invds + z.x);
    yv[1] = tanhf(a.y * invds + z.y);
    yv[2] = tanhf(a.z * invds + z.z);
    yv[3] = tanhf(a.w * invds + z.w);
    *reinterpret_cast<float4*>(y + (long long)r * 128 + lane * 4) = make_float4(yv[0], yv[1], yv[2], yv[3]);
    float tp = 0.0f, rp = 0.0f, gp = 0.0f;
    #pragma unroll
    for (int j = 0; j < 4; ++j) {
        tp += yv[j] * wrelS[lane*4 + j];
        rp += yv[j] * wrootS[lane*4 + j];
        gp += yv[j] * gwS[lane*4 + j];
    }
    #pragma unroll
    for (int m = 16; m >= 1; m >>= 1) {
        tp += __shfl_xor(tp, m, 32);
        rp += __shfl_xor(rp, m, 32);
        gp += __shfl_xor(gp, m, 32);
    }
    if (lane == 0) {
        tbuf[r]  = tp;
        rootd[r] = rp;
        gdot[r]  = gp;
    }
}

// ---------------- stage-1 readout pieces ----------------
__global__ __launch_bounds__(256) void k_gate(
    const float* __restrict__ X, const float* __restrict__ gw,
    float* __restrict__ g, int nrows)
{
    __shared__ float wS[128];
    if (threadIdx.x < 128) wS[threadIdx.x] = gw[threadIdx.x];
    __syncthreads();
    int i = blockIdx.x * 256 + threadIdx.x;
    if (i >= nrows) return;
    const float4* xrp = reinterpret_cast<const float4*>(X + (long long)i * 128);
    float s = 0.0f;
    #pragma unroll
    for (int k = 0; k < 32; ++k) {
        float4 v = xrp[k];
        s += v.x * wS[4*k] + v.y * wS[4*k+1] + v.z * wS[4*k+2] + v.w * wS[4*k+3];
    }
    g[i] = s;
}

__global__ __launch_bounds__(1024) void k_smstats(float* __restrict__ g, float* __restrict__ invp) {
    __shared__ float red[1024];
    int p = blockIdx.x, tid = threadIdx.x;
    float* gp = g + (long long)p * NN;
    float lmax = -INFINITY;
    for (int n = tid; n < NN; n += 1024) lmax = fmaxf(lmax, gp[n]);
    red[tid] = lmax; __syncthreads();
    for (int s = 512; s > 0; s >>= 1) { if (tid < s) red[tid] = fmaxf(red[tid], red[tid + s]); __syncthreads(); }
    float mx = red[0]; __syncthreads();
    float ls = 0.0f;
    for (int n = tid; n < NN; n += 1024) { float e = expf(gp[n] - mx); gp[n] = e; ls += e; }
    red[tid] = ls; __syncthreads();
    for (int s = 512; s > 0; s >>= 1) { if (tid < s) red[tid] += red[tid + s]; __syncthreads(); }
    if (tid == 0) invp[p] = 1.0f / red[0];
}

__global__ __launch_bounds__(128) void k_wsum(
    const float* __restrict__ X, const float* __restrict__ a,
    const float* __restrict__ invp, float* __restrict__ ro, int rowbase, int colOff)
{
    int p = blockIdx.x / BPG;
    int chunk = blockIdx.x % BPG;
    int d = threadIdx.x;
    long long base = (long long)p * NN;
    int r0 = chunk * RB, r1 = r0 + RB;
    float s = 0.0f;
    for (int n = r0; n < r1; ++n) {
        float w = a[base + n];
        if (w != 0.0f) s += w * X[(base + n) * 128 + d];
    }
    atomicAdd(&ro[(long long)(rowbase + p) * 384 + colOff + d], s * invp[p]);
}

// stage-2 weighted sum over alive rows only
__global__ __launch_bounds__(128) void k_wsum_c(
    const float* __restrict__ X, const float* __restrict__ gbuf, const float* __restrict__ fvec,
    const float* __restrict__ invp, const int* __restrict__ aliveIdx, int k,
    float* __restrict__ ro, int rowbaseRo, int colOff)
{
    int bpp = k / RB;
    int p = blockIdx.x / bpp;
    int chunk = blockIdx.x % bpp;
    int d = threadIdx.x;
    const int* ai = aliveIdx + (long long)p * k + chunk * RB;
    float s = 0.0f;
    for (int j = 0; j < RB; ++j) {
        int row = ai[j];
        float w = gbuf[row] * fvec[row];
        s += w * X[(long long)row * 128 + d];
    }
    atomicAdd(&ro[(long long)(rowbaseRo + p) * 384 + colOff + d], s * invp[p]);
}

// ---------------- GraphNorm ----------------
__global__ void k_colstat(const float* __restrict__ x, float* __restrict__ musum,
                          float* __restrict__ sqsum, int nrows) {
    int d = threadIdx.x;
    int r0 = blockIdx.x * 64;
    int r1 = min(r0 + 64, nrows);
    float s = 0.0f, q = 0.0f;
    for (int r = r0; r < r1; ++r) { float v = x[(long long)r * 128 + d]; s += v; q += v * v; }
    atomicAdd(&musum[d], s);
    atomicAdd(&sqsum[d], q);
}

__global__ void k_gnorm_apply(const float* __restrict__ x, float* __restrict__ y,
                              const float* __restrict__ musum, const float* __restrict__ sqsum,
                              const float* __restrict__ w, const float* __restrict__ b,
                              const float* __restrict__ ms, int nrows) {
    long long i = (long long)blockIdx.x * 256 + threadIdx.x;
    if (i >= (long long)nrows * 128) return;
    int d = (int)(i & 127);
    float inv_n = 1.0f / (float)nrows;
    float mu = musum[d] * inv_n;
    float c = mu * ms[d];
    float var = sqsum[d] * inv_n - 2.0f * c * mu + c * c;
    y[i] = w[d] * (x[i] - c) * rsqrtf(var + 1e-5f) + b[d];
}

// ---------------- mega top-k (1024 threads, parallel bucket select) ----------------
#define TCH 8   // NN/1024
__global__ __launch_bounds__(1024) void k_topk2(
    const int* __restrict__ rowptr, const int* __restrict__ col, int rowbase,
    const float* __restrict__ tb, const float* __restrict__ rootd,
    const float* __restrict__ gdot, const float* __restrict__ brelp, int bi, int allAlive,
    float* __restrict__ nalive, float* __restrict__ fvec, float* __restrict__ gbuf,
    float* __restrict__ invp, int* __restrict__ aliveIdx, int k)
{
    __shared__ unsigned keys[NN];
    __shared__ int hist[256];
    __shared__ int scan[1024];
    __shared__ float redf[1024];
    __shared__ unsigned sh_pref;
    __shared__ int sh_kneed;
    int p = blockIdx.x, tid = threadIdx.x;
    float brel = brelp[bi];
    long long pbase = (long long)p * NN;
    for (int n = tid; n < NN; n += 1024) {
        long long gl = pbase + n;
        int grow = rowbase + (int)gl;
        float s = brel + rootd[gl];
        int b = rowptr[grow], e = rowptr[grow + 1];
        for (int q = b; q < e; ++q) {
            int sl = col[q] - rowbase;
            s += allAlive ? tb[sl] : (tb[sl] * nalive[sl]);
        }
        bool alive = allAlive || (nalive[gl] > 0.5f);
        keys[n] = alive ? fkey(s) : 0u;
    }
    if (tid == 0) { sh_pref = 0u; sh_kneed = k; }
    __syncthreads();
    for (int lvl = 3; lvl >= 0; --lvl) {
        int sh = lvl * 8;
        if (tid < 256) hist[tid] = 0;
        unsigned pref = sh_pref; int kneed = sh_kneed;
        unsigned pmask = (lvl == 3) ? 0u : (0xFFFFFFFFu << (8 * (lvl + 1)));
        __syncthreads();
        for (int n = tid; n < NN; n += 1024) {
            unsigned kv = keys[n];
            if ((kv & pmask) == pref) atomicAdd(&hist[(kv >> sh) & 255], 1);
        }
        __syncthreads();
        if (tid < 256) scan[tid] = hist[tid];
        __syncthreads();
        for (int off = 1; off < 256; off <<= 1) {
            int v = 0;
            if (tid < 256 && tid + off < 256) v = scan[tid + off];
            __syncthreads();
            if (tid < 256) scan[tid] += v;
            __syncthreads();
        }
        if (tid < 256) {
            int c = scan[tid];
            int cex = c - hist[tid];
            if (c >= kneed && cex < kneed) {
                sh_pref = pref | ((unsigned)tid << sh);
                sh_kneed = kneed - cex;
            }
        }
        __syncthreads();
    }
    unsigned V = sh_pref;
    int seleq = sh_kneed;
    int c0 = tid * TCH, c1 = min(c0 + TCH, NN);
    int ceq = 0;
    for (int n = c0; n < c1; ++n) ceq += (keys[n] == V) ? 1 : 0;
    scan[tid] = ceq; __syncthreads();
    for (int off = 1; off < 1024; off <<= 1) {
        int u = (tid >= off) ? scan[tid - off] : 0;
        __syncthreads();
        scan[tid] += u;
        __syncthreads();
    }
    int rank = scan[tid] - ceq;
    unsigned selmask = 0u;
    int nsel = 0;
    float lmax = -INFINITY;
    for (int n = c0; n < c1; ++n) {
        unsigned kk = keys[n];
        bool sel = (kk > V) || (kk == V && rank < seleq);
        if (kk == V) rank++;
        long long gl = pbase + n;
        nalive[gl] = sel ? 1.0f : 0.0f;
        float f = 0.0f;
        if (sel) {
            f = tanhf(fkey_inv(kk));
            lmax = fmaxf(lmax, f * gdot[gl]);
            selmask |= (1u << (n - c0));
            ++nsel;
        }
        fvec[gl] = f;
    }
    redf[tid] = lmax; __syncthreads();
    for (int s = 512; s > 0; s >>= 1) { if (tid < s) redf[tid] = fmaxf(redf[tid], redf[tid + s]); __syncthreads(); }
    float mx = redf[0]; __syncthreads();
    scan[tid] = nsel; __syncthreads();
    for (int off = 1; off < 1024; off <<= 1) {
        int u = (tid >= off) ? scan[tid - off] : 0;
        __syncthreads();
        scan[tid] += u;
        __syncthreads();
    }
    int pos = scan[tid] - nsel;
    float lsum = 0.0f;
    for (int n = c0; n < c1; ++n) {
        if (selmask & (1u << (n - c0))) {
            long long gl = pbase + n;
            float e = expf(fvec[gl] * gdot[gl] - mx);
            gbuf[gl] = e;
            lsum += e;
            aliveIdx[(long long)p * k + pos] = (int)gl;
            ++pos;
        }
    }
    redf[tid] = lsum; __syncthreads();
    for (int s = 512; s > 0; s >>= 1) { if (tid < s) redf[tid] += redf[tid + s]; __syncthreads(); }
    if (tid == 0) invp[p] = 1.0f / redf[0];
}

// ---------------- head ----------------
__global__ __launch_bounds__(64) void k_head(
    const float* __restrict__ ro, const float* __restrict__ lin_w, const float* __restrict__ lin_b,
    const float* __restrict__ m1w, const float* __restrict__ m1b,
    const float* __restrict__ m2w, const float* __restrict__ m2b,
    const float* __restrict__ m3w, const float* __restrict__ m3b, float* __restrict__ out)
{
    __shared__ float v[33], h1[48], h2[16];
    int t = threadIdx.x;
    if (t < 33) {
        float s = lin_b[0];
        for (int k = 0; k < 384; ++k) s += ro[t * 384 + k] * lin_w[k];
        v[t] = tanhf(s);
    }
    __syncthreads();
    if (t < 48) {
        float s = m1b[t];
        for (int i = 0; i < 33; ++i) s += v[i] * m1w[i * 48 + t];
        h1[t] = tanhf(s);
    }
    __syncthreads();
    if (t < 16) {
        float s = m2b[t];
        for (int i = 0; i < 48; ++i) s += h1[i] * m2w[i * 16 + t];
        h2[t] = tanhf(s);
    }
    __syncthreads();
    if (t == 0) {
        float s = m3b[0];
        for (int i = 0; i < 16; ++i) s += h2[i] * m3w[i];
        float s1 = 1.0f / (1.0f + expf(-s));
        out[0] = 1.0f / (1.0f + expf(-s1));
    }
}

static inline int cdiv(long long a, long long b) { return (int)((a + b - 1) / b); }

extern "C" void kernel_launch(void* const* d_in, const int* in_sizes, int n_in,
                              void* d_out, int out_size, void* d_ws, size_t ws_size,
                              hipStream_t stream)
{
    (void)in_sizes; (void)n_in; (void)out_size;
    const float* h     = (const float*)d_in[0];
    const int*   eidx  = (const int*)d_in[1];
    const int*   seidx = (const int*)d_in[2];
    const float* Wl_a  = (const float*)d_in[3];
    const float* Wr_a  = (const float*)d_in[4];
    const float* bl_a  = (const float*)d_in[5];
    const float* Wl_s  = (const float*)d_in[6];
    const float* Wr_s  = (const float*)d_in[7];
    const float* bl_s  = (const float*)d_in[8];
    const float* gate_w = (const float*)d_in[9];
    const float* p_wrel = (const float*)d_in[11];
    const float* p_brel = (const float*)d_in[12];
    const float* p_wroot= (const float*)d_in[13];
    const float* nw    = (const float*)d_in[14];
    const float* nb    = (const float*)d_in[15];
    const float* nms   = (const float*)d_in[16];
    const float* lin_w = (const float*)d_in[17];
    const float* lin_b = (const float*)d_in[18];
    const float* m1w   = (const float*)d_in[19];
    const float* m1b   = (const float*)d_in[20];
    const float* m2w   = (const float*)d_in[21];
    const float* m2b   = (const float*)d_in[22];
    const float* m3w   = (const float*)d_in[23];
    const float* m3b   = (const float*)d_in[24];
    float* out = (float*)d_out;

    const int* esrc = eidx;
    const int* edst = eidx + EG;
    const int* ssrc = seidx;
    const int* sdst = seidx + ES_TOT;

    auto need_bytes = [](int chp) -> size_t {
        long long chn = (long long)chp * NN;
        long long f = chn * 128
                    + (long long)chp * KK1 * 128
                    + 2LL * NN * 128
                    + 5 * chn
                    + 64 + 33 * 384
                    + (long long)chp * KK1
                    + (PN + 1) + ES_TOT
                    + 2 * 16384                 // Wb1, Wb2 (bf16 packs)
                    + 64 * 24;
        return (size_t)f * 4;
    };
    int chp = 8;
    if (ws_size >= need_bytes(32)) chp = 32;
    else if (ws_size >= need_bytes(16)) chp = 16;
    int nch = PP / chp;
    long long ch_n = (long long)chp * NN;

    float* W = (float*)d_ws;
    size_t off = 0;
    auto alloc = [&](size_t nf) { float* p = W + off; off += (nf + 63) & ~(size_t)63; return p; };
    float* XA    = alloc((size_t)ch_n * DD);
    float* AGG   = alloc((size_t)chp * KK1 * DD);
    float* ZL0   = alloc((size_t)NN * DD);
    float* zself = alloc((size_t)NN * DD);
    float* tbuf  = alloc(ch_n);                 // aliased as gbuf
    float* rootd = alloc(ch_n);
    float* nal   = alloc(ch_n);
    float* fvec  = alloc(ch_n);
    float* gdot  = alloc(ch_n);
    float* invp  = alloc(64);
    float* ro    = alloc(33 * 384);
    int* aliveIdx = (int*)alloc((size_t)chp * KK1);
    int* s2rp    = (int*)alloc(PN + 1);
    int* s2col   = (int*)alloc(ES_TOT);
    short* Wb1   = (short*)alloc(16384);
    short* Wb2   = (short*)alloc(16384);
    float* gbuf = tbuf;

    // overlay: stage-1-only + CSR build temps live inside XA (dead before XA's first write)
    size_t ooff = 0;
    auto oalloc = [&](size_t nf) { float* p = XA + ooff; ooff += (nf + 63) & ~(size_t)63; return p; };
    float* xa    = oalloc((size_t)NN * DD);
    float* xb    = oalloc((size_t)NN * DD);
    float* agg1  = oalloc((size_t)NN * 16);
    float* deg1  = oalloc(NN);
    float* musum = oalloc(128);
    float* sqsum = oalloc(128);
    int* s1cnt  = (int*)oalloc(NN);
    int* s1rp   = (int*)oalloc(NN + 1);
    int* s1cur  = (int*)oalloc(NN);
    int* s1col  = (int*)oalloc(EG);
    int* s1part = (int*)oalloc(NN);
    int* s1bsum = (int*)oalloc(1024);
    int* s2cnt  = (int*)oalloc(PN);
    int* s2cur  = (int*)oalloc(PN);
    int* s2part = (int*)oalloc(PN);
    int* s2bsum = (int*)oalloc(1024);

    // ---------- CSR builds ----------
    int nb1 = cdiv(NN, 1024), nb2 = cdiv(PN, 1024);
    hipMemsetAsync(s1cnt, 0, NN * sizeof(int), stream);
    k_hist<<<cdiv(EG,256),256,0,stream>>>(edst, s1cnt, EG);
    k_scanA<<<nb1,1024,0,stream>>>(s1cnt, s1part, s1bsum, NN);
    k_scanB<<<1,1024,0,stream>>>(s1bsum, nb1);
    k_scanC<<<cdiv(NN,256),256,0,stream>>>(s1part, s1bsum, s1rp, s1cur, NN, EG);
    k_scatter<<<cdiv(EG,256),256,0,stream>>>(esrc, edst, s1cur, s1col, EG);

    hipMemsetAsync(s2cnt, 0, (size_t)PN * sizeof(int), stream);
    k_hist<<<cdiv(ES_TOT,256),256,0,stream>>>(sdst, s2cnt, ES_TOT);
    k_scanA<<<nb2,1024,0,stream>>>(s2cnt, s2part, s2bsum, PN);
    k_scanB<<<1,1024,0,stream>>>(s2bsum, nb2);
    k_scanC<<<cdiv(PN,256),256,0,stream>>>(s2part, s2bsum, s2rp, s2cur, PN, ES_TOT);
    k_scatter<<<cdiv(ES_TOT,256),256,0,stream>>>(ssrc, sdst, s2cur, s2col, ES_TOT);

    hipMemsetAsync(ro, 0, 33 * 384 * sizeof(float), stream);

    // bf16 weight packs for stage-2 L1/L2 MFMA
    k_packW<<<128,256,0,stream>>>(Wl_s + 3*16384, Wr_s + 3*16384, Wb1);
    k_packW<<<128,256,0,stream>>>(Wl_s + 4*16384, Wr_s + 4*16384, Wb2);

    // ---------- stage 1 ----------
    k_agg16<<<cdiv((long long)NN*16,256),256,0,stream>>>(h, s1rp, s1col, agg1, deg1, NN);
    k_sage16<<<cdiv((long long)NN*DD,256),256,0,stream>>>(h, agg1, deg1, Wl_a, Wr_a, bl_a, xa, NN);
    k_gate<<<cdiv(NN,256),256,0,stream>>>(xa, gate_w + 0*DD, gbuf, NN);
    k_smstats<<<1,1024,0,stream>>>(gbuf, invp);
    k_wsum<<<BPG,128,0,stream>>>(xa, gbuf, invp, ro, 0, 0);

    hipMemsetAsync(musum, 0, 128*sizeof(float), stream);
    hipMemsetAsync(sqsum, 0, 128*sizeof(float), stream);
    k_colstat<<<cdiv(NN,64),128,0,stream>>>(xa, musum, sqsum, NN);
    k_gnorm_apply<<<cdiv((long long)NN*DD,256),256,0,stream>>>(xa, xb, musum, sqsum, nw, nb, nms, NN);

    k_aggf<<<cdiv(NN,8),256,0,stream>>>(xb, s1rp, s1col, nullptr, nullptr, nullptr, 0, 0, 0, AGG, NN);
    k_sage_d<<<cdiv(NN,64),256,0,stream>>>(AGG, xb, nullptr, nullptr, 0,
        Wl_s + 0*16384, Wr_s + 0*16384, bl_s + 0*128, xa, NN,
        nullptr, nullptr, gate_w + 1*DD, nullptr, nullptr, gbuf);
    k_smstats<<<1,1024,0,stream>>>(gbuf, invp);
    k_wsum<<<BPG,128,0,stream>>>(xa, gbuf, invp, ro, 0, 128);

    hipMemsetAsync(musum, 0, 128*sizeof(float), stream);
    hipMemsetAsync(sqsum, 0, 128*sizeof(float), stream);
    k_colstat<<<cdiv(NN,64),128,0,stream>>>(xa, musum, sqsum, NN);
    k_gnorm_apply<<<cdiv((long long)NN*DD,256),256,0,stream>>>(xa, xb, musum, sqsum, nw, nb, nms, NN);

    k_aggf<<<cdiv(NN,8),256,0,stream>>>(xb, s1rp, s1col, nullptr, nullptr, nullptr, 0, 0, 0, AGG, NN);
    k_sage_d<<<cdiv(NN,64),256,0,stream>>>(AGG, xb, nullptr, nullptr, 0,
        Wl_s + 1*16384, Wr_s + 1*16384, bl_s + 1*128, xa, NN,
        nullptr, nullptr, gate_w + 2*DD, nullptr, nullptr, gbuf);
    k_smstats<<<1,1024,0,stream>>>(gbuf, invp);
    k_wsum<<<BPG,128,0,stream>>>(xa, gbuf, invp, ro, 0, 256);

    // ---------- stage 2 ----------
    k_gemm_self<<<cdiv(NN,64),256,0,stream>>>(xa, Wl_s + 2*16384, nullptr, ZL0, NN);
    k_gemm_self<<<cdiv(NN,64),256,0,stream>>>(xa, Wr_s + 2*16384, bl_s + 2*128, zself, NN);

    for (int c = 0; c < nch; ++c) {
        int nbase = (int)(c * ch_n);

        // ---- layer 0: gather-mean of ZL0 + zself (no GEMM; all rows alive) ----
        k_l0comb<<<(int)(ch_n/8),256,0,stream>>>(ZL0, zself, s2rp, s2col, nbase,
            p_wrel + 0*DD, p_wroot + 0*DD, gate_w + 3*DD,
            XA, tbuf, rootd, gdot, (int)ch_n);
        k_topk2<<<chp,1024,0,stream>>>(s2rp, s2col, nbase, tbuf, rootd, gdot, p_brel, 0, 1,
                                       nal, fvec, gbuf, invp, aliveIdx, KK1);
        k_wsum_c<<<chp*(KK1/RB),128,0,stream>>>(XA, gbuf, fvec, invp, aliveIdx, KK1, ro, 1 + c*chp, 0);

        // ---- layer 1: alive K1 rows, MFMA (in-place on XA) ----
        k_aggf<<<chp*(KK1/8),256,0,stream>>>(XA, s2rp, s2col, aliveIdx, nal, fvec, 2, 0, nbase, AGG, chp*KK1);
        k_sage_m<<<chp*KK1/128,256,0,stream>>>(AGG, XA, aliveIdx, fvec, Wb1, bl_s + 3*128, XA, chp*KK1,
            p_wrel + 1*DD, p_wroot + 1*DD, gate_w + 4*DD, tbuf, rootd, gdot);
        k_topk2<<<chp,1024,0,stream>>>(s2rp, s2col, nbase, tbuf, rootd, gdot, p_brel, 1, 0,
                                       nal, fvec, gbuf, invp, aliveIdx, KK2);
        k_wsum_c<<<chp*(KK2/RB),128,0,stream>>>(XA, gbuf, fvec, invp, aliveIdx, KK2, ro, 1 + c*chp, 128);

        // ---- layer 2: alive K2 rows, MFMA (in-place on XA) ----
        k_aggf<<<chp*(KK2/8),256,0,stream>>>(XA, s2rp, s2col, aliveIdx, nal, fvec, 2, 0, nbase, AGG, chp*KK2);
        k_sage_m<<<chp*KK2/128,256,0,stream>>>(AGG, XA, aliveIdx, fvec, Wb2, bl_s + 4*128, XA, chp*KK2,
            p_wrel + 2*DD, p_wroot + 2*DD, gate_w + 5*DD, tbuf, rootd, gdot);
        k_topk2<<<chp,1024,0,stream>>>(s2rp, s2col, nbase, tbuf, rootd, gdot, p_brel, 2, 0,
                                       nal, fvec, gbuf, invp, aliveIdx, KK3);
        k_wsum_c<<<chp*(KK3/RB),128,0,stream>>>(XA, gbuf, fvec, invp, aliveIdx, KK3, ro, 1 + c*chp, 256);
    }

    // ---------- head ----------
    k_head<<<1,64,0,stream>>>(ro, lin_w, lin_b, m1w, m1b, m2w, m2b, m3w, m3b, out);
}

// Round 16
// 748.947 us; speedup vs baseline: 3.5086x; 1.0637x over previous
//
#include <hip/hip_runtime.h>
#include <math.h>

#define NN      8000
#define PP      32
#define EG      128000
#define ES_TOT  131072     // P * 4096
#define ES_P    4096
#define PN      256000     // P * NN
#define DI      16
#define DD      128
#define KK1     6400
#define KK2     5120
#define KK3     4096
#define RB      64                   // rows per wsum block
#define BPG     (NN / RB)            // 125 blocks per graph (stage-1 wsum)

typedef __attribute__((ext_vector_type(8))) short short8;
typedef __attribute__((ext_vector_type(4))) float f32x4;

static __device__ __forceinline__ unsigned fkey(float f) {
    unsigned u = __float_as_uint(f);
    return (u & 0x80000000u) ? ~u : (u | 0x80000000u);
}
static __device__ __forceinline__ float fkey_inv(unsigned k) {
    unsigned u = (k & 0x80000000u) ? (k & 0x7FFFFFFFu) : ~k;
    return __uint_as_float(u);
}
static __device__ __forceinline__ unsigned short f2bf(float f) {
    unsigned u = __float_as_uint(f);
    u += 0x7FFFu + ((u >> 16) & 1u);   // RNE to bf16
    return (unsigned short)(u >> 16);
}

// ---------------- CSR build ----------------
__global__ void k_hist(const int* __restrict__ dst, int* __restrict__ cnt, int ne) {
    int e = blockIdx.x * 256 + threadIdx.x;
    if (e < ne) atomicAdd(&cnt[dst[e]], 1);
}

__global__ __launch_bounds__(1024) void k_scanA(const int* __restrict__ cnt,
                                                int* __restrict__ part,
                                                int* __restrict__ bsum, int n) {
    __shared__ int sh[1024];
    int t = threadIdx.x;
    int i = blockIdx.x * 1024 + t;
    int v = (i < n) ? cnt[i] : 0;
    sh[t] = v; __syncthreads();
    for (int off = 1; off < 1024; off <<= 1) {
        int u = (t >= off) ? sh[t - off] : 0;
        __syncthreads();
        sh[t] += u;
        __syncthreads();
    }
    if (i < n) part[i] = sh[t] - v;
    if (t == 1023) bsum[blockIdx.x] = sh[1023];
}

__global__ __launch_bounds__(1024) void k_scanB(int* __restrict__ bsum, int nb) {
    __shared__ int sh[1024];
    int t = threadIdx.x;
    int v = (t < nb) ? bsum[t] : 0;
    sh[t] = v; __syncthreads();
    for (int off = 1; off < 1024; off <<= 1) {
        int u = (t >= off) ? sh[t - off] : 0;
        __syncthreads();
        sh[t] += u;
        __syncthreads();
    }
    if (t < nb) bsum[t] = sh[t] - v;   // exclusive
}

__global__ void k_scanC(const int* __restrict__ part, const int* __restrict__ bsum,
                        int* __restrict__ rowptr, int* __restrict__ cursor, int n, int total) {
    int i = blockIdx.x * 256 + threadIdx.x;
    if (i < n) {
        int v = part[i] + bsum[i >> 10];
        rowptr[i] = v;
        cursor[i] = v;
    }
    if (i == 0) rowptr[n] = total;
}

__global__ void k_scatter(const int* __restrict__ src, const int* __restrict__ dst,
                          int* __restrict__ cursor, int* __restrict__ col, int ne) {
    int e = blockIdx.x * 256 + threadIdx.x;
    if (e >= ne) return;
    int pos = atomicAdd(&cursor[dst[e]], 1);
    col[pos] = src[e];
}

// ---------------- stage-1 layer a ----------------
__global__ __launch_bounds__(256) void k_agg16(const float* __restrict__ h,
                                               const int* __restrict__ rowptr,
                                               const int* __restrict__ col,
                                               float* __restrict__ agg, float* __restrict__ deg,
                                               int nrows) {
    int i = blockIdx.x * 256 + threadIdx.x;
    int r = i >> 4, j = i & 15;
    if (r >= nrows) return;
    int b = rowptr[r], e = rowptr[r + 1];
    float a = h[r * 16 + j];
    for (int q = b; q < e; ++q) a += h[col[q] * 16 + j];
    agg[r * 16 + j] = a;
    if (j == 0) deg[r] = 1.0f + (float)(e - b);
}

__global__ __launch_bounds__(256) void k_sage16(
    const float* __restrict__ h, const float* __restrict__ agg, const float* __restrict__ deg,
    const float* __restrict__ Wl, const float* __restrict__ Wr, const float* __restrict__ bl,
    float* __restrict__ y, int nrows)
{
    __shared__ float WlS[16][128], WrS[16][128];
    int tid = threadIdx.x;
    for (int i = tid; i < 16 * 128; i += 256) {
        WlS[i >> 7][i & 127] = Wl[i];
        WrS[i >> 7][i & 127] = Wr[i];
    }
    __syncthreads();
    long long o = (long long)blockIdx.x * 256 + tid;
    int row = (int)(o >> 7);
    if (row >= nrows) return;
    int d = (int)o & 127;
    float invd = 1.0f / fmaxf(deg[row], 1.0f);
    float s = bl[d];
    #pragma unroll
    for (int k = 0; k < 16; ++k)
        s += agg[row * 16 + k] * invd * WlS[k][d] + h[row * 16 + k] * WrS[k][d];
    y[(long long)row * 128 + d] = tanhf(s);
}

// ---------------- stage-1 CSR gather-aggregate (fp32 out) ----------------
__global__ __launch_bounds__(256) void k_aggf0(
    const float* __restrict__ x,
    const int* __restrict__ rowptr, const int* __restrict__ col,
    float* __restrict__ AGG, int nrowsC)
{
    int tid = threadIdx.x;
    int r = blockIdx.x * 8 + (tid >> 5);
    if (r >= nrowsC) return;
    int lane = tid & 31;
    int b = rowptr[r], e = rowptr[r + 1];
    float4 a = *reinterpret_cast<const float4*>(x + (long long)r * 128 + lane * 4);
    float dsum = 1.0f + (float)(e - b);
    for (int q = b; q < e; ++q) {
        int s = col[q];
        float4 v = *reinterpret_cast<const float4*>(x + (long long)s * 128 + lane * 4);
        a.x += v.x; a.y += v.y; a.z += v.z; a.w += v.w;
    }
    float invds = 1.0f / fmaxf(dsum, 1.0f);
    a.x *= invds; a.y *= invds; a.z *= invds; a.w *= invds;
    *reinterpret_cast<float4*>(AGG + (long long)r * 128 + lane * 4) = a;
}

// ---------------- stage-2 CSR gather-aggregate (bf16 out, alive-compacted) ----------------
// Identical numerics to fp32-AGG + later f2bf: same RNE of the same fp32 mean.
__global__ __launch_bounds__(256) void k_aggf2(
    const float* __restrict__ x,
    const int* __restrict__ rowptr, const int* __restrict__ col,
    const int* __restrict__ aliveIdx, const float* __restrict__ nal, const float* __restrict__ fvec,
    int rowbase,
    unsigned short* __restrict__ AGGb, int nrowsC)
{
    int tid = threadIdx.x;
    int r = blockIdx.x * 8 + (tid >> 5);
    if (r >= nrowsC) return;
    int lane = tid & 31;
    int orig = aliveIdx[r];
    int grow = rowbase + orig;
    int b = rowptr[grow], e = rowptr[grow + 1];
    float4 a = make_float4(0.0f, 0.0f, 0.0f, 0.0f);
    float dsum = 0.0f;
    for (int q = b; q < e; ++q) {
        int fr = col[q] - rowbase;
        if (nal[fr] == 0.0f) continue;
        dsum += 1.0f;
        float fw = fvec[fr];
        if (fw == 0.0f) continue;
        float4 v = *reinterpret_cast<const float4*>(x + (long long)fr * 128 + lane * 4);
        a.x += v.x * fw; a.y += v.y * fw; a.z += v.z * fw; a.w += v.w * fw;
    }
    float invds = 1.0f / fmaxf(dsum, 1.0f);
    ushort4 o;
    o.x = f2bf(a.x * invds); o.y = f2bf(a.y * invds);
    o.z = f2bf(a.z * invds); o.w = f2bf(a.w * invds);
    *reinterpret_cast<ushort4*>(AGGb + (long long)r * 128 + lane * 4) = o;
}

// ---------------- dense SAGE GEMM (fp32 v2 tile) — stage-1 only ----------------
__global__ __launch_bounds__(256) void k_sage_d(
    const float* __restrict__ AGG, const float* __restrict__ xsrc,
    const float* __restrict__ Wl, const float* __restrict__ Wr, const float* __restrict__ bl,
    float* __restrict__ y, int nrowsC,
    const float* __restrict__ gw, float* __restrict__ gdot)
{
    __shared__ float Ws[32 * 128];
    __shared__ float Is[32][68];
    __shared__ float gwS[128];
    int tid = threadIdx.x;
    long long row0 = (long long)blockIdx.x * 64;
    if (tid < 128 && gw) gwS[tid] = gw[tid];
    __syncthreads();
    int tx = tid & 31, ty = tid >> 5;
    float gg4[4] = {0,0,0,0};
    if (gw) { gg4[0]=gwS[tx*4]; gg4[1]=gwS[tx*4+1]; gg4[2]=gwS[tx*4+2]; gg4[3]=gwS[tx*4+3]; }
    int srow = tid & 63;
    int koff = (tid >> 6) * 8;
    long long crow = row0 + srow;
    if (crow >= nrowsC) crow = nrowsC - 1;
    const float* selfp = xsrc + crow * 128;
    const float* aggp = AGG + crow * 128;

    float acc[8][4] = {};
    for (int kb = 0; kb < 8; ++kb) {
        __syncthreads();
        bool isAgg = (kb < 4);
        const float* Wsrc = isAgg ? (Wl + kb * 32 * 128) : (Wr + (kb - 4) * 32 * 128);
        #pragma unroll
        for (int j = 0; j < 4; ++j) {
            int fl = j * 1024 + tid * 4;
            *reinterpret_cast<float4*>(&Ws[fl]) = *reinterpret_cast<const float4*>(&Wsrc[fl]);
        }
        {
            const float* sp = (isAgg ? (aggp + kb * 32) : (selfp + (kb - 4) * 32)) + koff;
            float4 v0 = *reinterpret_cast<const float4*>(sp);
            float4 v1 = *reinterpret_cast<const float4*>(sp + 4);
            Is[koff + 0][srow] = v0.x; Is[koff + 1][srow] = v0.y;
            Is[koff + 2][srow] = v0.z; Is[koff + 3][srow] = v0.w;
            Is[koff + 4][srow] = v1.x; Is[koff + 5][srow] = v1.y;
            Is[koff + 6][srow] = v1.z; Is[koff + 7][srow] = v1.w;
        }
        __syncthreads();
        #pragma unroll
        for (int kk = 0; kk < 32; ++kk) {
            float4 wv = *reinterpret_cast<const float4*>(&Ws[kk * 128 + tx * 4]);
            float4 i0 = *reinterpret_cast<const float4*>(&Is[kk][ty * 8]);
            float4 i1 = *reinterpret_cast<const float4*>(&Is[kk][ty * 8 + 4]);
            float ia[8] = {i0.x, i0.y, i0.z, i0.w, i1.x, i1.y, i1.z, i1.w};
            float wa[4] = {wv.x, wv.y, wv.z, wv.w};
            #pragma unroll
            for (int i = 0; i < 8; ++i)
                #pragma unroll
                for (int j = 0; j < 4; ++j)
                    acc[i][j] += ia[i] * wa[j];
        }
    }
    float4 bl0 = *reinterpret_cast<const float4*>(&bl[tx * 4]);
    float br[4] = {bl0.x, bl0.y, bl0.z, bl0.w};
    #pragma unroll
    for (int i = 0; i < 8; ++i) {
        long long row = row0 + ty * 8 + i;
        bool valid = (row < nrowsC);
        float yv[4];
        #pragma unroll
        for (int j = 0; j < 4; ++j) yv[j] = tanhf(acc[i][j] + br[j]);
        if (valid)
            *reinterpret_cast<float4*>(&y[row * 128 + tx * 4]) = make_float4(yv[0], yv[1], yv[2], yv[3]);
        float gp = 0.0f;
        #pragma unroll
        for (int j = 0; j < 4; ++j) if (gdot) gp += yv[j] * gg4[j];
        #pragma unroll
        for (int m = 16; m >= 1; m >>= 1) if (gdot) gp += __shfl_xor(gp, m, 32);
        if (tx == 0 && valid && gdot) gdot[row] = gp;
    }
}

// ---------------- bf16 weight pack ----------------
__global__ void k_packW(const float* __restrict__ Wl, const float* __restrict__ Wr,
                        short* __restrict__ Wb) {
    int i = blockIdx.x * 256 + threadIdx.x;
    if (i >= 32768) return;
    int kt = i >> 12, rem = i & 4095;
    int ct = rem >> 9; rem &= 511;
    int lane = rem >> 3, e = rem & 7;
    int k = kt * 32 + (lane >> 4) * 8 + e;
    int c = ct * 16 + (lane & 15);
    float v = (k < 128) ? Wl[k * 128 + c] : Wr[(k - 128) * 128 + c];
    Wb[i] = (short)f2bf(v);
}

// ---------------- MFMA SAGE GEMM (stage-2 L1/L2): bf16 inputs, fp32 accum ----------------
// y[orig] = tanh(AGGb[crow]@Wl + fvec[orig]*X[orig]@Wr + bl). rows multiple of 128.
__global__ __launch_bounds__(256) void k_sage_m(
    const unsigned short* __restrict__ AGGb, const float* __restrict__ X,
    const int* __restrict__ aliveIdx, const float* __restrict__ fvec,
    const short* __restrict__ Wb, const float* __restrict__ bl,
    float* __restrict__ y, int nrowsC,
    const float* __restrict__ wrel, const float* __restrict__ wroot, const float* __restrict__ gw,
    float* __restrict__ tbuf, float* __restrict__ rootd, float* __restrict__ gdot)
{
    __shared__ short8 lB[2048];   // half of Wb: 4kt x 8ct x 64lane frags = 32KB
    int tid = threadIdx.x;
    int lane = tid & 63;
    int wv = tid >> 6;
    long long rows0 = (long long)blockIdx.x * 128 + wv * 32;
    int arow = lane & 15;
    int ksl = (lane >> 4) * 8;

    int growA[2], origA[2];
    float fsA[2];
    #pragma unroll
    for (int rt = 0; rt < 2; ++rt) {
        growA[rt] = (int)(rows0 + rt * 16 + arow);
        origA[rt] = aliveIdx[growA[rt]];
        fsA[rt] = fvec[origA[rt]];
    }

    f32x4 acc[2][8] = {};
    const short8* Wbv = (const short8*)Wb;

    for (int half = 0; half < 2; ++half) {
        __syncthreads();
        #pragma unroll
        for (int i = 0; i < 8; ++i) {
            int idx = i * 256 + tid;
            lB[idx] = Wbv[half * 2048 + idx];
        }
        __syncthreads();
        #pragma unroll
        for (int ktl = 0; ktl < 4; ++ktl) {
            int kt = half * 4 + ktl;
            short8 bfr[8];
            #pragma unroll
            for (int ct = 0; ct < 8; ++ct)
                bfr[ct] = lB[(ktl * 8 + ct) * 64 + lane];
            #pragma unroll
            for (int rt = 0; rt < 2; ++rt) {
                short8 afr;
                if (kt < 4) {
                    afr = *reinterpret_cast<const short8*>(AGGb + (long long)growA[rt] * 128 + kt * 32 + ksl);
                } else {
                    const float* ap = X + (long long)origA[rt] * 128 + (kt - 4) * 32 + ksl;
                    float m = fsA[rt];
                    float4 a0 = *reinterpret_cast<const float4*>(ap);
                    float4 a1 = *reinterpret_cast<const float4*>(ap + 4);
                    afr[0] = (short)f2bf(a0.x * m); afr[1] = (short)f2bf(a0.y * m);
                    afr[2] = (short)f2bf(a0.z * m); afr[3] = (short)f2bf(a0.w * m);
                    afr[4] = (short)f2bf(a1.x * m); afr[5] = (short)f2bf(a1.y * m);
                    afr[6] = (short)f2bf(a1.z * m); afr[7] = (short)f2bf(a1.w * m);
                }
                #pragma unroll
                for (int ct = 0; ct < 8; ++ct)
                    acc[rt][ct] = __builtin_amdgcn_mfma_f32_16x16x32_bf16(afr, bfr[ct], acc[rt][ct], 0, 0, 0);
            }
        }
    }

    // epilogue: C/D layout col=lane&15, row=(lane>>4)*4+j
    int ocol = lane & 15;
    float blv[8], wrv[8], wov[8], ggv[8];
    #pragma unroll
    for (int ct = 0; ct < 8; ++ct) {
        int c = ct * 16 + ocol;
        blv[ct] = bl[c];
        wrv[ct] = wrel[c];
        wov[ct] = wroot[c];
        ggv[ct] = gw[c];
    }
    #pragma unroll
    for (int rt = 0; rt < 2; ++rt) {
        #pragma unroll
        for (int j = 0; j < 4; ++j) {
            int rloc = (lane >> 4) * 4 + j;
            long long grow = rows0 + rt * 16 + rloc;
            int orig = aliveIdx[grow];
            float tp = 0.0f, rp = 0.0f, gp = 0.0f;
            #pragma unroll
            for (int ct = 0; ct < 8; ++ct) {
                float v = tanhf(acc[rt][ct][j] + blv[ct]);
                y[(long long)orig * 128 + ct * 16 + ocol] = v;
                tp += v * wrv[ct]; rp += v * wov[ct]; gp += v * ggv[ct];
            }
            #pragma unroll
            for (int mm = 8; mm >= 1; mm >>= 1) {
                tp += __shfl_xor(tp, mm, 16);
                rp += __shfl_xor(rp, mm, 16);
                gp += __shfl_xor(gp, mm, 16);
            }
            if (ocol == 0) { tbuf[orig] = tp; rootd[orig] = rp; gdot[orig] = gp; }
        }
    }
}

// ---------------- plain GEMM: y = x@W (+ b), v2 tile ----------------
__global__ __launch_bounds__(256) void k_gemm_self(
    const float* __restrict__ x, const float* __restrict__ W, const float* __restrict__ b,
    float* __restrict__ y, int nrows)
{
    __shared__ float Ws[32 * 128];
    __shared__ float Is[32][68];
    int tid = threadIdx.x;
    long long row0 = (long long)blockIdx.x * 64;
    int tx = tid & 31, ty = tid >> 5;
    int srow = tid & 63;
    int koff = (tid >> 6) * 8;
    long long lrow = row0 + srow;
    if (lrow >= nrows) lrow = nrows - 1;
    const float* xrow = x + lrow * 128;
    float acc[8][4] = {};
    for (int kb = 0; kb < 4; ++kb) {
        __syncthreads();
        const float* Wsrc = W + kb * 32 * 128;
        #pragma unroll
        for (int j = 0; j < 4; ++j) {
            int fl = j * 1024 + tid * 4;
            *reinterpret_cast<float4*>(&Ws[fl]) = *reinterpret_cast<const float4*>(&Wsrc[fl]);
        }
        {
            const float* sp = xrow + kb * 32 + koff;
            float4 v0 = *reinterpret_cast<const float4*>(sp);
            float4 v1 = *reinterpret_cast<const float4*>(sp + 4);
            Is[koff + 0][srow] = v0.x; Is[koff + 1][srow] = v0.y;
            Is[koff + 2][srow] = v0.z; Is[koff + 3][srow] = v0.w;
            Is[koff + 4][srow] = v1.x; Is[koff + 5][srow] = v1.y;
            Is[koff + 6][srow] = v1.z; Is[koff + 7][srow] = v1.w;
        }
        __syncthreads();
        #pragma unroll
        for (int kk = 0; kk < 32; ++kk) {
            float4 wv = *reinterpret_cast<const float4*>(&Ws[kk * 128 + tx * 4]);
            float4 i0 = *reinterpret_cast<const float4*>(&Is[kk][ty * 8]);
            float4 i1 = *reinterpret_cast<const float4*>(&Is[kk][ty * 8 + 4]);
            float ia[8] = {i0.x, i0.y, i0.z, i0.w, i1.x, i1.y, i1.z, i1.w};
            float wa[4] = {wv.x, wv.y, wv.z, wv.w};
            #pragma unroll
            for (int i = 0; i < 8; ++i)
                #pragma unroll
                for (int j = 0; j < 4; ++j)
                    acc[i][j] += ia[i] * wa[j];
        }
    }
    float4 b0 = b ? *reinterpret_cast<const float4*>(&b[tx * 4]) : make_float4(0.f, 0.f, 0.f, 0.f);
    #pragma unroll
    for (int i = 0; i < 8; ++i) {
        long long row = row0 + ty * 8 + i;
        if (row >= nrows) continue;
        *reinterpret_cast<float4*>(&y[row * 128 + tx * 4]) =
            make_float4(acc[i][0] + b0.x, acc[i][1] + b0.y, acc[i][2] + b0.z, acc[i][3] + b0.w);
    }
}

// ---------------- stage-2 L0 combine (linear-map trick, no GEMM) ----------------
__global__ __launch_bounds__(256) void k_l0comb(
    const float* __restrict__ ZL0, const float* __restrict__ zself,
    const int* __restrict__ rowptr, const int* __restrict__ col, int rowbase,
    const float* __restrict__ wrel, const float* __restrict__ wroot, const float* __restrict__ gw,
    float* __restrict__ y, float* __restrict__ tbuf, float* __restrict__ rootd, float* __restrict__ gdot,
    int nrowsC)
{
    __shared__ float wrelS[128], wrootS[128], gwS[128];
    int tid = threadIdx.x;
    if (tid < 128) {
        wrelS[tid]  = wrel[tid];
        wrootS[tid] = wroot[tid];
        gwS[tid]    = gw[tid];
    }
    __syncthreads();
    int r = blockIdx.x * 8 + (tid >> 5);
    if (r >= nrowsC) return;
    int lane = tid & 31;
    int grow = rowbase + r;
    int b = rowptr[grow], e = rowptr[grow + 1];
    float4 a = make_float4(0.0f, 0.0f, 0.0f, 0.0f);
    for (int q = b; q < e; ++q) {
        int fr = col[q] % NN;
        float4 v = *reinterpret_cast<const float4*>(ZL0 + (long long)fr * 128 + lane * 4);
        a.x += v.x; a.y += v.y; a.z += v.z; a.w += v.w;
    }
    float invds = 1.0f / fmaxf((float)(e - b), 1.0f);
    const float4 z = *reinterpret_cast<const float4*>(zself + (long long)(r % NN) * 128 + lane * 4);
    float yv[4];
    yv[0] = tanhf(a.x * invds + z.x);
    yv[1] = tanhf(a.y * invds + z.y);
    yv[2] = tanhf(a.z * invds + z.z);
    yv[3] = tanhf(a.w * invds + z.w);
    *reinterpret_cast<float4*>(y + (long long)r * 128 + lane * 4) = make_float4(yv[0], yv[1], yv[2], yv[3]);
    float tp = 0.0f, rp = 0.0f, gp = 0.0f;
    #pragma unroll
    for (int j = 0; j < 4; ++j) {
        tp += yv[j] * wrelS[lane*4 + j];
        rp += yv[j] * wrootS[lane*4 + j];
        gp += yv[j] * gwS[lane*4 + j];
    }
    #pragma unroll
    for (int m = 16; m >= 1; m >>= 1) {
        tp += __shfl_xor(tp, m, 32);
        rp += __shfl_xor(rp, m, 32);
        gp += __shfl_xor(gp, m, 32);
    }
    if (lane == 0) {
        tbuf[r]  = tp;
        rootd[r] = rp;
        gdot[r]  = gp;
    }
}

// ---------------- stage-1 readout pieces ----------------
__global__ __launch_bounds__(256) void k_gate(
    const float* __restrict__ X, const float* __restrict__ gw,
    float* __restrict__ g, int nrows)
{
    __shared__ float wS[128];
    if (threadIdx.x < 128) wS[threadIdx.x] = gw[threadIdx.x];
    __syncthreads();
    int i = blockIdx.x * 256 + threadIdx.x;
    if (i >= nrows) return;
    const float4* xrp = reinterpret_cast<const float4*>(X + (long long)i * 128);
    float s = 0.0f;
    #pragma unroll
    for (int k = 0; k < 32; ++k) {
        float4 v = xrp[k];
        s += v.x * wS[4*k] + v.y * wS[4*k+1] + v.z * wS[4*k+2] + v.w * wS[4*k+3];
    }
    g[i] = s;
}

__global__ __launch_bounds__(1024) void k_smstats(float* __restrict__ g, float* __restrict__ invp) {
    __shared__ float red[1024];
    int p = blockIdx.x, tid = threadIdx.x;
    float* gp = g + (long long)p * NN;
    float lmax = -INFINITY;
    for (int n = tid; n < NN; n += 1024) lmax = fmaxf(lmax, gp[n]);
    red[tid] = lmax; __syncthreads();
    for (int s = 512; s > 0; s >>= 1) { if (tid < s) red[tid] = fmaxf(red[tid], red[tid + s]); __syncthreads(); }
    float mx = red[0]; __syncthreads();
    float ls = 0.0f;
    for (int n = tid; n < NN; n += 1024) { float e = expf(gp[n] - mx); gp[n] = e; ls += e; }
    red[tid] = ls; __syncthreads();
    for (int s = 512; s > 0; s >>= 1) { if (tid < s) red[tid] += red[tid + s]; __syncthreads(); }
    if (tid == 0) invp[p] = 1.0f / red[0];
}

__global__ __launch_bounds__(128) void k_wsum(
    const float* __restrict__ X, const float* __restrict__ a,
    const float* __restrict__ invp, float* __restrict__ ro, int rowbase, int colOff)
{
    int p = blockIdx.x / BPG;
    int chunk = blockIdx.x % BPG;
    int d = threadIdx.x;
    long long base = (long long)p * NN;
    int r0 = chunk * RB, r1 = r0 + RB;
    float s = 0.0f;
    for (int n = r0; n < r1; ++n) {
        float w = a[base + n];
        if (w != 0.0f) s += w * X[(base + n) * 128 + d];
    }
    atomicAdd(&ro[(long long)(rowbase + p) * 384 + colOff + d], s * invp[p]);
}

// stage-2 weighted sum over alive rows only
__global__ __launch_bounds__(128) void k_wsum_c(
    const float* __restrict__ X, const float* __restrict__ gbuf, const float* __restrict__ fvec,
    const float* __restrict__ invp, const int* __restrict__ aliveIdx, int k,
    float* __restrict__ ro, int rowbaseRo, int colOff)
{
    int bpp = k / RB;
    int p = blockIdx.x / bpp;
    int chunk = blockIdx.x % bpp;
    int d = threadIdx.x;
    const int* ai = aliveIdx + (long long)p * k + chunk * RB;
    float s = 0.0f;
    for (int j = 0; j < RB; ++j) {
        int row = ai[j];
        float w = gbuf[row] * fvec[row];
        s += w * X[(long long)row * 128 + d];
    }
    atomicAdd(&ro[(long long)(rowbaseRo + p) * 384 + colOff + d], s * invp[p]);
}

// ---------------- GraphNorm ----------------
__global__ void k_colstat(const float* __restrict__ x, float* __restrict__ musum,
                          float* __restrict__ sqsum, int nrows) {
    int d = threadIdx.x;
    int r0 = blockIdx.x * 64;
    int r1 = min(r0 + 64, nrows);
    float s = 0.0f, q = 0.0f;
    for (int r = r0; r < r1; ++r) { float v = x[(long long)r * 128 + d]; s += v; q += v * v; }
    atomicAdd(&musum[d], s);
    atomicAdd(&sqsum[d], q);
}

__global__ void k_gnorm_apply(const float* __restrict__ x, float* __restrict__ y,
                              const float* __restrict__ musum, const float* __restrict__ sqsum,
                              const float* __restrict__ w, const float* __restrict__ b,
                              const float* __restrict__ ms, int nrows) {
    long long i = (long long)blockIdx.x * 256 + threadIdx.x;
    if (i >= (long long)nrows * 128) return;
    int d = (int)(i & 127);
    float inv_n = 1.0f / (float)nrows;
    float mu = musum[d] * inv_n;
    float c = mu * ms[d];
    float var = sqsum[d] * inv_n - 2.0f * c * mu + c * c;
    y[i] = w[d] * (x[i] - c) * rsqrtf(var + 1e-5f) + b[d];
}

// ---------------- mega top-k (1024 threads, parallel bucket select) ----------------
#define TCH 8   // NN/1024
__global__ __launch_bounds__(1024) void k_topk2(
    const int* __restrict__ rowptr, const int* __restrict__ col, int rowbase,
    const float* __restrict__ tb, const float* __restrict__ rootd,
    const float* __restrict__ gdot, const float* __restrict__ brelp, int bi, int allAlive,
    float* __restrict__ nalive, float* __restrict__ fvec, float* __restrict__ gbuf,
    float* __restrict__ invp, int* __restrict__ aliveIdx, int k)
{
    __shared__ unsigned keys[NN];
    __shared__ int hist[256];
    __shared__ int scan[1024];
    __shared__ float redf[1024];
    __shared__ unsigned sh_pref;
    __shared__ int sh_kneed;
    int p = blockIdx.x, tid = threadIdx.x;
    float brel = brelp[bi];
    long long pbase = (long long)p * NN;
    for (int n = tid; n < NN; n += 1024) {
        long long gl = pbase + n;
        int grow = rowbase + (int)gl;
        float s = brel + rootd[gl];
        int b = rowptr[grow], e = rowptr[grow + 1];
        for (int q = b; q < e; ++q) {
            int sl = col[q] - rowbase;
            s += allAlive ? tb[sl] : (tb[sl] * nalive[sl]);
        }
        bool alive = allAlive || (nalive[gl] > 0.5f);
        keys[n] = alive ? fkey(s) : 0u;
    }
    if (tid == 0) { sh_pref = 0u; sh_kneed = k; }
    __syncthreads();
    for (int lvl = 3; lvl >= 0; --lvl) {
        int sh = lvl * 8;
        if (tid < 256) hist[tid] = 0;
        unsigned pref = sh_pref; int kneed = sh_kneed;
        unsigned pmask = (lvl == 3) ? 0u : (0xFFFFFFFFu << (8 * (lvl + 1)));
        __syncthreads();
        for (int n = tid; n < NN; n += 1024) {
            unsigned kv = keys[n];
            if ((kv & pmask) == pref) atomicAdd(&hist[(kv >> sh) & 255], 1);
        }
        __syncthreads();
        if (tid < 256) scan[tid] = hist[tid];
        __syncthreads();
        for (int off = 1; off < 256; off <<= 1) {
            int v = 0;
            if (tid < 256 && tid + off < 256) v = scan[tid + off];
            __syncthreads();
            if (tid < 256) scan[tid] += v;
            __syncthreads();
        }
        if (tid < 256) {
            int c = scan[tid];
            int cex = c - hist[tid];
            if (c >= kneed && cex < kneed) {
                sh_pref = pref | ((unsigned)tid << sh);
                sh_kneed = kneed - cex;
            }
        }
        __syncthreads();
    }
    unsigned V = sh_pref;
    int seleq = sh_kneed;
    int c0 = tid * TCH, c1 = min(c0 + TCH, NN);
    int ceq = 0;
    for (int n = c0; n < c1; ++n) ceq += (keys[n] == V) ? 1 : 0;
    scan[tid] = ceq; __syncthreads();
    for (int off = 1; off < 1024; off <<= 1) {
        int u = (tid >= off) ? scan[tid - off] : 0;
        __syncthreads();
        scan[tid] += u;
        __syncthreads();
    }
    int rank = scan[tid] - ceq;
    unsigned selmask = 0u;
    int nsel = 0;
    float lmax = -INFINITY;
    for (int n = c0; n < c1; ++n) {
        unsigned kk = keys[n];
        bool sel = (kk > V) || (kk == V && rank < seleq);
        if (kk == V) rank++;
        long long gl = pbase + n;
        nalive[gl] = sel ? 1.0f : 0.0f;
        float f = 0.0f;
        if (sel) {
            f = tanhf(fkey_inv(kk));
            lmax = fmaxf(lmax, f * gdot[gl]);
            selmask |= (1u << (n - c0));
            ++nsel;
        }
        fvec[gl] = f;
    }
    redf[tid] = lmax; __syncthreads();
    for (int s = 512; s > 0; s >>= 1) { if (tid < s) redf[tid] = fmaxf(redf[tid], redf[tid + s]); __syncthreads(); }
    float mx = redf[0]; __syncthreads();
    scan[tid] = nsel; __syncthreads();
    for (int off = 1; off < 1024; off <<= 1) {
        int u = (tid >= off) ? scan[tid - off] : 0;
        __syncthreads();
        scan[tid] += u;
        __syncthreads();
    }
    int pos = scan[tid] - nsel;
    float lsum = 0.0f;
    for (int n = c0; n < c1; ++n) {
        if (selmask & (1u << (n - c0))) {
            long long gl = pbase + n;
            float e = expf(fvec[gl] * gdot[gl] - mx);
            gbuf[gl] = e;
            lsum += e;
            aliveIdx[(long long)p * k + pos] = (int)gl;
            ++pos;
        }
    }
    redf[tid] = lsum; __syncthreads();
    for (int s = 512; s > 0; s >>= 1) { if (tid < s) redf[tid] += redf[tid + s]; __syncthreads(); }
    if (tid == 0) invp[p] = 1.0f / redf[0];
}

// ---------------- head ----------------
__global__ __launch_bounds__(64) void k_head(
    const float* __restrict__ ro, const float* __restrict__ lin_w, const float* __restrict__ lin_b,
    const float* __restrict__ m1w, const float* __restrict__ m1b,
    const float* __restrict__ m2w, const float* __restrict__ m2b,
    const float* __restrict__ m3w, const float* __restrict__ m3b, float* __restrict__ out)
{
    __shared__ float v[33], h1[48], h2[16];
    int t = threadIdx.x;
    if (t < 33) {
        float s = lin_b[0];
        for (int k = 0; k < 384; ++k) s += ro[t * 384 + k] * lin_w[k];
        v[t] = tanhf(s);
    }
    __syncthreads();
    if (t < 48) {
        float s = m1b[t];
        for (int i = 0; i < 33; ++i) s += v[i] * m1w[i * 48 + t];
        h1[t] = tanhf(s);
    }
    __syncthreads();
    if (t < 16) {
        float s = m2b[t];
        for (int i = 0; i < 48; ++i) s += h1[i] * m2w[i * 16 + t];
        h2[t] = tanhf(s);
    }
    __syncthreads();
    if (t == 0) {
        float s = m3b[0];
        for (int i = 0; i < 16; ++i) s += h2[i] * m3w[i];
        float s1 = 1.0f / (1.0f + expf(-s));
        out[0] = 1.0f / (1.0f + expf(-s1));
    }
}

static inline int cdiv(long long a, long long b) { return (int)((a + b - 1) / b); }

extern "C" void kernel_launch(void* const* d_in, const int* in_sizes, int n_in,
                              void* d_out, int out_size, void* d_ws, size_t ws_size,
                              hipStream_t stream)
{
    (void)in_sizes; (void)n_in; (void)out_size;
    const float* h     = (const float*)d_in[0];
    const int*   eidx  = (const int*)d_in[1];
    const int*   seidx = (const int*)d_in[2];
    const float* Wl_a  = (const float*)d_in[3];
    const float* Wr_a  = (const float*)d_in[4];
    const float* bl_a  = (const float*)d_in[5];
    const float* Wl_s  = (const float*)d_in[6];
    const float* Wr_s  = (const float*)d_in[7];
    const float* bl_s  = (const float*)d_in[8];
    const float* gate_w = (const float*)d_in[9];
    const float* p_wrel = (const float*)d_in[11];
    const float* p_brel = (const float*)d_in[12];
    const float* p_wroot= (const float*)d_in[13];
    const float* nw    = (const float*)d_in[14];
    const float* nb    = (const float*)d_in[15];
    const float* nms   = (const float*)d_in[16];
    const float* lin_w = (const float*)d_in[17];
    const float* lin_b = (const float*)d_in[18];
    const float* m1w   = (const float*)d_in[19];
    const float* m1b   = (const float*)d_in[20];
    const float* m2w   = (const float*)d_in[21];
    const float* m2b   = (const float*)d_in[22];
    const float* m3w   = (const float*)d_in[23];
    const float* m3b   = (const float*)d_in[24];
    float* out = (float*)d_out;

    const int* esrc = eidx;
    const int* edst = eidx + EG;
    const int* ssrc = seidx;
    const int* sdst = seidx + ES_TOT;

    auto need_bytes = [](int chp) -> size_t {
        long long chn = (long long)chp * NN;
        long long f = chn * 128
                    + (long long)chp * KK1 * 64     // AGGb (bf16)
                    + 2LL * NN * 128
                    + 5 * chn
                    + 64 + 33 * 384
                    + (long long)chp * KK1
                    + (PN + 1) + ES_TOT
                    + 2 * 16384
                    + 64 * 24;
        return (size_t)f * 4;
    };
    int chp = 8;
    if (ws_size >= need_bytes(32)) chp = 32;
    else if (ws_size >= need_bytes(16)) chp = 16;
    int nch = PP / chp;
    long long ch_n = (long long)chp * NN;

    float* W = (float*)d_ws;
    size_t off = 0;
    auto alloc = [&](size_t nf) { float* p = W + off; off += (nf + 63) & ~(size_t)63; return p; };
    float* XA    = alloc((size_t)ch_n * DD);
    unsigned short* AGGb = (unsigned short*)alloc((size_t)chp * KK1 * 64);
    float* ZL0   = alloc((size_t)NN * DD);
    float* zself = alloc((size_t)NN * DD);
    float* tbuf  = alloc(ch_n);                 // aliased as gbuf
    float* rootd = alloc(ch_n);
    float* nal   = alloc(ch_n);
    float* fvec  = alloc(ch_n);
    float* gdot  = alloc(ch_n);
    float* invp  = alloc(64);
    float* ro    = alloc(33 * 384);
    int* aliveIdx = (int*)alloc((size_t)chp * KK1);
    int* s2rp    = (int*)alloc(PN + 1);
    int* s2col   = (int*)alloc(ES_TOT);
    short* Wb1   = (short*)alloc(16384);
    short* Wb2   = (short*)alloc(16384);
    float* gbuf = tbuf;

    // overlay: stage-1-only + CSR build temps live inside XA (dead before XA's first write)
    size_t ooff = 0;
    auto oalloc = [&](size_t nf) { float* p = XA + ooff; ooff += (nf + 63) & ~(size_t)63; return p; };
    float* xa    = oalloc((size_t)NN * DD);
    float* xb    = oalloc((size_t)NN * DD);
    float* AGGs  = oalloc((size_t)NN * DD);     // stage-1 fp32 agg
    float* agg1  = oalloc((size_t)NN * 16);
    float* deg1  = oalloc(NN);
    float* musum = oalloc(128);
    float* sqsum = oalloc(128);
    int* s1cnt  = (int*)oalloc(NN);
    int* s1rp   = (int*)oalloc(NN + 1);
    int* s1cur  = (int*)oalloc(NN);
    int* s1col  = (int*)oalloc(EG);
    int* s1part = (int*)oalloc(NN);
    int* s1bsum = (int*)oalloc(1024);
    int* s2cnt  = (int*)oalloc(PN);
    int* s2cur  = (int*)oalloc(PN);
    int* s2part = (int*)oalloc(PN);
    int* s2bsum = (int*)oalloc(1024);

    // ---------- CSR builds ----------
    int nb1 = cdiv(NN, 1024), nb2 = cdiv(PN, 1024);
    hipMemsetAsync(s1cnt, 0, NN * sizeof(int), stream);
    k_hist<<<cdiv(EG,256),256,0,stream>>>(edst, s1cnt, EG);
    k_scanA<<<nb1,1024,0,stream>>>(s1cnt, s1part, s1bsum, NN);
    k_scanB<<<1,1024,0,stream>>>(s1bsum, nb1);
    k_scanC<<<cdiv(NN,256),256,0,stream>>>(s1part, s1bsum, s1rp, s1cur, NN, EG);
    k_scatter<<<cdiv(EG,256),256,0,stream>>>(esrc, edst, s1cur, s1col, EG);

    hipMemsetAsync(s2cnt, 0, (size_t)PN * sizeof(int), stream);
    k_hist<<<cdiv(ES_TOT,256),256,0,stream>>>(sdst, s2cnt, ES_TOT);
    k_scanA<<<nb2,1024,0,stream>>>(s2cnt, s2part, s2bsum, PN);
    k_scanB<<<1,1024,0,stream>>>(s2bsum, nb2);
    k_scanC<<<cdiv(PN,256),256,0,stream>>>(s2part, s2bsum, s2rp, s2cur, PN, ES_TOT);
    k_scatter<<<cdiv(ES_TOT,256),256,0,stream>>>(ssrc, sdst, s2cur, s2col, ES_TOT);

    hipMemsetAsync(ro, 0, 33 * 384 * sizeof(float), stream);

    // bf16 weight packs for stage-2 L1/L2 MFMA
    k_packW<<<128,256,0,stream>>>(Wl_s + 3*16384, Wr_s + 3*16384, Wb1);
    k_packW<<<128,256,0,stream>>>(Wl_s + 4*16384, Wr_s + 4*16384, Wb2);

    // ---------- stage 1 ----------
    k_agg16<<<cdiv((long long)NN*16,256),256,0,stream>>>(h, s1rp, s1col, agg1, deg1, NN);
    k_sage16<<<cdiv((long long)NN*DD,256),256,0,stream>>>(h, agg1, deg1, Wl_a, Wr_a, bl_a, xa, NN);
    k_gate<<<cdiv(NN,256),256,0,stream>>>(xa, gate_w + 0*DD, gbuf, NN);
    k_smstats<<<1,1024,0,stream>>>(gbuf, invp);
    k_wsum<<<BPG,128,0,stream>>>(xa, gbuf, invp, ro, 0, 0);

    hipMemsetAsync(musum, 0, 128*sizeof(float), stream);
    hipMemsetAsync(sqsum, 0, 128*sizeof(float), stream);
    k_colstat<<<cdiv(NN,64),128,0,stream>>>(xa, musum, sqsum, NN);
    k_gnorm_apply<<<cdiv((long long)NN*DD,256),256,0,stream>>>(xa, xb, musum, sqsum, nw, nb, nms, NN);

    k_aggf0<<<cdiv(NN,8),256,0,stream>>>(xb, s1rp, s1col, AGGs, NN);
    k_sage_d<<<cdiv(NN,64),256,0,stream>>>(AGGs, xb,
        Wl_s + 0*16384, Wr_s + 0*16384, bl_s + 0*128, xa, NN,
        gate_w + 1*DD, gbuf);
    k_smstats<<<1,1024,0,stream>>>(gbuf, invp);
    k_wsum<<<BPG,128,0,stream>>>(xa, gbuf, invp, ro, 0, 128);

    hipMemsetAsync(musum, 0, 128*sizeof(float), stream);
    hipMemsetAsync(sqsum, 0, 128*sizeof(float), stream);
    k_colstat<<<cdiv(NN,64),128,0,stream>>>(xa, musum, sqsum, NN);
    k_gnorm_apply<<<cdiv((long long)NN*DD,256),256,0,stream>>>(xa, xb, musum, sqsum, nw, nb, nms, NN);

    k_aggf0<<<cdiv(NN,8),256,0,stream>>>(xb, s1rp, s1col, AGGs, NN);
    k_sage_d<<<cdiv(NN,64),256,0,stream>>>(AGGs, xb,
        Wl_s + 1*16384, Wr_s + 1*16384, bl_s + 1*128, xa, NN,
        gate_w + 2*DD, gbuf);
    k_smstats<<<1,1024,0,stream>>>(gbuf, invp);
    k_wsum<<<BPG,128,0,stream>>>(xa, gbuf, invp, ro, 0, 256);

    // ---------- stage 2 ----------
    k_gemm_self<<<cdiv(NN,64),256,0,stream>>>(xa, Wl_s + 2*16384, nullptr, ZL0, NN);
    k_gemm_self<<<cdiv(NN,64),256,0,stream>>>(xa, Wr_s + 2*16384, bl_s + 2*128, zself, NN);

    for (int c = 0; c < nch; ++c) {
        int nbase = (int)(c * ch_n);

        // ---- layer 0: gather-mean of ZL0 + zself (no GEMM; all rows alive) ----
        k_l0comb<<<(int)(ch_n/8),256,0,stream>>>(ZL0, zself, s2rp, s2col, nbase,
            p_wrel + 0*DD, p_wroot + 0*DD, gate_w + 3*DD,
            XA, tbuf, rootd, gdot, (int)ch_n);
        k_topk2<<<chp,1024,0,stream>>>(s2rp, s2col, nbase, tbuf, rootd, gdot, p_brel, 0, 1,
                                       nal, fvec, gbuf, invp, aliveIdx, KK1);
        k_wsum_c<<<chp*(KK1/RB),128,0,stream>>>(XA, gbuf, fvec, invp, aliveIdx, KK1, ro, 1 + c*chp, 0);

        // ---- layer 1: alive K1 rows, bf16 AGG + MFMA (in-place on XA) ----
        k_aggf2<<<chp*(KK1/8),256,0,stream>>>(XA, s2rp, s2col, aliveIdx, nal, fvec, nbase, AGGb, chp*KK1);
        k_sage_m<<<chp*KK1/128,256,0,stream>>>(AGGb, XA, aliveIdx, fvec, Wb1, bl_s + 3*128, XA, chp*KK1,
            p_wrel + 1*DD, p_wroot + 1*DD, gate_w + 4*DD, tbuf, rootd, gdot);
        k_topk2<<<chp,1024,0,stream>>>(s2rp, s2col, nbase, tbuf, rootd, gdot, p_brel, 1, 0,
                                       nal, fvec, gbuf, invp, aliveIdx, KK2);
        k_wsum_c<<<chp*(KK2/RB),128,0,stream>>>(XA, gbuf, fvec, invp, aliveIdx, KK2, ro, 1 + c*chp, 128);

        // ---- layer 2: alive K2 rows, bf16 AGG + MFMA (in-place on XA) ----
        k_aggf2<<<chp*(KK2/8),256,0,stream>>>(XA, s2rp, s2col, aliveIdx, nal, fvec, nbase, AGGb, chp*KK2);
        k_sage_m<<<chp*KK2/128,256,0,stream>>>(AGGb, XA, aliveIdx, fvec, Wb2, bl_s + 4*128, XA, chp*KK2,
            p_wrel + 2*DD, p_wroot + 2*DD, gate_w + 5*DD, tbuf, rootd, gdot);
        k_topk2<<<chp,1024,0,stream>>>(s2rp, s2col, nbase, tbuf, rootd, gdot, p_brel, 2, 0,
                                       nal, fvec, gbuf, invp, aliveIdx, KK3);
        k_wsum_c<<<chp*(KK3/RB),128,0,stream>>>(XA, gbuf, fvec, invp, aliveIdx, KK3, ro, 1 + c*chp, 256);
    }

    // ---------- head ----------
    k_head<<<1,64,0,stream>>>(ro, lin_w, lin_b, m1w, m1b, m2w, m2b, m3w, m3b, out);
}